// Round 1
// baseline (1762.576 us; speedup 1.0000x reference)
//
#include <hip/hip_runtime.h>

// ---------------- problem constants ----------------
constexpr int NN_ = 4096;     // nodes
constexpr int INF = 28;       // input features
constexpr int NH  = 8;        // GAT heads
constexpr int CC  = 256;      // channels per head
constexpr int HC  = 2048;     // NH*CC
constexpr int HID = 256;
constexpr int NE  = 131072;   // edges per branch
constexpr int KK  = NH * INF; // 224

// ---------------- small precompute kernels ----------------

// Wa[b][kind][k][h] = sum_c W_b[k, h*CC+c] * a_{src/dst}_b[h,c]
// dote[b][h]        = sum_c We_b[h*CC+c]   * a_edge_b[h,c]
__global__ void k_small_pre(const float* __restrict__ Wt, const float* __restrict__ ast,
                            const float* __restrict__ adt, const float* __restrict__ Wet,
                            const float* __restrict__ aet,
                            const float* __restrict__ Wc, const float* __restrict__ asc,
                            const float* __restrict__ adc, const float* __restrict__ Wec,
                            const float* __restrict__ aec,
                            float* __restrict__ wa, float* __restrict__ dote)
{
    int i = blockIdx.x * blockDim.x + threadIdx.x;
    if (i < 2 * 2 * INF * NH) {
        int b = i / (2 * INF * NH);
        int r = i % (2 * INF * NH);
        int kind = r / (INF * NH);
        int r2 = r % (INF * NH);
        int k = r2 / NH, h = r2 % NH;
        const float* W = b ? Wc : Wt;
        const float* a = b ? (kind ? adc : asc) : (kind ? adt : ast);
        float s = 0.f;
        for (int c = 0; c < CC; ++c) s += W[k * HC + h * CC + c] * a[h * CC + c];
        wa[((b * 2 + kind) * INF + k) * NH + h] = s;
    } else if (i < 2 * 2 * INF * NH + 16) {
        int j = i - 2 * 2 * INF * NH;
        int b = j / NH, h = j % NH;
        const float* We = b ? Wec : Wet;
        const float* a  = b ? aec : aet;
        float s = 0.f;
        for (int c = 0; c < CC; ++c) s += We[h * CC + c] * a[h * CC + c];
        dote[b * NH + h] = s;
    }
}

// mean-sum of edge attrs per branch (self-loop fill value = sum/NE)
__global__ void k_mean(const float* __restrict__ ea_t, const float* __restrict__ ea_c,
                       float* __restrict__ meansum)
{
    int i = blockIdx.x * blockDim.x + threadIdx.x;   // grid exactly 2*NE
    int b = i / NE;
    float v = (b ? ea_c : ea_t)[i - b * NE];
    for (int off = 32; off; off >>= 1) v += __shfl_down(v, off);
    if ((threadIdx.x & 63) == 0) atomicAdd(&meansum[b], v);
}

// a_s / a_d for both branches: asd[bk][n][h] = sum_k x[n,k]*Wa[bk][k][h]
__global__ void k_as_ad(const float* __restrict__ x, const float* __restrict__ wa,
                        float* __restrict__ asd)
{
    int i = blockIdx.x * blockDim.x + threadIdx.x;
    if (i >= 4 * NN_ * NH) return;
    int bk = i / (NN_ * NH);
    int r = i % (NN_ * NH);
    int n = r / NH, h = r % NH;
    const float* W = wa + bk * INF * NH;
    const float* xr = x + n * INF;
    float s = 0.f;
#pragma unroll
    for (int k = 0; k < INF; ++k) s += xr[k] * W[k * NH + h];
    asd[(bk * NN_ + n) * NH + h] = s;
}

// bias_g[j] = bih[j] + bhh[j] + sum_hc b_t[hc]*Wih[j,hc]
__global__ void k_biasg(const float* __restrict__ bt, const float* __restrict__ Wih,
                        const float* __restrict__ bih, const float* __restrict__ bhh,
                        float* __restrict__ bg)
{
    int j = blockIdx.x * blockDim.x + threadIdx.x;
    if (j >= 1024) return;
    float s = bih[j] + bhh[j];
    const float* w = Wih + (size_t)j * HC;
    for (int c = 0; c < HC; ++c) s += bt[c] * w[c];
    bg[j] = s;
}

// M[kk,j] = sum_c W_t[k, h*CC+c] * Wih[j, h*CC+c]   (kk = h*INF + k)
__global__ void k_M(const float* __restrict__ Wt, const float* __restrict__ Wih,
                    float* __restrict__ M)
{
    int i = blockIdx.x * blockDim.x + threadIdx.x;
    if (i >= KK * 1024) return;
    int kk = i >> 10, j = i & 1023;
    int h = kk / INF, k = kk % INF;
    const float* wa = Wt + k * HC + h * CC;
    const float* wb = Wih + (size_t)j * HC + h * CC;
    float s = 0.f;
    for (int c = 0; c < CC; ++c) s += wa[c] * wb[c];
    M[kk * 1024 + j] = s;
}

// Bc[kk,c] = W_c[k, h*CC+c] / 8    (head-mean folded in)
__global__ void k_Bc(const float* __restrict__ Wc, float* __restrict__ Bc)
{
    int i = blockIdx.x * blockDim.x + threadIdx.x;
    if (i >= KK * CC) return;
    int kk = i / CC, c = i % CC;
    int h = kk / INF, k = kk % INF;
    Bc[i] = Wc[k * HC + h * CC + c] * 0.125f;
}

// ---------------- CSR build (group edges by dst) ----------------
__global__ void k_hist(const int* __restrict__ ei_t, const int* __restrict__ ei_c,
                       int* __restrict__ cnt)
{
    int i = blockIdx.x * blockDim.x + threadIdx.x;
    if (i >= 2 * NE) return;
    int b = i / NE, e = i - b * NE;
    const int* ei = b ? ei_c : ei_t;
    atomicAdd(&cnt[b * NN_ + ei[NE + e]], 1);
}

__global__ __launch_bounds__(1024) void k_scan(const int* __restrict__ cnt, int* __restrict__ rows)
{
    int b = blockIdx.x;
    const int* c = cnt + b * NN_;
    int* r = rows + b * (NN_ + 16);
    __shared__ int ts[1024];
    int t = threadIdx.x;
    int v0 = c[t * 4], v1 = c[t * 4 + 1], v2 = c[t * 4 + 2], v3 = c[t * 4 + 3];
    ts[t] = v0 + v1 + v2 + v3;
    __syncthreads();
    for (int off = 1; off < 1024; off <<= 1) {
        int add = (t >= off) ? ts[t - off] : 0;
        __syncthreads();
        ts[t] += add;
        __syncthreads();
    }
    int excl = (t == 0) ? 0 : ts[t - 1];
    r[t * 4 + 0] = excl; excl += v0;
    r[t * 4 + 1] = excl; excl += v1;
    r[t * 4 + 2] = excl; excl += v2;
    r[t * 4 + 3] = excl; excl += v3;
    if (t == 1023) r[NN_] = excl;
}

__global__ void k_scatter(const int* __restrict__ ei_t, const int* __restrict__ ei_c,
                          const float* __restrict__ ea_t, const float* __restrict__ ea_c,
                          const int* __restrict__ rows, int* __restrict__ cur,
                          int* __restrict__ srcs, float* __restrict__ eav)
{
    int i = blockIdx.x * blockDim.x + threadIdx.x;
    if (i >= 2 * NE) return;
    int b = i / NE, e = i - b * NE;
    const int* ei = b ? ei_c : ei_t;
    const float* ea = b ? ea_c : ea_t;
    int d = ei[NE + e];
    int pos = rows[b * (NN_ + 16) + d] + atomicAdd(&cur[b * NN_ + d], 1);
    srcs[b * NE + pos] = ei[e];
    eav[b * NE + pos] = ea[e];
}

// ---------------- GAT per-dst aggregation ----------------
// One wave per node. Softmax without max-subtraction (logits bounded ~|2|).
// Accumulates g[n,h,k] = sum_e w[e,h]*x[src,k]; k=31 column of ones gives den.
__global__ __launch_bounds__(64) void k_gat(
    const int* __restrict__ srcs, const float* __restrict__ eav,
    const int* __restrict__ rows, const float* __restrict__ x,
    const float* __restrict__ a_s, const float* __restrict__ a_d,
    const float* __restrict__ dote, const float* __restrict__ meansum,
    float* __restrict__ g)
{
    int n = blockIdx.x;
    int lane = threadIdx.x;
    __shared__ float xb[64][32];
    __shared__ float eb[64][8];
    __shared__ float denb[8];

    float adn[NH], dt[NH];
#pragma unroll
    for (int h = 0; h < NH; ++h) { adn[h] = a_d[n * NH + h]; dt[h] = dote[h]; }
    float mean_attr = meansum[0] * (1.0f / NE);

    const int hOwn = lane >> 3;
    const int kOwn = (lane & 7) * 4;

    float acc0, acc1, acc2, acc3;
    {   // implicit self-loop edge: src=dst=n, eattr=mean_attr
        float al = a_s[n * NH + hOwn] + adn[hOwn] + mean_attr * dt[hOwn];
        al = al > 0.f ? al : 0.2f * al;
        float es = __expf(al);
        float xv0 = (kOwn + 0 < INF) ? x[n * INF + kOwn + 0] : 0.f;
        float xv1 = (kOwn + 1 < INF) ? x[n * INF + kOwn + 1] : 0.f;
        float xv2 = (kOwn + 2 < INF) ? x[n * INF + kOwn + 2] : 0.f;
        float xv3 = (kOwn + 3 < INF) ? x[n * INF + kOwn + 3] : ((kOwn + 3 == 31) ? 1.f : 0.f);
        acc0 = es * xv0; acc1 = es * xv1; acc2 = es * xv2; acc3 = es * xv3;
    }

    int e0 = rows[n], e1 = rows[n + 1];
    for (int base = e0; base < e1; base += 64) {
        int m = e1 - base; if (m > 64) m = 64;
        if (lane < m) {
            int sidx = srcs[base + lane];
            float ea = eav[base + lane];
            const float4* xr = (const float4*)(x + sidx * INF);   // 112B rows, 16B aligned
#pragma unroll
            for (int q = 0; q < 7; ++q) ((float4*)&xb[lane][0])[q] = xr[q];
            xb[lane][28] = 0.f; xb[lane][29] = 0.f; xb[lane][30] = 0.f; xb[lane][31] = 1.f;
            const float* asr = a_s + sidx * NH;
#pragma unroll
            for (int h = 0; h < NH; ++h) {
                float al = asr[h] + adn[h] + ea * dt[h];
                al = al > 0.f ? al : 0.2f * al;
                eb[lane][h] = __expf(al);
            }
        }
        __syncthreads();
        for (int j = 0; j < m; ++j) {
            float e = eb[j][hOwn];
            float4 xv = *(const float4*)&xb[j][kOwn];
            acc0 += e * xv.x; acc1 += e * xv.y; acc2 += e * xv.z; acc3 += e * xv.w;
        }
        __syncthreads();
    }

    if ((lane & 7) == 7) denb[hOwn] = acc3;   // slot k==31 is the denominator
    __syncthreads();
    float inv = 1.0f / denb[hOwn];
    float* gr = g + n * KK + hOwn * INF + kOwn;
    if (kOwn + 0 < INF) gr[0] = acc0 * inv;
    if (kOwn + 1 < INF) gr[1] = acc1 * inv;
    if (kOwn + 2 < INF) gr[2] = acc2 * inv;
    if (kOwn + 3 < INF) gr[3] = acc3 * inv;
}

// ---------------- generic fp32 GEMM ----------------
// C[m,n] = sum_k A[m,k] * (BT ? B[n,k] : B[k,n]) + bias[n]; optional ReLU; optional C2 copy.
template<bool BT, bool RELU>
__global__ __launch_bounds__(256) void k_gemm(
    const float* __restrict__ A, int lda,
    const float* __restrict__ B, int ldb,
    const float* __restrict__ bias,
    float* __restrict__ C, int ldc,
    float* __restrict__ C2, int ldc2,
    int M, int N, int K)
{
    __shared__ float As[16][72];
    __shared__ float Bs[16][72];
    int t = threadIdx.x;
    int tx = t & 15, ty = t >> 4;
    int m0 = blockIdx.x * 64, n0 = blockIdx.y * 64;
    float acc[4][4];
#pragma unroll
    for (int i = 0; i < 4; ++i)
#pragma unroll
        for (int j = 0; j < 4; ++j) acc[i][j] = 0.f;

    for (int k0 = 0; k0 < K; k0 += 16) {
        {
            int row = t >> 2, q = t & 3;
            float4 av = make_float4(0.f, 0.f, 0.f, 0.f);
            if (m0 + row < M) av = *(const float4*)(A + (size_t)(m0 + row) * lda + k0 + q * 4);
            As[q * 4 + 0][row] = av.x; As[q * 4 + 1][row] = av.y;
            As[q * 4 + 2][row] = av.z; As[q * 4 + 3][row] = av.w;
            if (BT) {
                float4 bv = make_float4(0.f, 0.f, 0.f, 0.f);
                if (n0 + row < N) bv = *(const float4*)(B + (size_t)(n0 + row) * ldb + k0 + q * 4);
                Bs[q * 4 + 0][row] = bv.x; Bs[q * 4 + 1][row] = bv.y;
                Bs[q * 4 + 2][row] = bv.z; Bs[q * 4 + 3][row] = bv.w;
            } else {
                int kk = t >> 4, nq = t & 15;
                float4 bv = *(const float4*)(B + (size_t)(k0 + kk) * ldb + n0 + nq * 4);
                *(float4*)&Bs[kk][nq * 4] = bv;
            }
        }
        __syncthreads();
#pragma unroll
        for (int kk = 0; kk < 16; ++kk) {
            float4 a = *(const float4*)&As[kk][ty * 4];
            float4 b = *(const float4*)&Bs[kk][tx * 4];
            acc[0][0] += a.x * b.x; acc[0][1] += a.x * b.y; acc[0][2] += a.x * b.z; acc[0][3] += a.x * b.w;
            acc[1][0] += a.y * b.x; acc[1][1] += a.y * b.y; acc[1][2] += a.y * b.z; acc[1][3] += a.y * b.w;
            acc[2][0] += a.z * b.x; acc[2][1] += a.z * b.y; acc[2][2] += a.z * b.z; acc[2][3] += a.z * b.w;
            acc[3][0] += a.w * b.x; acc[3][1] += a.w * b.y; acc[3][2] += a.w * b.z; acc[3][3] += a.w * b.w;
        }
        __syncthreads();
    }
#pragma unroll
    for (int i = 0; i < 4; ++i) {
        int m = m0 + ty * 4 + i;
        if (m >= M) continue;
#pragma unroll
        for (int j = 0; j < 4; ++j) {
            int n = n0 + tx * 4 + j;
            if (n >= N) continue;
            float v = acc[i][j];
            if (bias) v += bias[n];
            if (RELU) v = v > 0.f ? v : 0.f;
            C[(size_t)m * ldc + n] = v;
            if (C2) C2[(size_t)m * ldc2 + n] = v;
        }
    }
}

// ---------------- LSTM elementwise ----------------
__global__ void k_lstm(const float* __restrict__ gates, float* __restrict__ hout,
                       float* __restrict__ concat)
{
    int i = blockIdx.x * blockDim.x + threadIdx.x;
    if (i >= NN_ * HID) return;
    int n = i >> 8, j = i & 255;
    const float* gr = gates + (size_t)n * 1024;
    float gi = gr[j], gg = gr[512 + j], go = gr[768 + j];
    float c = (1.f / (1.f + __expf(-gi))) * tanhf(gg);
    float h = (1.f / (1.f + __expf(-go))) * tanhf(c);
    hout[i] = h;
    concat[n * 512 + j] = h;
}

// ---------------- MHA (fp32, online, no max-subtraction; logits ~ +/-0.05) ----------------
// grid (64 q-tiles, 4 heads), 256 threads. Thread owns 4 q-rows x 4 dims.
__global__ __launch_bounds__(256) void k_attn(const float* __restrict__ qkv,
                                              float* __restrict__ out)
{
    __shared__ float Kt[64][64];
    __shared__ float Vt[64][64];
    int h = blockIdx.y;
    int t = threadIdx.x;
    int rg = t >> 4;            // row group: rows rg*4 .. rg*4+3
    int d0 = (t & 15) * 4;      // dim chunk
    int q0 = blockIdx.x * 64;

    float q[4][4], o[4][4], den[4];
#pragma unroll
    for (int i = 0; i < 4; ++i) {
        const float* qp = qkv + (size_t)(q0 + rg * 4 + i) * 768 + h * 64 + d0;
        float4 v = *(const float4*)qp;
        q[i][0] = v.x * 0.125f; q[i][1] = v.y * 0.125f;
        q[i][2] = v.z * 0.125f; q[i][3] = v.w * 0.125f;
        o[i][0] = o[i][1] = o[i][2] = o[i][3] = 0.f;
        den[i] = 0.f;
    }

    for (int kt = 0; kt < NN_; kt += 64) {
        for (int i = t; i < 1024; i += 256) {
            int j = i >> 4, f = (i & 15) * 4;
            *(float4*)&Kt[j][f] = *(const float4*)(qkv + (size_t)(kt + j) * 768 + 256 + h * 64 + f);
            *(float4*)&Vt[j][f] = *(const float4*)(qkv + (size_t)(kt + j) * 768 + 512 + h * 64 + f);
        }
        __syncthreads();
        for (int j = 0; j < 64; ++j) {
            float4 kv = *(const float4*)&Kt[j][d0];
            float s0 = q[0][0] * kv.x + q[0][1] * kv.y + q[0][2] * kv.z + q[0][3] * kv.w;
            float s1 = q[1][0] * kv.x + q[1][1] * kv.y + q[1][2] * kv.z + q[1][3] * kv.w;
            float s2 = q[2][0] * kv.x + q[2][1] * kv.y + q[2][2] * kv.z + q[2][3] * kv.w;
            float s3 = q[3][0] * kv.x + q[3][1] * kv.y + q[3][2] * kv.z + q[3][3] * kv.w;
            s0 += __shfl_xor(s0, 1); s0 += __shfl_xor(s0, 2); s0 += __shfl_xor(s0, 4); s0 += __shfl_xor(s0, 8);
            s1 += __shfl_xor(s1, 1); s1 += __shfl_xor(s1, 2); s1 += __shfl_xor(s1, 4); s1 += __shfl_xor(s1, 8);
            s2 += __shfl_xor(s2, 1); s2 += __shfl_xor(s2, 2); s2 += __shfl_xor(s2, 4); s2 += __shfl_xor(s2, 8);
            s3 += __shfl_xor(s3, 1); s3 += __shfl_xor(s3, 2); s3 += __shfl_xor(s3, 4); s3 += __shfl_xor(s3, 8);
            float4 vv = *(const float4*)&Vt[j][d0];
            float e0 = __expf(s0), e1 = __expf(s1), e2 = __expf(s2), e3 = __expf(s3);
            den[0] += e0; den[1] += e1; den[2] += e2; den[3] += e3;
            o[0][0] += e0 * vv.x; o[0][1] += e0 * vv.y; o[0][2] += e0 * vv.z; o[0][3] += e0 * vv.w;
            o[1][0] += e1 * vv.x; o[1][1] += e1 * vv.y; o[1][2] += e1 * vv.z; o[1][3] += e1 * vv.w;
            o[2][0] += e2 * vv.x; o[2][1] += e2 * vv.y; o[2][2] += e2 * vv.z; o[2][3] += e2 * vv.w;
            o[3][0] += e3 * vv.x; o[3][1] += e3 * vv.y; o[3][2] += e3 * vv.z; o[3][3] += e3 * vv.w;
        }
        __syncthreads();
    }
#pragma unroll
    for (int i = 0; i < 4; ++i) {
        float inv = 1.f / den[i];
        float* op = out + (size_t)(q0 + rg * 4 + i) * 256 + h * 64 + d0;
        *(float4*)op = make_float4(o[i][0] * inv, o[i][1] * inv, o[i][2] * inv, o[i][3] * inv);
    }
}

// ---------------- launch ----------------
extern "C" void kernel_launch(void* const* d_in, const int* in_sizes, int n_in,
                              void* d_out, int out_size, void* d_ws, size_t ws_size,
                              hipStream_t stream)
{
    const float* x      = (const float*)d_in[0];
    const int*   ei_t   = (const int*)d_in[1];
    const int*   ei_c   = (const int*)d_in[2];
    const float* ea_t   = (const float*)d_in[3];
    const float* ea_c   = (const float*)d_in[4];
    const float* W_t    = (const float*)d_in[5];
    const float* asrc_t = (const float*)d_in[6];
    const float* adst_t = (const float*)d_in[7];
    const float* We_t   = (const float*)d_in[8];
    const float* aedg_t = (const float*)d_in[9];
    const float* b_t    = (const float*)d_in[10];
    const float* W_c    = (const float*)d_in[11];
    const float* asrc_c = (const float*)d_in[12];
    const float* adst_c = (const float*)d_in[13];
    const float* We_c   = (const float*)d_in[14];
    const float* aedg_c = (const float*)d_in[15];
    const float* b_c    = (const float*)d_in[16];
    const float* Wih    = (const float*)d_in[17];
    const float* bih    = (const float*)d_in[19];
    const float* bhh    = (const float*)d_in[20];
    const float* min_w  = (const float*)d_in[21];
    const float* min_b  = (const float*)d_in[22];
    const float* mout_w = (const float*)d_in[23];
    const float* mout_b = (const float*)d_in[24];
    const float* fus_w  = (const float*)d_in[25];
    const float* fus_b  = (const float*)d_in[26];
    const float* out_w  = (const float*)d_in[27];
    const float* out_b  = (const float*)d_in[28];
    float* outp = (float*)d_out;

    // workspace layout (bytes, 256-aligned)
    char* W = (char*)d_ws;
    size_t off = 0;
    auto alloc = [&](size_t bytes) { size_t r = off; off += (bytes + 255) & ~(size_t)255; return r; };
    size_t oMean  = alloc(2 * 4);
    size_t oCnt   = alloc(2 * NN_ * 4);
    size_t oCur   = alloc(2 * NN_ * 4);
    size_t zeroBytes = off;                      // memset [0, zeroBytes)
    size_t oRows  = alloc(2 * (NN_ + 16) * 4);
    size_t oSrcs  = alloc(2 * NE * 4);
    size_t oEav   = alloc(2 * NE * 4);
    size_t oWa    = alloc(4 * INF * NH * 4);
    size_t oDote  = alloc(2 * NH * 4);
    size_t oAsd   = alloc(4 * NN_ * NH * 4);
    size_t oBg    = alloc(1024 * 4);
    size_t oM     = alloc((size_t)KK * 1024 * 4);
    size_t oBc    = alloc((size_t)KK * CC * 4);
    size_t oG     = alloc((size_t)2 * NN_ * KK * 4);
    size_t oGates = alloc((size_t)NN_ * 1024 * 4);   // aliased later by qkv
    size_t oHc    = alloc((size_t)NN_ * HID * 4);
    size_t oConcat= alloc((size_t)NN_ * 512 * 4);
    size_t oHfus  = alloc((size_t)NN_ * HID * 4);
    size_t oQkv   = oGates;   // lifetime disjoint (gates dead after k_lstm)
    size_t oAttno = oG;       // lifetime disjoint (g dead after its two GEMMs)
    (void)ws_size; (void)in_sizes; (void)n_in; (void)out_size;

    hipMemsetAsync(W, 0, zeroBytes, stream);

    k_small_pre<<<4, 256, 0, stream>>>(W_t, asrc_t, adst_t, We_t, aedg_t,
                                       W_c, asrc_c, adst_c, We_c, aedg_c,
                                       (float*)(W + oWa), (float*)(W + oDote));
    k_mean<<<2 * NE / 256, 256, 0, stream>>>(ea_t, ea_c, (float*)(W + oMean));
    k_hist<<<2 * NE / 256, 256, 0, stream>>>(ei_t, ei_c, (int*)(W + oCnt));
    k_scan<<<2, 1024, 0, stream>>>((int*)(W + oCnt), (int*)(W + oRows));
    k_scatter<<<2 * NE / 256, 256, 0, stream>>>(ei_t, ei_c, ea_t, ea_c,
                                                (int*)(W + oRows), (int*)(W + oCur),
                                                (int*)(W + oSrcs), (float*)(W + oEav));
    k_as_ad<<<512, 256, 0, stream>>>(x, (float*)(W + oWa), (float*)(W + oAsd));
    k_biasg<<<4, 256, 0, stream>>>(b_t, Wih, bih, bhh, (float*)(W + oBg));
    k_M<<<KK * 1024 / 256, 256, 0, stream>>>(W_t, Wih, (float*)(W + oM));
    k_Bc<<<KK * CC / 256, 256, 0, stream>>>(W_c, (float*)(W + oBc));

    // GAT aggregation -> g[branch][n][224]
    k_gat<<<NN_, 64, 0, stream>>>((int*)(W + oSrcs), (float*)(W + oEav), (int*)(W + oRows), x,
                                  (float*)(W + oAsd),                (float*)(W + oAsd) + NN_ * NH,
                                  (float*)(W + oDote),               (float*)(W + oMean),
                                  (float*)(W + oG));
    k_gat<<<NN_, 64, 0, stream>>>((int*)(W + oSrcs) + NE, (float*)(W + oEav) + NE,
                                  (int*)(W + oRows) + (NN_ + 16), x,
                                  (float*)(W + oAsd) + 2 * NN_ * NH, (float*)(W + oAsd) + 3 * NN_ * NH,
                                  (float*)(W + oDote) + NH,          (float*)(W + oMean) + 1,
                                  (float*)(W + oG) + (size_t)NN_ * KK);

    // temporal: gates = g_t @ M + bias_g ; then LSTM elementwise
    {
        dim3 grid(64, 16);
        k_gemm<false, false><<<grid, 256, 0, stream>>>(
            (float*)(W + oG), KK, (float*)(W + oM), 1024, (float*)(W + oBg),
            (float*)(W + oGates), 1024, nullptr, 0, NN_, 1024, KK);
    }
    k_lstm<<<NN_ * HID / 256, 256, 0, stream>>>((float*)(W + oGates),
                                                outp + 524288, (float*)(W + oConcat));

    // causal: h_c = g_c @ Bc + b_c
    {
        dim3 grid(64, 4);
        k_gemm<false, false><<<grid, 256, 0, stream>>>(
            (float*)(W + oG) + (size_t)NN_ * KK, KK, (float*)(W + oBc), CC, b_c,
            (float*)(W + oHc), HID, nullptr, 0, NN_, HID, KK);
    }
    // qkv = h_c @ min_w^T + min_b
    {
        dim3 grid(64, 12);
        k_gemm<true, false><<<grid, 256, 0, stream>>>(
            (float*)(W + oHc), HID, min_w, HID, min_b,
            (float*)(W + oQkv), 768, nullptr, 0, NN_, 768, HID);
    }
    // attention
    {
        dim3 grid(64, 4);
        k_attn<<<grid, 256, 0, stream>>>((float*)(W + oQkv), (float*)(W + oAttno));
    }
    // out-proj -> concat[:,256:512] and d_out h_causal
    {
        dim3 grid(64, 4);
        k_gemm<true, false><<<grid, 256, 0, stream>>>(
            (float*)(W + oAttno), HID, mout_w, HID, mout_b,
            (float*)(W + oConcat) + 256, 512, outp + 524288 + 1048576, 256, NN_, HID, HID);
    }
    // fusion: relu(concat @ fus_w^T + fus_b)
    {
        dim3 grid(64, 4);
        k_gemm<true, true><<<grid, 256, 0, stream>>>(
            (float*)(W + oConcat), 512, fus_w, 512, fus_b,
            (float*)(W + oHfus), HID, nullptr, 0, NN_, HID, 512);
    }
    // out = hfus @ out_w^T + out_b
    {
        dim3 grid(64, 2);
        k_gemm<true, false><<<grid, 256, 0, stream>>>(
            (float*)(W + oHfus), HID, out_w, HID, out_b,
            outp, 128, nullptr, 0, NN_, 128, HID);
    }
}

// Round 2
// 645.829 us; speedup vs baseline: 2.7292x; 2.7292x over previous
//
#include <hip/hip_runtime.h>
#include <hip/hip_bf16.h>

// ---------------- problem constants ----------------
constexpr int NN_ = 4096;     // nodes
constexpr int INF = 28;       // input features
constexpr int NH  = 8;        // GAT heads
constexpr int CC  = 256;      // channels per head
constexpr int HC  = 2048;     // NH*CC
constexpr int HID = 256;
constexpr int NE  = 131072;   // edges per branch
constexpr int KK  = NH * INF; // 224

typedef short bf16x8 __attribute__((ext_vector_type(8)));
typedef float f32x4 __attribute__((ext_vector_type(4)));

// ---------------- small precompute kernels ----------------

__global__ void k_small_pre(const float* __restrict__ Wt, const float* __restrict__ ast,
                            const float* __restrict__ adt, const float* __restrict__ Wet,
                            const float* __restrict__ aet,
                            const float* __restrict__ Wc, const float* __restrict__ asc,
                            const float* __restrict__ adc, const float* __restrict__ Wec,
                            const float* __restrict__ aec,
                            float* __restrict__ wa, float* __restrict__ dote)
{
    int i = blockIdx.x * blockDim.x + threadIdx.x;
    if (i < 2 * 2 * INF * NH) {
        int b = i / (2 * INF * NH);
        int r = i % (2 * INF * NH);
        int kind = r / (INF * NH);
        int r2 = r % (INF * NH);
        int k = r2 / NH, h = r2 % NH;
        const float* W = b ? Wc : Wt;
        const float* a = b ? (kind ? adc : asc) : (kind ? adt : ast);
        float s = 0.f;
        for (int c = 0; c < CC; ++c) s += W[k * HC + h * CC + c] * a[h * CC + c];
        wa[((b * 2 + kind) * INF + k) * NH + h] = s;
    } else if (i < 2 * 2 * INF * NH + 16) {
        int j = i - 2 * 2 * INF * NH;
        int b = j / NH, h = j % NH;
        const float* We = b ? Wec : Wet;
        const float* a  = b ? aec : aet;
        float s = 0.f;
        for (int c = 0; c < CC; ++c) s += We[h * CC + c] * a[h * CC + c];
        dote[b * NH + h] = s;
    }
}

__global__ void k_mean(const float* __restrict__ ea_t, const float* __restrict__ ea_c,
                       float* __restrict__ meansum)
{
    int i = blockIdx.x * blockDim.x + threadIdx.x;
    int b = i / NE;
    float v = (b ? ea_c : ea_t)[i - b * NE];
    for (int off = 32; off; off >>= 1) v += __shfl_down(v, off);
    if ((threadIdx.x & 63) == 0) atomicAdd(&meansum[b], v);
}

__global__ void k_as_ad(const float* __restrict__ x, const float* __restrict__ wa,
                        float* __restrict__ asd)
{
    int i = blockIdx.x * blockDim.x + threadIdx.x;
    if (i >= 4 * NN_ * NH) return;
    int bk = i / (NN_ * NH);
    int r = i % (NN_ * NH);
    int n = r / NH, h = r % NH;
    const float* W = wa + bk * INF * NH;
    const float* xr = x + n * INF;
    float s = 0.f;
#pragma unroll
    for (int k = 0; k < INF; ++k) s += xr[k] * W[k * NH + h];
    asd[(bk * NN_ + n) * NH + h] = s;
}

__global__ void k_biasg(const float* __restrict__ bt, const float* __restrict__ Wih,
                        const float* __restrict__ bih, const float* __restrict__ bhh,
                        float* __restrict__ bg)
{
    int j = blockIdx.x * blockDim.x + threadIdx.x;
    if (j >= 1024) return;
    float s = bih[j] + bhh[j];
    const float* w = Wih + (size_t)j * HC;
    for (int c = 0; c < HC; ++c) s += bt[c] * w[c];
    bg[j] = s;
}

__global__ void k_M(const float* __restrict__ Wt, const float* __restrict__ Wih,
                    float* __restrict__ M)
{
    int i = blockIdx.x * blockDim.x + threadIdx.x;
    if (i >= KK * 1024) return;
    int kk = i >> 10, j = i & 1023;
    int h = kk / INF, k = kk % INF;
    const float* wa = Wt + k * HC + h * CC;
    const float* wb = Wih + (size_t)j * HC + h * CC;
    float s = 0.f;
    for (int c = 0; c < CC; ++c) s += wa[c] * wb[c];
    M[kk * 1024 + j] = s;
}

__global__ void k_Bc(const float* __restrict__ Wc, float* __restrict__ Bc)
{
    int i = blockIdx.x * blockDim.x + threadIdx.x;
    if (i >= KK * CC) return;
    int kk = i / CC, c = i % CC;
    int h = kk / INF, k = kk % INF;
    Bc[i] = Wc[k * HC + h * CC + c] * 0.125f;
}

// ---------------- CSR build ----------------
__global__ void k_hist(const int* __restrict__ ei_t, const int* __restrict__ ei_c,
                       int* __restrict__ cnt)
{
    int i = blockIdx.x * blockDim.x + threadIdx.x;
    if (i >= 2 * NE) return;
    int b = i / NE, e = i - b * NE;
    const int* ei = b ? ei_c : ei_t;
    atomicAdd(&cnt[b * NN_ + ei[NE + e]], 1);
}

__global__ __launch_bounds__(1024) void k_scan(const int* __restrict__ cnt, int* __restrict__ rows)
{
    int b = blockIdx.x;
    const int* c = cnt + b * NN_;
    int* r = rows + b * (NN_ + 16);
    __shared__ int ts[1024];
    int t = threadIdx.x;
    int v0 = c[t * 4], v1 = c[t * 4 + 1], v2 = c[t * 4 + 2], v3 = c[t * 4 + 3];
    ts[t] = v0 + v1 + v2 + v3;
    __syncthreads();
    for (int off = 1; off < 1024; off <<= 1) {
        int add = (t >= off) ? ts[t - off] : 0;
        __syncthreads();
        ts[t] += add;
        __syncthreads();
    }
    int excl = (t == 0) ? 0 : ts[t - 1];
    r[t * 4 + 0] = excl; excl += v0;
    r[t * 4 + 1] = excl; excl += v1;
    r[t * 4 + 2] = excl; excl += v2;
    r[t * 4 + 3] = excl; excl += v3;
    if (t == 1023) r[NN_] = excl;
}

__global__ void k_scatter(const int* __restrict__ ei_t, const int* __restrict__ ei_c,
                          const float* __restrict__ ea_t, const float* __restrict__ ea_c,
                          const int* __restrict__ rows, int* __restrict__ cur,
                          int* __restrict__ srcs, float* __restrict__ eav)
{
    int i = blockIdx.x * blockDim.x + threadIdx.x;
    if (i >= 2 * NE) return;
    int b = i / NE, e = i - b * NE;
    const int* ei = b ? ei_c : ei_t;
    const float* ea = b ? ea_c : ea_t;
    int d = ei[NE + e];
    int pos = rows[b * (NN_ + 16) + d] + atomicAdd(&cur[b * NN_ + d], 1);
    srcs[b * NE + pos] = ei[e];
    eav[b * NE + pos] = ea[e];
}

// ---------------- GAT per-dst aggregation ----------------
__global__ __launch_bounds__(64) void k_gat(
    const int* __restrict__ srcs, const float* __restrict__ eav,
    const int* __restrict__ rows, const float* __restrict__ x,
    const float* __restrict__ a_s, const float* __restrict__ a_d,
    const float* __restrict__ dote, const float* __restrict__ meansum,
    float* __restrict__ g)
{
    int n = blockIdx.x;
    int lane = threadIdx.x;
    __shared__ float xb[64][32];
    __shared__ float eb[64][8];
    __shared__ float denb[8];

    float adn[NH], dt[NH];
#pragma unroll
    for (int h = 0; h < NH; ++h) { adn[h] = a_d[n * NH + h]; dt[h] = dote[h]; }
    float mean_attr = meansum[0] * (1.0f / NE);

    const int hOwn = lane >> 3;
    const int kOwn = (lane & 7) * 4;

    float acc0, acc1, acc2, acc3;
    {
        float al = a_s[n * NH + hOwn] + adn[hOwn] + mean_attr * dt[hOwn];
        al = al > 0.f ? al : 0.2f * al;
        float es = __expf(al);
        float xv0 = (kOwn + 0 < INF) ? x[n * INF + kOwn + 0] : 0.f;
        float xv1 = (kOwn + 1 < INF) ? x[n * INF + kOwn + 1] : 0.f;
        float xv2 = (kOwn + 2 < INF) ? x[n * INF + kOwn + 2] : 0.f;
        float xv3 = (kOwn + 3 < INF) ? x[n * INF + kOwn + 3] : ((kOwn + 3 == 31) ? 1.f : 0.f);
        acc0 = es * xv0; acc1 = es * xv1; acc2 = es * xv2; acc3 = es * xv3;
    }

    int e0 = rows[n], e1 = rows[n + 1];
    for (int base = e0; base < e1; base += 64) {
        int m = e1 - base; if (m > 64) m = 64;
        if (lane < m) {
            int sidx = srcs[base + lane];
            float ea = eav[base + lane];
            const float4* xr = (const float4*)(x + sidx * INF);
#pragma unroll
            for (int q = 0; q < 7; ++q) ((float4*)&xb[lane][0])[q] = xr[q];
            xb[lane][28] = 0.f; xb[lane][29] = 0.f; xb[lane][30] = 0.f; xb[lane][31] = 1.f;
            const float* asr = a_s + sidx * NH;
#pragma unroll
            for (int h = 0; h < NH; ++h) {
                float al = asr[h] + adn[h] + ea * dt[h];
                al = al > 0.f ? al : 0.2f * al;
                eb[lane][h] = __expf(al);
            }
        }
        __syncthreads();
        for (int j = 0; j < m; ++j) {
            float e = eb[j][hOwn];
            float4 xv = *(const float4*)&xb[j][kOwn];
            acc0 += e * xv.x; acc1 += e * xv.y; acc2 += e * xv.z; acc3 += e * xv.w;
        }
        __syncthreads();
    }

    if ((lane & 7) == 7) denb[hOwn] = acc3;
    __syncthreads();
    float inv = 1.0f / denb[hOwn];
    float* gr = g + n * KK + hOwn * INF + kOwn;
    if (kOwn + 0 < INF) gr[0] = acc0 * inv;
    if (kOwn + 1 < INF) gr[1] = acc1 * inv;
    if (kOwn + 2 < INF) gr[2] = acc2 * inv;
    if (kOwn + 3 < INF) gr[3] = acc3 * inv;
}

// ---------------- generic fp32 GEMM ----------------
template<bool BT, bool RELU>
__global__ __launch_bounds__(256) void k_gemm(
    const float* __restrict__ A, int lda,
    const float* __restrict__ B, int ldb,
    const float* __restrict__ bias,
    float* __restrict__ C, int ldc,
    float* __restrict__ C2, int ldc2,
    int M, int N, int K)
{
    __shared__ float As[16][72];
    __shared__ float Bs[16][72];
    int t = threadIdx.x;
    int tx = t & 15, ty = t >> 4;
    int m0 = blockIdx.x * 64, n0 = blockIdx.y * 64;
    float acc[4][4];
#pragma unroll
    for (int i = 0; i < 4; ++i)
#pragma unroll
        for (int j = 0; j < 4; ++j) acc[i][j] = 0.f;

    for (int k0 = 0; k0 < K; k0 += 16) {
        {
            int row = t >> 2, q = t & 3;
            float4 av = make_float4(0.f, 0.f, 0.f, 0.f);
            if (m0 + row < M) av = *(const float4*)(A + (size_t)(m0 + row) * lda + k0 + q * 4);
            As[q * 4 + 0][row] = av.x; As[q * 4 + 1][row] = av.y;
            As[q * 4 + 2][row] = av.z; As[q * 4 + 3][row] = av.w;
            if (BT) {
                float4 bv = make_float4(0.f, 0.f, 0.f, 0.f);
                if (n0 + row < N) bv = *(const float4*)(B + (size_t)(n0 + row) * ldb + k0 + q * 4);
                Bs[q * 4 + 0][row] = bv.x; Bs[q * 4 + 1][row] = bv.y;
                Bs[q * 4 + 2][row] = bv.z; Bs[q * 4 + 3][row] = bv.w;
            } else {
                int kk = t >> 4, nq = t & 15;
                float4 bv = *(const float4*)(B + (size_t)(k0 + kk) * ldb + n0 + nq * 4);
                *(float4*)&Bs[kk][nq * 4] = bv;
            }
        }
        __syncthreads();
#pragma unroll
        for (int kk = 0; kk < 16; ++kk) {
            float4 a = *(const float4*)&As[kk][ty * 4];
            float4 b = *(const float4*)&Bs[kk][tx * 4];
            acc[0][0] += a.x * b.x; acc[0][1] += a.x * b.y; acc[0][2] += a.x * b.z; acc[0][3] += a.x * b.w;
            acc[1][0] += a.y * b.x; acc[1][1] += a.y * b.y; acc[1][2] += a.y * b.z; acc[1][3] += a.y * b.w;
            acc[2][0] += a.z * b.x; acc[2][1] += a.z * b.y; acc[2][2] += a.z * b.z; acc[2][3] += a.z * b.w;
            acc[3][0] += a.w * b.x; acc[3][1] += a.w * b.y; acc[3][2] += a.w * b.z; acc[3][3] += a.w * b.w;
        }
        __syncthreads();
    }
#pragma unroll
    for (int i = 0; i < 4; ++i) {
        int m = m0 + ty * 4 + i;
        if (m >= M) continue;
#pragma unroll
        for (int j = 0; j < 4; ++j) {
            int n = n0 + tx * 4 + j;
            if (n >= N) continue;
            float v = acc[i][j];
            if (bias) v += bias[n];
            if (RELU) v = v > 0.f ? v : 0.f;
            C[(size_t)m * ldc + n] = v;
            if (C2) C2[(size_t)m * ldc2 + n] = v;
        }
    }
}

// ---------------- LSTM elementwise ----------------
__global__ void k_lstm(const float* __restrict__ gates, float* __restrict__ hout,
                       float* __restrict__ concat)
{
    int i = blockIdx.x * blockDim.x + threadIdx.x;
    if (i >= NN_ * HID) return;
    int n = i >> 8, j = i & 255;
    const float* gr = gates + (size_t)n * 1024;
    float gi = gr[j], gg = gr[512 + j], go = gr[768 + j];
    float c = (1.f / (1.f + __expf(-gi))) * tanhf(gg);
    float h = (1.f / (1.f + __expf(-go))) * tanhf(c);
    hout[i] = h;
    concat[n * 512 + j] = h;
}

// ---------------- MHA: bf16 MFMA flash attention ----------------
// qkv fp32 [N][768] -> Qb[h][n][64]*0.125, Kb[h][n][64], Vt[h][d][n]  (bf16)
__global__ void k_cvt(const float* __restrict__ qkv,
                      __hip_bfloat16* __restrict__ Qb, __hip_bfloat16* __restrict__ Kb,
                      __hip_bfloat16* __restrict__ Vt)
{
    int i = blockIdx.x * blockDim.x + threadIdx.x;   // NN_*256 threads
    int n = i >> 8, c = i & 255;
    int h = c >> 6, d = c & 63;
    const float* row = qkv + (size_t)n * 768;
    Qb[((size_t)h * NN_ + n) * 64 + d] = __float2bfloat16(row[c] * 0.125f);
    Kb[((size_t)h * NN_ + n) * 64 + d] = __float2bfloat16(row[256 + c]);
    Vt[((size_t)h * 64 + d) * NN_ + n] = __float2bfloat16(row[512 + c]);
}

// grid (NN_/64, 4 heads, 4 key-splits), 256 thr = 4 waves; wave owns 16 q-rows.
// No max-subtraction (logits ~ +/-0.01). Partial num/den per split, merged after.
__global__ __launch_bounds__(256) void k_attn_mfma(
    const __hip_bfloat16* __restrict__ Qb, const __hip_bfloat16* __restrict__ Kb,
    const __hip_bfloat16* __restrict__ Vt,
    float* __restrict__ num, float* __restrict__ den)
{
    __shared__ __hip_bfloat16 plds[4][512];          // per-wave 16x32 P tile
    int tid = threadIdx.x;
    int wave = tid >> 6, lane = tid & 63;
    int l16 = lane & 15, lgrp = lane >> 4;
    int h = blockIdx.y, split = blockIdx.z;
    int q0 = blockIdx.x * 64 + wave * 16;
    int kbase = split * 1024;

    const short* Qs = (const short*)Qb;
    const short* Ks = (const short*)Kb;
    const short* Vs = (const short*)Vt;

    // A-frag: lane holds Q[q0+l16][lgrp*8 .. +7] (contiguous bf16x8)
    bf16x8 qf0 = *(const bf16x8*)(Qs + ((size_t)h * NN_ + q0 + l16) * 64 + lgrp * 8);
    bf16x8 qf1 = *(const bf16x8*)(Qs + ((size_t)h * NN_ + q0 + l16) * 64 + 32 + lgrp * 8);

    f32x4 oacc[4];
#pragma unroll
    for (int dc = 0; dc < 4; ++dc) oacc[dc] = (f32x4){0.f, 0.f, 0.f, 0.f};
    float dn0 = 0.f, dn1 = 0.f, dn2 = 0.f, dn3 = 0.f;

    __hip_bfloat16* myp = plds[wave];

    for (int kt = 0; kt < 32; ++kt) {
        int k0 = kbase + kt * 32;
        // B-frags for S = Q*K^T: lane holds K[k0+kc*16+l16][lgrp*8 ..+7]
        bf16x8 kf00 = *(const bf16x8*)(Ks + ((size_t)h * NN_ + k0 + l16) * 64 + lgrp * 8);
        bf16x8 kf01 = *(const bf16x8*)(Ks + ((size_t)h * NN_ + k0 + l16) * 64 + 32 + lgrp * 8);
        bf16x8 kf10 = *(const bf16x8*)(Ks + ((size_t)h * NN_ + k0 + 16 + l16) * 64 + lgrp * 8);
        bf16x8 kf11 = *(const bf16x8*)(Ks + ((size_t)h * NN_ + k0 + 16 + l16) * 64 + 32 + lgrp * 8);
        f32x4 s0 = (f32x4){0.f, 0.f, 0.f, 0.f};
        f32x4 s1 = (f32x4){0.f, 0.f, 0.f, 0.f};
        s0 = __builtin_amdgcn_mfma_f32_16x16x32_bf16(qf0, kf00, s0, 0, 0, 0);
        s0 = __builtin_amdgcn_mfma_f32_16x16x32_bf16(qf1, kf01, s0, 0, 0, 0);
        s1 = __builtin_amdgcn_mfma_f32_16x16x32_bf16(qf0, kf10, s1, 0, 0, 0);
        s1 = __builtin_amdgcn_mfma_f32_16x16x32_bf16(qf1, kf11, s1, 0, 0, 0);
        // P = exp(S); D-layout: row = lgrp*4+r, cols l16 and 16+l16.
#pragma unroll
        for (int r = 0; r < 4; ++r) {
            float e0 = __expf(s0[r]);
            float e1 = __expf(s1[r]);
            if (r == 0) { dn0 += e0 + e1; } else if (r == 1) { dn1 += e0 + e1; }
            else if (r == 2) { dn2 += e0 + e1; } else { dn3 += e0 + e1; }
            int row = lgrp * 4 + r;
            int sw = ((row >> 1) & 3) << 3;                 // 8-short-chunk XOR swizzle
            myp[(row * 32 + l16) ^ sw]        = __float2bfloat16(e0);
            myp[(row * 32 + 16 + l16) ^ sw]   = __float2bfloat16(e1);
        }
        // A-frag of P: lane holds P[l16][lgrp*8 ..+7] (same swizzle)
        int rsw = ((l16 >> 1) & 3) << 3;
        bf16x8 pa = *(const bf16x8*)&myp[(l16 * 32 + lgrp * 8) ^ rsw];
        // B-frags of V: lane holds V[k0+lgrp*8 ..+7][dc*16+l16] via Vt
#pragma unroll
        for (int dc = 0; dc < 4; ++dc) {
            bf16x8 vf = *(const bf16x8*)(Vs + ((size_t)h * 64 + dc * 16 + l16) * NN_ + k0 + lgrp * 8);
            oacc[dc] = __builtin_amdgcn_mfma_f32_16x16x32_bf16(pa, vf, oacc[dc], 0, 0, 0);
        }
    }

    // reduce den across the 16 lanes sharing a row group
    dn0 += __shfl_xor(dn0, 1); dn0 += __shfl_xor(dn0, 2); dn0 += __shfl_xor(dn0, 4); dn0 += __shfl_xor(dn0, 8);
    dn1 += __shfl_xor(dn1, 1); dn1 += __shfl_xor(dn1, 2); dn1 += __shfl_xor(dn1, 4); dn1 += __shfl_xor(dn1, 8);
    dn2 += __shfl_xor(dn2, 1); dn2 += __shfl_xor(dn2, 2); dn2 += __shfl_xor(dn2, 4); dn2 += __shfl_xor(dn2, 8);
    dn3 += __shfl_xor(dn3, 1); dn3 += __shfl_xor(dn3, 2); dn3 += __shfl_xor(dn3, 4); dn3 += __shfl_xor(dn3, 8);

    size_t pb = (size_t)(split * 4 + h) * NN_;
#pragma unroll
    for (int dc = 0; dc < 4; ++dc)
#pragma unroll
        for (int r = 0; r < 4; ++r)
            num[(pb + q0 + lgrp * 4 + r) * 64 + dc * 16 + l16] = oacc[dc][r];
    if (l16 == 0) {
        den[pb + q0 + lgrp * 4 + 0] = dn0;
        den[pb + q0 + lgrp * 4 + 1] = dn1;
        den[pb + q0 + lgrp * 4 + 2] = dn2;
        den[pb + q0 + lgrp * 4 + 3] = dn3;
    }
}

__global__ void k_merge(const float* __restrict__ num, const float* __restrict__ den,
                        float* __restrict__ out)
{
    int i = blockIdx.x * blockDim.x + threadIdx.x;   // NN_*256
    int n = i >> 8, c = i & 255;
    int h = c >> 6, d = c & 63;
    float ns = 0.f, dsum = 0.f;
#pragma unroll
    for (int s = 0; s < 4; ++s) {
        ns += num[((size_t)(s * 4 + h) * NN_ + n) * 64 + d];
        dsum += den[(size_t)(s * 4 + h) * NN_ + n];
    }
    out[(size_t)n * 256 + c] = ns / dsum;
}

// ---------------- launch ----------------
extern "C" void kernel_launch(void* const* d_in, const int* in_sizes, int n_in,
                              void* d_out, int out_size, void* d_ws, size_t ws_size,
                              hipStream_t stream)
{
    const float* x      = (const float*)d_in[0];
    const int*   ei_t   = (const int*)d_in[1];
    const int*   ei_c   = (const int*)d_in[2];
    const float* ea_t   = (const float*)d_in[3];
    const float* ea_c   = (const float*)d_in[4];
    const float* W_t    = (const float*)d_in[5];
    const float* asrc_t = (const float*)d_in[6];
    const float* adst_t = (const float*)d_in[7];
    const float* We_t   = (const float*)d_in[8];
    const float* aedg_t = (const float*)d_in[9];
    const float* b_t    = (const float*)d_in[10];
    const float* W_c    = (const float*)d_in[11];
    const float* asrc_c = (const float*)d_in[12];
    const float* adst_c = (const float*)d_in[13];
    const float* We_c   = (const float*)d_in[14];
    const float* aedg_c = (const float*)d_in[15];
    const float* b_c    = (const float*)d_in[16];
    const float* Wih    = (const float*)d_in[17];
    const float* bih    = (const float*)d_in[19];
    const float* bhh    = (const float*)d_in[20];
    const float* min_w  = (const float*)d_in[21];
    const float* min_b  = (const float*)d_in[22];
    const float* mout_w = (const float*)d_in[23];
    const float* mout_b = (const float*)d_in[24];
    const float* fus_w  = (const float*)d_in[25];
    const float* fus_b  = (const float*)d_in[26];
    const float* out_w  = (const float*)d_in[27];
    const float* out_b  = (const float*)d_in[28];
    float* outp = (float*)d_out;

    char* W = (char*)d_ws;
    size_t off = 0;
    auto alloc = [&](size_t bytes) { size_t r = off; off += (bytes + 255) & ~(size_t)255; return r; };
    size_t oMean  = alloc(2 * 4);
    size_t oCnt   = alloc(2 * NN_ * 4);
    size_t oCur   = alloc(2 * NN_ * 4);
    size_t zeroBytes = off;
    size_t oRows  = alloc(2 * (NN_ + 16) * 4);
    size_t oSrcs  = alloc(2 * NE * 4);
    size_t oEav   = alloc(2 * NE * 4);
    size_t oWa    = alloc(4 * INF * NH * 4);
    size_t oDote  = alloc(2 * NH * 4);
    size_t oAsd   = alloc(4 * NN_ * NH * 4);
    size_t oBg    = alloc(1024 * 4);
    size_t oM     = alloc((size_t)KK * 1024 * 4);
    size_t oBc    = alloc((size_t)KK * CC * 4);
    size_t oG     = alloc((size_t)2 * NN_ * KK * 4);
    size_t oGates = alloc((size_t)NN_ * 1024 * 4);   // 16 MB; reused as qkv then num
    size_t oHc    = alloc((size_t)NN_ * HID * 4);
    size_t oConcat= alloc((size_t)NN_ * 512 * 4);
    size_t oHfus  = alloc((size_t)NN_ * HID * 4);
    size_t oQb    = alloc((size_t)4 * NN_ * 64 * 2);
    size_t oKb    = alloc((size_t)4 * NN_ * 64 * 2);
    size_t oVt    = alloc((size_t)4 * NN_ * 64 * 2);
    size_t oDen   = alloc((size_t)16 * NN_ * 4);
    size_t oQkv   = oGates;   // qkv fp32 [N][768] (12.6MB) — gates dead after k_lstm
    size_t oNum   = oGates;   // num fp32 [16][N][64] (16MB) — qkv dead after k_cvt
    size_t oAttno = oG;       // attn out fp32 [N][256] — g dead after its two GEMMs
    (void)ws_size; (void)in_sizes; (void)n_in; (void)out_size;

    hipMemsetAsync(W, 0, zeroBytes, stream);

    k_small_pre<<<4, 256, 0, stream>>>(W_t, asrc_t, adst_t, We_t, aedg_t,
                                       W_c, asrc_c, adst_c, We_c, aedg_c,
                                       (float*)(W + oWa), (float*)(W + oDote));
    k_mean<<<2 * NE / 256, 256, 0, stream>>>(ea_t, ea_c, (float*)(W + oMean));
    k_hist<<<2 * NE / 256, 256, 0, stream>>>(ei_t, ei_c, (int*)(W + oCnt));
    k_scan<<<2, 1024, 0, stream>>>((int*)(W + oCnt), (int*)(W + oRows));
    k_scatter<<<2 * NE / 256, 256, 0, stream>>>(ei_t, ei_c, ea_t, ea_c,
                                                (int*)(W + oRows), (int*)(W + oCur),
                                                (int*)(W + oSrcs), (float*)(W + oEav));
    k_as_ad<<<512, 256, 0, stream>>>(x, (float*)(W + oWa), (float*)(W + oAsd));
    k_biasg<<<4, 256, 0, stream>>>(b_t, Wih, bih, bhh, (float*)(W + oBg));
    k_M<<<KK * 1024 / 256, 256, 0, stream>>>(W_t, Wih, (float*)(W + oM));
    k_Bc<<<KK * CC / 256, 256, 0, stream>>>(W_c, (float*)(W + oBc));

    k_gat<<<NN_, 64, 0, stream>>>((int*)(W + oSrcs), (float*)(W + oEav), (int*)(W + oRows), x,
                                  (float*)(W + oAsd),                (float*)(W + oAsd) + NN_ * NH,
                                  (float*)(W + oDote),               (float*)(W + oMean),
                                  (float*)(W + oG));
    k_gat<<<NN_, 64, 0, stream>>>((int*)(W + oSrcs) + NE, (float*)(W + oEav) + NE,
                                  (int*)(W + oRows) + (NN_ + 16), x,
                                  (float*)(W + oAsd) + 2 * NN_ * NH, (float*)(W + oAsd) + 3 * NN_ * NH,
                                  (float*)(W + oDote) + NH,          (float*)(W + oMean) + 1,
                                  (float*)(W + oG) + (size_t)NN_ * KK);

    {
        dim3 grid(64, 16);
        k_gemm<false, false><<<grid, 256, 0, stream>>>(
            (float*)(W + oG), KK, (float*)(W + oM), 1024, (float*)(W + oBg),
            (float*)(W + oGates), 1024, nullptr, 0, NN_, 1024, KK);
    }
    k_lstm<<<NN_ * HID / 256, 256, 0, stream>>>((float*)(W + oGates),
                                                outp + 524288, (float*)(W + oConcat));

    {
        dim3 grid(64, 4);
        k_gemm<false, false><<<grid, 256, 0, stream>>>(
            (float*)(W + oG) + (size_t)NN_ * KK, KK, (float*)(W + oBc), CC, b_c,
            (float*)(W + oHc), HID, nullptr, 0, NN_, HID, KK);
    }
    {
        dim3 grid(64, 12);
        k_gemm<true, false><<<grid, 256, 0, stream>>>(
            (float*)(W + oHc), HID, min_w, HID, min_b,
            (float*)(W + oQkv), 768, nullptr, 0, NN_, 768, HID);
    }
    // bf16 conversion + MFMA flash attention (key-split 4) + merge
    k_cvt<<<NN_, 256, 0, stream>>>((float*)(W + oQkv),
                                   (__hip_bfloat16*)(W + oQb), (__hip_bfloat16*)(W + oKb),
                                   (__hip_bfloat16*)(W + oVt));
    {
        dim3 grid(NN_ / 64, 4, 4);
        k_attn_mfma<<<grid, 256, 0, stream>>>(
            (__hip_bfloat16*)(W + oQb), (__hip_bfloat16*)(W + oKb), (__hip_bfloat16*)(W + oVt),
            (float*)(W + oNum), (float*)(W + oDen));
    }
    k_merge<<<NN_, 256, 0, stream>>>((float*)(W + oNum), (float*)(W + oDen),
                                     (float*)(W + oAttno));

    {
        dim3 grid(64, 4);
        k_gemm<true, false><<<grid, 256, 0, stream>>>(
            (float*)(W + oAttno), HID, mout_w, HID, mout_b,
            (float*)(W + oConcat) + 256, 512, outp + 524288 + 1048576, 256, NN_, HID, HID);
    }
    {
        dim3 grid(64, 4);
        k_gemm<true, true><<<grid, 256, 0, stream>>>(
            (float*)(W + oConcat), 512, fus_w, 512, fus_b,
            (float*)(W + oHfus), HID, nullptr, 0, NN_, HID, 512);
    }
    {
        dim3 grid(64, 2);
        k_gemm<true, false><<<grid, 256, 0, stream>>>(
            (float*)(W + oHfus), HID, out_w, HID, out_b,
            outp, 128, nullptr, 0, NN_, 128, HID);
    }
}

// Round 3
// 605.719 us; speedup vs baseline: 2.9099x; 1.0662x over previous
//
#include <hip/hip_runtime.h>
#include <hip/hip_bf16.h>

// ---------------- problem constants ----------------
constexpr int NN_ = 4096;     // nodes
constexpr int INF = 28;       // input features
constexpr int NH  = 8;        // GAT heads
constexpr int CC  = 256;      // channels per head
constexpr int HC  = 2048;     // NH*CC
constexpr int HID = 256;
constexpr int NE  = 131072;   // edges per branch
constexpr int KK  = NH * INF; // 224

typedef short bf16x8 __attribute__((ext_vector_type(8)));
typedef float f32x4 __attribute__((ext_vector_type(4)));

__device__ inline void split_store(float v, __hip_bfloat16* H, __hip_bfloat16* L, size_t idx)
{
    __hip_bfloat16 h = __float2bfloat16(v);
    H[idx] = h;
    L[idx] = __float2bfloat16(v - __bfloat162float(h));
}

// ---------------- small precompute kernels ----------------

__global__ void k_small_pre(const float* __restrict__ Wt, const float* __restrict__ ast,
                            const float* __restrict__ adt, const float* __restrict__ Wet,
                            const float* __restrict__ aet,
                            const float* __restrict__ Wc, const float* __restrict__ asc,
                            const float* __restrict__ adc, const float* __restrict__ Wec,
                            const float* __restrict__ aec,
                            float* __restrict__ wa, float* __restrict__ dote)
{
    int i = blockIdx.x * blockDim.x + threadIdx.x;
    if (i < 2 * 2 * INF * NH) {
        int b = i / (2 * INF * NH);
        int r = i % (2 * INF * NH);
        int kind = r / (INF * NH);
        int r2 = r % (INF * NH);
        int k = r2 / NH, h = r2 % NH;
        const float* W = b ? Wc : Wt;
        const float* a = b ? (kind ? adc : asc) : (kind ? adt : ast);
        float s = 0.f;
        for (int c = 0; c < CC; ++c) s += W[k * HC + h * CC + c] * a[h * CC + c];
        wa[((b * 2 + kind) * INF + k) * NH + h] = s;
    } else if (i < 2 * 2 * INF * NH + 16) {
        int j = i - 2 * 2 * INF * NH;
        int b = j / NH, h = j % NH;
        const float* We = b ? Wec : Wet;
        const float* a  = b ? aec : aet;
        float s = 0.f;
        for (int c = 0; c < CC; ++c) s += We[h * CC + c] * a[h * CC + c];
        dote[b * NH + h] = s;
    }
}

__global__ void k_mean(const float* __restrict__ ea_t, const float* __restrict__ ea_c,
                       float* __restrict__ meansum)
{
    int i = blockIdx.x * blockDim.x + threadIdx.x;
    int b = i / NE;
    float v = (b ? ea_c : ea_t)[i - b * NE];
    for (int off = 32; off; off >>= 1) v += __shfl_down(v, off);
    if ((threadIdx.x & 63) == 0) atomicAdd(&meansum[b], v);
}

__global__ void k_as_ad(const float* __restrict__ x, const float* __restrict__ wa,
                        float* __restrict__ asd)
{
    int i = blockIdx.x * blockDim.x + threadIdx.x;
    if (i >= 4 * NN_ * NH) return;
    int bk = i / (NN_ * NH);
    int r = i % (NN_ * NH);
    int n = r / NH, h = r % NH;
    const float* W = wa + bk * INF * NH;
    const float* xr = x + n * INF;
    float s = 0.f;
#pragma unroll
    for (int k = 0; k < INF; ++k) s += xr[k] * W[k * NH + h];
    asd[(bk * NN_ + n) * NH + h] = s;
}

__global__ void k_biasg(const float* __restrict__ bt, const float* __restrict__ Wih,
                        const float* __restrict__ bih, const float* __restrict__ bhh,
                        float* __restrict__ bg)
{
    int j = blockIdx.x * blockDim.x + threadIdx.x;
    if (j >= 1024) return;
    float s = bih[j] + bhh[j];
    const float* w = Wih + (size_t)j * HC;
    for (int c = 0; c < HC; ++c) s += bt[c] * w[c];
    bg[j] = s;
}

// fused hi/lo split of the static weights (one launch)
__global__ void k_split_all(const float* __restrict__ Wih,  __hip_bfloat16* WihH,  __hip_bfloat16* WihL,
                            const float* __restrict__ Wt,   __hip_bfloat16* WtH,   __hip_bfloat16* WtL,
                            const float* __restrict__ minw, __hip_bfloat16* minH,  __hip_bfloat16* minL,
                            const float* __restrict__ moutw,__hip_bfloat16* moutH, __hip_bfloat16* moutL,
                            const float* __restrict__ fusw, __hip_bfloat16* fusH,  __hip_bfloat16* fusL,
                            const float* __restrict__ outw, __hip_bfloat16* outH,  __hip_bfloat16* outL)
{
    int i = blockIdx.x * blockDim.x + threadIdx.x;
    // segment sizes: 2097152, 57344, 196608, 65536, 131072, 32768 (cum below)
    if (i < 2097152)                   split_store(Wih[i],            WihH,  WihL,  i);
    else if (i < 2097152 + 57344)      split_store(Wt[i - 2097152],   WtH,   WtL,   i - 2097152);
    else if (i < 2154496 + 196608)     split_store(minw[i - 2154496], minH,  minL,  i - 2154496);
    else if (i < 2351104 + 65536)      split_store(moutw[i - 2351104],moutH, moutL, i - 2351104);
    else if (i < 2416640 + 131072)     split_store(fusw[i - 2416640], fusH,  fusL,  i - 2416640);
    else if (i < 2547712 + 32768)      split_store(outw[i - 2547712], outH,  outL,  i - 2547712);
}

// Bct[c][kk] = Wc[k, h*CC+c] / 8  (head-mean folded), hi/lo bf16
__global__ void k_bct(const float* __restrict__ Wc, __hip_bfloat16* __restrict__ BH,
                      __hip_bfloat16* __restrict__ BL)
{
    int i = blockIdx.x * blockDim.x + threadIdx.x;
    if (i >= CC * KK) return;
    int c = i / KK, kk = i % KK;
    int h = kk / INF, k = kk % INF;
    split_store(Wc[k * HC + h * CC + c] * 0.125f, BH, BL, i);
}

// ---------------- CSR build ----------------
__global__ void k_hist(const int* __restrict__ ei_t, const int* __restrict__ ei_c,
                       int* __restrict__ cnt)
{
    int i = blockIdx.x * blockDim.x + threadIdx.x;
    if (i >= 2 * NE) return;
    int b = i / NE, e = i - b * NE;
    const int* ei = b ? ei_c : ei_t;
    atomicAdd(&cnt[b * NN_ + ei[NE + e]], 1);
}

__global__ __launch_bounds__(1024) void k_scan(const int* __restrict__ cnt, int* __restrict__ rows)
{
    int b = blockIdx.x;
    const int* c = cnt + b * NN_;
    int* r = rows + b * (NN_ + 16);
    __shared__ int ts[1024];
    int t = threadIdx.x;
    int v0 = c[t * 4], v1 = c[t * 4 + 1], v2 = c[t * 4 + 2], v3 = c[t * 4 + 3];
    ts[t] = v0 + v1 + v2 + v3;
    __syncthreads();
    for (int off = 1; off < 1024; off <<= 1) {
        int add = (t >= off) ? ts[t - off] : 0;
        __syncthreads();
        ts[t] += add;
        __syncthreads();
    }
    int excl = (t == 0) ? 0 : ts[t - 1];
    r[t * 4 + 0] = excl; excl += v0;
    r[t * 4 + 1] = excl; excl += v1;
    r[t * 4 + 2] = excl; excl += v2;
    r[t * 4 + 3] = excl; excl += v3;
    if (t == 1023) r[NN_] = excl;
}

__global__ void k_scatter(const int* __restrict__ ei_t, const int* __restrict__ ei_c,
                          const float* __restrict__ ea_t, const float* __restrict__ ea_c,
                          const int* __restrict__ rows, int* __restrict__ cur,
                          int* __restrict__ srcs, float* __restrict__ eav)
{
    int i = blockIdx.x * blockDim.x + threadIdx.x;
    if (i >= 2 * NE) return;
    int b = i / NE, e = i - b * NE;
    const int* ei = b ? ei_c : ei_t;
    const float* ea = b ? ea_c : ea_t;
    int d = ei[NE + e];
    int pos = rows[b * (NN_ + 16) + d] + atomicAdd(&cur[b * NN_ + d], 1);
    srcs[b * NE + pos] = ei[e];
    eav[b * NE + pos] = ea[e];
}

// ---------------- GAT per-dst aggregation (writes hi/lo bf16 g) ----------------
__global__ __launch_bounds__(64) void k_gat(
    const int* __restrict__ srcs, const float* __restrict__ eav,
    const int* __restrict__ rows, const float* __restrict__ x,
    const float* __restrict__ a_s, const float* __restrict__ a_d,
    const float* __restrict__ dote, const float* __restrict__ meansum,
    __hip_bfloat16* __restrict__ gH, __hip_bfloat16* __restrict__ gL)
{
    int n = blockIdx.x;
    int lane = threadIdx.x;
    __shared__ float xb[64][32];
    __shared__ float eb[64][8];
    __shared__ float denb[8];

    float adn[NH], dt[NH];
#pragma unroll
    for (int h = 0; h < NH; ++h) { adn[h] = a_d[n * NH + h]; dt[h] = dote[h]; }
    float mean_attr = meansum[0] * (1.0f / NE);

    const int hOwn = lane >> 3;
    const int kOwn = (lane & 7) * 4;

    float acc0, acc1, acc2, acc3;
    {
        float al = a_s[n * NH + hOwn] + adn[hOwn] + mean_attr * dt[hOwn];
        al = al > 0.f ? al : 0.2f * al;
        float es = __expf(al);
        float xv0 = (kOwn + 0 < INF) ? x[n * INF + kOwn + 0] : 0.f;
        float xv1 = (kOwn + 1 < INF) ? x[n * INF + kOwn + 1] : 0.f;
        float xv2 = (kOwn + 2 < INF) ? x[n * INF + kOwn + 2] : 0.f;
        float xv3 = (kOwn + 3 < INF) ? x[n * INF + kOwn + 3] : ((kOwn + 3 == 31) ? 1.f : 0.f);
        acc0 = es * xv0; acc1 = es * xv1; acc2 = es * xv2; acc3 = es * xv3;
    }

    int e0 = rows[n], e1 = rows[n + 1];
    for (int base = e0; base < e1; base += 64) {
        int m = e1 - base; if (m > 64) m = 64;
        if (lane < m) {
            int sidx = srcs[base + lane];
            float ea = eav[base + lane];
            const float4* xr = (const float4*)(x + sidx * INF);
#pragma unroll
            for (int q = 0; q < 7; ++q) ((float4*)&xb[lane][0])[q] = xr[q];
            xb[lane][28] = 0.f; xb[lane][29] = 0.f; xb[lane][30] = 0.f; xb[lane][31] = 1.f;
            const float* asr = a_s + sidx * NH;
#pragma unroll
            for (int h = 0; h < NH; ++h) {
                float al = asr[h] + adn[h] + ea * dt[h];
                al = al > 0.f ? al : 0.2f * al;
                eb[lane][h] = __expf(al);
            }
        }
        __syncthreads();
        for (int j = 0; j < m; ++j) {
            float e = eb[j][hOwn];
            float4 xv = *(const float4*)&xb[j][kOwn];
            acc0 += e * xv.x; acc1 += e * xv.y; acc2 += e * xv.z; acc3 += e * xv.w;
        }
        __syncthreads();
    }

    if ((lane & 7) == 7) denb[hOwn] = acc3;
    __syncthreads();
    float inv = 1.0f / denb[hOwn];
    size_t gr = (size_t)n * KK + hOwn * INF + kOwn;
    if (kOwn + 0 < INF) split_store(acc0 * inv, gH, gL, gr + 0);
    if (kOwn + 1 < INF) split_store(acc1 * inv, gH, gL, gr + 1);
    if (kOwn + 2 < INF) split_store(acc2 * inv, gH, gL, gr + 2);
    if (kOwn + 3 < INF) split_store(acc3 * inv, gH, gL, gr + 3);
}

// ---------------- bf16x3-split MFMA GEMM ----------------
// C[m,n] = sum_k A[m,k]*B[n,k]  with A = Ahi+Alo, B = Bhi+Blo (bf16 pairs).
// acc += hi*hi + hi*lo + lo*hi  (3 MFMAs, ~fp32 accuracy).
// Block: 256 thr = 4 waves, BM=128 (wave owns 32 rows), BN=64.
// Batched via blockIdx.z: A/B advance by aOffZ/bOffZ elems, C column by cOffZ.
template<bool RELU>
__global__ __launch_bounds__(256) void k_mgemm(
    const __hip_bfloat16* __restrict__ Ahi_, const __hip_bfloat16* __restrict__ Alo_, int lda, int aOffZ,
    const __hip_bfloat16* __restrict__ Bhi_, const __hip_bfloat16* __restrict__ Blo_, int ldb, int bOffZ,
    const float* __restrict__ bias,
    float* __restrict__ Cf, int ldcf,
    __hip_bfloat16* __restrict__ Chi, __hip_bfloat16* __restrict__ Clo, int ldch, int cOffZ,
    int M, int N, int K)
{
    int z = blockIdx.z;
    const short* Ah = (const short*)Ahi_ + (size_t)z * aOffZ;
    const short* Al = (const short*)Alo_ + (size_t)z * aOffZ;
    const short* Bh = (const short*)Bhi_ + (size_t)z * bOffZ;
    const short* Bl = (const short*)Blo_ + (size_t)z * bOffZ;
    int wave = threadIdx.x >> 6, lane = threadIdx.x & 63;
    int l16 = lane & 15, lgrp = lane >> 4;
    int m0 = blockIdx.x * 128 + wave * 32;
    int n0 = blockIdx.y * 64;

    f32x4 acc[2][4];
#pragma unroll
    for (int i = 0; i < 2; ++i)
#pragma unroll
        for (int j = 0; j < 4; ++j) acc[i][j] = (f32x4){0.f, 0.f, 0.f, 0.f};

    int nrow[4]; bool nval[4];
#pragma unroll
    for (int ns = 0; ns < 4; ++ns) { nrow[ns] = n0 + ns * 16 + l16; nval[ns] = nrow[ns] < N; }

    for (int k0 = 0; k0 < K; k0 += 32) {
        size_t ka = (size_t)k0 + lgrp * 8;
        bf16x8 ah0 = *(const bf16x8*)(Ah + (size_t)(m0 + l16) * lda + ka);
        bf16x8 ah1 = *(const bf16x8*)(Ah + (size_t)(m0 + 16 + l16) * lda + ka);
        bf16x8 al0 = *(const bf16x8*)(Al + (size_t)(m0 + l16) * lda + ka);
        bf16x8 al1 = *(const bf16x8*)(Al + (size_t)(m0 + 16 + l16) * lda + ka);
        bf16x8 bh[4], bl[4];
#pragma unroll
        for (int ns = 0; ns < 4; ++ns) {
            bh[ns] = (bf16x8){0, 0, 0, 0, 0, 0, 0, 0};
            bl[ns] = (bf16x8){0, 0, 0, 0, 0, 0, 0, 0};
            if (nval[ns]) {
                bh[ns] = *(const bf16x8*)(Bh + (size_t)nrow[ns] * ldb + ka);
                bl[ns] = *(const bf16x8*)(Bl + (size_t)nrow[ns] * ldb + ka);
            }
        }
#pragma unroll
        for (int ns = 0; ns < 4; ++ns) {
            acc[0][ns] = __builtin_amdgcn_mfma_f32_16x16x32_bf16(ah0, bh[ns], acc[0][ns], 0, 0, 0);
            acc[0][ns] = __builtin_amdgcn_mfma_f32_16x16x32_bf16(ah0, bl[ns], acc[0][ns], 0, 0, 0);
            acc[0][ns] = __builtin_amdgcn_mfma_f32_16x16x32_bf16(al0, bh[ns], acc[0][ns], 0, 0, 0);
            acc[1][ns] = __builtin_amdgcn_mfma_f32_16x16x32_bf16(ah1, bh[ns], acc[1][ns], 0, 0, 0);
            acc[1][ns] = __builtin_amdgcn_mfma_f32_16x16x32_bf16(ah1, bl[ns], acc[1][ns], 0, 0, 0);
            acc[1][ns] = __builtin_amdgcn_mfma_f32_16x16x32_bf16(al1, bh[ns], acc[1][ns], 0, 0, 0);
        }
    }

#pragma unroll
    for (int ms = 0; ms < 2; ++ms)
#pragma unroll
        for (int ns = 0; ns < 4; ++ns)
#pragma unroll
            for (int r = 0; r < 4; ++r) {
                int m = m0 + ms * 16 + lgrp * 4 + r;
                int n = n0 + ns * 16 + l16;
                if (n >= N) continue;
                float v = acc[ms][ns][r];
                if (bias) v += bias[n];
                if (RELU) v = v > 0.f ? v : 0.f;
                if (Cf) Cf[(size_t)m * ldcf + n] = v;
                if (Chi) split_store(v, Chi, Clo, (size_t)m * ldch + (size_t)z * cOffZ + n);
            }
}

// ---------------- LSTM elementwise ----------------
__global__ void k_lstm(const float* __restrict__ gates, float* __restrict__ hout,
                       __hip_bfloat16* __restrict__ ccH, __hip_bfloat16* __restrict__ ccL)
{
    int i = blockIdx.x * blockDim.x + threadIdx.x;
    if (i >= NN_ * HID) return;
    int n = i >> 8, j = i & 255;
    const float* gr = gates + (size_t)n * 1024;
    float gi = gr[j], gg = gr[512 + j], go = gr[768 + j];
    float c = (1.f / (1.f + __expf(-gi))) * tanhf(gg);
    float h = (1.f / (1.f + __expf(-go))) * tanhf(c);
    hout[i] = h;
    split_store(h, ccH, ccL, (size_t)n * 512 + j);
}

// ---------------- MHA: bf16 MFMA flash attention ----------------
__global__ void k_cvt(const float* __restrict__ qkv,
                      __hip_bfloat16* __restrict__ Qb, __hip_bfloat16* __restrict__ Kb,
                      __hip_bfloat16* __restrict__ Vt)
{
    int i = blockIdx.x * blockDim.x + threadIdx.x;
    int n = i >> 8, c = i & 255;
    int h = c >> 6, d = c & 63;
    const float* row = qkv + (size_t)n * 768;
    Qb[((size_t)h * NN_ + n) * 64 + d] = __float2bfloat16(row[c] * 0.125f);
    Kb[((size_t)h * NN_ + n) * 64 + d] = __float2bfloat16(row[256 + c]);
    Vt[((size_t)h * 64 + d) * NN_ + n] = __float2bfloat16(row[512 + c]);
}

__global__ __launch_bounds__(256) void k_attn_mfma(
    const __hip_bfloat16* __restrict__ Qb, const __hip_bfloat16* __restrict__ Kb,
    const __hip_bfloat16* __restrict__ Vt,
    float* __restrict__ num, float* __restrict__ den)
{
    __shared__ __hip_bfloat16 plds[4][512];
    int tid = threadIdx.x;
    int wave = tid >> 6, lane = tid & 63;
    int l16 = lane & 15, lgrp = lane >> 4;
    int h = blockIdx.y, split = blockIdx.z;
    int q0 = blockIdx.x * 64 + wave * 16;
    int kbase = split * 1024;

    const short* Qs = (const short*)Qb;
    const short* Ks = (const short*)Kb;
    const short* Vs = (const short*)Vt;

    bf16x8 qf0 = *(const bf16x8*)(Qs + ((size_t)h * NN_ + q0 + l16) * 64 + lgrp * 8);
    bf16x8 qf1 = *(const bf16x8*)(Qs + ((size_t)h * NN_ + q0 + l16) * 64 + 32 + lgrp * 8);

    f32x4 oacc[4];
#pragma unroll
    for (int dc = 0; dc < 4; ++dc) oacc[dc] = (f32x4){0.f, 0.f, 0.f, 0.f};
    float dn0 = 0.f, dn1 = 0.f, dn2 = 0.f, dn3 = 0.f;

    __hip_bfloat16* myp = plds[wave];

    for (int kt = 0; kt < 32; ++kt) {
        int k0 = kbase + kt * 32;
        bf16x8 kf00 = *(const bf16x8*)(Ks + ((size_t)h * NN_ + k0 + l16) * 64 + lgrp * 8);
        bf16x8 kf01 = *(const bf16x8*)(Ks + ((size_t)h * NN_ + k0 + l16) * 64 + 32 + lgrp * 8);
        bf16x8 kf10 = *(const bf16x8*)(Ks + ((size_t)h * NN_ + k0 + 16 + l16) * 64 + lgrp * 8);
        bf16x8 kf11 = *(const bf16x8*)(Ks + ((size_t)h * NN_ + k0 + 16 + l16) * 64 + 32 + lgrp * 8);
        f32x4 s0 = (f32x4){0.f, 0.f, 0.f, 0.f};
        f32x4 s1 = (f32x4){0.f, 0.f, 0.f, 0.f};
        s0 = __builtin_amdgcn_mfma_f32_16x16x32_bf16(qf0, kf00, s0, 0, 0, 0);
        s0 = __builtin_amdgcn_mfma_f32_16x16x32_bf16(qf1, kf01, s0, 0, 0, 0);
        s1 = __builtin_amdgcn_mfma_f32_16x16x32_bf16(qf0, kf10, s1, 0, 0, 0);
        s1 = __builtin_amdgcn_mfma_f32_16x16x32_bf16(qf1, kf11, s1, 0, 0, 0);
#pragma unroll
        for (int r = 0; r < 4; ++r) {
            float e0 = __expf(s0[r]);
            float e1 = __expf(s1[r]);
            if (r == 0) { dn0 += e0 + e1; } else if (r == 1) { dn1 += e0 + e1; }
            else if (r == 2) { dn2 += e0 + e1; } else { dn3 += e0 + e1; }
            int row = lgrp * 4 + r;
            int sw = ((row >> 1) & 3) << 3;
            myp[(row * 32 + l16) ^ sw]        = __float2bfloat16(e0);
            myp[(row * 32 + 16 + l16) ^ sw]   = __float2bfloat16(e1);
        }
        int rsw = ((l16 >> 1) & 3) << 3;
        bf16x8 pa = *(const bf16x8*)&myp[(l16 * 32 + lgrp * 8) ^ rsw];
#pragma unroll
        for (int dc = 0; dc < 4; ++dc) {
            bf16x8 vf = *(const bf16x8*)(Vs + ((size_t)h * 64 + dc * 16 + l16) * NN_ + k0 + lgrp * 8);
            oacc[dc] = __builtin_amdgcn_mfma_f32_16x16x32_bf16(pa, vf, oacc[dc], 0, 0, 0);
        }
    }

    dn0 += __shfl_xor(dn0, 1); dn0 += __shfl_xor(dn0, 2); dn0 += __shfl_xor(dn0, 4); dn0 += __shfl_xor(dn0, 8);
    dn1 += __shfl_xor(dn1, 1); dn1 += __shfl_xor(dn1, 2); dn1 += __shfl_xor(dn1, 4); dn1 += __shfl_xor(dn1, 8);
    dn2 += __shfl_xor(dn2, 1); dn2 += __shfl_xor(dn2, 2); dn2 += __shfl_xor(dn2, 4); dn2 += __shfl_xor(dn2, 8);
    dn3 += __shfl_xor(dn3, 1); dn3 += __shfl_xor(dn3, 2); dn3 += __shfl_xor(dn3, 4); dn3 += __shfl_xor(dn3, 8);

    size_t pb = (size_t)(split * 4 + h) * NN_;
#pragma unroll
    for (int dc = 0; dc < 4; ++dc)
#pragma unroll
        for (int r = 0; r < 4; ++r)
            num[(pb + q0 + lgrp * 4 + r) * 64 + dc * 16 + l16] = oacc[dc][r];
    if (l16 == 0) {
        den[pb + q0 + lgrp * 4 + 0] = dn0;
        den[pb + q0 + lgrp * 4 + 1] = dn1;
        den[pb + q0 + lgrp * 4 + 2] = dn2;
        den[pb + q0 + lgrp * 4 + 3] = dn3;
    }
}

__global__ void k_merge(const float* __restrict__ num, const float* __restrict__ den,
                        __hip_bfloat16* __restrict__ aoH, __hip_bfloat16* __restrict__ aoL)
{
    int i = blockIdx.x * blockDim.x + threadIdx.x;
    int n = i >> 8, c = i & 255;
    int h = c >> 6, d = c & 63;
    float ns = 0.f, dsum = 0.f;
#pragma unroll
    for (int s = 0; s < 4; ++s) {
        ns += num[((size_t)(s * 4 + h) * NN_ + n) * 64 + d];
        dsum += den[(size_t)(s * 4 + h) * NN_ + n];
    }
    split_store(ns / dsum, aoH, aoL, (size_t)n * 256 + c);
}

// ---------------- launch ----------------
extern "C" void kernel_launch(void* const* d_in, const int* in_sizes, int n_in,
                              void* d_out, int out_size, void* d_ws, size_t ws_size,
                              hipStream_t stream)
{
    const float* x      = (const float*)d_in[0];
    const int*   ei_t   = (const int*)d_in[1];
    const int*   ei_c   = (const int*)d_in[2];
    const float* ea_t   = (const float*)d_in[3];
    const float* ea_c   = (const float*)d_in[4];
    const float* W_t    = (const float*)d_in[5];
    const float* asrc_t = (const float*)d_in[6];
    const float* adst_t = (const float*)d_in[7];
    const float* We_t   = (const float*)d_in[8];
    const float* aedg_t = (const float*)d_in[9];
    const float* b_t    = (const float*)d_in[10];
    const float* W_c    = (const float*)d_in[11];
    const float* asrc_c = (const float*)d_in[12];
    const float* adst_c = (const float*)d_in[13];
    const float* We_c   = (const float*)d_in[14];
    const float* aedg_c = (const float*)d_in[15];
    const float* b_c    = (const float*)d_in[16];
    const float* Wih    = (const float*)d_in[17];
    const float* bih    = (const float*)d_in[19];
    const float* bhh    = (const float*)d_in[20];
    const float* min_w  = (const float*)d_in[21];
    const float* min_b  = (const float*)d_in[22];
    const float* mout_w = (const float*)d_in[23];
    const float* mout_b = (const float*)d_in[24];
    const float* fus_w  = (const float*)d_in[25];
    const float* fus_b  = (const float*)d_in[26];
    const float* out_w  = (const float*)d_in[27];
    const float* out_b  = (const float*)d_in[28];
    float* outp = (float*)d_out;

    char* W = (char*)d_ws;
    size_t off = 0;
    auto alloc = [&](size_t bytes) { size_t r = off; off += (bytes + 255) & ~(size_t)255; return r; };
    size_t oMean  = alloc(2 * 4);
    size_t oCnt   = alloc(2 * NN_ * 4);
    size_t oCur   = alloc(2 * NN_ * 4);
    size_t zeroBytes = off;
    size_t oRows  = alloc(2 * (NN_ + 16) * 4);
    size_t oSrcs  = alloc(2 * NE * 4);
    size_t oEav   = alloc(2 * NE * 4);
    size_t oWa    = alloc(4 * INF * NH * 4);
    size_t oDote  = alloc(2 * NH * 4);
    size_t oAsd   = alloc(4 * NN_ * NH * 4);
    size_t oBg    = alloc(1024 * 4);
    size_t oGH    = alloc((size_t)2 * NN_ * KK * 2);   // g hi (both branches)
    size_t oGL    = alloc((size_t)2 * NN_ * KK * 2);   // g lo
    size_t oMtH   = alloc((size_t)1024 * KK * 2);
    size_t oMtL   = alloc((size_t)1024 * KK * 2);
    size_t oBctH  = alloc((size_t)CC * KK * 2);
    size_t oBctL  = alloc((size_t)CC * KK * 2);
    size_t oWihH  = alloc((size_t)1024 * HC * 2);      // 4.19MB, reused as concatHi
    size_t oWihL  = alloc((size_t)1024 * HC * 2);      // reused as concatLo
    size_t oWtH   = alloc((size_t)INF * HC * 2);
    size_t oWtL   = alloc((size_t)INF * HC * 2);
    size_t oMinH  = alloc((size_t)768 * HID * 2);
    size_t oMinL  = alloc((size_t)768 * HID * 2);
    size_t oMoutH = alloc((size_t)HID * HID * 2);
    size_t oMoutL = alloc((size_t)HID * HID * 2);
    size_t oFusH  = alloc((size_t)HID * 512 * 2);
    size_t oFusL  = alloc((size_t)HID * 512 * 2);
    size_t oOutwH = alloc((size_t)128 * HID * 2);
    size_t oOutwL = alloc((size_t)128 * HID * 2);
    size_t oGates = alloc((size_t)NN_ * 1024 * 4);     // 16.8MB; reused as qkv, then num
    size_t oHcH   = alloc((size_t)NN_ * HID * 2);      // reused as hfusHi
    size_t oHcL   = alloc((size_t)NN_ * HID * 2);      // reused as hfusLo
    size_t oQb    = alloc((size_t)4 * NN_ * 64 * 2);
    size_t oKb    = alloc((size_t)4 * NN_ * 64 * 2);
    size_t oVt    = alloc((size_t)4 * NN_ * 64 * 2);
    size_t oDen   = alloc((size_t)16 * NN_ * 4);
    size_t oQkv   = oGates;   // gates dead after k_lstm
    size_t oNum   = oGates;   // qkv dead after k_cvt
    size_t oCcH   = oWihH;    // WihSplit dead after M-GEMM
    size_t oCcL   = oWihL;
    size_t oAoH   = oGH;      // g dead after gates & hc GEMMs
    size_t oAoL   = oGL;
    size_t oHfH   = oHcH;     // hc dead after qkv GEMM
    size_t oHfL   = oHcL;
    (void)ws_size; (void)in_sizes; (void)n_in; (void)out_size;

    hipMemsetAsync(W, 0, zeroBytes, stream);

    k_small_pre<<<4, 256, 0, stream>>>(W_t, asrc_t, adst_t, We_t, aedg_t,
                                       W_c, asrc_c, adst_c, We_c, aedg_c,
                                       (float*)(W + oWa), (float*)(W + oDote));
    k_mean<<<2 * NE / 256, 256, 0, stream>>>(ea_t, ea_c, (float*)(W + oMean));
    k_hist<<<2 * NE / 256, 256, 0, stream>>>(ei_t, ei_c, (int*)(W + oCnt));
    k_scan<<<2, 1024, 0, stream>>>((int*)(W + oCnt), (int*)(W + oRows));
    k_scatter<<<2 * NE / 256, 256, 0, stream>>>(ei_t, ei_c, ea_t, ea_c,
                                                (int*)(W + oRows), (int*)(W + oCur),
                                                (int*)(W + oSrcs), (float*)(W + oEav));
    k_as_ad<<<512, 256, 0, stream>>>(x, (float*)(W + oWa), (float*)(W + oAsd));
    k_biasg<<<4, 256, 0, stream>>>(b_t, Wih, bih, bhh, (float*)(W + oBg));
    k_split_all<<<10080, 256, 0, stream>>>(
        Wih,    (__hip_bfloat16*)(W + oWihH),  (__hip_bfloat16*)(W + oWihL),
        W_t,    (__hip_bfloat16*)(W + oWtH),   (__hip_bfloat16*)(W + oWtL),
        min_w,  (__hip_bfloat16*)(W + oMinH),  (__hip_bfloat16*)(W + oMinL),
        mout_w, (__hip_bfloat16*)(W + oMoutH), (__hip_bfloat16*)(W + oMoutL),
        fus_w,  (__hip_bfloat16*)(W + oFusH),  (__hip_bfloat16*)(W + oFusL),
        out_w,  (__hip_bfloat16*)(W + oOutwH), (__hip_bfloat16*)(W + oOutwL));
    k_bct<<<CC * KK / 256, 256, 0, stream>>>(W_c, (__hip_bfloat16*)(W + oBctH),
                                             (__hip_bfloat16*)(W + oBctL));

    k_gat<<<NN_, 64, 0, stream>>>((int*)(W + oSrcs), (float*)(W + oEav), (int*)(W + oRows), x,
                                  (float*)(W + oAsd),                (float*)(W + oAsd) + NN_ * NH,
                                  (float*)(W + oDote),               (float*)(W + oMean),
                                  (__hip_bfloat16*)(W + oGH),        (__hip_bfloat16*)(W + oGL));
    k_gat<<<NN_, 64, 0, stream>>>((int*)(W + oSrcs) + NE, (float*)(W + oEav) + NE,
                                  (int*)(W + oRows) + (NN_ + 16), x,
                                  (float*)(W + oAsd) + 2 * NN_ * NH, (float*)(W + oAsd) + 3 * NN_ * NH,
                                  (float*)(W + oDote) + NH,          (float*)(W + oMean) + 1,
                                  (__hip_bfloat16*)(W + oGH) + (size_t)NN_ * KK,
                                  (__hip_bfloat16*)(W + oGL) + (size_t)NN_ * KK);

    // Mt[j][h*28+k] = sum_c Wih[j][h*256+c] * Wt[k][h*256+c]  — batched over h
    {
        dim3 grid(1024 / 128, 1, 8);
        k_mgemm<false><<<grid, 256, 0, stream>>>(
            (__hip_bfloat16*)(W + oWihH), (__hip_bfloat16*)(W + oWihL), HC, CC,
            (__hip_bfloat16*)(W + oWtH),  (__hip_bfloat16*)(W + oWtL),  HC, CC,
            nullptr, nullptr, 0,
            (__hip_bfloat16*)(W + oMtH), (__hip_bfloat16*)(W + oMtL), KK, INF,
            1024, INF, CC);
    }
    // gates = g_t @ Mt^T + bias_g
    {
        dim3 grid(NN_ / 128, 1024 / 64, 1);
        k_mgemm<false><<<grid, 256, 0, stream>>>(
            (__hip_bfloat16*)(W + oGH), (__hip_bfloat16*)(W + oGL), KK, 0,
            (__hip_bfloat16*)(W + oMtH), (__hip_bfloat16*)(W + oMtL), KK, 0,
            (float*)(W + oBg), (float*)(W + oGates), 1024,
            nullptr, nullptr, 0, 0,
            NN_, 1024, KK);
    }
    k_lstm<<<NN_ * HID / 256, 256, 0, stream>>>((float*)(W + oGates), outp + 524288,
                                                (__hip_bfloat16*)(W + oCcH), (__hip_bfloat16*)(W + oCcL));
    // h_c = g_c @ Bct^T + b_c  -> hi/lo
    {
        dim3 grid(NN_ / 128, HID / 64, 1);
        k_mgemm<false><<<grid, 256, 0, stream>>>(
            (__hip_bfloat16*)(W + oGH) + (size_t)NN_ * KK, (__hip_bfloat16*)(W + oGL) + (size_t)NN_ * KK, KK, 0,
            (__hip_bfloat16*)(W + oBctH), (__hip_bfloat16*)(W + oBctL), KK, 0,
            b_c, nullptr, 0,
            (__hip_bfloat16*)(W + oHcH), (__hip_bfloat16*)(W + oHcL), HID, 0,
            NN_, HID, KK);
    }
    // qkv = h_c @ min_w^T + min_b  (fp32)
    {
        dim3 grid(NN_ / 128, 768 / 64, 1);
        k_mgemm<false><<<grid, 256, 0, stream>>>(
            (__hip_bfloat16*)(W + oHcH), (__hip_bfloat16*)(W + oHcL), HID, 0,
            (__hip_bfloat16*)(W + oMinH), (__hip_bfloat16*)(W + oMinL), HID, 0,
            min_b, (float*)(W + oQkv), 768,
            nullptr, nullptr, 0, 0,
            NN_, 768, HID);
    }
    k_cvt<<<NN_, 256, 0, stream>>>((float*)(W + oQkv),
                                   (__hip_bfloat16*)(W + oQb), (__hip_bfloat16*)(W + oKb),
                                   (__hip_bfloat16*)(W + oVt));
    {
        dim3 grid(NN_ / 64, 4, 4);
        k_attn_mfma<<<grid, 256, 0, stream>>>(
            (__hip_bfloat16*)(W + oQb), (__hip_bfloat16*)(W + oKb), (__hip_bfloat16*)(W + oVt),
            (float*)(W + oNum), (float*)(W + oDen));
    }
    k_merge<<<NN_, 256, 0, stream>>>((float*)(W + oNum), (float*)(W + oDen),
                                     (__hip_bfloat16*)(W + oAoH), (__hip_bfloat16*)(W + oAoL));
    // out-proj: concat[:,256:512] (hi/lo) + h_causal (fp32 d_out)
    {
        dim3 grid(NN_ / 128, HID / 64, 1);
        k_mgemm<false><<<grid, 256, 0, stream>>>(
            (__hip_bfloat16*)(W + oAoH), (__hip_bfloat16*)(W + oAoL), HID, 0,
            (__hip_bfloat16*)(W + oMoutH), (__hip_bfloat16*)(W + oMoutL), HID, 0,
            mout_b, outp + 524288 + 1048576, 256,
            (__hip_bfloat16*)(W + oCcH) + 256, (__hip_bfloat16*)(W + oCcL) + 256, 512, 0,
            NN_, HID, HID);
    }
    // fusion: relu(concat @ fus_w^T + fus_b) -> hi/lo
    {
        dim3 grid(NN_ / 128, HID / 64, 1);
        k_mgemm<true><<<grid, 256, 0, stream>>>(
            (__hip_bfloat16*)(W + oCcH), (__hip_bfloat16*)(W + oCcL), 512, 0,
            (__hip_bfloat16*)(W + oFusH), (__hip_bfloat16*)(W + oFusL), 512, 0,
            fus_b, nullptr, 0,
            (__hip_bfloat16*)(W + oHfH), (__hip_bfloat16*)(W + oHfL), HID, 0,
            NN_, HID, 512);
    }
    // out = hfus @ out_w^T + out_b  (fp32 d_out)
    {
        dim3 grid(NN_ / 128, 128 / 64, 1);
        k_mgemm<false><<<grid, 256, 0, stream>>>(
            (__hip_bfloat16*)(W + oHfH), (__hip_bfloat16*)(W + oHfL), HID, 0,
            (__hip_bfloat16*)(W + oOutwH), (__hip_bfloat16*)(W + oOutwL), HID, 0,
            out_b, outp, 128,
            nullptr, nullptr, 0, 0,
            NN_, 128, HID);
    }
}

// Round 4
// 518.201 us; speedup vs baseline: 3.4013x; 1.1689x over previous
//
#include <hip/hip_runtime.h>
#include <hip/hip_bf16.h>

// ---------------- problem constants ----------------
constexpr int NN_ = 4096;     // nodes
constexpr int INF = 28;       // input features
constexpr int NH  = 8;        // GAT heads
constexpr int CC  = 256;      // channels per head
constexpr int HC  = 2048;     // NH*CC
constexpr int HID = 256;
constexpr int NE  = 131072;   // edges per branch
constexpr int KK  = NH * INF; // 224

typedef short bf16x8 __attribute__((ext_vector_type(8)));
typedef float f32x4 __attribute__((ext_vector_type(4)));

__device__ inline void split_store(float v, __hip_bfloat16* H, __hip_bfloat16* L, size_t idx)
{
    __hip_bfloat16 h = __float2bfloat16(v);
    H[idx] = h;
    L[idx] = __float2bfloat16(v - __bfloat162float(h));
}

__device__ inline float wave_sum(float v)
{
    v += __shfl_xor(v, 1);  v += __shfl_xor(v, 2);  v += __shfl_xor(v, 4);
    v += __shfl_xor(v, 8);  v += __shfl_xor(v, 16); v += __shfl_xor(v, 32);
    return v;
}

// ---------------- small precompute (wave-per-output) ----------------
// w < 896:  wa[b][kind][k][h] = sum_c W_b[k, h*CC+c] * a_{src/dst}_b[h,c]
// 896..911: dote[b][h] = sum_c We_b[h*CC+c] * a_edge_b[h,c]
__global__ void k_small_pre(const float* __restrict__ Wt, const float* __restrict__ ast,
                            const float* __restrict__ adt, const float* __restrict__ Wet,
                            const float* __restrict__ aet,
                            const float* __restrict__ Wc, const float* __restrict__ asc,
                            const float* __restrict__ adc, const float* __restrict__ Wec,
                            const float* __restrict__ aec,
                            float* __restrict__ wa, float* __restrict__ dote)
{
    int w = (blockIdx.x * blockDim.x + threadIdx.x) >> 6;
    int lane = threadIdx.x & 63;
    if (w < 2 * 2 * INF * NH) {
        int b = w / (2 * INF * NH);
        int r = w % (2 * INF * NH);
        int kind = r / (INF * NH);
        int r2 = r % (INF * NH);
        int k = r2 / NH, h = r2 % NH;
        const float* Wm = b ? Wc : Wt;
        const float* a  = b ? (kind ? adc : asc) : (kind ? adt : ast);
        float s = 0.f;
        for (int c = lane; c < CC; c += 64) s += Wm[k * HC + h * CC + c] * a[h * CC + c];
        s = wave_sum(s);
        if (lane == 0) wa[((b * 2 + kind) * INF + k) * NH + h] = s;
    } else if (w < 2 * 2 * INF * NH + 16) {
        int j = w - 2 * 2 * INF * NH;
        int b = j / NH, h = j % NH;
        const float* We = b ? Wec : Wet;
        const float* a  = b ? aec : aet;
        float s = 0.f;
        for (int c = lane; c < CC; c += 64) s += We[h * CC + c] * a[h * CC + c];
        s = wave_sum(s);
        if (lane == 0) dote[b * NH + h] = s;
    }
}

// ---------------- fused mean-sum + dst histogram ----------------
__global__ void k_mean_hist(const float* __restrict__ ea_t, const float* __restrict__ ea_c,
                            const int* __restrict__ ei_t, const int* __restrict__ ei_c,
                            float* __restrict__ meansum, int* __restrict__ cnt)
{
    int i = blockIdx.x * blockDim.x + threadIdx.x;   // grid exactly 2*NE
    int b = i / NE, e = i - b * NE;
    float v = (b ? ea_c : ea_t)[e];
    for (int off = 32; off; off >>= 1) v += __shfl_down(v, off);
    if ((threadIdx.x & 63) == 0) atomicAdd(&meansum[b], v);
    const int* ei = b ? ei_c : ei_t;
    atomicAdd(&cnt[b * NN_ + ei[NE + e]], 1);
}

__global__ void k_as_ad(const float* __restrict__ x, const float* __restrict__ wa,
                        float* __restrict__ asd)
{
    int i = blockIdx.x * blockDim.x + threadIdx.x;
    if (i >= 4 * NN_ * NH) return;
    int bk = i / (NN_ * NH);
    int r = i % (NN_ * NH);
    int n = r / NH, h = r % NH;
    const float* W = wa + bk * INF * NH;
    const float* xr = x + n * INF;
    float s = 0.f;
#pragma unroll
    for (int k = 0; k < INF; ++k) s += xr[k] * W[k * NH + h];
    asd[(bk * NN_ + n) * NH + h] = s;
}

// bias_g[j] = bih[j] + bhh[j] + sum_c b_t[c]*Wih[j,c]  — one wave per j
__global__ void k_biasg(const float* __restrict__ bt, const float* __restrict__ Wih,
                        const float* __restrict__ bih, const float* __restrict__ bhh,
                        float* __restrict__ bg)
{
    int j = (blockIdx.x * blockDim.x + threadIdx.x) >> 6;
    int lane = threadIdx.x & 63;
    if (j >= 1024) return;
    const float* w = Wih + (size_t)j * HC;
    float s = 0.f;
    for (int c = lane; c < HC; c += 64) s += bt[c] * w[c];
    s = wave_sum(s);
    if (lane == 0) bg[j] = s + bih[j] + bhh[j];
}

// fused hi/lo split of static weights + Bct build (one launch)
__global__ void k_split_all(const float* __restrict__ Wih,  __hip_bfloat16* WihH,  __hip_bfloat16* WihL,
                            const float* __restrict__ Wt,   __hip_bfloat16* WtH,   __hip_bfloat16* WtL,
                            const float* __restrict__ minw, __hip_bfloat16* minH,  __hip_bfloat16* minL,
                            const float* __restrict__ moutw,__hip_bfloat16* moutH, __hip_bfloat16* moutL,
                            const float* __restrict__ fusw, __hip_bfloat16* fusH,  __hip_bfloat16* fusL,
                            const float* __restrict__ outw, __hip_bfloat16* outH,  __hip_bfloat16* outL,
                            const float* __restrict__ Wc,   __hip_bfloat16* BH,    __hip_bfloat16* BL)
{
    int i = blockIdx.x * blockDim.x + threadIdx.x;
    if (i < 2097152)                   split_store(Wih[i],            WihH,  WihL,  i);
    else if (i < 2097152 + 57344)      split_store(Wt[i - 2097152],   WtH,   WtL,   i - 2097152);
    else if (i < 2154496 + 196608)     split_store(minw[i - 2154496], minH,  minL,  i - 2154496);
    else if (i < 2351104 + 65536)      split_store(moutw[i - 2351104],moutH, moutL, i - 2351104);
    else if (i < 2416640 + 131072)     split_store(fusw[i - 2416640], fusH,  fusL,  i - 2416640);
    else if (i < 2547712 + 32768)      split_store(outw[i - 2547712], outH,  outL,  i - 2547712);
    else if (i < 2580480 + 57344) {    // Bct[c][kk] = Wc[k, h*CC+c]/8
        int i2 = i - 2580480;
        int c = i2 / KK, kk = i2 % KK;
        int h = kk / INF, k = kk % INF;
        split_store(Wc[k * HC + h * CC + c] * 0.125f, BH, BL, i2);
    }
}

// ---------------- CSR build ----------------
__global__ __launch_bounds__(1024) void k_scan(const int* __restrict__ cnt, int* __restrict__ rows)
{
    int b = blockIdx.x;
    const int* c = cnt + b * NN_;
    int* r = rows + b * (NN_ + 16);
    __shared__ int ts[1024];
    int t = threadIdx.x;
    int v0 = c[t * 4], v1 = c[t * 4 + 1], v2 = c[t * 4 + 2], v3 = c[t * 4 + 3];
    ts[t] = v0 + v1 + v2 + v3;
    __syncthreads();
    for (int off = 1; off < 1024; off <<= 1) {
        int add = (t >= off) ? ts[t - off] : 0;
        __syncthreads();
        ts[t] += add;
        __syncthreads();
    }
    int excl = (t == 0) ? 0 : ts[t - 1];
    r[t * 4 + 0] = excl; excl += v0;
    r[t * 4 + 1] = excl; excl += v1;
    r[t * 4 + 2] = excl; excl += v2;
    r[t * 4 + 3] = excl; excl += v3;
    if (t == 1023) r[NN_] = excl;
}

__global__ void k_scatter(const int* __restrict__ ei_t, const int* __restrict__ ei_c,
                          const float* __restrict__ ea_t, const float* __restrict__ ea_c,
                          const int* __restrict__ rows, int* __restrict__ cur,
                          int* __restrict__ srcs, float* __restrict__ eav)
{
    int i = blockIdx.x * blockDim.x + threadIdx.x;
    if (i >= 2 * NE) return;
    int b = i / NE, e = i - b * NE;
    const int* ei = b ? ei_c : ei_t;
    const float* ea = b ? ea_c : ea_t;
    int d = ei[NE + e];
    int pos = rows[b * (NN_ + 16) + d] + atomicAdd(&cur[b * NN_ + d], 1);
    srcs[b * NE + pos] = ei[e];
    eav[b * NE + pos] = ea[e];
}

// ---------------- GAT per-dst aggregation (writes hi/lo bf16 g) ----------------
__global__ __launch_bounds__(64) void k_gat(
    const int* __restrict__ srcs, const float* __restrict__ eav,
    const int* __restrict__ rows, const float* __restrict__ x,
    const float* __restrict__ a_s, const float* __restrict__ a_d,
    const float* __restrict__ dote, const float* __restrict__ meansum,
    __hip_bfloat16* __restrict__ gH, __hip_bfloat16* __restrict__ gL)
{
    int n = blockIdx.x;
    int lane = threadIdx.x;
    __shared__ float xb[64][32];
    __shared__ float eb[64][8];
    __shared__ float denb[8];

    float adn[NH], dt[NH];
#pragma unroll
    for (int h = 0; h < NH; ++h) { adn[h] = a_d[n * NH + h]; dt[h] = dote[h]; }
    float mean_attr = meansum[0] * (1.0f / NE);

    const int hOwn = lane >> 3;
    const int kOwn = (lane & 7) * 4;

    float acc0, acc1, acc2, acc3;
    {
        float al = a_s[n * NH + hOwn] + adn[hOwn] + mean_attr * dt[hOwn];
        al = al > 0.f ? al : 0.2f * al;
        float es = __expf(al);
        float xv0 = (kOwn + 0 < INF) ? x[n * INF + kOwn + 0] : 0.f;
        float xv1 = (kOwn + 1 < INF) ? x[n * INF + kOwn + 1] : 0.f;
        float xv2 = (kOwn + 2 < INF) ? x[n * INF + kOwn + 2] : 0.f;
        float xv3 = (kOwn + 3 < INF) ? x[n * INF + kOwn + 3] : ((kOwn + 3 == 31) ? 1.f : 0.f);
        acc0 = es * xv0; acc1 = es * xv1; acc2 = es * xv2; acc3 = es * xv3;
    }

    int e0 = rows[n], e1 = rows[n + 1];
    for (int base = e0; base < e1; base += 64) {
        int m = e1 - base; if (m > 64) m = 64;
        if (lane < m) {
            int sidx = srcs[base + lane];
            float ea = eav[base + lane];
            const float4* xr = (const float4*)(x + sidx * INF);
#pragma unroll
            for (int q = 0; q < 7; ++q) ((float4*)&xb[lane][0])[q] = xr[q];
            xb[lane][28] = 0.f; xb[lane][29] = 0.f; xb[lane][30] = 0.f; xb[lane][31] = 1.f;
            const float* asr = a_s + sidx * NH;
#pragma unroll
            for (int h = 0; h < NH; ++h) {
                float al = asr[h] + adn[h] + ea * dt[h];
                al = al > 0.f ? al : 0.2f * al;
                eb[lane][h] = __expf(al);
            }
        }
        __syncthreads();
        for (int j = 0; j < m; ++j) {
            float e = eb[j][hOwn];
            float4 xv = *(const float4*)&xb[j][kOwn];
            acc0 += e * xv.x; acc1 += e * xv.y; acc2 += e * xv.z; acc3 += e * xv.w;
        }
        __syncthreads();
    }

    if ((lane & 7) == 7) denb[hOwn] = acc3;
    __syncthreads();
    float inv = 1.0f / denb[hOwn];
    size_t gr = (size_t)n * KK + hOwn * INF + kOwn;
    if (kOwn + 0 < INF) split_store(acc0 * inv, gH, gL, gr + 0);
    if (kOwn + 1 < INF) split_store(acc1 * inv, gH, gL, gr + 1);
    if (kOwn + 2 < INF) split_store(acc2 * inv, gH, gL, gr + 2);
    if (kOwn + 3 < INF) split_store(acc3 * inv, gH, gL, gr + 3);
}

// ---------------- bf16x3-split MFMA GEMM ----------------
template<bool RELU>
__global__ __launch_bounds__(256) void k_mgemm(
    const __hip_bfloat16* __restrict__ Ahi_, const __hip_bfloat16* __restrict__ Alo_, int lda, int aOffZ,
    const __hip_bfloat16* __restrict__ Bhi_, const __hip_bfloat16* __restrict__ Blo_, int ldb, int bOffZ,
    const float* __restrict__ bias,
    float* __restrict__ Cf, int ldcf,
    __hip_bfloat16* __restrict__ Chi, __hip_bfloat16* __restrict__ Clo, int ldch, int cOffZ,
    int M, int N, int K)
{
    int z = blockIdx.z;
    const short* Ah = (const short*)Ahi_ + (size_t)z * aOffZ;
    const short* Al = (const short*)Alo_ + (size_t)z * aOffZ;
    const short* Bh = (const short*)Bhi_ + (size_t)z * bOffZ;
    const short* Bl = (const short*)Blo_ + (size_t)z * bOffZ;
    int wave = threadIdx.x >> 6, lane = threadIdx.x & 63;
    int l16 = lane & 15, lgrp = lane >> 4;
    int m0 = blockIdx.x * 128 + wave * 32;
    int n0 = blockIdx.y * 64;

    f32x4 acc[2][4];
#pragma unroll
    for (int i = 0; i < 2; ++i)
#pragma unroll
        for (int j = 0; j < 4; ++j) acc[i][j] = (f32x4){0.f, 0.f, 0.f, 0.f};

    int nrow[4]; bool nval[4];
#pragma unroll
    for (int ns = 0; ns < 4; ++ns) { nrow[ns] = n0 + ns * 16 + l16; nval[ns] = nrow[ns] < N; }

    for (int k0 = 0; k0 < K; k0 += 32) {
        size_t ka = (size_t)k0 + lgrp * 8;
        bf16x8 ah0 = *(const bf16x8*)(Ah + (size_t)(m0 + l16) * lda + ka);
        bf16x8 ah1 = *(const bf16x8*)(Ah + (size_t)(m0 + 16 + l16) * lda + ka);
        bf16x8 al0 = *(const bf16x8*)(Al + (size_t)(m0 + l16) * lda + ka);
        bf16x8 al1 = *(const bf16x8*)(Al + (size_t)(m0 + 16 + l16) * lda + ka);
        bf16x8 bh[4], bl[4];
#pragma unroll
        for (int ns = 0; ns < 4; ++ns) {
            bh[ns] = (bf16x8){0, 0, 0, 0, 0, 0, 0, 0};
            bl[ns] = (bf16x8){0, 0, 0, 0, 0, 0, 0, 0};
            if (nval[ns]) {
                bh[ns] = *(const bf16x8*)(Bh + (size_t)nrow[ns] * ldb + ka);
                bl[ns] = *(const bf16x8*)(Bl + (size_t)nrow[ns] * ldb + ka);
            }
        }
#pragma unroll
        for (int ns = 0; ns < 4; ++ns) {
            acc[0][ns] = __builtin_amdgcn_mfma_f32_16x16x32_bf16(ah0, bh[ns], acc[0][ns], 0, 0, 0);
            acc[0][ns] = __builtin_amdgcn_mfma_f32_16x16x32_bf16(ah0, bl[ns], acc[0][ns], 0, 0, 0);
            acc[0][ns] = __builtin_amdgcn_mfma_f32_16x16x32_bf16(al0, bh[ns], acc[0][ns], 0, 0, 0);
            acc[1][ns] = __builtin_amdgcn_mfma_f32_16x16x32_bf16(ah1, bh[ns], acc[1][ns], 0, 0, 0);
            acc[1][ns] = __builtin_amdgcn_mfma_f32_16x16x32_bf16(ah1, bl[ns], acc[1][ns], 0, 0, 0);
            acc[1][ns] = __builtin_amdgcn_mfma_f32_16x16x32_bf16(al1, bh[ns], acc[1][ns], 0, 0, 0);
        }
    }

#pragma unroll
    for (int ms = 0; ms < 2; ++ms)
#pragma unroll
        for (int ns = 0; ns < 4; ++ns)
#pragma unroll
            for (int r = 0; r < 4; ++r) {
                int m = m0 + ms * 16 + lgrp * 4 + r;
                int n = n0 + ns * 16 + l16;
                if (n >= N) continue;
                float v = acc[ms][ns][r];
                if (bias) v += bias[n];
                if (RELU) v = v > 0.f ? v : 0.f;
                if (Cf) Cf[(size_t)m * ldcf + n] = v;
                if (Chi) split_store(v, Chi, Clo, (size_t)m * ldch + (size_t)z * cOffZ + n);
            }
}

// ---------------- LSTM elementwise ----------------
__global__ void k_lstm(const float* __restrict__ gates, float* __restrict__ hout,
                       __hip_bfloat16* __restrict__ ccH, __hip_bfloat16* __restrict__ ccL)
{
    int i = blockIdx.x * blockDim.x + threadIdx.x;
    if (i >= NN_ * HID) return;
    int n = i >> 8, j = i & 255;
    const float* gr = gates + (size_t)n * 1024;
    float gi = gr[j], gg = gr[512 + j], go = gr[768 + j];
    float c = (1.f / (1.f + __expf(-gi))) * tanhf(gg);
    float h = (1.f / (1.f + __expf(-go))) * tanhf(c);
    hout[i] = h;
    split_store(h, ccH, ccL, (size_t)n * 512 + j);
}

// ---------------- MHA: bf16 MFMA flash attention ----------------
__global__ void k_cvt(const float* __restrict__ qkv,
                      __hip_bfloat16* __restrict__ Qb, __hip_bfloat16* __restrict__ Kb,
                      __hip_bfloat16* __restrict__ Vt)
{
    int i = blockIdx.x * blockDim.x + threadIdx.x;
    int n = i >> 8, c = i & 255;
    int h = c >> 6, d = c & 63;
    const float* row = qkv + (size_t)n * 768;
    Qb[((size_t)h * NN_ + n) * 64 + d] = __float2bfloat16(row[c] * 0.125f);
    Kb[((size_t)h * NN_ + n) * 64 + d] = __float2bfloat16(row[256 + c]);
    Vt[((size_t)h * 64 + d) * NN_ + n] = __float2bfloat16(row[512 + c]);
}

// grid (NN_/16, 4 heads), 512 thr = 8 waves. All waves share one 16-q-row tile;
// wave w covers keys [w*512, w*512+512). Partial (num,den) merged in LDS.
// No max-subtraction (logits ~ +/-0.01). Output written as hi/lo bf16 split.
__global__ __launch_bounds__(512) void k_attn_mfma(
    const __hip_bfloat16* __restrict__ Qb, const __hip_bfloat16* __restrict__ Kb,
    const __hip_bfloat16* __restrict__ Vt,
    __hip_bfloat16* __restrict__ aoH, __hip_bfloat16* __restrict__ aoL)
{
    __shared__ __hip_bfloat16 plds[8][512];
    __shared__ float redN[4][16][64];
    __shared__ float redD[4][16];
    int tid = threadIdx.x;
    int wave = tid >> 6, lane = tid & 63;
    int l16 = lane & 15, lgrp = lane >> 4;
    int h = blockIdx.y;
    int q0 = blockIdx.x * 16;
    int kbase = wave * 512;

    const short* Qs = (const short*)Qb;
    const short* Ks = (const short*)Kb;
    const short* Vs = (const short*)Vt;

    bf16x8 qf0 = *(const bf16x8*)(Qs + ((size_t)h * NN_ + q0 + l16) * 64 + lgrp * 8);
    bf16x8 qf1 = *(const bf16x8*)(Qs + ((size_t)h * NN_ + q0 + l16) * 64 + 32 + lgrp * 8);

    f32x4 oacc[4];
#pragma unroll
    for (int dc = 0; dc < 4; ++dc) oacc[dc] = (f32x4){0.f, 0.f, 0.f, 0.f};
    float dn[4] = {0.f, 0.f, 0.f, 0.f};

    __hip_bfloat16* myp = plds[wave];

    for (int kt = 0; kt < 16; ++kt) {
        int k0 = kbase + kt * 32;
        // K fragments first (oldest in vmcnt queue -> S-MFMAs wait only on these)
        bf16x8 kf00 = *(const bf16x8*)(Ks + ((size_t)h * NN_ + k0 + l16) * 64 + lgrp * 8);
        bf16x8 kf01 = *(const bf16x8*)(Ks + ((size_t)h * NN_ + k0 + l16) * 64 + 32 + lgrp * 8);
        bf16x8 kf10 = *(const bf16x8*)(Ks + ((size_t)h * NN_ + k0 + 16 + l16) * 64 + lgrp * 8);
        bf16x8 kf11 = *(const bf16x8*)(Ks + ((size_t)h * NN_ + k0 + 16 + l16) * 64 + 32 + lgrp * 8);
        // V fragments issued early; consumed only at the PV MFMAs
        bf16x8 vf[4];
#pragma unroll
        for (int dc = 0; dc < 4; ++dc)
            vf[dc] = *(const bf16x8*)(Vs + ((size_t)h * 64 + dc * 16 + l16) * NN_ + k0 + lgrp * 8);

        f32x4 s0 = (f32x4){0.f, 0.f, 0.f, 0.f};
        f32x4 s1 = (f32x4){0.f, 0.f, 0.f, 0.f};
        s0 = __builtin_amdgcn_mfma_f32_16x16x32_bf16(qf0, kf00, s0, 0, 0, 0);
        s0 = __builtin_amdgcn_mfma_f32_16x16x32_bf16(qf1, kf01, s0, 0, 0, 0);
        s1 = __builtin_amdgcn_mfma_f32_16x16x32_bf16(qf0, kf10, s1, 0, 0, 0);
        s1 = __builtin_amdgcn_mfma_f32_16x16x32_bf16(qf1, kf11, s1, 0, 0, 0);
#pragma unroll
        for (int r = 0; r < 4; ++r) {
            float e0 = __expf(s0[r]);
            float e1 = __expf(s1[r]);
            dn[r] += e0 + e1;
            int row = lgrp * 4 + r;
            int sw = ((row >> 1) & 3) << 3;
            myp[(row * 32 + l16) ^ sw]        = __float2bfloat16(e0);
            myp[(row * 32 + 16 + l16) ^ sw]   = __float2bfloat16(e1);
        }
        int rsw = ((l16 >> 1) & 3) << 3;
        bf16x8 pa = *(const bf16x8*)&myp[(l16 * 32 + lgrp * 8) ^ rsw];
#pragma unroll
        for (int dc = 0; dc < 4; ++dc)
            oacc[dc] = __builtin_amdgcn_mfma_f32_16x16x32_bf16(pa, vf[dc], oacc[dc], 0, 0, 0);
    }

    // reduce den across the 16 lanes sharing a row group
#pragma unroll
    for (int r = 0; r < 4; ++r) {
        dn[r] += __shfl_xor(dn[r], 1); dn[r] += __shfl_xor(dn[r], 2);
        dn[r] += __shfl_xor(dn[r], 4); dn[r] += __shfl_xor(dn[r], 8);
    }

    // LDS merge tree: 8 -> 4 -> 2 -> 1
    if (wave >= 4) {
        int s = wave - 4;
#pragma unroll
        for (int dc = 0; dc < 4; ++dc)
#pragma unroll
            for (int r = 0; r < 4; ++r) redN[s][lgrp * 4 + r][dc * 16 + l16] = oacc[dc][r];
        if (l16 == 0) { redD[s][lgrp * 4 + 0] = dn[0]; redD[s][lgrp * 4 + 1] = dn[1];
                        redD[s][lgrp * 4 + 2] = dn[2]; redD[s][lgrp * 4 + 3] = dn[3]; }
    }
    __syncthreads();
    if (wave < 4) {
#pragma unroll
        for (int dc = 0; dc < 4; ++dc)
#pragma unroll
            for (int r = 0; r < 4; ++r) oacc[dc][r] += redN[wave][lgrp * 4 + r][dc * 16 + l16];
#pragma unroll
        for (int r = 0; r < 4; ++r) dn[r] += redD[wave][lgrp * 4 + r];
    }
    __syncthreads();
    if (wave == 2 || wave == 3) {
        int s = wave - 2;
#pragma unroll
        for (int dc = 0; dc < 4; ++dc)
#pragma unroll
            for (int r = 0; r < 4; ++r) redN[s][lgrp * 4 + r][dc * 16 + l16] = oacc[dc][r];
        if (l16 == 0) { redD[s][lgrp * 4 + 0] = dn[0]; redD[s][lgrp * 4 + 1] = dn[1];
                        redD[s][lgrp * 4 + 2] = dn[2]; redD[s][lgrp * 4 + 3] = dn[3]; }
    }
    __syncthreads();
    if (wave < 2) {
#pragma unroll
        for (int dc = 0; dc < 4; ++dc)
#pragma unroll
            for (int r = 0; r < 4; ++r) oacc[dc][r] += redN[wave][lgrp * 4 + r][dc * 16 + l16];
#pragma unroll
        for (int r = 0; r < 4; ++r) dn[r] += redD[wave][lgrp * 4 + r];
    }
    __syncthreads();
    if (wave == 1) {
#pragma unroll
        for (int dc = 0; dc < 4; ++dc)
#pragma unroll
            for (int r = 0; r < 4; ++r) redN[0][lgrp * 4 + r][dc * 16 + l16] = oacc[dc][r];
        if (l16 == 0) { redD[0][lgrp * 4 + 0] = dn[0]; redD[0][lgrp * 4 + 1] = dn[1];
                        redD[0][lgrp * 4 + 2] = dn[2]; redD[0][lgrp * 4 + 3] = dn[3]; }
    }
    __syncthreads();
    if (wave == 0) {
#pragma unroll
        for (int dc = 0; dc < 4; ++dc)
#pragma unroll
            for (int r = 0; r < 4; ++r) oacc[dc][r] += redN[0][lgrp * 4 + r][dc * 16 + l16];
        float inv[4];
#pragma unroll
        for (int r = 0; r < 4; ++r) inv[r] = 1.f / (dn[r] + redD[0][lgrp * 4 + r]);
#pragma unroll
        for (int dc = 0; dc < 4; ++dc)
#pragma unroll
            for (int r = 0; r < 4; ++r)
                split_store(oacc[dc][r] * inv[r], aoH, aoL,
                            (size_t)(q0 + lgrp * 4 + r) * 256 + h * 64 + dc * 16 + l16);
    }
}

// ---------------- launch ----------------
extern "C" void kernel_launch(void* const* d_in, const int* in_sizes, int n_in,
                              void* d_out, int out_size, void* d_ws, size_t ws_size,
                              hipStream_t stream)
{
    const float* x      = (const float*)d_in[0];
    const int*   ei_t   = (const int*)d_in[1];
    const int*   ei_c   = (const int*)d_in[2];
    const float* ea_t   = (const float*)d_in[3];
    const float* ea_c   = (const float*)d_in[4];
    const float* W_t    = (const float*)d_in[5];
    const float* asrc_t = (const float*)d_in[6];
    const float* adst_t = (const float*)d_in[7];
    const float* We_t   = (const float*)d_in[8];
    const float* aedg_t = (const float*)d_in[9];
    const float* b_t    = (const float*)d_in[10];
    const float* W_c    = (const float*)d_in[11];
    const float* asrc_c = (const float*)d_in[12];
    const float* adst_c = (const float*)d_in[13];
    const float* We_c   = (const float*)d_in[14];
    const float* aedg_c = (const float*)d_in[15];
    const float* b_c    = (const float*)d_in[16];
    const float* Wih    = (const float*)d_in[17];
    const float* bih    = (const float*)d_in[19];
    const float* bhh    = (const float*)d_in[20];
    const float* min_w  = (const float*)d_in[21];
    const float* min_b  = (const float*)d_in[22];
    const float* mout_w = (const float*)d_in[23];
    const float* mout_b = (const float*)d_in[24];
    const float* fus_w  = (const float*)d_in[25];
    const float* fus_b  = (const float*)d_in[26];
    const float* out_w  = (const float*)d_in[27];
    const float* out_b  = (const float*)d_in[28];
    float* outp = (float*)d_out;

    char* W = (char*)d_ws;
    size_t off = 0;
    auto alloc = [&](size_t bytes) { size_t r = off; off += (bytes + 255) & ~(size_t)255; return r; };
    size_t oMean  = alloc(2 * 4);
    size_t oCnt   = alloc(2 * NN_ * 4);
    size_t oCur   = alloc(2 * NN_ * 4);
    size_t zeroBytes = off;
    size_t oRows  = alloc(2 * (NN_ + 16) * 4);
    size_t oSrcs  = alloc(2 * NE * 4);
    size_t oEav   = alloc(2 * NE * 4);
    size_t oWa    = alloc(4 * INF * NH * 4);
    size_t oDote  = alloc(2 * NH * 4);
    size_t oAsd   = alloc(4 * NN_ * NH * 4);
    size_t oBg    = alloc(1024 * 4);
    size_t oGH    = alloc((size_t)2 * NN_ * KK * 2);
    size_t oGL    = alloc((size_t)2 * NN_ * KK * 2);
    size_t oMtH   = alloc((size_t)1024 * KK * 2);
    size_t oMtL   = alloc((size_t)1024 * KK * 2);
    size_t oBctH  = alloc((size_t)CC * KK * 2);
    size_t oBctL  = alloc((size_t)CC * KK * 2);
    size_t oWihH  = alloc((size_t)1024 * HC * 2);      // reused as concatHi
    size_t oWihL  = alloc((size_t)1024 * HC * 2);      // reused as concatLo
    size_t oWtH   = alloc((size_t)INF * HC * 2);
    size_t oWtL   = alloc((size_t)INF * HC * 2);
    size_t oMinH  = alloc((size_t)768 * HID * 2);
    size_t oMinL  = alloc((size_t)768 * HID * 2);
    size_t oMoutH = alloc((size_t)HID * HID * 2);
    size_t oMoutL = alloc((size_t)HID * HID * 2);
    size_t oFusH  = alloc((size_t)HID * 512 * 2);
    size_t oFusL  = alloc((size_t)HID * 512 * 2);
    size_t oOutwH = alloc((size_t)128 * HID * 2);
    size_t oOutwL = alloc((size_t)128 * HID * 2);
    size_t oGates = alloc((size_t)NN_ * 1024 * 4);     // reused as qkv
    size_t oHcH   = alloc((size_t)NN_ * HID * 2);      // reused as hfusHi
    size_t oHcL   = alloc((size_t)NN_ * HID * 2);      // reused as hfusLo
    size_t oQb    = alloc((size_t)4 * NN_ * 64 * 2);
    size_t oKb    = alloc((size_t)4 * NN_ * 64 * 2);
    size_t oVt    = alloc((size_t)4 * NN_ * 64 * 2);
    size_t oQkv   = oGates;   // gates dead after k_lstm
    size_t oCcH   = oWihH;    // WihSplit dead after Mt GEMM
    size_t oCcL   = oWihL;
    size_t oAoH   = oGH;      // g dead after gates & hc GEMMs
    size_t oAoL   = oGL;
    size_t oHfH   = oHcH;     // hc dead after qkv GEMM
    size_t oHfL   = oHcL;
    (void)ws_size; (void)in_sizes; (void)n_in; (void)out_size;

    hipMemsetAsync(W, 0, zeroBytes, stream);

    k_small_pre<<<228, 256, 0, stream>>>(W_t, asrc_t, adst_t, We_t, aedg_t,
                                         W_c, asrc_c, adst_c, We_c, aedg_c,
                                         (float*)(W + oWa), (float*)(W + oDote));
    k_mean_hist<<<2 * NE / 256, 256, 0, stream>>>(ea_t, ea_c, ei_t, ei_c,
                                                  (float*)(W + oMean), (int*)(W + oCnt));
    k_scan<<<2, 1024, 0, stream>>>((int*)(W + oCnt), (int*)(W + oRows));
    k_scatter<<<2 * NE / 256, 256, 0, stream>>>(ei_t, ei_c, ea_t, ea_c,
                                                (int*)(W + oRows), (int*)(W + oCur),
                                                (int*)(W + oSrcs), (float*)(W + oEav));
    k_as_ad<<<512, 256, 0, stream>>>(x, (float*)(W + oWa), (float*)(W + oAsd));
    k_biasg<<<256, 256, 0, stream>>>(b_t, Wih, bih, bhh, (float*)(W + oBg));
    k_split_all<<<10304, 256, 0, stream>>>(
        Wih,    (__hip_bfloat16*)(W + oWihH),  (__hip_bfloat16*)(W + oWihL),
        W_t,    (__hip_bfloat16*)(W + oWtH),   (__hip_bfloat16*)(W + oWtL),
        min_w,  (__hip_bfloat16*)(W + oMinH),  (__hip_bfloat16*)(W + oMinL),
        mout_w, (__hip_bfloat16*)(W + oMoutH), (__hip_bfloat16*)(W + oMoutL),
        fus_w,  (__hip_bfloat16*)(W + oFusH),  (__hip_bfloat16*)(W + oFusL),
        out_w,  (__hip_bfloat16*)(W + oOutwH), (__hip_bfloat16*)(W + oOutwL),
        W_c,    (__hip_bfloat16*)(W + oBctH),  (__hip_bfloat16*)(W + oBctL));

    k_gat<<<NN_, 64, 0, stream>>>((int*)(W + oSrcs), (float*)(W + oEav), (int*)(W + oRows), x,
                                  (float*)(W + oAsd),                (float*)(W + oAsd) + NN_ * NH,
                                  (float*)(W + oDote),               (float*)(W + oMean),
                                  (__hip_bfloat16*)(W + oGH),        (__hip_bfloat16*)(W + oGL));
    k_gat<<<NN_, 64, 0, stream>>>((int*)(W + oSrcs) + NE, (float*)(W + oEav) + NE,
                                  (int*)(W + oRows) + (NN_ + 16), x,
                                  (float*)(W + oAsd) + 2 * NN_ * NH, (float*)(W + oAsd) + 3 * NN_ * NH,
                                  (float*)(W + oDote) + NH,          (float*)(W + oMean) + 1,
                                  (__hip_bfloat16*)(W + oGH) + (size_t)NN_ * KK,
                                  (__hip_bfloat16*)(W + oGL) + (size_t)NN_ * KK);

    // Mt[j][h*28+k] = sum_c Wih[j][h*256+c] * Wt[k][h*256+c]  — batched over h
    {
        dim3 grid(1024 / 128, 1, 8);
        k_mgemm<false><<<grid, 256, 0, stream>>>(
            (__hip_bfloat16*)(W + oWihH), (__hip_bfloat16*)(W + oWihL), HC, CC,
            (__hip_bfloat16*)(W + oWtH),  (__hip_bfloat16*)(W + oWtL),  HC, CC,
            nullptr, nullptr, 0,
            (__hip_bfloat16*)(W + oMtH), (__hip_bfloat16*)(W + oMtL), KK, INF,
            1024, INF, CC);
    }
    // gates = g_t @ Mt^T + bias_g
    {
        dim3 grid(NN_ / 128, 1024 / 64, 1);
        k_mgemm<false><<<grid, 256, 0, stream>>>(
            (__hip_bfloat16*)(W + oGH), (__hip_bfloat16*)(W + oGL), KK, 0,
            (__hip_bfloat16*)(W + oMtH), (__hip_bfloat16*)(W + oMtL), KK, 0,
            (float*)(W + oBg), (float*)(W + oGates), 1024,
            nullptr, nullptr, 0, 0,
            NN_, 1024, KK);
    }
    k_lstm<<<NN_ * HID / 256, 256, 0, stream>>>((float*)(W + oGates), outp + 524288,
                                                (__hip_bfloat16*)(W + oCcH), (__hip_bfloat16*)(W + oCcL));
    // h_c = g_c @ Bct^T + b_c  -> hi/lo
    {
        dim3 grid(NN_ / 128, HID / 64, 1);
        k_mgemm<false><<<grid, 256, 0, stream>>>(
            (__hip_bfloat16*)(W + oGH) + (size_t)NN_ * KK, (__hip_bfloat16*)(W + oGL) + (size_t)NN_ * KK, KK, 0,
            (__hip_bfloat16*)(W + oBctH), (__hip_bfloat16*)(W + oBctL), KK, 0,
            b_c, nullptr, 0,
            (__hip_bfloat16*)(W + oHcH), (__hip_bfloat16*)(W + oHcL), HID, 0,
            NN_, HID, KK);
    }
    // qkv = h_c @ min_w^T + min_b  (fp32)
    {
        dim3 grid(NN_ / 128, 768 / 64, 1);
        k_mgemm<false><<<grid, 256, 0, stream>>>(
            (__hip_bfloat16*)(W + oHcH), (__hip_bfloat16*)(W + oHcL), HID, 0,
            (__hip_bfloat16*)(W + oMinH), (__hip_bfloat16*)(W + oMinL), HID, 0,
            min_b, (float*)(W + oQkv), 768,
            nullptr, nullptr, 0, 0,
            NN_, 768, HID);
    }
    k_cvt<<<NN_, 256, 0, stream>>>((float*)(W + oQkv),
                                   (__hip_bfloat16*)(W + oQb), (__hip_bfloat16*)(W + oKb),
                                   (__hip_bfloat16*)(W + oVt));
    // attention: 8-wave blocks, k-split in LDS, writes hi/lo directly
    {
        dim3 grid(NN_ / 16, 4);
        k_attn_mfma<<<grid, 512, 0, stream>>>(
            (__hip_bfloat16*)(W + oQb), (__hip_bfloat16*)(W + oKb), (__hip_bfloat16*)(W + oVt),
            (__hip_bfloat16*)(W + oAoH), (__hip_bfloat16*)(W + oAoL));
    }
    // out-proj: concat[:,256:512] (hi/lo) + h_causal (fp32 d_out)
    {
        dim3 grid(NN_ / 128, HID / 64, 1);
        k_mgemm<false><<<grid, 256, 0, stream>>>(
            (__hip_bfloat16*)(W + oAoH), (__hip_bfloat16*)(W + oAoL), HID, 0,
            (__hip_bfloat16*)(W + oMoutH), (__hip_bfloat16*)(W + oMoutL), HID, 0,
            mout_b, outp + 524288 + 1048576, 256,
            (__hip_bfloat16*)(W + oCcH) + 256, (__hip_bfloat16*)(W + oCcL) + 256, 512, 0,
            NN_, HID, HID);
    }
    // fusion: relu(concat @ fus_w^T + fus_b) -> hi/lo
    {
        dim3 grid(NN_ / 128, HID / 64, 1);
        k_mgemm<true><<<grid, 256, 0, stream>>>(
            (__hip_bfloat16*)(W + oCcH), (__hip_bfloat16*)(W + oCcL), 512, 0,
            (__hip_bfloat16*)(W + oFusH), (__hip_bfloat16*)(W + oFusL), 512, 0,
            fus_b, nullptr, 0,
            (__hip_bfloat16*)(W + oHfH), (__hip_bfloat16*)(W + oHfL), HID, 0,
            NN_, HID, 512);
    }
    // out = hfus @ out_w^T + out_b  (fp32 d_out)
    {
        dim3 grid(NN_ / 128, 128 / 64, 1);
        k_mgemm<false><<<grid, 256, 0, stream>>>(
            (__hip_bfloat16*)(W + oHfH), (__hip_bfloat16*)(W + oHfL), HID, 0,
            (__hip_bfloat16*)(W + oOutwH), (__hip_bfloat16*)(W + oOutwL), HID, 0,
            out_b, outp, 128,
            nullptr, nullptr, 0, 0,
            NN_, 128, HID);
    }
}

// Round 5
// 449.079 us; speedup vs baseline: 3.9249x; 1.1539x over previous
//
#include <hip/hip_runtime.h>
#include <hip/hip_bf16.h>

// ---------------- problem constants ----------------
constexpr int NN_ = 4096;     // nodes
constexpr int INF = 28;       // input features
constexpr int NH  = 8;        // GAT heads
constexpr int CC  = 256;      // channels per head
constexpr int HC  = 2048;     // NH*CC
constexpr int HID = 256;
constexpr int NE  = 131072;   // edges per branch
constexpr int KK  = NH * INF; // 224

typedef short bf16x8 __attribute__((ext_vector_type(8)));
typedef short bf16x4 __attribute__((ext_vector_type(4)));
typedef float f32x4 __attribute__((ext_vector_type(4)));

__device__ inline void split_store(float v, __hip_bfloat16* H, __hip_bfloat16* L, size_t idx)
{
    __hip_bfloat16 h = __float2bfloat16(v);
    H[idx] = h;
    L[idx] = __float2bfloat16(v - __bfloat162float(h));
}

__device__ inline short f2bs(float v)
{
    __hip_bfloat16 h = __float2bfloat16(v);
    return *reinterpret_cast<short*>(&h);
}

__device__ inline float wave_sum(float v)
{
    v += __shfl_xor(v, 1);  v += __shfl_xor(v, 2);  v += __shfl_xor(v, 4);
    v += __shfl_xor(v, 8);  v += __shfl_xor(v, 16); v += __shfl_xor(v, 32);
    return v;
}

// ---------------- stage 1: split_all + small_pre + biasg + mean_hist (one launch) ----------------
// block ranges: [0,10304) split_all | [10304,10532) small_pre | [10532,10788) biasg | [10788,11812) mean_hist
__global__ void k_stage1(
    // split_all
    const float* __restrict__ Wih,  __hip_bfloat16* WihH,  __hip_bfloat16* WihL,
    const float* __restrict__ Wt,   __hip_bfloat16* WtH,   __hip_bfloat16* WtL,
    const float* __restrict__ minw, __hip_bfloat16* minH,  __hip_bfloat16* minL,
    const float* __restrict__ moutw,__hip_bfloat16* moutH, __hip_bfloat16* moutL,
    const float* __restrict__ fusw, __hip_bfloat16* fusH,  __hip_bfloat16* fusL,
    const float* __restrict__ outw, __hip_bfloat16* outH,  __hip_bfloat16* outL,
    const float* __restrict__ Wc,   __hip_bfloat16* BH,    __hip_bfloat16* BL,
    // small_pre
    const float* __restrict__ ast, const float* __restrict__ adt,
    const float* __restrict__ Wet, const float* __restrict__ aet,
    const float* __restrict__ asc, const float* __restrict__ adc,
    const float* __restrict__ Wec, const float* __restrict__ aec,
    float* __restrict__ wa, float* __restrict__ dote,
    // biasg
    const float* __restrict__ bt, const float* __restrict__ bih, const float* __restrict__ bhh,
    float* __restrict__ bg,
    // mean_hist
    const float* __restrict__ ea_t, const float* __restrict__ ea_c,
    const int* __restrict__ ei_t, const int* __restrict__ ei_c,
    float* __restrict__ meansum, int* __restrict__ cnt)
{
    int bx = blockIdx.x;
    if (bx < 10304) {
        int i = bx * 256 + threadIdx.x;
        if (i < 2097152)                   split_store(Wih[i],            WihH,  WihL,  i);
        else if (i < 2097152 + 57344)      split_store(Wt[i - 2097152],   WtH,   WtL,   i - 2097152);
        else if (i < 2154496 + 196608)     split_store(minw[i - 2154496], minH,  minL,  i - 2154496);
        else if (i < 2351104 + 65536)      split_store(moutw[i - 2351104],moutH, moutL, i - 2351104);
        else if (i < 2416640 + 131072)     split_store(fusw[i - 2416640], fusH,  fusL,  i - 2416640);
        else if (i < 2547712 + 32768)      split_store(outw[i - 2547712], outH,  outL,  i - 2547712);
        else if (i < 2580480 + 57344) {    // Bct[c][kk] = Wc[k, h*CC+c]/8
            int i2 = i - 2580480;
            int c = i2 / KK, kk = i2 % KK;
            int h = kk / INF, k = kk % INF;
            split_store(Wc[k * HC + h * CC + c] * 0.125f, BH, BL, i2);
        }
    } else if (bx < 10532) {
        int w = ((bx - 10304) * 256 + threadIdx.x) >> 6;
        int lane = threadIdx.x & 63;
        if (w < 2 * 2 * INF * NH) {
            int b = w / (2 * INF * NH);
            int r = w % (2 * INF * NH);
            int kind = r / (INF * NH);
            int r2 = r % (INF * NH);
            int k = r2 / NH, h = r2 % NH;
            const float* Wm = b ? Wc : Wt;
            const float* a  = b ? (kind ? adc : asc) : (kind ? adt : ast);
            float s = 0.f;
            for (int c = lane; c < CC; c += 64) s += Wm[k * HC + h * CC + c] * a[h * CC + c];
            s = wave_sum(s);
            if (lane == 0) wa[((b * 2 + kind) * INF + k) * NH + h] = s;
        } else if (w < 2 * 2 * INF * NH + 16) {
            int j = w - 2 * 2 * INF * NH;
            int b = j / NH, h = j % NH;
            const float* We = b ? Wec : Wet;
            const float* a  = b ? aec : aet;
            float s = 0.f;
            for (int c = lane; c < CC; c += 64) s += We[h * CC + c] * a[h * CC + c];
            s = wave_sum(s);
            if (lane == 0) dote[b * NH + h] = s;
        }
    } else if (bx < 10788) {
        int j = ((bx - 10532) * 256 + threadIdx.x) >> 6;
        int lane = threadIdx.x & 63;
        if (j < 1024) {
            const float* w = Wih + (size_t)j * HC;
            float s = 0.f;
            for (int c = lane; c < HC; c += 64) s += bt[c] * w[c];
            s = wave_sum(s);
            if (lane == 0) bg[j] = s + bih[j] + bhh[j];
        }
    } else {
        int i = (bx - 10788) * 256 + threadIdx.x;
        int b = i / NE, e = i - b * NE;
        float v = (b ? ea_c : ea_t)[e];
        for (int off = 32; off; off >>= 1) v += __shfl_down(v, off);
        if ((threadIdx.x & 63) == 0) atomicAdd(&meansum[b], v);
        const int* ei = b ? ei_c : ei_t;
        atomicAdd(&cnt[b * NN_ + ei[NE + e]], 1);
    }
}

// ---------------- stage 2: as_ad + CSR scan (one launch) ----------------
// blocks [0,512) as_ad | [512,514) scan (256 thr, 16 elems/thread)
__global__ __launch_bounds__(256) void k_stage2(
    const float* __restrict__ x, const float* __restrict__ wa, float* __restrict__ asd,
    const int* __restrict__ cnt, int* __restrict__ rows)
{
    int bx = blockIdx.x;
    if (bx < 512) {
        int i = bx * 256 + threadIdx.x;
        int bk = i / (NN_ * NH);
        int r = i % (NN_ * NH);
        int n = r / NH, h = r % NH;
        const float* W = wa + bk * INF * NH;
        const float* xr = x + n * INF;
        float s = 0.f;
#pragma unroll
        for (int k = 0; k < INF; ++k) s += xr[k] * W[k * NH + h];
        asd[(bk * NN_ + n) * NH + h] = s;
    } else {
        int b = bx - 512;
        const float* dummy = x; (void)dummy;
        const int* c = cnt + b * NN_;
        int* r = rows + b * (NN_ + 16);
        __shared__ int ts[256];
        int t = threadIdx.x;
        int v[16]; int s = 0;
#pragma unroll
        for (int i = 0; i < 16; ++i) { v[i] = c[t * 16 + i]; s += v[i]; }
        ts[t] = s;
        __syncthreads();
        for (int off = 1; off < 256; off <<= 1) {
            int add = (t >= off) ? ts[t - off] : 0;
            __syncthreads();
            ts[t] += add;
            __syncthreads();
        }
        int excl = t ? ts[t - 1] : 0;
#pragma unroll
        for (int i = 0; i < 16; ++i) { r[t * 16 + i] = excl; excl += v[i]; }
        if (t == 255) r[NN_] = excl;
    }
}

__global__ void k_scatter(const int* __restrict__ ei_t, const int* __restrict__ ei_c,
                          const float* __restrict__ ea_t, const float* __restrict__ ea_c,
                          const int* __restrict__ rows, int* __restrict__ cur,
                          int* __restrict__ srcs, float* __restrict__ eav)
{
    int i = blockIdx.x * blockDim.x + threadIdx.x;
    if (i >= 2 * NE) return;
    int b = i / NE, e = i - b * NE;
    const int* ei = b ? ei_c : ei_t;
    const float* ea = b ? ea_c : ea_t;
    int d = ei[NE + e];
    int pos = rows[b * (NN_ + 16) + d] + atomicAdd(&cur[b * NN_ + d], 1);
    srcs[b * NE + pos] = ei[e];
    eav[b * NE + pos] = ea[e];
}

// ---------------- GAT per-dst aggregation, both branches in one grid ----------------
__global__ __launch_bounds__(64) void k_gat(
    const int* __restrict__ srcs, const float* __restrict__ eav,
    const int* __restrict__ rows, const float* __restrict__ x,
    const float* __restrict__ asd, const float* __restrict__ dote,
    const float* __restrict__ meansum,
    __hip_bfloat16* __restrict__ gH, __hip_bfloat16* __restrict__ gL)
{
    int b = blockIdx.x >> 12;           // branch
    int n = blockIdx.x & 4095;
    srcs += (size_t)b * NE; eav += (size_t)b * NE; rows += b * (NN_ + 16);
    const float* a_s = asd + (size_t)(2 * b) * NN_ * NH;
    const float* a_d = asd + (size_t)(2 * b + 1) * NN_ * NH;
    dote += b * NH;
    gH += (size_t)b * NN_ * KK; gL += (size_t)b * NN_ * KK;

    int lane = threadIdx.x;
    __shared__ float xb[64][32];
    __shared__ float eb[64][8];
    __shared__ float denb[8];

    float adn[NH], dt[NH];
#pragma unroll
    for (int h = 0; h < NH; ++h) { adn[h] = a_d[n * NH + h]; dt[h] = dote[h]; }
    float mean_attr = meansum[b] * (1.0f / NE);

    const int hOwn = lane >> 3;
    const int kOwn = (lane & 7) * 4;

    float acc0, acc1, acc2, acc3;
    {
        float al = a_s[n * NH + hOwn] + adn[hOwn] + mean_attr * dt[hOwn];
        al = al > 0.f ? al : 0.2f * al;
        float es = __expf(al);
        float xv0 = (kOwn + 0 < INF) ? x[n * INF + kOwn + 0] : 0.f;
        float xv1 = (kOwn + 1 < INF) ? x[n * INF + kOwn + 1] : 0.f;
        float xv2 = (kOwn + 2 < INF) ? x[n * INF + kOwn + 2] : 0.f;
        float xv3 = (kOwn + 3 < INF) ? x[n * INF + kOwn + 3] : ((kOwn + 3 == 31) ? 1.f : 0.f);
        acc0 = es * xv0; acc1 = es * xv1; acc2 = es * xv2; acc3 = es * xv3;
    }

    int e0 = rows[n], e1 = rows[n + 1];
    for (int base = e0; base < e1; base += 64) {
        int m = e1 - base; if (m > 64) m = 64;
        if (lane < m) {
            int sidx = srcs[base + lane];
            float ea = eav[base + lane];
            const float4* xr = (const float4*)(x + sidx * INF);
#pragma unroll
            for (int q = 0; q < 7; ++q) ((float4*)&xb[lane][0])[q] = xr[q];
            xb[lane][28] = 0.f; xb[lane][29] = 0.f; xb[lane][30] = 0.f; xb[lane][31] = 1.f;
            const float* asr = a_s + sidx * NH;
#pragma unroll
            for (int h = 0; h < NH; ++h) {
                float al = asr[h] + adn[h] + ea * dt[h];
                al = al > 0.f ? al : 0.2f * al;
                eb[lane][h] = __expf(al);
            }
        }
        __syncthreads();
        for (int j = 0; j < m; ++j) {
            float e = eb[j][hOwn];
            float4 xv = *(const float4*)&xb[j][kOwn];
            acc0 += e * xv.x; acc1 += e * xv.y; acc2 += e * xv.z; acc3 += e * xv.w;
        }
        __syncthreads();
    }

    if ((lane & 7) == 7) denb[hOwn] = acc3;
    __syncthreads();
    float inv = 1.0f / denb[hOwn];
    size_t gr = (size_t)n * KK + hOwn * INF + kOwn;
    if (kOwn + 0 < INF) split_store(acc0 * inv, gH, gL, gr + 0);
    if (kOwn + 1 < INF) split_store(acc1 * inv, gH, gL, gr + 1);
    if (kOwn + 2 < INF) split_store(acc2 * inv, gH, gL, gr + 2);
    if (kOwn + 3 < INF) split_store(acc3 * inv, gH, gL, gr + 3);
}

// ---------------- bf16x3-split MFMA GEMM ----------------
// MS=2: BM=128 (wave owns 32 rows); MS=1: BM=64. nSkip: if >0, n0 >= nSkip gets +256 (skip dead f-gate cols).
template<bool RELU, int MS>
__global__ __launch_bounds__(256) void k_mgemm(
    const __hip_bfloat16* __restrict__ Ahi_, const __hip_bfloat16* __restrict__ Alo_, int lda, int aOffZ,
    const __hip_bfloat16* __restrict__ Bhi_, const __hip_bfloat16* __restrict__ Blo_, int ldb, int bOffZ,
    const float* __restrict__ bias,
    float* __restrict__ Cf, int ldcf,
    __hip_bfloat16* __restrict__ Chi, __hip_bfloat16* __restrict__ Clo, int ldch, int cOffZ,
    int nSkip, int M, int N, int K)
{
    int z = blockIdx.z;
    const short* Ah = (const short*)Ahi_ + (size_t)z * aOffZ;
    const short* Al = (const short*)Alo_ + (size_t)z * aOffZ;
    const short* Bh = (const short*)Bhi_ + (size_t)z * bOffZ;
    const short* Bl = (const short*)Blo_ + (size_t)z * bOffZ;
    int wave = threadIdx.x >> 6, lane = threadIdx.x & 63;
    int l16 = lane & 15, lgrp = lane >> 4;
    int m0 = blockIdx.x * (64 * MS) + wave * (16 * MS);
    int n0 = blockIdx.y * 64;
    if (nSkip && n0 >= nSkip) n0 += 256;

    f32x4 acc[MS][4];
#pragma unroll
    for (int i = 0; i < MS; ++i)
#pragma unroll
        for (int j = 0; j < 4; ++j) acc[i][j] = (f32x4){0.f, 0.f, 0.f, 0.f};

    int nrow[4]; bool nval[4];
#pragma unroll
    for (int ns = 0; ns < 4; ++ns) { nrow[ns] = n0 + ns * 16 + l16; nval[ns] = nrow[ns] < N; }

    for (int k0 = 0; k0 < K; k0 += 32) {
        size_t ka = (size_t)k0 + lgrp * 8;
        bf16x8 ah[MS], al[MS];
#pragma unroll
        for (int ms = 0; ms < MS; ++ms) {
            ah[ms] = *(const bf16x8*)(Ah + (size_t)(m0 + ms * 16 + l16) * lda + ka);
            al[ms] = *(const bf16x8*)(Al + (size_t)(m0 + ms * 16 + l16) * lda + ka);
        }
        bf16x8 bh[4], bl[4];
#pragma unroll
        for (int ns = 0; ns < 4; ++ns) {
            bh[ns] = (bf16x8){0, 0, 0, 0, 0, 0, 0, 0};
            bl[ns] = (bf16x8){0, 0, 0, 0, 0, 0, 0, 0};
            if (nval[ns]) {
                bh[ns] = *(const bf16x8*)(Bh + (size_t)nrow[ns] * ldb + ka);
                bl[ns] = *(const bf16x8*)(Bl + (size_t)nrow[ns] * ldb + ka);
            }
        }
#pragma unroll
        for (int ns = 0; ns < 4; ++ns)
#pragma unroll
            for (int ms = 0; ms < MS; ++ms) {
                acc[ms][ns] = __builtin_amdgcn_mfma_f32_16x16x32_bf16(ah[ms], bh[ns], acc[ms][ns], 0, 0, 0);
                acc[ms][ns] = __builtin_amdgcn_mfma_f32_16x16x32_bf16(ah[ms], bl[ns], acc[ms][ns], 0, 0, 0);
                acc[ms][ns] = __builtin_amdgcn_mfma_f32_16x16x32_bf16(al[ms], bh[ns], acc[ms][ns], 0, 0, 0);
            }
    }

#pragma unroll
    for (int ms = 0; ms < MS; ++ms)
#pragma unroll
        for (int ns = 0; ns < 4; ++ns)
#pragma unroll
            for (int r = 0; r < 4; ++r) {
                int m = m0 + ms * 16 + lgrp * 4 + r;
                int n = n0 + ns * 16 + l16;
                if (n >= N) continue;
                float v = acc[ms][ns][r];
                if (bias) v += bias[n];
                if (RELU) v = v > 0.f ? v : 0.f;
                if (Cf) Cf[(size_t)m * ldcf + n] = v;
                if (Chi) split_store(v, Chi, Clo, (size_t)m * ldch + (size_t)z * cOffZ + n);
            }
}

// ---------------- LSTM elementwise ----------------
__global__ void k_lstm(const float* __restrict__ gates, float* __restrict__ hout,
                       __hip_bfloat16* __restrict__ ccH, __hip_bfloat16* __restrict__ ccL)
{
    int i = blockIdx.x * blockDim.x + threadIdx.x;
    if (i >= NN_ * HID) return;
    int n = i >> 8, j = i & 255;
    const float* gr = gates + (size_t)n * 1024;
    float gi = gr[j], gg = gr[512 + j], go = gr[768 + j];
    float c = (1.f / (1.f + __expf(-gi))) * tanhf(gg);
    float h = (1.f / (1.f + __expf(-go))) * tanhf(c);
    hout[i] = h;
    split_store(h, ccH, ccL, (size_t)n * 512 + j);
}

// ---------------- MHA: bf16 MFMA flash attention (LDS-free P) ----------------
__global__ void k_cvt(const float* __restrict__ qkv,
                      __hip_bfloat16* __restrict__ Qb, __hip_bfloat16* __restrict__ Kb,
                      __hip_bfloat16* __restrict__ Vt)
{
    int i = blockIdx.x * blockDim.x + threadIdx.x;
    int n = i >> 8, c = i & 255;
    int h = c >> 6, d = c & 63;
    const float* row = qkv + (size_t)n * 768;
    Qb[((size_t)h * NN_ + n) * 64 + d] = __float2bfloat16(row[c] * 0.125f);
    Kb[((size_t)h * NN_ + n) * 64 + d] = __float2bfloat16(row[256 + c]);
    Vt[((size_t)h * 64 + d) * NN_ + n] = __float2bfloat16(row[512 + c]);
}

// grid (NN_/32, 4 heads), 512 thr = 8 waves. Block owns 32 q-rows (2 q-tiles);
// wave w covers keys [w*512, w*512+512). Swapped QK^T (S^T = mfma(K,Q)) makes each
// lane hold a P-row slice that feeds the PV A-fragment directly (key relabeling
// within each 32-tile, consistently applied to V) — no LDS in the main loop.
__global__ __launch_bounds__(512) void k_attn_mfma(
    const __hip_bfloat16* __restrict__ Qb, const __hip_bfloat16* __restrict__ Kb,
    const __hip_bfloat16* __restrict__ Vt,
    __hip_bfloat16* __restrict__ aoH, __hip_bfloat16* __restrict__ aoL)
{
    __shared__ float redN[4][2][16][65];
    __shared__ float redD[4][2][16];
    int tid = threadIdx.x;
    int wave = tid >> 6, lane = tid & 63;
    int l16 = lane & 15, lgrp = lane >> 4;
    int h = blockIdx.y;
    int q0 = blockIdx.x * 32;
    int kbase = wave * 512;

    const short* Qs = (const short*)Qb;
    const short* Ks = (const short*)Kb;
    const short* Vs = (const short*)Vt;

    // Q as B-fragment: lane = q-col (l16), k-dim = d (lgrp*8..+7)
    bf16x8 qf[2][2];
#pragma unroll
    for (int qt = 0; qt < 2; ++qt)
#pragma unroll
        for (int dh = 0; dh < 2; ++dh)
            qf[qt][dh] = *(const bf16x8*)(Qs + ((size_t)h * NN_ + q0 + qt * 16 + l16) * 64 + dh * 32 + lgrp * 8);

    f32x4 oacc[2][4];
#pragma unroll
    for (int qt = 0; qt < 2; ++qt)
#pragma unroll
        for (int dc = 0; dc < 4; ++dc) oacc[qt][dc] = (f32x4){0.f, 0.f, 0.f, 0.f};
    float dn[2] = {0.f, 0.f};

#pragma unroll 2
    for (int kt = 0; kt < 16; ++kt) {
        int k0 = kbase + kt * 32;
        // K as A-fragment: lane row = key (l16), cols = d
        bf16x8 kfa[2][2];
#pragma unroll
        for (int kh = 0; kh < 2; ++kh)
#pragma unroll
            for (int dh = 0; dh < 2; ++dh)
                kfa[kh][dh] = *(const bf16x8*)(Ks + ((size_t)h * NN_ + k0 + kh * 16 + l16) * 64 + dh * 32 + lgrp * 8);
        // V as B-fragment with relabeled key order: j<4 -> k0+lgrp*4+j ; j>=4 -> k0+16+lgrp*4+(j-4)
        bf16x4 vlo[4], vhi[4];
#pragma unroll
        for (int dc = 0; dc < 4; ++dc) {
            const short* vp = Vs + ((size_t)h * 64 + dc * 16 + l16) * NN_ + k0 + lgrp * 4;
            vlo[dc] = *(const bf16x4*)(vp);
            vhi[dc] = *(const bf16x4*)(vp + 16);
        }
        // S^T tiles: st[kh] covers keys kh*16..+15 (rows) x 16 q (cols)
        f32x4 st[2][2]; // [kh][qt]
#pragma unroll
        for (int kh = 0; kh < 2; ++kh)
#pragma unroll
            for (int qt = 0; qt < 2; ++qt) {
                f32x4 s = (f32x4){0.f, 0.f, 0.f, 0.f};
                s = __builtin_amdgcn_mfma_f32_16x16x32_bf16(kfa[kh][0], qf[qt][0], s, 0, 0, 0);
                s = __builtin_amdgcn_mfma_f32_16x16x32_bf16(kfa[kh][1], qf[qt][1], s, 0, 0, 0);
                st[kh][qt] = s;
            }
        // exp + pack into PV A-fragment (lane holds q=l16, keys {lgrp*4+r} u {16+lgrp*4+r})
#pragma unroll
        for (int qt = 0; qt < 2; ++qt) {
            bf16x8 pa;
            float dsum = 0.f;
#pragma unroll
            for (int r = 0; r < 4; ++r) {
                float e0 = __expf(st[0][qt][r]);
                float e1 = __expf(st[1][qt][r]);
                dsum += e0 + e1;
                pa[r]     = f2bs(e0);
                pa[4 + r] = f2bs(e1);
            }
            dn[qt] += dsum;
#pragma unroll
            for (int dc = 0; dc < 4; ++dc) {
                bf16x8 vf = __builtin_shufflevector(vlo[dc], vhi[dc], 0, 1, 2, 3, 4, 5, 6, 7);
                oacc[qt][dc] = __builtin_amdgcn_mfma_f32_16x16x32_bf16(pa, vf, oacc[qt][dc], 0, 0, 0);
            }
        }
    }

    // full per-q denominator: reduce over the 4 lane groups
#pragma unroll
    for (int qt = 0; qt < 2; ++qt) {
        dn[qt] += __shfl_xor(dn[qt], 16);
        dn[qt] += __shfl_xor(dn[qt], 32);
    }

    // LDS merge tree: 8 -> 4 -> 2 -> 1
#define STORE_(s)                                                                   \
    {                                                                               \
        _Pragma("unroll") for (int qt = 0; qt < 2; ++qt) {                          \
            _Pragma("unroll") for (int dc = 0; dc < 4; ++dc)                        \
                _Pragma("unroll") for (int r = 0; r < 4; ++r)                       \
                    redN[s][qt][lgrp * 4 + r][dc * 16 + l16] = oacc[qt][dc][r];     \
            if (lane < 16) redD[s][qt][lane] = dn[qt];                              \
        }                                                                           \
    }
#define ACCUM_(s)                                                                   \
    {                                                                               \
        _Pragma("unroll") for (int qt = 0; qt < 2; ++qt) {                          \
            _Pragma("unroll") for (int dc = 0; dc < 4; ++dc)                        \
                _Pragma("unroll") for (int r = 0; r < 4; ++r)                       \
                    oacc[qt][dc][r] += redN[s][qt][lgrp * 4 + r][dc * 16 + l16];    \
            dn[qt] += redD[s][qt][l16];                                             \
        }                                                                           \
    }
    if (wave >= 4) STORE_(wave - 4);
    __syncthreads();
    if (wave < 4) ACCUM_(wave);
    __syncthreads();
    if (wave == 2 || wave == 3) STORE_(wave - 2);
    __syncthreads();
    if (wave < 2) ACCUM_(wave);
    __syncthreads();
    if (wave == 1) STORE_(0);
    __syncthreads();
    if (wave == 0) {
        ACCUM_(0);
#pragma unroll
        for (int qt = 0; qt < 2; ++qt) {
            float inv = 1.f / dn[qt];
#pragma unroll
            for (int r = 0; r < 4; ++r) {
                float invr = __shfl(inv, lgrp * 4 + r);
#pragma unroll
                for (int dc = 0; dc < 4; ++dc)
                    split_store(oacc[qt][dc][r] * invr, aoH, aoL,
                                (size_t)(q0 + qt * 16 + lgrp * 4 + r) * 256 + h * 64 + dc * 16 + l16);
            }
        }
    }
#undef STORE_
#undef ACCUM_
}

// ---------------- launch ----------------
extern "C" void kernel_launch(void* const* d_in, const int* in_sizes, int n_in,
                              void* d_out, int out_size, void* d_ws, size_t ws_size,
                              hipStream_t stream)
{
    const float* x      = (const float*)d_in[0];
    const int*   ei_t   = (const int*)d_in[1];
    const int*   ei_c   = (const int*)d_in[2];
    const float* ea_t   = (const float*)d_in[3];
    const float* ea_c   = (const float*)d_in[4];
    const float* W_t    = (const float*)d_in[5];
    const float* asrc_t = (const float*)d_in[6];
    const float* adst_t = (const float*)d_in[7];
    const float* We_t   = (const float*)d_in[8];
    const float* aedg_t = (const float*)d_in[9];
    const float* b_t    = (const float*)d_in[10];
    const float* W_c    = (const float*)d_in[11];
    const float* asrc_c = (const float*)d_in[12];
    const float* adst_c = (const float*)d_in[13];
    const float* We_c   = (const float*)d_in[14];
    const float* aedg_c = (const float*)d_in[15];
    const float* b_c    = (const float*)d_in[16];
    const float* Wih    = (const float*)d_in[17];
    const float* bih    = (const float*)d_in[19];
    const float* bhh    = (const float*)d_in[20];
    const float* min_w  = (const float*)d_in[21];
    const float* min_b  = (const float*)d_in[22];
    const float* mout_w = (const float*)d_in[23];
    const float* mout_b = (const float*)d_in[24];
    const float* fus_w  = (const float*)d_in[25];
    const float* fus_b  = (const float*)d_in[26];
    const float* out_w  = (const float*)d_in[27];
    const float* out_b  = (const float*)d_in[28];
    float* outp = (float*)d_out;

    char* W = (char*)d_ws;
    size_t off = 0;
    auto alloc = [&](size_t bytes) { size_t r = off; off += (bytes + 255) & ~(size_t)255; return r; };
    size_t oMean  = alloc(2 * 4);
    size_t oCnt   = alloc(2 * NN_ * 4);
    size_t oCur   = alloc(2 * NN_ * 4);
    size_t zeroBytes = off;
    size_t oRows  = alloc(2 * (NN_ + 16) * 4);
    size_t oSrcs  = alloc(2 * NE * 4);
    size_t oEav   = alloc(2 * NE * 4);
    size_t oWa    = alloc(4 * INF * NH * 4);
    size_t oDote  = alloc(2 * NH * 4);
    size_t oAsd   = alloc(4 * NN_ * NH * 4);
    size_t oBg    = alloc(1024 * 4);
    size_t oGH    = alloc((size_t)2 * NN_ * KK * 2);
    size_t oGL    = alloc((size_t)2 * NN_ * KK * 2);
    size_t oMtH   = alloc((size_t)1024 * KK * 2);
    size_t oMtL   = alloc((size_t)1024 * KK * 2);
    size_t oBctH  = alloc((size_t)CC * KK * 2);
    size_t oBctL  = alloc((size_t)CC * KK * 2);
    size_t oWihH  = alloc((size_t)1024 * HC * 2);      // reused as concatHi
    size_t oWihL  = alloc((size_t)1024 * HC * 2);      // reused as concatLo
    size_t oWtH   = alloc((size_t)INF * HC * 2);
    size_t oWtL   = alloc((size_t)INF * HC * 2);
    size_t oMinH  = alloc((size_t)768 * HID * 2);
    size_t oMinL  = alloc((size_t)768 * HID * 2);
    size_t oMoutH = alloc((size_t)HID * HID * 2);
    size_t oMoutL = alloc((size_t)HID * HID * 2);
    size_t oFusH  = alloc((size_t)HID * 512 * 2);
    size_t oFusL  = alloc((size_t)HID * 512 * 2);
    size_t oOutwH = alloc((size_t)128 * HID * 2);
    size_t oOutwL = alloc((size_t)128 * HID * 2);
    size_t oGates = alloc((size_t)NN_ * 1024 * 4);     // reused as qkv
    size_t oHcH   = alloc((size_t)NN_ * HID * 2);      // reused as hfusHi
    size_t oHcL   = alloc((size_t)NN_ * HID * 2);      // reused as hfusLo
    size_t oQb    = alloc((size_t)4 * NN_ * 64 * 2);
    size_t oKb    = alloc((size_t)4 * NN_ * 64 * 2);
    size_t oVt    = alloc((size_t)4 * NN_ * 64 * 2);
    size_t oQkv   = oGates;   // gates dead after k_lstm
    size_t oCcH   = oWihH;    // WihSplit dead after Mt GEMM
    size_t oCcL   = oWihL;
    size_t oAoH   = oGH;      // g dead after gates & hc GEMMs
    size_t oAoL   = oGL;
    size_t oHfH   = oHcH;     // hc dead after qkv GEMM
    size_t oHfL   = oHcL;
    (void)ws_size; (void)in_sizes; (void)n_in; (void)out_size;

    hipMemsetAsync(W, 0, zeroBytes, stream);

    // stage 1: weight splits + GAT scalar precomputes + bias_g + mean/hist
    k_stage1<<<11812, 256, 0, stream>>>(
        Wih,    (__hip_bfloat16*)(W + oWihH),  (__hip_bfloat16*)(W + oWihL),
        W_t,    (__hip_bfloat16*)(W + oWtH),   (__hip_bfloat16*)(W + oWtL),
        min_w,  (__hip_bfloat16*)(W + oMinH),  (__hip_bfloat16*)(W + oMinL),
        mout_w, (__hip_bfloat16*)(W + oMoutH), (__hip_bfloat16*)(W + oMoutL),
        fus_w,  (__hip_bfloat16*)(W + oFusH),  (__hip_bfloat16*)(W + oFusL),
        out_w,  (__hip_bfloat16*)(W + oOutwH), (__hip_bfloat16*)(W + oOutwL),
        W_c,    (__hip_bfloat16*)(W + oBctH),  (__hip_bfloat16*)(W + oBctL),
        asrc_t, adst_t, We_t, aedg_t, asrc_c, adst_c, We_c, aedg_c,
        (float*)(W + oWa), (float*)(W + oDote),
        b_t, bih, bhh, (float*)(W + oBg),
        ea_t, ea_c, ei_t, ei_c, (float*)(W + oMean), (int*)(W + oCnt));
    // stage 2: a_s/a_d + CSR scan
    k_stage2<<<514, 256, 0, stream>>>(x, (float*)(W + oWa), (float*)(W + oAsd),
                                      (int*)(W + oCnt), (int*)(W + oRows));
    // Mt[j][h*28+k] = sum_c Wih[j][h*256+c] * Wt[k][h*256+c] — batched over heads
    {
        dim3 grid(8, 1, 8);
        k_mgemm<false, 2><<<grid, 256, 0, stream>>>(
            (__hip_bfloat16*)(W + oWihH), (__hip_bfloat16*)(W + oWihL), HC, CC,
            (__hip_bfloat16*)(W + oWtH),  (__hip_bfloat16*)(W + oWtL),  HC, CC,
            nullptr, nullptr, 0,
            (__hip_bfloat16*)(W + oMtH), (__hip_bfloat16*)(W + oMtL), KK, INF,
            0, 1024, INF, CC);
    }
    k_scatter<<<2 * NE / 256, 256, 0, stream>>>(ei_t, ei_c, ea_t, ea_c,
                                                (int*)(W + oRows), (int*)(W + oCur),
                                                (int*)(W + oSrcs), (float*)(W + oEav));
    // GAT aggregation, both branches
    k_gat<<<2 * NN_, 64, 0, stream>>>((int*)(W + oSrcs), (float*)(W + oEav), (int*)(W + oRows), x,
                                      (float*)(W + oAsd), (float*)(W + oDote), (float*)(W + oMean),
                                      (__hip_bfloat16*)(W + oGH), (__hip_bfloat16*)(W + oGL));
    // gates = g_t @ Mt^T + bias_g (skip dead f-gate columns 256..511)
    {
        dim3 grid(32, 12, 1);
        k_mgemm<false, 2><<<grid, 256, 0, stream>>>(
            (__hip_bfloat16*)(W + oGH), (__hip_bfloat16*)(W + oGL), KK, 0,
            (__hip_bfloat16*)(W + oMtH), (__hip_bfloat16*)(W + oMtL), KK, 0,
            (float*)(W + oBg), (float*)(W + oGates), 1024,
            nullptr, nullptr, 0, 0,
            256, NN_, 1024, KK);
    }
    k_lstm<<<NN_ * HID / 256, 256, 0, stream>>>((float*)(W + oGates), outp + 524288,
                                                (__hip_bfloat16*)(W + oCcH), (__hip_bfloat16*)(W + oCcL));
    // h_c = g_c @ Bct^T + b_c -> hi/lo
    {
        dim3 grid(64, 4, 1);
        k_mgemm<false, 1><<<grid, 256, 0, stream>>>(
            (__hip_bfloat16*)(W + oGH) + (size_t)NN_ * KK, (__hip_bfloat16*)(W + oGL) + (size_t)NN_ * KK, KK, 0,
            (__hip_bfloat16*)(W + oBctH), (__hip_bfloat16*)(W + oBctL), KK, 0,
            b_c, nullptr, 0,
            (__hip_bfloat16*)(W + oHcH), (__hip_bfloat16*)(W + oHcL), HID, 0,
            0, NN_, HID, KK);
    }
    // qkv = h_c @ min_w^T + min_b (fp32)
    {
        dim3 grid(32, 12, 1);
        k_mgemm<false, 2><<<grid, 256, 0, stream>>>(
            (__hip_bfloat16*)(W + oHcH), (__hip_bfloat16*)(W + oHcL), HID, 0,
            (__hip_bfloat16*)(W + oMinH), (__hip_bfloat16*)(W + oMinL), HID, 0,
            min_b, (float*)(W + oQkv), 768,
            nullptr, nullptr, 0, 0,
            0, NN_, 768, HID);
    }
    k_cvt<<<NN_, 256, 0, stream>>>((float*)(W + oQkv),
                                   (__hip_bfloat16*)(W + oQb), (__hip_bfloat16*)(W + oKb),
                                   (__hip_bfloat16*)(W + oVt));
    // attention: 32 q-rows/block, LDS-free in-register softmax/PV
    {
        dim3 grid(NN_ / 32, 4);
        k_attn_mfma<<<grid, 512, 0, stream>>>(
            (__hip_bfloat16*)(W + oQb), (__hip_bfloat16*)(W + oKb), (__hip_bfloat16*)(W + oVt),
            (__hip_bfloat16*)(W + oAoH), (__hip_bfloat16*)(W + oAoL));
    }
    // out-proj: concat[:,256:512] (hi/lo) + h_causal (fp32 d_out)
    {
        dim3 grid(64, 4, 1);
        k_mgemm<false, 1><<<grid, 256, 0, stream>>>(
            (__hip_bfloat16*)(W + oAoH), (__hip_bfloat16*)(W + oAoL), HID, 0,
            (__hip_bfloat16*)(W + oMoutH), (__hip_bfloat16*)(W + oMoutL), HID, 0,
            mout_b, outp + 524288 + 1048576, 256,
            (__hip_bfloat16*)(W + oCcH) + 256, (__hip_bfloat16*)(W + oCcL) + 256, 512, 0,
            0, NN_, HID, HID);
    }
    // fusion: relu(concat @ fus_w^T + fus_b) -> hi/lo
    {
        dim3 grid(64, 4, 1);
        k_mgemm<true, 1><<<grid, 256, 0, stream>>>(
            (__hip_bfloat16*)(W + oCcH), (__hip_bfloat16*)(W + oCcL), 512, 0,
            (__hip_bfloat16*)(W + oFusH), (__hip_bfloat16*)(W + oFusL), 512, 0,
            fus_b, nullptr, 0,
            (__hip_bfloat16*)(W + oHfH), (__hip_bfloat16*)(W + oHfL), HID, 0,
            0, NN_, HID, 512);
    }
    // out = hfus @ out_w^T + out_b (fp32 d_out)
    {
        dim3 grid(64, 2, 1);
        k_mgemm<false, 1><<<grid, 256, 0, stream>>>(
            (__hip_bfloat16*)(W + oHfH), (__hip_bfloat16*)(W + oHfL), HID, 0,
            (__hip_bfloat16*)(W + oOutwH), (__hip_bfloat16*)(W + oOutwL), HID, 0,
            out_b, outp, 128,
            nullptr, nullptr, 0, 0,
            0, NN_, 128, HID);
    }
}

// Round 6
// 443.670 us; speedup vs baseline: 3.9727x; 1.0122x over previous
//
#include <hip/hip_runtime.h>
#include <hip/hip_bf16.h>

// ---------------- problem constants ----------------
constexpr int NN_ = 4096;     // nodes
constexpr int INF = 28;       // input features
constexpr int NH  = 8;        // GAT heads
constexpr int CC  = 256;      // channels per head
constexpr int HC  = 2048;     // NH*CC
constexpr int HID = 256;
constexpr int NE  = 131072;   // edges per branch
constexpr int KK  = NH * INF; // 224

typedef short bf16x8 __attribute__((ext_vector_type(8)));
typedef short bf16x4 __attribute__((ext_vector_type(4)));
typedef float f32x4 __attribute__((ext_vector_type(4)));

__device__ inline void split_store(float v, __hip_bfloat16* H, __hip_bfloat16* L, size_t idx)
{
    __hip_bfloat16 h = __float2bfloat16(v);
    H[idx] = h;
    L[idx] = __float2bfloat16(v - __bfloat162float(h));
}

__device__ inline short f2bs(float v)
{
    __hip_bfloat16 h = __float2bfloat16(v);
    return *reinterpret_cast<short*>(&h);
}

__device__ inline float wave_sum(float v)
{
    v += __shfl_xor(v, 1);  v += __shfl_xor(v, 2);  v += __shfl_xor(v, 4);
    v += __shfl_xor(v, 8);  v += __shfl_xor(v, 16); v += __shfl_xor(v, 32);
    return v;
}

// ---------------- stage 1: split_all + small_pre + biasg + mean_hist (one launch) ----------------
__global__ void k_stage1(
    const float* __restrict__ Wih,  __hip_bfloat16* WihH,  __hip_bfloat16* WihL,
    const float* __restrict__ Wt,   __hip_bfloat16* WtH,   __hip_bfloat16* WtL,
    const float* __restrict__ minw, __hip_bfloat16* minH,  __hip_bfloat16* minL,
    const float* __restrict__ moutw,__hip_bfloat16* moutH, __hip_bfloat16* moutL,
    const float* __restrict__ fusw, __hip_bfloat16* fusH,  __hip_bfloat16* fusL,
    const float* __restrict__ outw, __hip_bfloat16* outH,  __hip_bfloat16* outL,
    const float* __restrict__ Wc,   __hip_bfloat16* BH,    __hip_bfloat16* BL,
    const float* __restrict__ ast, const float* __restrict__ adt,
    const float* __restrict__ Wet, const float* __restrict__ aet,
    const float* __restrict__ asc, const float* __restrict__ adc,
    const float* __restrict__ Wec, const float* __restrict__ aec,
    float* __restrict__ wa, float* __restrict__ dote,
    const float* __restrict__ bt, const float* __restrict__ bih, const float* __restrict__ bhh,
    float* __restrict__ bg,
    const float* __restrict__ ea_t, const float* __restrict__ ea_c,
    const int* __restrict__ ei_t, const int* __restrict__ ei_c,
    float* __restrict__ meansum, int* __restrict__ cnt)
{
    int bx = blockIdx.x;
    if (bx < 10304) {
        int i = bx * 256 + threadIdx.x;
        if (i < 2097152)                   split_store(Wih[i],            WihH,  WihL,  i);
        else if (i < 2097152 + 57344)      split_store(Wt[i - 2097152],   WtH,   WtL,   i - 2097152);
        else if (i < 2154496 + 196608)     split_store(minw[i - 2154496], minH,  minL,  i - 2154496);
        else if (i < 2351104 + 65536)      split_store(moutw[i - 2351104],moutH, moutL, i - 2351104);
        else if (i < 2416640 + 131072)     split_store(fusw[i - 2416640], fusH,  fusL,  i - 2416640);
        else if (i < 2547712 + 32768)      split_store(outw[i - 2547712], outH,  outL,  i - 2547712);
        else if (i < 2580480 + 57344) {    // Bct[c][kk] = Wc[k, h*CC+c]/8
            int i2 = i - 2580480;
            int c = i2 / KK, kk = i2 % KK;
            int h = kk / INF, k = kk % INF;
            split_store(Wc[k * HC + h * CC + c] * 0.125f, BH, BL, i2);
        }
    } else if (bx < 10532) {
        int w = ((bx - 10304) * 256 + threadIdx.x) >> 6;
        int lane = threadIdx.x & 63;
        if (w < 2 * 2 * INF * NH) {
            int b = w / (2 * INF * NH);
            int r = w % (2 * INF * NH);
            int kind = r / (INF * NH);
            int r2 = r % (INF * NH);
            int k = r2 / NH, h = r2 % NH;
            const float* Wm = b ? Wc : Wt;
            const float* a  = b ? (kind ? adc : asc) : (kind ? adt : ast);
            float s = 0.f;
            for (int c = lane; c < CC; c += 64) s += Wm[k * HC + h * CC + c] * a[h * CC + c];
            s = wave_sum(s);
            if (lane == 0) wa[((b * 2 + kind) * INF + k) * NH + h] = s;
        } else if (w < 2 * 2 * INF * NH + 16) {
            int j = w - 2 * 2 * INF * NH;
            int b = j / NH, h = j % NH;
            const float* We = b ? Wec : Wet;
            const float* a  = b ? aec : aet;
            float s = 0.f;
            for (int c = lane; c < CC; c += 64) s += We[h * CC + c] * a[h * CC + c];
            s = wave_sum(s);
            if (lane == 0) dote[b * NH + h] = s;
        }
    } else if (bx < 10788) {
        int j = ((bx - 10532) * 256 + threadIdx.x) >> 6;
        int lane = threadIdx.x & 63;
        if (j < 1024) {
            const float* w = Wih + (size_t)j * HC;
            float s = 0.f;
            for (int c = lane; c < HC; c += 64) s += bt[c] * w[c];
            s = wave_sum(s);
            if (lane == 0) bg[j] = s + bih[j] + bhh[j];
        }
    } else {
        int i = (bx - 10788) * 256 + threadIdx.x;
        int b = i / NE, e = i - b * NE;
        float v = (b ? ea_c : ea_t)[e];
        for (int off = 32; off; off >>= 1) v += __shfl_down(v, off);
        if ((threadIdx.x & 63) == 0) atomicAdd(&meansum[b], v);
        const int* ei = b ? ei_c : ei_t;
        atomicAdd(&cnt[b * NN_ + ei[NE + e]], 1);
    }
}

// ---------------- stage 2: as_ad + CSR scan (one launch) ----------------
__global__ __launch_bounds__(256) void k_stage2(
    const float* __restrict__ x, const float* __restrict__ wa, float* __restrict__ asd,
    const int* __restrict__ cnt, int* __restrict__ rows)
{
    int bx = blockIdx.x;
    if (bx < 512) {
        int i = bx * 256 + threadIdx.x;
        int bk = i / (NN_ * NH);
        int r = i % (NN_ * NH);
        int n = r / NH, h = r % NH;
        const float* W = wa + bk * INF * NH;
        const float* xr = x + n * INF;
        float s = 0.f;
#pragma unroll
        for (int k = 0; k < INF; ++k) s += xr[k] * W[k * NH + h];
        asd[(bk * NN_ + n) * NH + h] = s;
    } else {
        int b = bx - 512;
        const int* c = cnt + b * NN_;
        int* r = rows + b * (NN_ + 16);
        __shared__ int ts[256];
        int t = threadIdx.x;
        int v[16]; int s = 0;
#pragma unroll
        for (int i = 0; i < 16; ++i) { v[i] = c[t * 16 + i]; s += v[i]; }
        ts[t] = s;
        __syncthreads();
        for (int off = 1; off < 256; off <<= 1) {
            int add = (t >= off) ? ts[t - off] : 0;
            __syncthreads();
            ts[t] += add;
            __syncthreads();
        }
        int excl = t ? ts[t - 1] : 0;
#pragma unroll
        for (int i = 0; i < 16; ++i) { r[t * 16 + i] = excl; excl += v[i]; }
        if (t == 255) r[NN_] = excl;
    }
}

__global__ void k_scatter(const int* __restrict__ ei_t, const int* __restrict__ ei_c,
                          const float* __restrict__ ea_t, const float* __restrict__ ea_c,
                          const int* __restrict__ rows, int* __restrict__ cur,
                          int* __restrict__ srcs, float* __restrict__ eav)
{
    int i = blockIdx.x * blockDim.x + threadIdx.x;
    if (i >= 2 * NE) return;
    int b = i / NE, e = i - b * NE;
    const int* ei = b ? ei_c : ei_t;
    const float* ea = b ? ea_c : ea_t;
    int d = ei[NE + e];
    int pos = rows[b * (NN_ + 16) + d] + atomicAdd(&cur[b * NN_ + d], 1);
    srcs[b * NE + pos] = ei[e];
    eav[b * NE + pos] = ea[e];
}

// ---------------- GAT per-dst aggregation, both branches in one grid ----------------
__global__ __launch_bounds__(64) void k_gat(
    const int* __restrict__ srcs, const float* __restrict__ eav,
    const int* __restrict__ rows, const float* __restrict__ x,
    const float* __restrict__ asd, const float* __restrict__ dote,
    const float* __restrict__ meansum,
    __hip_bfloat16* __restrict__ gH, __hip_bfloat16* __restrict__ gL)
{
    int b = blockIdx.x >> 12;           // branch
    int n = blockIdx.x & 4095;
    srcs += (size_t)b * NE; eav += (size_t)b * NE; rows += b * (NN_ + 16);
    const float* a_s = asd + (size_t)(2 * b) * NN_ * NH;
    const float* a_d = asd + (size_t)(2 * b + 1) * NN_ * NH;
    dote += b * NH;
    gH += (size_t)b * NN_ * KK; gL += (size_t)b * NN_ * KK;

    int lane = threadIdx.x;
    __shared__ float xb[64][32];
    __shared__ float eb[64][8];
    __shared__ float denb[8];

    float adn[NH], dt[NH];
#pragma unroll
    for (int h = 0; h < NH; ++h) { adn[h] = a_d[n * NH + h]; dt[h] = dote[h]; }
    float mean_attr = meansum[b] * (1.0f / NE);

    const int hOwn = lane >> 3;
    const int kOwn = (lane & 7) * 4;

    float acc0, acc1, acc2, acc3;
    {
        float al = a_s[n * NH + hOwn] + adn[hOwn] + mean_attr * dt[hOwn];
        al = al > 0.f ? al : 0.2f * al;
        float es = __expf(al);
        float xv0 = (kOwn + 0 < INF) ? x[n * INF + kOwn + 0] : 0.f;
        float xv1 = (kOwn + 1 < INF) ? x[n * INF + kOwn + 1] : 0.f;
        float xv2 = (kOwn + 2 < INF) ? x[n * INF + kOwn + 2] : 0.f;
        float xv3 = (kOwn + 3 < INF) ? x[n * INF + kOwn + 3] : ((kOwn + 3 == 31) ? 1.f : 0.f);
        acc0 = es * xv0; acc1 = es * xv1; acc2 = es * xv2; acc3 = es * xv3;
    }

    int e0 = rows[n], e1 = rows[n + 1];
    for (int base = e0; base < e1; base += 64) {
        int m = e1 - base; if (m > 64) m = 64;
        if (lane < m) {
            int sidx = srcs[base + lane];
            float ea = eav[base + lane];
            const float4* xr = (const float4*)(x + sidx * INF);
#pragma unroll
            for (int q = 0; q < 7; ++q) ((float4*)&xb[lane][0])[q] = xr[q];
            xb[lane][28] = 0.f; xb[lane][29] = 0.f; xb[lane][30] = 0.f; xb[lane][31] = 1.f;
            const float* asr = a_s + sidx * NH;
#pragma unroll
            for (int h = 0; h < NH; ++h) {
                float al = asr[h] + adn[h] + ea * dt[h];
                al = al > 0.f ? al : 0.2f * al;
                eb[lane][h] = __expf(al);
            }
        }
        __syncthreads();
        for (int j = 0; j < m; ++j) {
            float e = eb[j][hOwn];
            float4 xv = *(const float4*)&xb[j][kOwn];
            acc0 += e * xv.x; acc1 += e * xv.y; acc2 += e * xv.z; acc3 += e * xv.w;
        }
        __syncthreads();
    }

    if ((lane & 7) == 7) denb[hOwn] = acc3;
    __syncthreads();
    float inv = 1.0f / denb[hOwn];
    size_t gr = (size_t)n * KK + hOwn * INF + kOwn;
    if (kOwn + 0 < INF) split_store(acc0 * inv, gH, gL, gr + 0);
    if (kOwn + 1 < INF) split_store(acc1 * inv, gH, gL, gr + 1);
    if (kOwn + 2 < INF) split_store(acc2 * inv, gH, gL, gr + 2);
    if (kOwn + 3 < INF) split_store(acc3 * inv, gH, gL, gr + 3);
}

// ---------------- bf16x3-split MFMA GEMM ----------------
// MS: rows per wave /16. nSkip: skip dead f-gate cols. EPI==1: write qkv directly
// as bf16 Qb[h][n][d]*0.125 / Kb[h][n][d] / Vt[h][d][n] (replaces k_cvt).
template<bool RELU, int MS, int EPI>
__global__ __launch_bounds__(256) void k_mgemm(
    const __hip_bfloat16* __restrict__ Ahi_, const __hip_bfloat16* __restrict__ Alo_, int lda, int aOffZ,
    const __hip_bfloat16* __restrict__ Bhi_, const __hip_bfloat16* __restrict__ Blo_, int ldb, int bOffZ,
    const float* __restrict__ bias,
    float* __restrict__ Cf, int ldcf,
    __hip_bfloat16* __restrict__ Chi, __hip_bfloat16* __restrict__ Clo, int ldch, int cOffZ,
    __hip_bfloat16* __restrict__ Qbp, __hip_bfloat16* __restrict__ Kbp, __hip_bfloat16* __restrict__ Vtp,
    int nSkip, int M, int N, int K)
{
    int z = blockIdx.z;
    const short* Ah = (const short*)Ahi_ + (size_t)z * aOffZ;
    const short* Al = (const short*)Alo_ + (size_t)z * aOffZ;
    const short* Bh = (const short*)Bhi_ + (size_t)z * bOffZ;
    const short* Bl = (const short*)Blo_ + (size_t)z * bOffZ;
    int wave = threadIdx.x >> 6, lane = threadIdx.x & 63;
    int l16 = lane & 15, lgrp = lane >> 4;
    int m0 = blockIdx.x * (64 * MS) + wave * (16 * MS);
    int n0 = blockIdx.y * 64;
    if (nSkip && n0 >= nSkip) n0 += 256;

    f32x4 acc[MS][4];
#pragma unroll
    for (int i = 0; i < MS; ++i)
#pragma unroll
        for (int j = 0; j < 4; ++j) acc[i][j] = (f32x4){0.f, 0.f, 0.f, 0.f};

    int nrow[4]; bool nval[4];
#pragma unroll
    for (int ns = 0; ns < 4; ++ns) { nrow[ns] = n0 + ns * 16 + l16; nval[ns] = nrow[ns] < N; }

    for (int k0 = 0; k0 < K; k0 += 32) {
        size_t ka = (size_t)k0 + lgrp * 8;
        bf16x8 ah[MS], al[MS];
#pragma unroll
        for (int ms = 0; ms < MS; ++ms) {
            ah[ms] = *(const bf16x8*)(Ah + (size_t)(m0 + ms * 16 + l16) * lda + ka);
            al[ms] = *(const bf16x8*)(Al + (size_t)(m0 + ms * 16 + l16) * lda + ka);
        }
        bf16x8 bh[4], bl[4];
#pragma unroll
        for (int ns = 0; ns < 4; ++ns) {
            bh[ns] = (bf16x8){0, 0, 0, 0, 0, 0, 0, 0};
            bl[ns] = (bf16x8){0, 0, 0, 0, 0, 0, 0, 0};
            if (nval[ns]) {
                bh[ns] = *(const bf16x8*)(Bh + (size_t)nrow[ns] * ldb + ka);
                bl[ns] = *(const bf16x8*)(Bl + (size_t)nrow[ns] * ldb + ka);
            }
        }
#pragma unroll
        for (int ns = 0; ns < 4; ++ns)
#pragma unroll
            for (int ms = 0; ms < MS; ++ms) {
                acc[ms][ns] = __builtin_amdgcn_mfma_f32_16x16x32_bf16(ah[ms], bh[ns], acc[ms][ns], 0, 0, 0);
                acc[ms][ns] = __builtin_amdgcn_mfma_f32_16x16x32_bf16(ah[ms], bl[ns], acc[ms][ns], 0, 0, 0);
                acc[ms][ns] = __builtin_amdgcn_mfma_f32_16x16x32_bf16(al[ms], bh[ns], acc[ms][ns], 0, 0, 0);
            }
    }

#pragma unroll
    for (int ms = 0; ms < MS; ++ms)
#pragma unroll
        for (int ns = 0; ns < 4; ++ns)
#pragma unroll
            for (int r = 0; r < 4; ++r) {
                int m = m0 + ms * 16 + lgrp * 4 + r;
                int n = n0 + ns * 16 + l16;
                if (n >= N) continue;
                float v = acc[ms][ns][r];
                if (bias) v += bias[n];
                if (RELU) v = v > 0.f ? v : 0.f;
                if (EPI == 1) {
                    int sec = n >> 8, hh = (n >> 6) & 3, d = n & 63;
                    if (sec == 0)      Qbp[((size_t)hh * NN_ + m) * 64 + d] = __float2bfloat16(v * 0.125f);
                    else if (sec == 1) Kbp[((size_t)hh * NN_ + m) * 64 + d] = __float2bfloat16(v);
                    else               Vtp[((size_t)hh * 64 + d) * NN_ + m] = __float2bfloat16(v);
                } else {
                    if (Cf) Cf[(size_t)m * ldcf + n] = v;
                    if (Chi) split_store(v, Chi, Clo, (size_t)m * ldch + (size_t)z * cOffZ + n);
                }
            }
}

// ---------------- LSTM elementwise ----------------
__global__ void k_lstm(const float* __restrict__ gates, float* __restrict__ hout,
                       __hip_bfloat16* __restrict__ ccH, __hip_bfloat16* __restrict__ ccL)
{
    int i = blockIdx.x * blockDim.x + threadIdx.x;
    if (i >= NN_ * HID) return;
    int n = i >> 8, j = i & 255;
    const float* gr = gates + (size_t)n * 1024;
    float gi = gr[j], gg = gr[512 + j], go = gr[768 + j];
    float c = (1.f / (1.f + __expf(-gi))) * tanhf(gg);
    float h = (1.f / (1.f + __expf(-go))) * tanhf(c);
    hout[i] = h;
    split_store(h, ccH, ccL, (size_t)n * 512 + j);
}

// ---------------- MHA: bf16 MFMA flash attention, register double-buffered ----------------
// grid (NN_/32, 4 heads), 512 thr = 8 waves. Block owns 32 q-rows (2 q-tiles);
// wave w covers keys [w*512, w*512+512). Swapped QK^T; in-register softmax/PV.
// Explicit 2-stage pipeline: issue tile k+1's K/V loads before computing tile k
// so the ~200-400cyc L2 latency hides under the 8-MFMA + 8-exp compute phase.
__global__ __launch_bounds__(512) void k_attn_mfma(
    const __hip_bfloat16* __restrict__ Qb, const __hip_bfloat16* __restrict__ Kb,
    const __hip_bfloat16* __restrict__ Vt,
    __hip_bfloat16* __restrict__ aoH, __hip_bfloat16* __restrict__ aoL)
{
    __shared__ float redN[4][2][16][65];
    __shared__ float redD[4][2][16];
    int tid = threadIdx.x;
    int wave = tid >> 6, lane = tid & 63;
    int l16 = lane & 15, lgrp = lane >> 4;
    int h = blockIdx.y;
    int q0 = blockIdx.x * 32;
    int kbase = wave * 512;

    const short* Qs = (const short*)Qb;
    const short* Kbase_ = (const short*)Kb + (size_t)h * NN_ * 64;
    const short* Vbase_ = (const short*)Vt + (size_t)h * 64 * NN_;

    bf16x8 qf[2][2];
#pragma unroll
    for (int qt = 0; qt < 2; ++qt)
#pragma unroll
        for (int dh = 0; dh < 2; ++dh)
            qf[qt][dh] = *(const bf16x8*)(Qs + ((size_t)h * NN_ + q0 + qt * 16 + l16) * 64 + dh * 32 + lgrp * 8);

    f32x4 oacc[2][4];
#pragma unroll
    for (int qt = 0; qt < 2; ++qt)
#pragma unroll
        for (int dc = 0; dc < 4; ++dc) oacc[qt][dc] = (f32x4){0.f, 0.f, 0.f, 0.f};
    float dn[2] = {0.f, 0.f};

    bf16x8 kA[2][2], kB[2][2];
    bf16x4 vloA[4], vhiA[4], vloB[4], vhiB[4];

#define LOADK(K0, kf)                                                                 \
    { int k0_ = (K0);                                                                 \
      _Pragma("unroll") for (int kh = 0; kh < 2; ++kh)                                \
      _Pragma("unroll") for (int dh = 0; dh < 2; ++dh)                                \
          kf[kh][dh] = *(const bf16x8*)(Kbase_ + (size_t)(k0_ + kh * 16 + l16) * 64   \
                                        + dh * 32 + lgrp * 8); }
#define LOADV(K0, vlo, vhi)                                                           \
    { int k0_ = (K0);                                                                 \
      _Pragma("unroll") for (int dc = 0; dc < 4; ++dc) {                              \
          const short* vp_ = Vbase_ + (size_t)(dc * 16 + l16) * NN_ + k0_ + lgrp * 4; \
          vlo[dc] = *(const bf16x4*)vp_;                                              \
          vhi[dc] = *(const bf16x4*)(vp_ + 16); } }
#define COMPUTE(kf, vlo, vhi)                                                         \
    { f32x4 st_[2][2];                                                                \
      _Pragma("unroll") for (int kh = 0; kh < 2; ++kh)                                \
      _Pragma("unroll") for (int qt = 0; qt < 2; ++qt) {                              \
          f32x4 s_ = (f32x4){0.f, 0.f, 0.f, 0.f};                                     \
          s_ = __builtin_amdgcn_mfma_f32_16x16x32_bf16(kf[kh][0], qf[qt][0], s_, 0, 0, 0); \
          s_ = __builtin_amdgcn_mfma_f32_16x16x32_bf16(kf[kh][1], qf[qt][1], s_, 0, 0, 0); \
          st_[kh][qt] = s_; }                                                         \
      _Pragma("unroll") for (int qt = 0; qt < 2; ++qt) {                              \
          bf16x8 pa_;                                                                 \
          float dsum_ = 0.f;                                                          \
          _Pragma("unroll") for (int r = 0; r < 4; ++r) {                             \
              float e0_ = __expf(st_[0][qt][r]);                                      \
              float e1_ = __expf(st_[1][qt][r]);                                      \
              dsum_ += e0_ + e1_;                                                     \
              pa_[r]     = f2bs(e0_);                                                 \
              pa_[4 + r] = f2bs(e1_); }                                               \
          dn[qt] += dsum_;                                                            \
          _Pragma("unroll") for (int dc = 0; dc < 4; ++dc) {                          \
              bf16x8 vf_ = __builtin_shufflevector(vlo[dc], vhi[dc], 0, 1, 2, 3, 4, 5, 6, 7); \
              oacc[qt][dc] = __builtin_amdgcn_mfma_f32_16x16x32_bf16(pa_, vf_, oacc[qt][dc], 0, 0, 0); } } }

    LOADK(kbase, kA); LOADV(kbase, vloA, vhiA);
    for (int kt = 0; kt < 16; kt += 2) {
        int k1 = kbase + (kt + 1) * 32;
        LOADK(k1, kB); LOADV(k1, vloB, vhiB);
        COMPUTE(kA, vloA, vhiA);
        if (kt + 2 < 16) {
            int k2 = kbase + (kt + 2) * 32;
            LOADK(k2, kA); LOADV(k2, vloA, vhiA);
        }
        COMPUTE(kB, vloB, vhiB);
    }
#undef LOADK
#undef LOADV
#undef COMPUTE

    // full per-q denominator: reduce over the 4 lane groups
#pragma unroll
    for (int qt = 0; qt < 2; ++qt) {
        dn[qt] += __shfl_xor(dn[qt], 16);
        dn[qt] += __shfl_xor(dn[qt], 32);
    }

    // LDS merge tree: 8 -> 4 -> 2 -> 1
#define STORE_(s)                                                                   \
    {                                                                               \
        _Pragma("unroll") for (int qt = 0; qt < 2; ++qt) {                          \
            _Pragma("unroll") for (int dc = 0; dc < 4; ++dc)                        \
                _Pragma("unroll") for (int r = 0; r < 4; ++r)                       \
                    redN[s][qt][lgrp * 4 + r][dc * 16 + l16] = oacc[qt][dc][r];     \
            if (lane < 16) redD[s][qt][lane] = dn[qt];                              \
        }                                                                           \
    }
#define ACCUM_(s)                                                                   \
    {                                                                               \
        _Pragma("unroll") for (int qt = 0; qt < 2; ++qt) {                          \
            _Pragma("unroll") for (int dc = 0; dc < 4; ++dc)                        \
                _Pragma("unroll") for (int r = 0; r < 4; ++r)                       \
                    oacc[qt][dc][r] += redN[s][qt][lgrp * 4 + r][dc * 16 + l16];    \
            dn[qt] += redD[s][qt][l16];                                             \
        }                                                                           \
    }
    if (wave >= 4) STORE_(wave - 4);
    __syncthreads();
    if (wave < 4) ACCUM_(wave);
    __syncthreads();
    if (wave == 2 || wave == 3) STORE_(wave - 2);
    __syncthreads();
    if (wave < 2) ACCUM_(wave);
    __syncthreads();
    if (wave == 1) STORE_(0);
    __syncthreads();
    if (wave == 0) {
        ACCUM_(0);
#pragma unroll
        for (int qt = 0; qt < 2; ++qt) {
            float inv = 1.f / dn[qt];
#pragma unroll
            for (int r = 0; r < 4; ++r) {
                float invr = __shfl(inv, lgrp * 4 + r);
#pragma unroll
                for (int dc = 0; dc < 4; ++dc)
                    split_store(oacc[qt][dc][r] * invr, aoH, aoL,
                                (size_t)(q0 + qt * 16 + lgrp * 4 + r) * 256 + h * 64 + dc * 16 + l16);
            }
        }
    }
#undef STORE_
#undef ACCUM_
}

// ---------------- launch ----------------
extern "C" void kernel_launch(void* const* d_in, const int* in_sizes, int n_in,
                              void* d_out, int out_size, void* d_ws, size_t ws_size,
                              hipStream_t stream)
{
    const float* x      = (const float*)d_in[0];
    const int*   ei_t   = (const int*)d_in[1];
    const int*   ei_c   = (const int*)d_in[2];
    const float* ea_t   = (const float*)d_in[3];
    const float* ea_c   = (const float*)d_in[4];
    const float* W_t    = (const float*)d_in[5];
    const float* asrc_t = (const float*)d_in[6];
    const float* adst_t = (const float*)d_in[7];
    const float* We_t   = (const float*)d_in[8];
    const float* aedg_t = (const float*)d_in[9];
    const float* b_t    = (const float*)d_in[10];
    const float* W_c    = (const float*)d_in[11];
    const float* asrc_c = (const float*)d_in[12];
    const float* adst_c = (const float*)d_in[13];
    const float* We_c   = (const float*)d_in[14];
    const float* aedg_c = (const float*)d_in[15];
    const float* b_c    = (const float*)d_in[16];
    const float* Wih    = (const float*)d_in[17];
    const float* bih    = (const float*)d_in[19];
    const float* bhh    = (const float*)d_in[20];
    const float* min_w  = (const float*)d_in[21];
    const float* min_b  = (const float*)d_in[22];
    const float* mout_w = (const float*)d_in[23];
    const float* mout_b = (const float*)d_in[24];
    const float* fus_w  = (const float*)d_in[25];
    const float* fus_b  = (const float*)d_in[26];
    const float* out_w  = (const float*)d_in[27];
    const float* out_b  = (const float*)d_in[28];
    float* outp = (float*)d_out;

    char* W = (char*)d_ws;
    size_t off = 0;
    auto alloc = [&](size_t bytes) { size_t r = off; off += (bytes + 255) & ~(size_t)255; return r; };
    size_t oMean  = alloc(2 * 4);
    size_t oCnt   = alloc(2 * NN_ * 4);
    size_t oCur   = alloc(2 * NN_ * 4);
    size_t zeroBytes = off;
    size_t oRows  = alloc(2 * (NN_ + 16) * 4);
    size_t oSrcs  = alloc(2 * NE * 4);
    size_t oEav   = alloc(2 * NE * 4);
    size_t oWa    = alloc(4 * INF * NH * 4);
    size_t oDote  = alloc(2 * NH * 4);
    size_t oAsd   = alloc(4 * NN_ * NH * 4);
    size_t oBg    = alloc(1024 * 4);
    size_t oGH    = alloc((size_t)2 * NN_ * KK * 2);
    size_t oGL    = alloc((size_t)2 * NN_ * KK * 2);
    size_t oMtH   = alloc((size_t)1024 * KK * 2);
    size_t oMtL   = alloc((size_t)1024 * KK * 2);
    size_t oBctH  = alloc((size_t)CC * KK * 2);
    size_t oBctL  = alloc((size_t)CC * KK * 2);
    size_t oWihH  = alloc((size_t)1024 * HC * 2);      // reused as concatHi
    size_t oWihL  = alloc((size_t)1024 * HC * 2);      // reused as concatLo
    size_t oWtH   = alloc((size_t)INF * HC * 2);
    size_t oWtL   = alloc((size_t)INF * HC * 2);
    size_t oMinH  = alloc((size_t)768 * HID * 2);
    size_t oMinL  = alloc((size_t)768 * HID * 2);
    size_t oMoutH = alloc((size_t)HID * HID * 2);
    size_t oMoutL = alloc((size_t)HID * HID * 2);
    size_t oFusH  = alloc((size_t)HID * 512 * 2);
    size_t oFusL  = alloc((size_t)HID * 512 * 2);
    size_t oOutwH = alloc((size_t)128 * HID * 2);
    size_t oOutwL = alloc((size_t)128 * HID * 2);
    size_t oGates = alloc((size_t)NN_ * 1024 * 4);
    size_t oHcH   = alloc((size_t)NN_ * HID * 2);      // reused as hfusHi
    size_t oHcL   = alloc((size_t)NN_ * HID * 2);      // reused as hfusLo
    size_t oQb    = alloc((size_t)4 * NN_ * 64 * 2);
    size_t oKb    = alloc((size_t)4 * NN_ * 64 * 2);
    size_t oVt    = alloc((size_t)4 * NN_ * 64 * 2);
    size_t oCcH   = oWihH;    // WihSplit dead after Mt GEMM
    size_t oCcL   = oWihL;
    size_t oAoH   = oGH;      // g dead after gates & hc GEMMs
    size_t oAoL   = oGL;
    size_t oHfH   = oHcH;     // hc dead after qkv GEMM
    size_t oHfL   = oHcL;
    (void)ws_size; (void)in_sizes; (void)n_in; (void)out_size;

    hipMemsetAsync(W, 0, zeroBytes, stream);

    // stage 1: weight splits + GAT scalar precomputes + bias_g + mean/hist
    k_stage1<<<11812, 256, 0, stream>>>(
        Wih,    (__hip_bfloat16*)(W + oWihH),  (__hip_bfloat16*)(W + oWihL),
        W_t,    (__hip_bfloat16*)(W + oWtH),   (__hip_bfloat16*)(W + oWtL),
        min_w,  (__hip_bfloat16*)(W + oMinH),  (__hip_bfloat16*)(W + oMinL),
        mout_w, (__hip_bfloat16*)(W + oMoutH), (__hip_bfloat16*)(W + oMoutL),
        fus_w,  (__hip_bfloat16*)(W + oFusH),  (__hip_bfloat16*)(W + oFusL),
        out_w,  (__hip_bfloat16*)(W + oOutwH), (__hip_bfloat16*)(W + oOutwL),
        W_c,    (__hip_bfloat16*)(W + oBctH),  (__hip_bfloat16*)(W + oBctL),
        asrc_t, adst_t, We_t, aedg_t, asrc_c, adst_c, We_c, aedg_c,
        (float*)(W + oWa), (float*)(W + oDote),
        b_t, bih, bhh, (float*)(W + oBg),
        ea_t, ea_c, ei_t, ei_c, (float*)(W + oMean), (int*)(W + oCnt));
    // stage 2: a_s/a_d + CSR scan
    k_stage2<<<514, 256, 0, stream>>>(x, (float*)(W + oWa), (float*)(W + oAsd),
                                      (int*)(W + oCnt), (int*)(W + oRows));
    // Mt[j][h*28+k] = sum_c Wih[j][h*256+c] * Wt[k][h*256+c] — batched over heads
    {
        dim3 grid(8, 1, 8);
        k_mgemm<false, 2, 0><<<grid, 256, 0, stream>>>(
            (__hip_bfloat16*)(W + oWihH), (__hip_bfloat16*)(W + oWihL), HC, CC,
            (__hip_bfloat16*)(W + oWtH),  (__hip_bfloat16*)(W + oWtL),  HC, CC,
            nullptr, nullptr, 0,
            (__hip_bfloat16*)(W + oMtH), (__hip_bfloat16*)(W + oMtL), KK, INF,
            nullptr, nullptr, nullptr,
            0, 1024, INF, CC);
    }
    k_scatter<<<2 * NE / 256, 256, 0, stream>>>(ei_t, ei_c, ea_t, ea_c,
                                                (int*)(W + oRows), (int*)(W + oCur),
                                                (int*)(W + oSrcs), (float*)(W + oEav));
    // GAT aggregation, both branches
    k_gat<<<2 * NN_, 64, 0, stream>>>((int*)(W + oSrcs), (float*)(W + oEav), (int*)(W + oRows), x,
                                      (float*)(W + oAsd), (float*)(W + oDote), (float*)(W + oMean),
                                      (__hip_bfloat16*)(W + oGH), (__hip_bfloat16*)(W + oGL));
    // gates = g_t @ Mt^T + bias_g (skip dead f-gate columns 256..511)
    {
        dim3 grid(32, 12, 1);
        k_mgemm<false, 2, 0><<<grid, 256, 0, stream>>>(
            (__hip_bfloat16*)(W + oGH), (__hip_bfloat16*)(W + oGL), KK, 0,
            (__hip_bfloat16*)(W + oMtH), (__hip_bfloat16*)(W + oMtL), KK, 0,
            (float*)(W + oBg), (float*)(W + oGates), 1024,
            nullptr, nullptr, 0, 0,
            nullptr, nullptr, nullptr,
            256, NN_, 1024, KK);
    }
    k_lstm<<<NN_ * HID / 256, 256, 0, stream>>>((float*)(W + oGates), outp + 524288,
                                                (__hip_bfloat16*)(W + oCcH), (__hip_bfloat16*)(W + oCcL));
    // h_c = g_c @ Bct^T + b_c -> hi/lo
    {
        dim3 grid(64, 4, 1);
        k_mgemm<false, 1, 0><<<grid, 256, 0, stream>>>(
            (__hip_bfloat16*)(W + oGH) + (size_t)NN_ * KK, (__hip_bfloat16*)(W + oGL) + (size_t)NN_ * KK, KK, 0,
            (__hip_bfloat16*)(W + oBctH), (__hip_bfloat16*)(W + oBctL), KK, 0,
            b_c, nullptr, 0,
            (__hip_bfloat16*)(W + oHcH), (__hip_bfloat16*)(W + oHcL), HID, 0,
            nullptr, nullptr, nullptr,
            0, NN_, HID, KK);
    }
    // qkv = h_c @ min_w^T + min_b, written directly as bf16 Qb/Kb/Vt (fused k_cvt)
    {
        dim3 grid(32, 12, 1);
        k_mgemm<false, 2, 1><<<grid, 256, 0, stream>>>(
            (__hip_bfloat16*)(W + oHcH), (__hip_bfloat16*)(W + oHcL), HID, 0,
            (__hip_bfloat16*)(W + oMinH), (__hip_bfloat16*)(W + oMinL), HID, 0,
            min_b, nullptr, 0,
            nullptr, nullptr, 0, 0,
            (__hip_bfloat16*)(W + oQb), (__hip_bfloat16*)(W + oKb), (__hip_bfloat16*)(W + oVt),
            0, NN_, 768, HID);
    }
    // attention: 32 q-rows/block, register double-buffered K/V stream
    {
        dim3 grid(NN_ / 32, 4);
        k_attn_mfma<<<grid, 512, 0, stream>>>(
            (__hip_bfloat16*)(W + oQb), (__hip_bfloat16*)(W + oKb), (__hip_bfloat16*)(W + oVt),
            (__hip_bfloat16*)(W + oAoH), (__hip_bfloat16*)(W + oAoL));
    }
    // out-proj: concat[:,256:512] (hi/lo) + h_causal (fp32 d_out)
    {
        dim3 grid(64, 4, 1);
        k_mgemm<false, 1, 0><<<grid, 256, 0, stream>>>(
            (__hip_bfloat16*)(W + oAoH), (__hip_bfloat16*)(W + oAoL), HID, 0,
            (__hip_bfloat16*)(W + oMoutH), (__hip_bfloat16*)(W + oMoutL), HID, 0,
            mout_b, outp + 524288 + 1048576, 256,
            (__hip_bfloat16*)(W + oCcH) + 256, (__hip_bfloat16*)(W + oCcL) + 256, 512, 0,
            nullptr, nullptr, nullptr,
            0, NN_, HID, HID);
    }
    // fusion: relu(concat @ fus_w^T + fus_b) -> hi/lo
    {
        dim3 grid(64, 4, 1);
        k_mgemm<true, 1, 0><<<grid, 256, 0, stream>>>(
            (__hip_bfloat16*)(W + oCcH), (__hip_bfloat16*)(W + oCcL), 512, 0,
            (__hip_bfloat16*)(W + oFusH), (__hip_bfloat16*)(W + oFusL), 512, 0,
            fus_b, nullptr, 0,
            (__hip_bfloat16*)(W + oHfH), (__hip_bfloat16*)(W + oHfL), HID, 0,
            nullptr, nullptr, nullptr,
            0, NN_, HID, 512);
    }
    // out = hfus @ out_w^T + out_b (fp32 d_out)
    {
        dim3 grid(64, 2, 1);
        k_mgemm<false, 1, 0><<<grid, 256, 0, stream>>>(
            (__hip_bfloat16*)(W + oHfH), (__hip_bfloat16*)(W + oHfL), HID, 0,
            (__hip_bfloat16*)(W + oOutwH), (__hip_bfloat16*)(W + oOutwL), HID, 0,
            out_b, outp, 128,
            nullptr, nullptr, 0, 0,
            nullptr, nullptr, nullptr,
            0, NN_, 128, HID);
    }
}

// Round 7
// 418.337 us; speedup vs baseline: 4.2133x; 1.0606x over previous
//
#include <hip/hip_runtime.h>
#include <hip/hip_bf16.h>

// ---------------- problem constants ----------------
constexpr int NN_ = 4096;     // nodes
constexpr int INF = 28;       // input features
constexpr int NH  = 8;        // GAT heads
constexpr int CC  = 256;      // channels per head
constexpr int HC  = 2048;     // NH*CC
constexpr int HID = 256;
constexpr int NE  = 131072;   // edges per branch
constexpr int KK  = NH * INF; // 224

typedef short bf16x8 __attribute__((ext_vector_type(8)));
typedef short bf16x4 __attribute__((ext_vector_type(4)));
typedef float f32x4 __attribute__((ext_vector_type(4)));

__device__ inline void split_store(float v, __hip_bfloat16* H, __hip_bfloat16* L, size_t idx)
{
    __hip_bfloat16 h = __float2bfloat16(v);
    H[idx] = h;
    L[idx] = __float2bfloat16(v - __bfloat162float(h));
}

__device__ inline short f2bs(float v)
{
    __hip_bfloat16 h = __float2bfloat16(v);
    return *reinterpret_cast<short*>(&h);
}

__device__ inline float wave_sum(float v)
{
    v += __shfl_xor(v, 1);  v += __shfl_xor(v, 2);  v += __shfl_xor(v, 4);
    v += __shfl_xor(v, 8);  v += __shfl_xor(v, 16); v += __shfl_xor(v, 32);
    return v;
}

// ---------------- stage 1: split_all + small_pre + biasg + mean_hist (one launch) ----------------
__global__ void k_stage1(
    const float* __restrict__ Wih,  __hip_bfloat16* WihH,  __hip_bfloat16* WihL,
    const float* __restrict__ Wt,   __hip_bfloat16* WtH,   __hip_bfloat16* WtL,
    const float* __restrict__ minw, __hip_bfloat16* minH,  __hip_bfloat16* minL,
    const float* __restrict__ moutw,__hip_bfloat16* moutH, __hip_bfloat16* moutL,
    const float* __restrict__ fusw, __hip_bfloat16* fusH,  __hip_bfloat16* fusL,
    const float* __restrict__ outw, __hip_bfloat16* outH,  __hip_bfloat16* outL,
    const float* __restrict__ Wc,   __hip_bfloat16* BH,    __hip_bfloat16* BL,
    const float* __restrict__ ast, const float* __restrict__ adt,
    const float* __restrict__ Wet, const float* __restrict__ aet,
    const float* __restrict__ asc, const float* __restrict__ adc,
    const float* __restrict__ Wec, const float* __restrict__ aec,
    float* __restrict__ wa, float* __restrict__ dote,
    const float* __restrict__ bt, const float* __restrict__ bih, const float* __restrict__ bhh,
    float* __restrict__ bg,
    const float* __restrict__ ea_t, const float* __restrict__ ea_c,
    const int* __restrict__ ei_t, const int* __restrict__ ei_c,
    float* __restrict__ meansum, int* __restrict__ cnt)
{
    int bx = blockIdx.x;
    if (bx < 10304) {
        int i = bx * 256 + threadIdx.x;
        if (i < 2097152)                   split_store(Wih[i],            WihH,  WihL,  i);
        else if (i < 2097152 + 57344)      split_store(Wt[i - 2097152],   WtH,   WtL,   i - 2097152);
        else if (i < 2154496 + 196608)     split_store(minw[i - 2154496], minH,  minL,  i - 2154496);
        else if (i < 2351104 + 65536)      split_store(moutw[i - 2351104],moutH, moutL, i - 2351104);
        else if (i < 2416640 + 131072)     split_store(fusw[i - 2416640], fusH,  fusL,  i - 2416640);
        else if (i < 2547712 + 32768)      split_store(outw[i - 2547712], outH,  outL,  i - 2547712);
        else if (i < 2580480 + 57344) {    // Bct[c][kk] = Wc[k, h*CC+c]/8
            int i2 = i - 2580480;
            int c = i2 / KK, kk = i2 % KK;
            int h = kk / INF, k = kk % INF;
            split_store(Wc[k * HC + h * CC + c] * 0.125f, BH, BL, i2);
        }
    } else if (bx < 10532) {
        int w = ((bx - 10304) * 256 + threadIdx.x) >> 6;
        int lane = threadIdx.x & 63;
        if (w < 2 * 2 * INF * NH) {
            int b = w / (2 * INF * NH);
            int r = w % (2 * INF * NH);
            int kind = r / (INF * NH);
            int r2 = r % (INF * NH);
            int k = r2 / NH, h = r2 % NH;
            const float* Wm = b ? Wc : Wt;
            const float* a  = b ? (kind ? adc : asc) : (kind ? adt : ast);
            float s = 0.f;
            for (int c = lane; c < CC; c += 64) s += Wm[k * HC + h * CC + c] * a[h * CC + c];
            s = wave_sum(s);
            if (lane == 0) wa[((b * 2 + kind) * INF + k) * NH + h] = s;
        } else if (w < 2 * 2 * INF * NH + 16) {
            int j = w - 2 * 2 * INF * NH;
            int b = j / NH, h = j % NH;
            const float* We = b ? Wec : Wet;
            const float* a  = b ? aec : aet;
            float s = 0.f;
            for (int c = lane; c < CC; c += 64) s += We[h * CC + c] * a[h * CC + c];
            s = wave_sum(s);
            if (lane == 0) dote[b * NH + h] = s;
        }
    } else if (bx < 10788) {
        int j = ((bx - 10532) * 256 + threadIdx.x) >> 6;
        int lane = threadIdx.x & 63;
        if (j < 1024) {
            const float* w = Wih + (size_t)j * HC;
            float s = 0.f;
            for (int c = lane; c < HC; c += 64) s += bt[c] * w[c];
            s = wave_sum(s);
            if (lane == 0) bg[j] = s + bih[j] + bhh[j];
        }
    } else {
        int i = (bx - 10788) * 256 + threadIdx.x;
        int b = i / NE, e = i - b * NE;
        float v = (b ? ea_c : ea_t)[e];
        for (int off = 32; off; off >>= 1) v += __shfl_down(v, off);
        if ((threadIdx.x & 63) == 0) atomicAdd(&meansum[b], v);
        const int* ei = b ? ei_c : ei_t;
        atomicAdd(&cnt[b * NN_ + ei[NE + e]], 1);
    }
}

// ---------------- stage 2: as_ad + CSR scan (one launch) ----------------
__global__ __launch_bounds__(256) void k_stage2(
    const float* __restrict__ x, const float* __restrict__ wa, float* __restrict__ asd,
    const int* __restrict__ cnt, int* __restrict__ rows)
{
    int bx = blockIdx.x;
    if (bx < 512) {
        int i = bx * 256 + threadIdx.x;
        int bk = i / (NN_ * NH);
        int r = i % (NN_ * NH);
        int n = r / NH, h = r % NH;
        const float* W = wa + bk * INF * NH;
        const float* xr = x + n * INF;
        float s = 0.f;
#pragma unroll
        for (int k = 0; k < INF; ++k) s += xr[k] * W[k * NH + h];
        asd[(bk * NN_ + n) * NH + h] = s;
    } else {
        int b = bx - 512;
        const int* c = cnt + b * NN_;
        int* r = rows + b * (NN_ + 16);
        __shared__ int ts[256];
        int t = threadIdx.x;
        int v[16]; int s = 0;
#pragma unroll
        for (int i = 0; i < 16; ++i) { v[i] = c[t * 16 + i]; s += v[i]; }
        ts[t] = s;
        __syncthreads();
        for (int off = 1; off < 256; off <<= 1) {
            int add = (t >= off) ? ts[t - off] : 0;
            __syncthreads();
            ts[t] += add;
            __syncthreads();
        }
        int excl = t ? ts[t - 1] : 0;
#pragma unroll
        for (int i = 0; i < 16; ++i) { r[t * 16 + i] = excl; excl += v[i]; }
        if (t == 255) r[NN_] = excl;
    }
}

__global__ void k_scatter(const int* __restrict__ ei_t, const int* __restrict__ ei_c,
                          const float* __restrict__ ea_t, const float* __restrict__ ea_c,
                          const int* __restrict__ rows, int* __restrict__ cur,
                          int* __restrict__ srcs, float* __restrict__ eav)
{
    int i = blockIdx.x * blockDim.x + threadIdx.x;
    if (i >= 2 * NE) return;
    int b = i / NE, e = i - b * NE;
    const int* ei = b ? ei_c : ei_t;
    const float* ea = b ? ea_c : ea_t;
    int d = ei[NE + e];
    int pos = rows[b * (NN_ + 16) + d] + atomicAdd(&cur[b * NN_ + d], 1);
    srcs[b * NE + pos] = ei[e];
    eav[b * NE + pos] = ea[e];
}

// ---------------- GAT per-dst aggregation, both branches in one grid ----------------
__global__ __launch_bounds__(64) void k_gat(
    const int* __restrict__ srcs, const float* __restrict__ eav,
    const int* __restrict__ rows, const float* __restrict__ x,
    const float* __restrict__ asd, const float* __restrict__ dote,
    const float* __restrict__ meansum,
    __hip_bfloat16* __restrict__ gH, __hip_bfloat16* __restrict__ gL)
{
    int b = blockIdx.x >> 12;           // branch
    int n = blockIdx.x & 4095;
    srcs += (size_t)b * NE; eav += (size_t)b * NE; rows += b * (NN_ + 16);
    const float* a_s = asd + (size_t)(2 * b) * NN_ * NH;
    const float* a_d = asd + (size_t)(2 * b + 1) * NN_ * NH;
    dote += b * NH;
    gH += (size_t)b * NN_ * KK; gL += (size_t)b * NN_ * KK;

    int lane = threadIdx.x;
    __shared__ float xb[64][32];
    __shared__ float eb[64][8];
    __shared__ float denb[8];

    float adn[NH], dt[NH];
#pragma unroll
    for (int h = 0; h < NH; ++h) { adn[h] = a_d[n * NH + h]; dt[h] = dote[h]; }
    float mean_attr = meansum[b] * (1.0f / NE);

    const int hOwn = lane >> 3;
    const int kOwn = (lane & 7) * 4;

    float acc0, acc1, acc2, acc3;
    {
        float al = a_s[n * NH + hOwn] + adn[hOwn] + mean_attr * dt[hOwn];
        al = al > 0.f ? al : 0.2f * al;
        float es = __expf(al);
        float xv0 = (kOwn + 0 < INF) ? x[n * INF + kOwn + 0] : 0.f;
        float xv1 = (kOwn + 1 < INF) ? x[n * INF + kOwn + 1] : 0.f;
        float xv2 = (kOwn + 2 < INF) ? x[n * INF + kOwn + 2] : 0.f;
        float xv3 = (kOwn + 3 < INF) ? x[n * INF + kOwn + 3] : ((kOwn + 3 == 31) ? 1.f : 0.f);
        acc0 = es * xv0; acc1 = es * xv1; acc2 = es * xv2; acc3 = es * xv3;
    }

    int e0 = rows[n], e1 = rows[n + 1];
    for (int base = e0; base < e1; base += 64) {
        int m = e1 - base; if (m > 64) m = 64;
        if (lane < m) {
            int sidx = srcs[base + lane];
            float ea = eav[base + lane];
            const float4* xr = (const float4*)(x + sidx * INF);
#pragma unroll
            for (int q = 0; q < 7; ++q) ((float4*)&xb[lane][0])[q] = xr[q];
            xb[lane][28] = 0.f; xb[lane][29] = 0.f; xb[lane][30] = 0.f; xb[lane][31] = 1.f;
            const float* asr = a_s + sidx * NH;
#pragma unroll
            for (int h = 0; h < NH; ++h) {
                float al = asr[h] + adn[h] + ea * dt[h];
                al = al > 0.f ? al : 0.2f * al;
                eb[lane][h] = __expf(al);
            }
        }
        __syncthreads();
        for (int j = 0; j < m; ++j) {
            float e = eb[j][hOwn];
            float4 xv = *(const float4*)&xb[j][kOwn];
            acc0 += e * xv.x; acc1 += e * xv.y; acc2 += e * xv.z; acc3 += e * xv.w;
        }
        __syncthreads();
    }

    if ((lane & 7) == 7) denb[hOwn] = acc3;
    __syncthreads();
    float inv = 1.0f / denb[hOwn];
    size_t gr = (size_t)n * KK + hOwn * INF + kOwn;
    if (kOwn + 0 < INF) split_store(acc0 * inv, gH, gL, gr + 0);
    if (kOwn + 1 < INF) split_store(acc1 * inv, gH, gL, gr + 1);
    if (kOwn + 2 < INF) split_store(acc2 * inv, gH, gL, gr + 2);
    if (kOwn + 3 < INF) split_store(acc3 * inv, gH, gL, gr + 3);
}

// ---------------- bf16x3-split MFMA GEMM ----------------
// MS: rows per wave /16. nSkip: skip dead f-gate cols. EPI==1: write qkv directly
// as bf16 Qb[h][n][64]*0.125 / Kb[h][n][64] / Vt[h][kt][64][32] (replaces k_cvt).
template<bool RELU, int MS, int EPI>
__global__ __launch_bounds__(256) void k_mgemm(
    const __hip_bfloat16* __restrict__ Ahi_, const __hip_bfloat16* __restrict__ Alo_, int lda, int aOffZ,
    const __hip_bfloat16* __restrict__ Bhi_, const __hip_bfloat16* __restrict__ Blo_, int ldb, int bOffZ,
    const float* __restrict__ bias,
    float* __restrict__ Cf, int ldcf,
    __hip_bfloat16* __restrict__ Chi, __hip_bfloat16* __restrict__ Clo, int ldch, int cOffZ,
    __hip_bfloat16* __restrict__ Qbp, __hip_bfloat16* __restrict__ Kbp, __hip_bfloat16* __restrict__ Vtp,
    int nSkip, int M, int N, int K)
{
    int z = blockIdx.z;
    const short* Ah = (const short*)Ahi_ + (size_t)z * aOffZ;
    const short* Al = (const short*)Alo_ + (size_t)z * aOffZ;
    const short* Bh = (const short*)Bhi_ + (size_t)z * bOffZ;
    const short* Bl = (const short*)Blo_ + (size_t)z * bOffZ;
    int wave = threadIdx.x >> 6, lane = threadIdx.x & 63;
    int l16 = lane & 15, lgrp = lane >> 4;
    int m0 = blockIdx.x * (64 * MS) + wave * (16 * MS);
    int n0 = blockIdx.y * 64;
    if (nSkip && n0 >= nSkip) n0 += 256;

    f32x4 acc[MS][4];
#pragma unroll
    for (int i = 0; i < MS; ++i)
#pragma unroll
        for (int j = 0; j < 4; ++j) acc[i][j] = (f32x4){0.f, 0.f, 0.f, 0.f};

    int nrow[4]; bool nval[4];
#pragma unroll
    for (int ns = 0; ns < 4; ++ns) { nrow[ns] = n0 + ns * 16 + l16; nval[ns] = nrow[ns] < N; }

    for (int k0 = 0; k0 < K; k0 += 32) {
        size_t ka = (size_t)k0 + lgrp * 8;
        bf16x8 ah[MS], al[MS];
#pragma unroll
        for (int ms = 0; ms < MS; ++ms) {
            ah[ms] = *(const bf16x8*)(Ah + (size_t)(m0 + ms * 16 + l16) * lda + ka);
            al[ms] = *(const bf16x8*)(Al + (size_t)(m0 + ms * 16 + l16) * lda + ka);
        }
        bf16x8 bh[4], bl[4];
#pragma unroll
        for (int ns = 0; ns < 4; ++ns) {
            bh[ns] = (bf16x8){0, 0, 0, 0, 0, 0, 0, 0};
            bl[ns] = (bf16x8){0, 0, 0, 0, 0, 0, 0, 0};
            if (nval[ns]) {
                bh[ns] = *(const bf16x8*)(Bh + (size_t)nrow[ns] * ldb + ka);
                bl[ns] = *(const bf16x8*)(Bl + (size_t)nrow[ns] * ldb + ka);
            }
        }
#pragma unroll
        for (int ns = 0; ns < 4; ++ns)
#pragma unroll
            for (int ms = 0; ms < MS; ++ms) {
                acc[ms][ns] = __builtin_amdgcn_mfma_f32_16x16x32_bf16(ah[ms], bh[ns], acc[ms][ns], 0, 0, 0);
                acc[ms][ns] = __builtin_amdgcn_mfma_f32_16x16x32_bf16(ah[ms], bl[ns], acc[ms][ns], 0, 0, 0);
                acc[ms][ns] = __builtin_amdgcn_mfma_f32_16x16x32_bf16(al[ms], bh[ns], acc[ms][ns], 0, 0, 0);
            }
    }

#pragma unroll
    for (int ms = 0; ms < MS; ++ms)
#pragma unroll
        for (int ns = 0; ns < 4; ++ns)
#pragma unroll
            for (int r = 0; r < 4; ++r) {
                int m = m0 + ms * 16 + lgrp * 4 + r;
                int n = n0 + ns * 16 + l16;
                if (n >= N) continue;
                float v = acc[ms][ns][r];
                if (bias) v += bias[n];
                if (RELU) v = v > 0.f ? v : 0.f;
                if (EPI == 1) {
                    int sec = n >> 8, hh = (n >> 6) & 3, d = n & 63;
                    if (sec == 0)      Qbp[((size_t)hh * NN_ + m) * 64 + d] = __float2bfloat16(v * 0.125f);
                    else if (sec == 1) Kbp[((size_t)hh * NN_ + m) * 64 + d] = __float2bfloat16(v);
                    else               Vtp[(((size_t)hh * (NN_ / 32) + (m >> 5)) * 64 + d) * 32 + (m & 31)]
                                           = __float2bfloat16(v);
                } else {
                    if (Cf) Cf[(size_t)m * ldcf + n] = v;
                    if (Chi) split_store(v, Chi, Clo, (size_t)m * ldch + (size_t)z * cOffZ + n);
                }
            }
}

// ---------------- LSTM elementwise ----------------
__global__ void k_lstm(const float* __restrict__ gates, float* __restrict__ hout,
                       __hip_bfloat16* __restrict__ ccH, __hip_bfloat16* __restrict__ ccL)
{
    int i = blockIdx.x * blockDim.x + threadIdx.x;
    if (i >= NN_ * HID) return;
    int n = i >> 8, j = i & 255;
    const float* gr = gates + (size_t)n * 1024;
    float gi = gr[j], gg = gr[512 + j], go = gr[768 + j];
    float c = (1.f / (1.f + __expf(-gi))) * tanhf(gg);
    float h = (1.f / (1.f + __expf(-go))) * tanhf(c);
    hout[i] = h;
    split_store(h, ccH, ccL, (size_t)n * 512 + j);
}

// ---------------- MHA: bf16 MFMA flash attention ----------------
// grid (NN_/32, 4 heads), 512 thr = 8 waves. Block owns 32 q-rows (2 q-tiles);
// wave w covers keys [w*512, w*512+512). Swapped QK^T; in-register softmax/PV.
// V layout is TILED: Vt[h][ktile][d=64][32 keys] — each 32-key tile is a contiguous
// 4 KB block, so V fragment loads span 1 KB contiguous (no 8 KB power-of-2 channel
// conflicts; that stride was the R5/R6 ~96 us wall).
__global__ __launch_bounds__(512) void k_attn_mfma(
    const __hip_bfloat16* __restrict__ Qb, const __hip_bfloat16* __restrict__ Kb,
    const __hip_bfloat16* __restrict__ Vt,
    __hip_bfloat16* __restrict__ aoH, __hip_bfloat16* __restrict__ aoL)
{
    __shared__ float redN[4][2][16][65];
    __shared__ float redD[4][2][16];
    int tid = threadIdx.x;
    int wave = tid >> 6, lane = tid & 63;
    int l16 = lane & 15, lgrp = lane >> 4;
    int h = blockIdx.y;
    int q0 = blockIdx.x * 32;
    int kbase = wave * 512;

    const short* Qs = (const short*)Qb;
    const short* Kbase_ = (const short*)Kb + (size_t)h * NN_ * 64;
    const short* Vbase_ = (const short*)Vt + (size_t)h * NN_ * 64;

    bf16x8 qf[2][2];
#pragma unroll
    for (int qt = 0; qt < 2; ++qt)
#pragma unroll
        for (int dh = 0; dh < 2; ++dh)
            qf[qt][dh] = *(const bf16x8*)(Qs + ((size_t)h * NN_ + q0 + qt * 16 + l16) * 64 + dh * 32 + lgrp * 8);

    f32x4 oacc[2][4];
#pragma unroll
    for (int qt = 0; qt < 2; ++qt)
#pragma unroll
        for (int dc = 0; dc < 4; ++dc) oacc[qt][dc] = (f32x4){0.f, 0.f, 0.f, 0.f};
    float dn[2] = {0.f, 0.f};

    bf16x8 kA[2][2], kB[2][2];
    bf16x4 vloA[4], vhiA[4], vloB[4], vhiB[4];

#define LOADK(K0, kf)                                                                 \
    { int k0_ = (K0);                                                                 \
      _Pragma("unroll") for (int kh = 0; kh < 2; ++kh)                                \
      _Pragma("unroll") for (int dh = 0; dh < 2; ++dh)                                \
          kf[kh][dh] = *(const bf16x8*)(Kbase_ + (size_t)(k0_ + kh * 16 + l16) * 64   \
                                        + dh * 32 + lgrp * 8); }
#define LOADV(K0, vlo, vhi)                                                           \
    { const short* tb_ = Vbase_ + ((size_t)((K0) >> 5)) * 2048;                       \
      _Pragma("unroll") for (int dc = 0; dc < 4; ++dc) {                              \
          const short* vp_ = tb_ + (dc * 16 + l16) * 32 + lgrp * 4;                   \
          vlo[dc] = *(const bf16x4*)vp_;                                              \
          vhi[dc] = *(const bf16x4*)(vp_ + 16); } }
#define COMPUTE(kf, vlo, vhi)                                                         \
    { f32x4 st_[2][2];                                                                \
      _Pragma("unroll") for (int kh = 0; kh < 2; ++kh)                                \
      _Pragma("unroll") for (int qt = 0; qt < 2; ++qt) {                              \
          f32x4 s_ = (f32x4){0.f, 0.f, 0.f, 0.f};                                     \
          s_ = __builtin_amdgcn_mfma_f32_16x16x32_bf16(kf[kh][0], qf[qt][0], s_, 0, 0, 0); \
          s_ = __builtin_amdgcn_mfma_f32_16x16x32_bf16(kf[kh][1], qf[qt][1], s_, 0, 0, 0); \
          st_[kh][qt] = s_; }                                                         \
      _Pragma("unroll") for (int qt = 0; qt < 2; ++qt) {                              \
          bf16x8 pa_;                                                                 \
          float dsum_ = 0.f;                                                          \
          _Pragma("unroll") for (int r = 0; r < 4; ++r) {                             \
              float e0_ = __expf(st_[0][qt][r]);                                      \
              float e1_ = __expf(st_[1][qt][r]);                                      \
              dsum_ += e0_ + e1_;                                                     \
              pa_[r]     = f2bs(e0_);                                                 \
              pa_[4 + r] = f2bs(e1_); }                                               \
          dn[qt] += dsum_;                                                            \
          _Pragma("unroll") for (int dc = 0; dc < 4; ++dc) {                          \
              bf16x8 vf_ = __builtin_shufflevector(vlo[dc], vhi[dc], 0, 1, 2, 3, 4, 5, 6, 7); \
              oacc[qt][dc] = __builtin_amdgcn_mfma_f32_16x16x32_bf16(pa_, vf_, oacc[qt][dc], 0, 0, 0); } } }

    LOADK(kbase, kA); LOADV(kbase, vloA, vhiA);
    for (int kt = 0; kt < 16; kt += 2) {
        int k1 = kbase + (kt + 1) * 32;
        LOADK(k1, kB); LOADV(k1, vloB, vhiB);
        COMPUTE(kA, vloA, vhiA);
        if (kt + 2 < 16) {
            int k2 = kbase + (kt + 2) * 32;
            LOADK(k2, kA); LOADV(k2, vloA, vhiA);
        }
        COMPUTE(kB, vloB, vhiB);
    }
#undef LOADK
#undef LOADV
#undef COMPUTE

    // full per-q denominator: reduce over the 4 lane groups
#pragma unroll
    for (int qt = 0; qt < 2; ++qt) {
        dn[qt] += __shfl_xor(dn[qt], 16);
        dn[qt] += __shfl_xor(dn[qt], 32);
    }

    // LDS merge tree: 8 -> 4 -> 2 -> 1
#define STORE_(s)                                                                   \
    {                                                                               \
        _Pragma("unroll") for (int qt = 0; qt < 2; ++qt) {                          \
            _Pragma("unroll") for (int dc = 0; dc < 4; ++dc)                        \
                _Pragma("unroll") for (int r = 0; r < 4; ++r)                       \
                    redN[s][qt][lgrp * 4 + r][dc * 16 + l16] = oacc[qt][dc][r];     \
            if (lane < 16) redD[s][qt][lane] = dn[qt];                              \
        }                                                                           \
    }
#define ACCUM_(s)                                                                   \
    {                                                                               \
        _Pragma("unroll") for (int qt = 0; qt < 2; ++qt) {                          \
            _Pragma("unroll") for (int dc = 0; dc < 4; ++dc)                        \
                _Pragma("unroll") for (int r = 0; r < 4; ++r)                       \
                    oacc[qt][dc][r] += redN[s][qt][lgrp * 4 + r][dc * 16 + l16];    \
            dn[qt] += redD[s][qt][l16];                                             \
        }                                                                           \
    }
    if (wave >= 4) STORE_(wave - 4);
    __syncthreads();
    if (wave < 4) ACCUM_(wave);
    __syncthreads();
    if (wave == 2 || wave == 3) STORE_(wave - 2);
    __syncthreads();
    if (wave < 2) ACCUM_(wave);
    __syncthreads();
    if (wave == 1) STORE_(0);
    __syncthreads();
    if (wave == 0) {
        ACCUM_(0);
#pragma unroll
        for (int qt = 0; qt < 2; ++qt) {
            float inv = 1.f / dn[qt];
#pragma unroll
            for (int r = 0; r < 4; ++r) {
                float invr = __shfl(inv, lgrp * 4 + r);
#pragma unroll
                for (int dc = 0; dc < 4; ++dc)
                    split_store(oacc[qt][dc][r] * invr, aoH, aoL,
                                (size_t)(q0 + qt * 16 + lgrp * 4 + r) * 256 + h * 64 + dc * 16 + l16);
            }
        }
    }
#undef STORE_
#undef ACCUM_
}

// ---------------- launch ----------------
extern "C" void kernel_launch(void* const* d_in, const int* in_sizes, int n_in,
                              void* d_out, int out_size, void* d_ws, size_t ws_size,
                              hipStream_t stream)
{
    const float* x      = (const float*)d_in[0];
    const int*   ei_t   = (const int*)d_in[1];
    const int*   ei_c   = (const int*)d_in[2];
    const float* ea_t   = (const float*)d_in[3];
    const float* ea_c   = (const float*)d_in[4];
    const float* W_t    = (const float*)d_in[5];
    const float* asrc_t = (const float*)d_in[6];
    const float* adst_t = (const float*)d_in[7];
    const float* We_t   = (const float*)d_in[8];
    const float* aedg_t = (const float*)d_in[9];
    const float* b_t    = (const float*)d_in[10];
    const float* W_c    = (const float*)d_in[11];
    const float* asrc_c = (const float*)d_in[12];
    const float* adst_c = (const float*)d_in[13];
    const float* We_c   = (const float*)d_in[14];
    const float* aedg_c = (const float*)d_in[15];
    const float* b_c    = (const float*)d_in[16];
    const float* Wih    = (const float*)d_in[17];
    const float* bih    = (const float*)d_in[19];
    const float* bhh    = (const float*)d_in[20];
    const float* min_w  = (const float*)d_in[21];
    const float* min_b  = (const float*)d_in[22];
    const float* mout_w = (const float*)d_in[23];
    const float* mout_b = (const float*)d_in[24];
    const float* fus_w  = (const float*)d_in[25];
    const float* fus_b  = (const float*)d_in[26];
    const float* out_w  = (const float*)d_in[27];
    const float* out_b  = (const float*)d_in[28];
    float* outp = (float*)d_out;

    char* W = (char*)d_ws;
    size_t off = 0;
    auto alloc = [&](size_t bytes) { size_t r = off; off += (bytes + 255) & ~(size_t)255; return r; };
    size_t oMean  = alloc(2 * 4);
    size_t oCnt   = alloc(2 * NN_ * 4);
    size_t oCur   = alloc(2 * NN_ * 4);
    size_t zeroBytes = off;
    size_t oRows  = alloc(2 * (NN_ + 16) * 4);
    size_t oSrcs  = alloc(2 * NE * 4);
    size_t oEav   = alloc(2 * NE * 4);
    size_t oWa    = alloc(4 * INF * NH * 4);
    size_t oDote  = alloc(2 * NH * 4);
    size_t oAsd   = alloc(4 * NN_ * NH * 4);
    size_t oBg    = alloc(1024 * 4);
    size_t oGH    = alloc((size_t)2 * NN_ * KK * 2);
    size_t oGL    = alloc((size_t)2 * NN_ * KK * 2);
    size_t oMtH   = alloc((size_t)1024 * KK * 2);
    size_t oMtL   = alloc((size_t)1024 * KK * 2);
    size_t oBctH  = alloc((size_t)CC * KK * 2);
    size_t oBctL  = alloc((size_t)CC * KK * 2);
    size_t oWihH  = alloc((size_t)1024 * HC * 2);      // reused as concatHi
    size_t oWihL  = alloc((size_t)1024 * HC * 2);      // reused as concatLo
    size_t oWtH   = alloc((size_t)INF * HC * 2);
    size_t oWtL   = alloc((size_t)INF * HC * 2);
    size_t oMinH  = alloc((size_t)768 * HID * 2);
    size_t oMinL  = alloc((size_t)768 * HID * 2);
    size_t oMoutH = alloc((size_t)HID * HID * 2);
    size_t oMoutL = alloc((size_t)HID * HID * 2);
    size_t oFusH  = alloc((size_t)HID * 512 * 2);
    size_t oFusL  = alloc((size_t)HID * 512 * 2);
    size_t oOutwH = alloc((size_t)128 * HID * 2);
    size_t oOutwL = alloc((size_t)128 * HID * 2);
    size_t oGates = alloc((size_t)NN_ * 1024 * 4);
    size_t oHcH   = alloc((size_t)NN_ * HID * 2);      // reused as hfusHi
    size_t oHcL   = alloc((size_t)NN_ * HID * 2);      // reused as hfusLo
    size_t oQb    = alloc((size_t)4 * NN_ * 64 * 2);
    size_t oKb    = alloc((size_t)4 * NN_ * 64 * 2);
    size_t oVt    = alloc((size_t)4 * NN_ * 64 * 2);
    size_t oCcH   = oWihH;    // WihSplit dead after Mt GEMM
    size_t oCcL   = oWihL;
    size_t oAoH   = oGH;      // g dead after gates & hc GEMMs
    size_t oAoL   = oGL;
    size_t oHfH   = oHcH;     // hc dead after qkv GEMM
    size_t oHfL   = oHcL;
    (void)ws_size; (void)in_sizes; (void)n_in; (void)out_size;

    hipMemsetAsync(W, 0, zeroBytes, stream);

    // stage 1: weight splits + GAT scalar precomputes + bias_g + mean/hist
    k_stage1<<<11812, 256, 0, stream>>>(
        Wih,    (__hip_bfloat16*)(W + oWihH),  (__hip_bfloat16*)(W + oWihL),
        W_t,    (__hip_bfloat16*)(W + oWtH),   (__hip_bfloat16*)(W + oWtL),
        min_w,  (__hip_bfloat16*)(W + oMinH),  (__hip_bfloat16*)(W + oMinL),
        mout_w, (__hip_bfloat16*)(W + oMoutH), (__hip_bfloat16*)(W + oMoutL),
        fus_w,  (__hip_bfloat16*)(W + oFusH),  (__hip_bfloat16*)(W + oFusL),
        out_w,  (__hip_bfloat16*)(W + oOutwH), (__hip_bfloat16*)(W + oOutwL),
        W_c,    (__hip_bfloat16*)(W + oBctH),  (__hip_bfloat16*)(W + oBctL),
        asrc_t, adst_t, We_t, aedg_t, asrc_c, adst_c, We_c, aedg_c,
        (float*)(W + oWa), (float*)(W + oDote),
        b_t, bih, bhh, (float*)(W + oBg),
        ea_t, ea_c, ei_t, ei_c, (float*)(W + oMean), (int*)(W + oCnt));
    // stage 2: a_s/a_d + CSR scan
    k_stage2<<<514, 256, 0, stream>>>(x, (float*)(W + oWa), (float*)(W + oAsd),
                                      (int*)(W + oCnt), (int*)(W + oRows));
    // Mt[j][h*28+k] = sum_c Wih[j][h*256+c] * Wt[k][h*256+c] — batched over heads
    {
        dim3 grid(8, 1, 8);
        k_mgemm<false, 2, 0><<<grid, 256, 0, stream>>>(
            (__hip_bfloat16*)(W + oWihH), (__hip_bfloat16*)(W + oWihL), HC, CC,
            (__hip_bfloat16*)(W + oWtH),  (__hip_bfloat16*)(W + oWtL),  HC, CC,
            nullptr, nullptr, 0,
            (__hip_bfloat16*)(W + oMtH), (__hip_bfloat16*)(W + oMtL), KK, INF,
            nullptr, nullptr, nullptr,
            0, 1024, INF, CC);
    }
    k_scatter<<<2 * NE / 256, 256, 0, stream>>>(ei_t, ei_c, ea_t, ea_c,
                                                (int*)(W + oRows), (int*)(W + oCur),
                                                (int*)(W + oSrcs), (float*)(W + oEav));
    // GAT aggregation, both branches
    k_gat<<<2 * NN_, 64, 0, stream>>>((int*)(W + oSrcs), (float*)(W + oEav), (int*)(W + oRows), x,
                                      (float*)(W + oAsd), (float*)(W + oDote), (float*)(W + oMean),
                                      (__hip_bfloat16*)(W + oGH), (__hip_bfloat16*)(W + oGL));
    // gates = g_t @ Mt^T + bias_g (skip dead f-gate columns 256..511)
    {
        dim3 grid(32, 12, 1);
        k_mgemm<false, 2, 0><<<grid, 256, 0, stream>>>(
            (__hip_bfloat16*)(W + oGH), (__hip_bfloat16*)(W + oGL), KK, 0,
            (__hip_bfloat16*)(W + oMtH), (__hip_bfloat16*)(W + oMtL), KK, 0,
            (float*)(W + oBg), (float*)(W + oGates), 1024,
            nullptr, nullptr, 0, 0,
            nullptr, nullptr, nullptr,
            256, NN_, 1024, KK);
    }
    k_lstm<<<NN_ * HID / 256, 256, 0, stream>>>((float*)(W + oGates), outp + 524288,
                                                (__hip_bfloat16*)(W + oCcH), (__hip_bfloat16*)(W + oCcL));
    // h_c = g_c @ Bct^T + b_c -> hi/lo
    {
        dim3 grid(64, 4, 1);
        k_mgemm<false, 1, 0><<<grid, 256, 0, stream>>>(
            (__hip_bfloat16*)(W + oGH) + (size_t)NN_ * KK, (__hip_bfloat16*)(W + oGL) + (size_t)NN_ * KK, KK, 0,
            (__hip_bfloat16*)(W + oBctH), (__hip_bfloat16*)(W + oBctL), KK, 0,
            b_c, nullptr, 0,
            (__hip_bfloat16*)(W + oHcH), (__hip_bfloat16*)(W + oHcL), HID, 0,
            nullptr, nullptr, nullptr,
            0, NN_, HID, KK);
    }
    // qkv = h_c @ min_w^T + min_b, written directly as bf16 Qb/Kb/Vt-tiled (fused k_cvt)
    {
        dim3 grid(32, 12, 1);
        k_mgemm<false, 2, 1><<<grid, 256, 0, stream>>>(
            (__hip_bfloat16*)(W + oHcH), (__hip_bfloat16*)(W + oHcL), HID, 0,
            (__hip_bfloat16*)(W + oMinH), (__hip_bfloat16*)(W + oMinL), HID, 0,
            min_b, nullptr, 0,
            nullptr, nullptr, 0, 0,
            (__hip_bfloat16*)(W + oQb), (__hip_bfloat16*)(W + oKb), (__hip_bfloat16*)(W + oVt),
            0, NN_, 768, HID);
    }
    // attention: 32 q-rows/block, tiled-V, register double-buffered K/V stream
    {
        dim3 grid(NN_ / 32, 4);
        k_attn_mfma<<<grid, 512, 0, stream>>>(
            (__hip_bfloat16*)(W + oQb), (__hip_bfloat16*)(W + oKb), (__hip_bfloat16*)(W + oVt),
            (__hip_bfloat16*)(W + oAoH), (__hip_bfloat16*)(W + oAoL));
    }
    // out-proj: concat[:,256:512] (hi/lo) + h_causal (fp32 d_out)
    {
        dim3 grid(64, 4, 1);
        k_mgemm<false, 1, 0><<<grid, 256, 0, stream>>>(
            (__hip_bfloat16*)(W + oAoH), (__hip_bfloat16*)(W + oAoL), HID, 0,
            (__hip_bfloat16*)(W + oMoutH), (__hip_bfloat16*)(W + oMoutL), HID, 0,
            mout_b, outp + 524288 + 1048576, 256,
            (__hip_bfloat16*)(W + oCcH) + 256, (__hip_bfloat16*)(W + oCcL) + 256, 512, 0,
            nullptr, nullptr, nullptr,
            0, NN_, HID, HID);
    }
    // fusion: relu(concat @ fus_w^T + fus_b) -> hi/lo
    {
        dim3 grid(64, 4, 1);
        k_mgemm<true, 1, 0><<<grid, 256, 0, stream>>>(
            (__hip_bfloat16*)(W + oCcH), (__hip_bfloat16*)(W + oCcL), 512, 0,
            (__hip_bfloat16*)(W + oFusH), (__hip_bfloat16*)(W + oFusL), 512, 0,
            fus_b, nullptr, 0,
            (__hip_bfloat16*)(W + oHfH), (__hip_bfloat16*)(W + oHfL), HID, 0,
            nullptr, nullptr, nullptr,
            0, NN_, HID, 512);
    }
    // out = hfus @ out_w^T + out_b (fp32 d_out)
    {
        dim3 grid(64, 2, 1);
        k_mgemm<false, 1, 0><<<grid, 256, 0, stream>>>(
            (__hip_bfloat16*)(W + oHfH), (__hip_bfloat16*)(W + oHfL), HID, 0,
            (__hip_bfloat16*)(W + oOutwH), (__hip_bfloat16*)(W + oOutwL), HID, 0,
            out_b, outp, 128,
            nullptr, nullptr, 0, 0,
            nullptr, nullptr, nullptr,
            0, NN_, 128, HID);
    }
}

// Round 8
// 412.088 us; speedup vs baseline: 4.2772x; 1.0152x over previous
//
#include <hip/hip_runtime.h>
#include <hip/hip_bf16.h>

// ---------------- problem constants ----------------
constexpr int NN_ = 4096;     // nodes
constexpr int INF = 28;       // input features
constexpr int NH  = 8;        // GAT heads
constexpr int CC  = 256;      // channels per head
constexpr int HC  = 2048;     // NH*CC
constexpr int HID = 256;
constexpr int NE  = 131072;   // edges per branch
constexpr int KK  = NH * INF; // 224

typedef short bf16x8 __attribute__((ext_vector_type(8)));
typedef short bf16x4 __attribute__((ext_vector_type(4)));
typedef float f32x4 __attribute__((ext_vector_type(4)));

__device__ inline void split_store(float v, __hip_bfloat16* H, __hip_bfloat16* L, size_t idx)
{
    __hip_bfloat16 h = __float2bfloat16(v);
    H[idx] = h;
    L[idx] = __float2bfloat16(v - __bfloat162float(h));
}

__device__ inline short f2bs(float v)
{
    __hip_bfloat16 h = __float2bfloat16(v);
    return *reinterpret_cast<short*>(&h);
}

__device__ inline float wave_sum(float v)
{
    v += __shfl_xor(v, 1);  v += __shfl_xor(v, 2);  v += __shfl_xor(v, 4);
    v += __shfl_xor(v, 8);  v += __shfl_xor(v, 16); v += __shfl_xor(v, 32);
    return v;
}

// ---------------- stage 1: split_all + small_pre + biasg + mean_hist (one launch) ----------------
__global__ void k_stage1(
    const float* __restrict__ Wih,  __hip_bfloat16* WihH,  __hip_bfloat16* WihL,
    const float* __restrict__ Wt,   __hip_bfloat16* WtH,   __hip_bfloat16* WtL,
    const float* __restrict__ minw, __hip_bfloat16* minH,  __hip_bfloat16* minL,
    const float* __restrict__ moutw,__hip_bfloat16* moutH, __hip_bfloat16* moutL,
    const float* __restrict__ fusw, __hip_bfloat16* fusH,  __hip_bfloat16* fusL,
    const float* __restrict__ outw, __hip_bfloat16* outH,  __hip_bfloat16* outL,
    const float* __restrict__ Wc,   __hip_bfloat16* BH,    __hip_bfloat16* BL,
    const float* __restrict__ ast, const float* __restrict__ adt,
    const float* __restrict__ Wet, const float* __restrict__ aet,
    const float* __restrict__ asc, const float* __restrict__ adc,
    const float* __restrict__ Wec, const float* __restrict__ aec,
    float* __restrict__ wa, float* __restrict__ dote,
    const float* __restrict__ bt, const float* __restrict__ bih, const float* __restrict__ bhh,
    float* __restrict__ bg,
    const float* __restrict__ ea_t, const float* __restrict__ ea_c,
    const int* __restrict__ ei_t, const int* __restrict__ ei_c,
    float* __restrict__ meansum, int* __restrict__ cnt)
{
    int bx = blockIdx.x;
    if (bx < 10304) {
        int i = bx * 256 + threadIdx.x;
        if (i < 2097152)                   split_store(Wih[i],            WihH,  WihL,  i);
        else if (i < 2097152 + 57344)      split_store(Wt[i - 2097152],   WtH,   WtL,   i - 2097152);
        else if (i < 2154496 + 196608)     split_store(minw[i - 2154496], minH,  minL,  i - 2154496);
        else if (i < 2351104 + 65536)      split_store(moutw[i - 2351104],moutH, moutL, i - 2351104);
        else if (i < 2416640 + 131072)     split_store(fusw[i - 2416640], fusH,  fusL,  i - 2416640);
        else if (i < 2547712 + 32768)      split_store(outw[i - 2547712], outH,  outL,  i - 2547712);
        else if (i < 2580480 + 57344) {    // Bct[c][kk] = Wc[k, h*CC+c]/8
            int i2 = i - 2580480;
            int c = i2 / KK, kk = i2 % KK;
            int h = kk / INF, k = kk % INF;
            split_store(Wc[k * HC + h * CC + c] * 0.125f, BH, BL, i2);
        }
    } else if (bx < 10532) {
        int w = ((bx - 10304) * 256 + threadIdx.x) >> 6;
        int lane = threadIdx.x & 63;
        if (w < 2 * 2 * INF * NH) {
            int b = w / (2 * INF * NH);
            int r = w % (2 * INF * NH);
            int kind = r / (INF * NH);
            int r2 = r % (INF * NH);
            int k = r2 / NH, h = r2 % NH;
            const float* Wm = b ? Wc : Wt;
            const float* a  = b ? (kind ? adc : asc) : (kind ? adt : ast);
            float s = 0.f;
            for (int c = lane; c < CC; c += 64) s += Wm[k * HC + h * CC + c] * a[h * CC + c];
            s = wave_sum(s);
            if (lane == 0) wa[((b * 2 + kind) * INF + k) * NH + h] = s;
        } else if (w < 2 * 2 * INF * NH + 16) {
            int j = w - 2 * 2 * INF * NH;
            int b = j / NH, h = j % NH;
            const float* We = b ? Wec : Wet;
            const float* a  = b ? aec : aet;
            float s = 0.f;
            for (int c = lane; c < CC; c += 64) s += We[h * CC + c] * a[h * CC + c];
            s = wave_sum(s);
            if (lane == 0) dote[b * NH + h] = s;
        }
    } else if (bx < 10788) {
        int j = ((bx - 10532) * 256 + threadIdx.x) >> 6;
        int lane = threadIdx.x & 63;
        if (j < 1024) {
            const float* w = Wih + (size_t)j * HC;
            float s = 0.f;
            for (int c = lane; c < HC; c += 64) s += bt[c] * w[c];
            s = wave_sum(s);
            if (lane == 0) bg[j] = s + bih[j] + bhh[j];
        }
    } else {
        int i = (bx - 10788) * 256 + threadIdx.x;
        int b = i / NE, e = i - b * NE;
        float v = (b ? ea_c : ea_t)[e];
        for (int off = 32; off; off >>= 1) v += __shfl_down(v, off);
        if ((threadIdx.x & 63) == 0) atomicAdd(&meansum[b], v);
        const int* ei = b ? ei_c : ei_t;
        atomicAdd(&cnt[b * NN_ + ei[NE + e]], 1);
    }
}

// ---------------- stage 2: as_ad + CSR scan (one launch) ----------------
__global__ __launch_bounds__(256) void k_stage2(
    const float* __restrict__ x, const float* __restrict__ wa, float* __restrict__ asd,
    const int* __restrict__ cnt, int* __restrict__ rows)
{
    int bx = blockIdx.x;
    if (bx < 512) {
        int i = bx * 256 + threadIdx.x;
        int bk = i / (NN_ * NH);
        int r = i % (NN_ * NH);
        int n = r / NH, h = r % NH;
        const float* W = wa + bk * INF * NH;
        const float* xr = x + n * INF;
        float s = 0.f;
#pragma unroll
        for (int k = 0; k < INF; ++k) s += xr[k] * W[k * NH + h];
        asd[(bk * NN_ + n) * NH + h] = s;
    } else {
        int b = bx - 512;
        const int* c = cnt + b * NN_;
        int* r = rows + b * (NN_ + 16);
        __shared__ int ts[256];
        int t = threadIdx.x;
        int v[16]; int s = 0;
#pragma unroll
        for (int i = 0; i < 16; ++i) { v[i] = c[t * 16 + i]; s += v[i]; }
        ts[t] = s;
        __syncthreads();
        for (int off = 1; off < 256; off <<= 1) {
            int add = (t >= off) ? ts[t - off] : 0;
            __syncthreads();
            ts[t] += add;
            __syncthreads();
        }
        int excl = t ? ts[t - 1] : 0;
#pragma unroll
        for (int i = 0; i < 16; ++i) { r[t * 16 + i] = excl; excl += v[i]; }
        if (t == 255) r[NN_] = excl;
    }
}

__global__ void k_scatter(const int* __restrict__ ei_t, const int* __restrict__ ei_c,
                          const float* __restrict__ ea_t, const float* __restrict__ ea_c,
                          const int* __restrict__ rows, int* __restrict__ cur,
                          int* __restrict__ srcs, float* __restrict__ eav)
{
    int i = blockIdx.x * blockDim.x + threadIdx.x;
    if (i >= 2 * NE) return;
    int b = i / NE, e = i - b * NE;
    const int* ei = b ? ei_c : ei_t;
    const float* ea = b ? ea_c : ea_t;
    int d = ei[NE + e];
    int pos = rows[b * (NN_ + 16) + d] + atomicAdd(&cur[b * NN_ + d], 1);
    srcs[b * NE + pos] = ei[e];
    eav[b * NE + pos] = ea[e];
}

// ---------------- GAT per-dst aggregation, both branches in one grid ----------------
__global__ __launch_bounds__(64) void k_gat(
    const int* __restrict__ srcs, const float* __restrict__ eav,
    const int* __restrict__ rows, const float* __restrict__ x,
    const float* __restrict__ asd, const float* __restrict__ dote,
    const float* __restrict__ meansum,
    __hip_bfloat16* __restrict__ gH, __hip_bfloat16* __restrict__ gL)
{
    int b = blockIdx.x >> 12;           // branch
    int n = blockIdx.x & 4095;
    srcs += (size_t)b * NE; eav += (size_t)b * NE; rows += b * (NN_ + 16);
    const float* a_s = asd + (size_t)(2 * b) * NN_ * NH;
    const float* a_d = asd + (size_t)(2 * b + 1) * NN_ * NH;
    dote += b * NH;
    gH += (size_t)b * NN_ * KK; gL += (size_t)b * NN_ * KK;

    int lane = threadIdx.x;
    __shared__ float xb[64][32];
    __shared__ float eb[64][8];
    __shared__ float denb[8];

    float adn[NH], dt[NH];
#pragma unroll
    for (int h = 0; h < NH; ++h) { adn[h] = a_d[n * NH + h]; dt[h] = dote[h]; }
    float mean_attr = meansum[b] * (1.0f / NE);

    const int hOwn = lane >> 3;
    const int kOwn = (lane & 7) * 4;

    float acc0, acc1, acc2, acc3;
    {
        float al = a_s[n * NH + hOwn] + adn[hOwn] + mean_attr * dt[hOwn];
        al = al > 0.f ? al : 0.2f * al;
        float es = __expf(al);
        float xv0 = (kOwn + 0 < INF) ? x[n * INF + kOwn + 0] : 0.f;
        float xv1 = (kOwn + 1 < INF) ? x[n * INF + kOwn + 1] : 0.f;
        float xv2 = (kOwn + 2 < INF) ? x[n * INF + kOwn + 2] : 0.f;
        float xv3 = (kOwn + 3 < INF) ? x[n * INF + kOwn + 3] : ((kOwn + 3 == 31) ? 1.f : 0.f);
        acc0 = es * xv0; acc1 = es * xv1; acc2 = es * xv2; acc3 = es * xv3;
    }

    int e0 = rows[n], e1 = rows[n + 1];
    for (int base = e0; base < e1; base += 64) {
        int m = e1 - base; if (m > 64) m = 64;
        if (lane < m) {
            int sidx = srcs[base + lane];
            float ea = eav[base + lane];
            const float4* xr = (const float4*)(x + sidx * INF);
#pragma unroll
            for (int q = 0; q < 7; ++q) ((float4*)&xb[lane][0])[q] = xr[q];
            xb[lane][28] = 0.f; xb[lane][29] = 0.f; xb[lane][30] = 0.f; xb[lane][31] = 1.f;
            const float* asr = a_s + sidx * NH;
#pragma unroll
            for (int h = 0; h < NH; ++h) {
                float al = asr[h] + adn[h] + ea * dt[h];
                al = al > 0.f ? al : 0.2f * al;
                eb[lane][h] = __expf(al);
            }
        }
        __syncthreads();
        for (int j = 0; j < m; ++j) {
            float e = eb[j][hOwn];
            float4 xv = *(const float4*)&xb[j][kOwn];
            acc0 += e * xv.x; acc1 += e * xv.y; acc2 += e * xv.z; acc3 += e * xv.w;
        }
        __syncthreads();
    }

    if ((lane & 7) == 7) denb[hOwn] = acc3;
    __syncthreads();
    float inv = 1.0f / denb[hOwn];
    size_t gr = (size_t)n * KK + hOwn * INF + kOwn;
    if (kOwn + 0 < INF) split_store(acc0 * inv, gH, gL, gr + 0);
    if (kOwn + 1 < INF) split_store(acc1 * inv, gH, gL, gr + 1);
    if (kOwn + 2 < INF) split_store(acc2 * inv, gH, gL, gr + 2);
    if (kOwn + 3 < INF) split_store(acc3 * inv, gH, gL, gr + 3);
}

// ---------------- bf16x3-split MFMA GEMM ----------------
// MS: rows per wave /16. EPI==1: write qkv directly as bf16
// Qb[h][n][64]*0.125 / Kb[h][n][64] / Vt[h][kt][64][32] (replaces k_cvt).
template<bool RELU, int MS, int EPI>
__global__ __launch_bounds__(256) void k_mgemm(
    const __hip_bfloat16* __restrict__ Ahi_, const __hip_bfloat16* __restrict__ Alo_, int lda, int aOffZ,
    const __hip_bfloat16* __restrict__ Bhi_, const __hip_bfloat16* __restrict__ Blo_, int ldb, int bOffZ,
    const float* __restrict__ bias,
    float* __restrict__ Cf, int ldcf,
    __hip_bfloat16* __restrict__ Chi, __hip_bfloat16* __restrict__ Clo, int ldch, int cOffZ,
    __hip_bfloat16* __restrict__ Qbp, __hip_bfloat16* __restrict__ Kbp, __hip_bfloat16* __restrict__ Vtp,
    int M, int N, int K)
{
    int z = blockIdx.z;
    const short* Ah = (const short*)Ahi_ + (size_t)z * aOffZ;
    const short* Al = (const short*)Alo_ + (size_t)z * aOffZ;
    const short* Bh = (const short*)Bhi_ + (size_t)z * bOffZ;
    const short* Bl = (const short*)Blo_ + (size_t)z * bOffZ;
    int wave = threadIdx.x >> 6, lane = threadIdx.x & 63;
    int l16 = lane & 15, lgrp = lane >> 4;
    int m0 = blockIdx.x * (64 * MS) + wave * (16 * MS);
    int n0 = blockIdx.y * 64;

    f32x4 acc[MS][4];
#pragma unroll
    for (int i = 0; i < MS; ++i)
#pragma unroll
        for (int j = 0; j < 4; ++j) acc[i][j] = (f32x4){0.f, 0.f, 0.f, 0.f};

    int nrow[4]; bool nval[4];
#pragma unroll
    for (int ns = 0; ns < 4; ++ns) { nrow[ns] = n0 + ns * 16 + l16; nval[ns] = nrow[ns] < N; }

#pragma unroll 2
    for (int k0 = 0; k0 < K; k0 += 32) {
        size_t ka = (size_t)k0 + lgrp * 8;
        bf16x8 ah[MS], al[MS];
#pragma unroll
        for (int ms = 0; ms < MS; ++ms) {
            ah[ms] = *(const bf16x8*)(Ah + (size_t)(m0 + ms * 16 + l16) * lda + ka);
            al[ms] = *(const bf16x8*)(Al + (size_t)(m0 + ms * 16 + l16) * lda + ka);
        }
        bf16x8 bh[4], bl[4];
#pragma unroll
        for (int ns = 0; ns < 4; ++ns) {
            bh[ns] = (bf16x8){0, 0, 0, 0, 0, 0, 0, 0};
            bl[ns] = (bf16x8){0, 0, 0, 0, 0, 0, 0, 0};
            if (nval[ns]) {
                bh[ns] = *(const bf16x8*)(Bh + (size_t)nrow[ns] * ldb + ka);
                bl[ns] = *(const bf16x8*)(Bl + (size_t)nrow[ns] * ldb + ka);
            }
        }
#pragma unroll
        for (int ns = 0; ns < 4; ++ns)
#pragma unroll
            for (int ms = 0; ms < MS; ++ms) {
                acc[ms][ns] = __builtin_amdgcn_mfma_f32_16x16x32_bf16(ah[ms], bh[ns], acc[ms][ns], 0, 0, 0);
                acc[ms][ns] = __builtin_amdgcn_mfma_f32_16x16x32_bf16(ah[ms], bl[ns], acc[ms][ns], 0, 0, 0);
                acc[ms][ns] = __builtin_amdgcn_mfma_f32_16x16x32_bf16(al[ms], bh[ns], acc[ms][ns], 0, 0, 0);
            }
    }

#pragma unroll
    for (int ms = 0; ms < MS; ++ms)
#pragma unroll
        for (int ns = 0; ns < 4; ++ns)
#pragma unroll
            for (int r = 0; r < 4; ++r) {
                int m = m0 + ms * 16 + lgrp * 4 + r;
                int n = n0 + ns * 16 + l16;
                if (n >= N) continue;
                float v = acc[ms][ns][r];
                if (bias) v += bias[n];
                if (RELU) v = v > 0.f ? v : 0.f;
                if (EPI == 1) {
                    int sec = n >> 8, hh = (n >> 6) & 3, d = n & 63;
                    if (sec == 0)      Qbp[((size_t)hh * NN_ + m) * 64 + d] = __float2bfloat16(v * 0.125f);
                    else if (sec == 1) Kbp[((size_t)hh * NN_ + m) * 64 + d] = __float2bfloat16(v);
                    else               Vtp[(((size_t)hh * (NN_ / 32) + (m >> 5)) * 64 + d) * 32 + (m & 31)]
                                           = __float2bfloat16(v);
                } else {
                    if (Cf) Cf[(size_t)m * ldcf + n] = v;
                    if (Chi) split_store(v, Chi, Clo, (size_t)m * ldch + (size_t)z * cOffZ + n);
                }
            }
}

// ---------------- fused gates GEMM + LSTM ----------------
// gates = g_t @ Mt^T (+bias_g) for sections i/g/o only (f-gate dead: c0=0), then
// LSTM elementwise in-register; writes h_temporal (fp32 d_out) + concat hi/lo.
// grid (NN_/64, HID/64), 256 thr = 4 waves, wave owns 16 rows. A preloaded once.
__global__ __launch_bounds__(256) void k_gates_lstm(
    const __hip_bfloat16* __restrict__ gHi, const __hip_bfloat16* __restrict__ gLo,
    const __hip_bfloat16* __restrict__ MtH, const __hip_bfloat16* __restrict__ MtL,
    const float* __restrict__ bg,
    float* __restrict__ hout, __hip_bfloat16* __restrict__ ccH, __hip_bfloat16* __restrict__ ccL)
{
    int wave = threadIdx.x >> 6, lane = threadIdx.x & 63;
    int l16 = lane & 15, lgrp = lane >> 4;
    int m0 = blockIdx.x * 64 + wave * 16;
    int n0 = blockIdx.y * 64;
    const short* Ah = (const short*)gHi;
    const short* Al = (const short*)gLo;
    const short* Bh = (const short*)MtH;
    const short* Bl = (const short*)MtL;

    // preload the wave's A fragments for all 7 k-steps (K=224)
    bf16x8 ah[7], al[7];
#pragma unroll
    for (int k = 0; k < 7; ++k) {
        size_t ka = (size_t)k * 32 + lgrp * 8;
        ah[k] = *(const bf16x8*)(Ah + (size_t)(m0 + l16) * KK + ka);
        al[k] = *(const bf16x8*)(Al + (size_t)(m0 + l16) * KK + ka);
    }

    const int secBase[3] = {0, 512, 768};   // i, g, o rows of Mt
    f32x4 acc[3][4];
#pragma unroll
    for (int s = 0; s < 3; ++s) {
#pragma unroll
        for (int ns = 0; ns < 4; ++ns) acc[s][ns] = (f32x4){0.f, 0.f, 0.f, 0.f};
        const short* Bhs = Bh + (size_t)(secBase[s] + n0) * KK;
        const short* Bls = Bl + (size_t)(secBase[s] + n0) * KK;
#pragma unroll
        for (int k = 0; k < 7; ++k) {
            size_t ka = (size_t)k * 32 + lgrp * 8;
            bf16x8 bh[4], bl[4];
#pragma unroll
            for (int ns = 0; ns < 4; ++ns) {
                bh[ns] = *(const bf16x8*)(Bhs + (size_t)(ns * 16 + l16) * KK + ka);
                bl[ns] = *(const bf16x8*)(Bls + (size_t)(ns * 16 + l16) * KK + ka);
            }
#pragma unroll
            for (int ns = 0; ns < 4; ++ns) {
                acc[s][ns] = __builtin_amdgcn_mfma_f32_16x16x32_bf16(ah[k], bh[ns], acc[s][ns], 0, 0, 0);
                acc[s][ns] = __builtin_amdgcn_mfma_f32_16x16x32_bf16(ah[k], bl[ns], acc[s][ns], 0, 0, 0);
                acc[s][ns] = __builtin_amdgcn_mfma_f32_16x16x32_bf16(al[k], bh[ns], acc[s][ns], 0, 0, 0);
            }
        }
    }

#pragma unroll
    for (int ns = 0; ns < 4; ++ns)
#pragma unroll
        for (int r = 0; r < 4; ++r) {
            int m = m0 + lgrp * 4 + r;
            int n = n0 + ns * 16 + l16;
            float gi = acc[0][ns][r] + bg[n];
            float gg = acc[1][ns][r] + bg[512 + n];
            float go = acc[2][ns][r] + bg[768 + n];
            float c = (1.f / (1.f + __expf(-gi))) * tanhf(gg);
            float h = (1.f / (1.f + __expf(-go))) * tanhf(c);
            hout[(size_t)m * 256 + n] = h;
            split_store(h, ccH, ccL, (size_t)m * 512 + n);
        }
}

// ---------------- MHA: bf16 MFMA flash attention ----------------
// grid 512 (flattened), 512 thr = 8 waves. Head→XCD-group swizzle: xcd = wg&7
// serves head xcd>>1, so each XCD's L2 holds ONE head's K/V (1.5MB << 4MB) —
// fixes the 17.4MB HBM re-fetch (6MB working set thrashing all 8 L2s).
// Block owns 32 q-rows; wave w covers keys [w*512, w*512+512). Swapped QK^T,
// in-register softmax/PV, tiled V (Vt[h][kt][64][32]).
__global__ __launch_bounds__(512) void k_attn_mfma(
    const __hip_bfloat16* __restrict__ Qb, const __hip_bfloat16* __restrict__ Kb,
    const __hip_bfloat16* __restrict__ Vt,
    __hip_bfloat16* __restrict__ aoH, __hip_bfloat16* __restrict__ aoL)
{
    __shared__ float redN[4][2][16][65];
    __shared__ float redD[4][2][16];
    int tid = threadIdx.x;
    int wave = tid >> 6, lane = tid & 63;
    int l16 = lane & 15, lgrp = lane >> 4;
    int wg = blockIdx.x;
    int xcd = wg & 7;
    int h = xcd >> 1;
    int q0 = (((wg >> 3) << 1) | (xcd & 1)) * 32;
    int kbase = wave * 512;

    const short* Qs = (const short*)Qb;
    const short* Kbase_ = (const short*)Kb + (size_t)h * NN_ * 64;
    const short* Vbase_ = (const short*)Vt + (size_t)h * NN_ * 64;

    bf16x8 qf[2][2];
#pragma unroll
    for (int qt = 0; qt < 2; ++qt)
#pragma unroll
        for (int dh = 0; dh < 2; ++dh)
            qf[qt][dh] = *(const bf16x8*)(Qs + ((size_t)h * NN_ + q0 + qt * 16 + l16) * 64 + dh * 32 + lgrp * 8);

    f32x4 oacc[2][4];
#pragma unroll
    for (int qt = 0; qt < 2; ++qt)
#pragma unroll
        for (int dc = 0; dc < 4; ++dc) oacc[qt][dc] = (f32x4){0.f, 0.f, 0.f, 0.f};
    float dn[2] = {0.f, 0.f};

    bf16x8 kA[2][2], kB[2][2];
    bf16x4 vloA[4], vhiA[4], vloB[4], vhiB[4];

#define LOADK(K0, kf)                                                                 \
    { int k0_ = (K0);                                                                 \
      _Pragma("unroll") for (int kh = 0; kh < 2; ++kh)                                \
      _Pragma("unroll") for (int dh = 0; dh < 2; ++dh)                                \
          kf[kh][dh] = *(const bf16x8*)(Kbase_ + (size_t)(k0_ + kh * 16 + l16) * 64   \
                                        + dh * 32 + lgrp * 8); }
#define LOADV(K0, vlo, vhi)                                                           \
    { const short* tb_ = Vbase_ + ((size_t)((K0) >> 5)) * 2048;                       \
      _Pragma("unroll") for (int dc = 0; dc < 4; ++dc) {                              \
          const short* vp_ = tb_ + (dc * 16 + l16) * 32 + lgrp * 4;                   \
          vlo[dc] = *(const bf16x4*)vp_;                                              \
          vhi[dc] = *(const bf16x4*)(vp_ + 16); } }
#define COMPUTE(kf, vlo, vhi)                                                         \
    { f32x4 st_[2][2];                                                                \
      _Pragma("unroll") for (int kh = 0; kh < 2; ++kh)                                \
      _Pragma("unroll") for (int qt = 0; qt < 2; ++qt) {                              \
          f32x4 s_ = (f32x4){0.f, 0.f, 0.f, 0.f};                                     \
          s_ = __builtin_amdgcn_mfma_f32_16x16x32_bf16(kf[kh][0], qf[qt][0], s_, 0, 0, 0); \
          s_ = __builtin_amdgcn_mfma_f32_16x16x32_bf16(kf[kh][1], qf[qt][1], s_, 0, 0, 0); \
          st_[kh][qt] = s_; }                                                         \
      _Pragma("unroll") for (int qt = 0; qt < 2; ++qt) {                              \
          bf16x8 pa_;                                                                 \
          float dsum_ = 0.f;                                                          \
          _Pragma("unroll") for (int r = 0; r < 4; ++r) {                             \
              float e0_ = __expf(st_[0][qt][r]);                                      \
              float e1_ = __expf(st_[1][qt][r]);                                      \
              dsum_ += e0_ + e1_;                                                     \
              pa_[r]     = f2bs(e0_);                                                 \
              pa_[4 + r] = f2bs(e1_); }                                               \
          dn[qt] += dsum_;                                                            \
          _Pragma("unroll") for (int dc = 0; dc < 4; ++dc) {                          \
              bf16x8 vf_ = __builtin_shufflevector(vlo[dc], vhi[dc], 0, 1, 2, 3, 4, 5, 6, 7); \
              oacc[qt][dc] = __builtin_amdgcn_mfma_f32_16x16x32_bf16(pa_, vf_, oacc[qt][dc], 0, 0, 0); } } }

    LOADK(kbase, kA); LOADV(kbase, vloA, vhiA);
    for (int kt = 0; kt < 16; kt += 2) {
        int k1 = kbase + (kt + 1) * 32;
        LOADK(k1, kB); LOADV(k1, vloB, vhiB);
        COMPUTE(kA, vloA, vhiA);
        if (kt + 2 < 16) {
            int k2 = kbase + (kt + 2) * 32;
            LOADK(k2, kA); LOADV(k2, vloA, vhiA);
        }
        COMPUTE(kB, vloB, vhiB);
    }
#undef LOADK
#undef LOADV
#undef COMPUTE

    // full per-q denominator: reduce over the 4 lane groups
#pragma unroll
    for (int qt = 0; qt < 2; ++qt) {
        dn[qt] += __shfl_xor(dn[qt], 16);
        dn[qt] += __shfl_xor(dn[qt], 32);
    }

    // LDS merge tree: 8 -> 4 -> 2 -> 1
#define STORE_(s)                                                                   \
    {                                                                               \
        _Pragma("unroll") for (int qt = 0; qt < 2; ++qt) {                          \
            _Pragma("unroll") for (int dc = 0; dc < 4; ++dc)                        \
                _Pragma("unroll") for (int r = 0; r < 4; ++r)                       \
                    redN[s][qt][lgrp * 4 + r][dc * 16 + l16] = oacc[qt][dc][r];     \
            if (lane < 16) redD[s][qt][lane] = dn[qt];                              \
        }                                                                           \
    }
#define ACCUM_(s)                                                                   \
    {                                                                               \
        _Pragma("unroll") for (int qt = 0; qt < 2; ++qt) {                          \
            _Pragma("unroll") for (int dc = 0; dc < 4; ++dc)                        \
                _Pragma("unroll") for (int r = 0; r < 4; ++r)                       \
                    oacc[qt][dc][r] += redN[s][qt][lgrp * 4 + r][dc * 16 + l16];    \
            dn[qt] += redD[s][qt][l16];                                             \
        }                                                                           \
    }
    if (wave >= 4) STORE_(wave - 4);
    __syncthreads();
    if (wave < 4) ACCUM_(wave);
    __syncthreads();
    if (wave == 2 || wave == 3) STORE_(wave - 2);
    __syncthreads();
    if (wave < 2) ACCUM_(wave);
    __syncthreads();
    if (wave == 1) STORE_(0);
    __syncthreads();
    if (wave == 0) {
        ACCUM_(0);
#pragma unroll
        for (int qt = 0; qt < 2; ++qt) {
            float inv = 1.f / dn[qt];
#pragma unroll
            for (int r = 0; r < 4; ++r) {
                float invr = __shfl(inv, lgrp * 4 + r);
#pragma unroll
                for (int dc = 0; dc < 4; ++dc)
                    split_store(oacc[qt][dc][r] * invr, aoH, aoL,
                                (size_t)(q0 + qt * 16 + lgrp * 4 + r) * 256 + h * 64 + dc * 16 + l16);
            }
        }
    }
#undef STORE_
#undef ACCUM_
}

// ---------------- launch ----------------
extern "C" void kernel_launch(void* const* d_in, const int* in_sizes, int n_in,
                              void* d_out, int out_size, void* d_ws, size_t ws_size,
                              hipStream_t stream)
{
    const float* x      = (const float*)d_in[0];
    const int*   ei_t   = (const int*)d_in[1];
    const int*   ei_c   = (const int*)d_in[2];
    const float* ea_t   = (const float*)d_in[3];
    const float* ea_c   = (const float*)d_in[4];
    const float* W_t    = (const float*)d_in[5];
    const float* asrc_t = (const float*)d_in[6];
    const float* adst_t = (const float*)d_in[7];
    const float* We_t   = (const float*)d_in[8];
    const float* aedg_t = (const float*)d_in[9];
    const float* b_t    = (const float*)d_in[10];
    const float* W_c    = (const float*)d_in[11];
    const float* asrc_c = (const float*)d_in[12];
    const float* adst_c = (const float*)d_in[13];
    const float* We_c   = (const float*)d_in[14];
    const float* aedg_c = (const float*)d_in[15];
    const float* b_c    = (const float*)d_in[16];
    const float* Wih    = (const float*)d_in[17];
    const float* bih    = (const float*)d_in[19];
    const float* bhh    = (const float*)d_in[20];
    const float* min_w  = (const float*)d_in[21];
    const float* min_b  = (const float*)d_in[22];
    const float* mout_w = (const float*)d_in[23];
    const float* mout_b = (const float*)d_in[24];
    const float* fus_w  = (const float*)d_in[25];
    const float* fus_b  = (const float*)d_in[26];
    const float* out_w  = (const float*)d_in[27];
    const float* out_b  = (const float*)d_in[28];
    float* outp = (float*)d_out;

    char* W = (char*)d_ws;
    size_t off = 0;
    auto alloc = [&](size_t bytes) { size_t r = off; off += (bytes + 255) & ~(size_t)255; return r; };
    size_t oMean  = alloc(2 * 4);
    size_t oCnt   = alloc(2 * NN_ * 4);
    size_t oCur   = alloc(2 * NN_ * 4);
    size_t zeroBytes = off;
    size_t oRows  = alloc(2 * (NN_ + 16) * 4);
    size_t oSrcs  = alloc(2 * NE * 4);
    size_t oEav   = alloc(2 * NE * 4);
    size_t oWa    = alloc(4 * INF * NH * 4);
    size_t oDote  = alloc(2 * NH * 4);
    size_t oAsd   = alloc(4 * NN_ * NH * 4);
    size_t oBg    = alloc(1024 * 4);
    size_t oGH    = alloc((size_t)2 * NN_ * KK * 2);
    size_t oGL    = alloc((size_t)2 * NN_ * KK * 2);
    size_t oMtH   = alloc((size_t)1024 * KK * 2);
    size_t oMtL   = alloc((size_t)1024 * KK * 2);
    size_t oBctH  = alloc((size_t)CC * KK * 2);
    size_t oBctL  = alloc((size_t)CC * KK * 2);
    size_t oWihH  = alloc((size_t)1024 * HC * 2);      // reused as concatHi
    size_t oWihL  = alloc((size_t)1024 * HC * 2);      // reused as concatLo
    size_t oWtH   = alloc((size_t)INF * HC * 2);
    size_t oWtL   = alloc((size_t)INF * HC * 2);
    size_t oMinH  = alloc((size_t)768 * HID * 2);
    size_t oMinL  = alloc((size_t)768 * HID * 2);
    size_t oMoutH = alloc((size_t)HID * HID * 2);
    size_t oMoutL = alloc((size_t)HID * HID * 2);
    size_t oFusH  = alloc((size_t)HID * 512 * 2);
    size_t oFusL  = alloc((size_t)HID * 512 * 2);
    size_t oOutwH = alloc((size_t)128 * HID * 2);
    size_t oOutwL = alloc((size_t)128 * HID * 2);
    size_t oHcH   = alloc((size_t)NN_ * HID * 2);      // reused as hfusHi
    size_t oHcL   = alloc((size_t)NN_ * HID * 2);      // reused as hfusLo
    size_t oQb    = alloc((size_t)4 * NN_ * 64 * 2);
    size_t oKb    = alloc((size_t)4 * NN_ * 64 * 2);
    size_t oVt    = alloc((size_t)4 * NN_ * 64 * 2);
    size_t oCcH   = oWihH;    // WihSplit dead after Mt GEMM
    size_t oCcL   = oWihL;
    size_t oAoH   = oGH;      // g dead after gates & hc GEMMs
    size_t oAoL   = oGL;
    size_t oHfH   = oHcH;     // hc dead after qkv GEMM
    size_t oHfL   = oHcL;
    (void)ws_size; (void)in_sizes; (void)n_in; (void)out_size;

    hipMemsetAsync(W, 0, zeroBytes, stream);

    // stage 1: weight splits + GAT scalar precomputes + bias_g + mean/hist
    k_stage1<<<11812, 256, 0, stream>>>(
        Wih,    (__hip_bfloat16*)(W + oWihH),  (__hip_bfloat16*)(W + oWihL),
        W_t,    (__hip_bfloat16*)(W + oWtH),   (__hip_bfloat16*)(W + oWtL),
        min_w,  (__hip_bfloat16*)(W + oMinH),  (__hip_bfloat16*)(W + oMinL),
        mout_w, (__hip_bfloat16*)(W + oMoutH), (__hip_bfloat16*)(W + oMoutL),
        fus_w,  (__hip_bfloat16*)(W + oFusH),  (__hip_bfloat16*)(W + oFusL),
        out_w,  (__hip_bfloat16*)(W + oOutwH), (__hip_bfloat16*)(W + oOutwL),
        W_c,    (__hip_bfloat16*)(W + oBctH),  (__hip_bfloat16*)(W + oBctL),
        asrc_t, adst_t, We_t, aedg_t, asrc_c, adst_c, We_c, aedg_c,
        (float*)(W + oWa), (float*)(W + oDote),
        b_t, bih, bhh, (float*)(W + oBg),
        ea_t, ea_c, ei_t, ei_c, (float*)(W + oMean), (int*)(W + oCnt));
    // stage 2: a_s/a_d + CSR scan
    k_stage2<<<514, 256, 0, stream>>>(x, (float*)(W + oWa), (float*)(W + oAsd),
                                      (int*)(W + oCnt), (int*)(W + oRows));
    // Mt[j][h*28+k] = sum_c Wih[j][h*256+c] * Wt[k][h*256+c] — batched over heads
    {
        dim3 grid(8, 1, 8);
        k_mgemm<false, 2, 0><<<grid, 256, 0, stream>>>(
            (__hip_bfloat16*)(W + oWihH), (__hip_bfloat16*)(W + oWihL), HC, CC,
            (__hip_bfloat16*)(W + oWtH),  (__hip_bfloat16*)(W + oWtL),  HC, CC,
            nullptr, nullptr, 0,
            (__hip_bfloat16*)(W + oMtH), (__hip_bfloat16*)(W + oMtL), KK, INF,
            nullptr, nullptr, nullptr,
            1024, INF, CC);
    }
    k_scatter<<<2 * NE / 256, 256, 0, stream>>>(ei_t, ei_c, ea_t, ea_c,
                                                (int*)(W + oRows), (int*)(W + oCur),
                                                (int*)(W + oSrcs), (float*)(W + oEav));
    // GAT aggregation, both branches
    k_gat<<<2 * NN_, 64, 0, stream>>>((int*)(W + oSrcs), (float*)(W + oEav), (int*)(W + oRows), x,
                                      (float*)(W + oAsd), (float*)(W + oDote), (float*)(W + oMean),
                                      (__hip_bfloat16*)(W + oGH), (__hip_bfloat16*)(W + oGL));
    // fused gates GEMM (i/g/o) + LSTM -> h_temporal (d_out) + concat hi/lo
    {
        dim3 grid(NN_ / 64, HID / 64);
        k_gates_lstm<<<grid, 256, 0, stream>>>(
            (__hip_bfloat16*)(W + oGH), (__hip_bfloat16*)(W + oGL),
            (__hip_bfloat16*)(W + oMtH), (__hip_bfloat16*)(W + oMtL),
            (float*)(W + oBg),
            outp + 524288, (__hip_bfloat16*)(W + oCcH), (__hip_bfloat16*)(W + oCcL));
    }
    // h_c = g_c @ Bct^T + b_c -> hi/lo
    {
        dim3 grid(64, 4, 1);
        k_mgemm<false, 1, 0><<<grid, 256, 0, stream>>>(
            (__hip_bfloat16*)(W + oGH) + (size_t)NN_ * KK, (__hip_bfloat16*)(W + oGL) + (size_t)NN_ * KK, KK, 0,
            (__hip_bfloat16*)(W + oBctH), (__hip_bfloat16*)(W + oBctL), KK, 0,
            b_c, nullptr, 0,
            (__hip_bfloat16*)(W + oHcH), (__hip_bfloat16*)(W + oHcL), HID, 0,
            nullptr, nullptr, nullptr,
            NN_, HID, KK);
    }
    // qkv = h_c @ min_w^T + min_b, written directly as bf16 Qb/Kb/Vt-tiled (fused k_cvt)
    {
        dim3 grid(32, 12, 1);
        k_mgemm<false, 2, 1><<<grid, 256, 0, stream>>>(
            (__hip_bfloat16*)(W + oHcH), (__hip_bfloat16*)(W + oHcL), HID, 0,
            (__hip_bfloat16*)(W + oMinH), (__hip_bfloat16*)(W + oMinL), HID, 0,
            min_b, nullptr, 0,
            nullptr, nullptr, 0, 0,
            (__hip_bfloat16*)(W + oQb), (__hip_bfloat16*)(W + oKb), (__hip_bfloat16*)(W + oVt),
            NN_, 768, HID);
    }
    // attention: head->XCD-group swizzled blocks, tiled-V, reg double-buffer
    {
        k_attn_mfma<<<512, 512, 0, stream>>>(
            (__hip_bfloat16*)(W + oQb), (__hip_bfloat16*)(W + oKb), (__hip_bfloat16*)(W + oVt),
            (__hip_bfloat16*)(W + oAoH), (__hip_bfloat16*)(W + oAoL));
    }
    // out-proj: concat[:,256:512] (hi/lo) + h_causal (fp32 d_out)
    {
        dim3 grid(64, 4, 1);
        k_mgemm<false, 1, 0><<<grid, 256, 0, stream>>>(
            (__hip_bfloat16*)(W + oAoH), (__hip_bfloat16*)(W + oAoL), HID, 0,
            (__hip_bfloat16*)(W + oMoutH), (__hip_bfloat16*)(W + oMoutL), HID, 0,
            mout_b, outp + 524288 + 1048576, 256,
            (__hip_bfloat16*)(W + oCcH) + 256, (__hip_bfloat16*)(W + oCcL) + 256, 512, 0,
            nullptr, nullptr, nullptr,
            NN_, HID, HID);
    }
    // fusion: relu(concat @ fus_w^T + fus_b) -> hi/lo
    {
        dim3 grid(64, 4, 1);
        k_mgemm<true, 1, 0><<<grid, 256, 0, stream>>>(
            (__hip_bfloat16*)(W + oCcH), (__hip_bfloat16*)(W + oCcL), 512, 0,
            (__hip_bfloat16*)(W + oFusH), (__hip_bfloat16*)(W + oFusL), 512, 0,
            fus_b, nullptr, 0,
            (__hip_bfloat16*)(W + oHfH), (__hip_bfloat16*)(W + oHfL), HID, 0,
            nullptr, nullptr, nullptr,
            NN_, HID, 512);
    }
    // out = hfus @ out_w^T + out_b (fp32 d_out)
    {
        dim3 grid(64, 2, 1);
        k_mgemm<false, 1, 0><<<grid, 256, 0, stream>>>(
            (__hip_bfloat16*)(W + oHfH), (__hip_bfloat16*)(W + oHfL), HID, 0,
            (__hip_bfloat16*)(W + oOutwH), (__hip_bfloat16*)(W + oOutwL), HID, 0,
            out_b, outp, 128,
            nullptr, nullptr, 0, 0,
            nullptr, nullptr, nullptr,
            NN_, 128, HID);
    }
}

// Round 9
// 401.411 us; speedup vs baseline: 4.3909x; 1.0266x over previous
//
#include <hip/hip_runtime.h>
#include <hip/hip_bf16.h>

// ---------------- problem constants ----------------
constexpr int NN_ = 4096;     // nodes
constexpr int INF = 28;       // input features
constexpr int NH  = 8;        // GAT heads
constexpr int CC  = 256;      // channels per head
constexpr int HC  = 2048;     // NH*CC
constexpr int HID = 256;
constexpr int NE  = 131072;   // edges per branch
constexpr int KK  = NH * INF; // 224

typedef short bf16x8 __attribute__((ext_vector_type(8)));
typedef short bf16x4 __attribute__((ext_vector_type(4)));
typedef float f32x4 __attribute__((ext_vector_type(4)));

__device__ inline void split_store(float v, __hip_bfloat16* H, __hip_bfloat16* L, size_t idx)
{
    __hip_bfloat16 h = __float2bfloat16(v);
    H[idx] = h;
    L[idx] = __float2bfloat16(v - __bfloat162float(h));
}

__device__ inline short f2bs(float v)
{
    __hip_bfloat16 h = __float2bfloat16(v);
    return *reinterpret_cast<short*>(&h);
}

__device__ inline float wave_sum(float v)
{
    v += __shfl_xor(v, 1);  v += __shfl_xor(v, 2);  v += __shfl_xor(v, 4);
    v += __shfl_xor(v, 8);  v += __shfl_xor(v, 16); v += __shfl_xor(v, 32);
    return v;
}

// ---------------- stage 1: split_all + small_pre + biasg + mean_hist (one launch) ----------------
__global__ void k_stage1(
    const float* __restrict__ Wih,  __hip_bfloat16* WihH,  __hip_bfloat16* WihL,
    const float* __restrict__ Wt,   __hip_bfloat16* WtH,   __hip_bfloat16* WtL,
    const float* __restrict__ minw, __hip_bfloat16* minH,  __hip_bfloat16* minL,
    const float* __restrict__ moutw,__hip_bfloat16* moutH, __hip_bfloat16* moutL,
    const float* __restrict__ fusw, __hip_bfloat16* fusH,  __hip_bfloat16* fusL,
    const float* __restrict__ outw, __hip_bfloat16* outH,  __hip_bfloat16* outL,
    const float* __restrict__ Wc,   __hip_bfloat16* BH,    __hip_bfloat16* BL,
    const float* __restrict__ ast, const float* __restrict__ adt,
    const float* __restrict__ Wet, const float* __restrict__ aet,
    const float* __restrict__ asc, const float* __restrict__ adc,
    const float* __restrict__ Wec, const float* __restrict__ aec,
    float* __restrict__ wa, float* __restrict__ dote,
    const float* __restrict__ bt, const float* __restrict__ bih, const float* __restrict__ bhh,
    float* __restrict__ bg,
    const float* __restrict__ ea_t, const float* __restrict__ ea_c,
    const int* __restrict__ ei_t, const int* __restrict__ ei_c,
    float* __restrict__ meansum, int* __restrict__ cnt)
{
    int bx = blockIdx.x;
    if (bx < 10304) {
        int i = bx * 256 + threadIdx.x;
        if (i < 2097152)                   split_store(Wih[i],            WihH,  WihL,  i);
        else if (i < 2097152 + 57344)      split_store(Wt[i - 2097152],   WtH,   WtL,   i - 2097152);
        else if (i < 2154496 + 196608)     split_store(minw[i - 2154496], minH,  minL,  i - 2154496);
        else if (i < 2351104 + 65536)      split_store(moutw[i - 2351104],moutH, moutL, i - 2351104);
        else if (i < 2416640 + 131072)     split_store(fusw[i - 2416640], fusH,  fusL,  i - 2416640);
        else if (i < 2547712 + 32768)      split_store(outw[i - 2547712], outH,  outL,  i - 2547712);
        else if (i < 2580480 + 57344) {    // Bct[c][kk] = Wc[k, h*CC+c]/8
            int i2 = i - 2580480;
            int c = i2 / KK, kk = i2 % KK;
            int h = kk / INF, k = kk % INF;
            split_store(Wc[k * HC + h * CC + c] * 0.125f, BH, BL, i2);
        }
    } else if (bx < 10532) {
        int w = ((bx - 10304) * 256 + threadIdx.x) >> 6;
        int lane = threadIdx.x & 63;
        if (w < 2 * 2 * INF * NH) {
            int b = w / (2 * INF * NH);
            int r = w % (2 * INF * NH);
            int kind = r / (INF * NH);
            int r2 = r % (INF * NH);
            int k = r2 / NH, h = r2 % NH;
            const float* Wm = b ? Wc : Wt;
            const float* a  = b ? (kind ? adc : asc) : (kind ? adt : ast);
            float s = 0.f;
            for (int c = lane; c < CC; c += 64) s += Wm[k * HC + h * CC + c] * a[h * CC + c];
            s = wave_sum(s);
            if (lane == 0) wa[((b * 2 + kind) * INF + k) * NH + h] = s;
        } else if (w < 2 * 2 * INF * NH + 16) {
            int j = w - 2 * 2 * INF * NH;
            int b = j / NH, h = j % NH;
            const float* We = b ? Wec : Wet;
            const float* a  = b ? aec : aet;
            float s = 0.f;
            for (int c = lane; c < CC; c += 64) s += We[h * CC + c] * a[h * CC + c];
            s = wave_sum(s);
            if (lane == 0) dote[b * NH + h] = s;
        }
    } else if (bx < 10788) {
        int j = ((bx - 10532) * 256 + threadIdx.x) >> 6;
        int lane = threadIdx.x & 63;
        if (j < 1024) {
            const float* w = Wih + (size_t)j * HC;
            float s = 0.f;
            for (int c = lane; c < HC; c += 64) s += bt[c] * w[c];
            s = wave_sum(s);
            if (lane == 0) bg[j] = s + bih[j] + bhh[j];
        }
    } else {
        int i = (bx - 10788) * 256 + threadIdx.x;
        int b = i / NE, e = i - b * NE;
        float v = (b ? ea_c : ea_t)[e];
        for (int off = 32; off; off >>= 1) v += __shfl_down(v, off);
        if ((threadIdx.x & 63) == 0) atomicAdd(&meansum[b], v);
        const int* ei = b ? ei_c : ei_t;
        atomicAdd(&cnt[b * NN_ + ei[NE + e]], 1);
    }
}

// ---------------- stage 2: as_ad + CSR scan (one launch) ----------------
__global__ __launch_bounds__(256) void k_stage2(
    const float* __restrict__ x, const float* __restrict__ wa, float* __restrict__ asd,
    const int* __restrict__ cnt, int* __restrict__ rows)
{
    int bx = blockIdx.x;
    if (bx < 512) {
        int i = bx * 256 + threadIdx.x;
        int bk = i / (NN_ * NH);
        int r = i % (NN_ * NH);
        int n = r / NH, h = r % NH;
        const float* W = wa + bk * INF * NH;
        const float* xr = x + n * INF;
        float s = 0.f;
#pragma unroll
        for (int k = 0; k < INF; ++k) s += xr[k] * W[k * NH + h];
        asd[(bk * NN_ + n) * NH + h] = s;
    } else {
        int b = bx - 512;
        const int* c = cnt + b * NN_;
        int* r = rows + b * (NN_ + 16);
        __shared__ int ts[256];
        int t = threadIdx.x;
        int v[16]; int s = 0;
#pragma unroll
        for (int i = 0; i < 16; ++i) { v[i] = c[t * 16 + i]; s += v[i]; }
        ts[t] = s;
        __syncthreads();
        for (int off = 1; off < 256; off <<= 1) {
            int add = (t >= off) ? ts[t - off] : 0;
            __syncthreads();
            ts[t] += add;
            __syncthreads();
        }
        int excl = t ? ts[t - 1] : 0;
#pragma unroll
        for (int i = 0; i < 16; ++i) { r[t * 16 + i] = excl; excl += v[i]; }
        if (t == 255) r[NN_] = excl;
    }
}

__global__ void k_scatter(const int* __restrict__ ei_t, const int* __restrict__ ei_c,
                          const float* __restrict__ ea_t, const float* __restrict__ ea_c,
                          const int* __restrict__ rows, int* __restrict__ cur,
                          int* __restrict__ srcs, float* __restrict__ eav)
{
    int i = blockIdx.x * blockDim.x + threadIdx.x;
    if (i >= 2 * NE) return;
    int b = i / NE, e = i - b * NE;
    const int* ei = b ? ei_c : ei_t;
    const float* ea = b ? ea_c : ea_t;
    int d = ei[NE + e];
    int pos = rows[b * (NN_ + 16) + d] + atomicAdd(&cur[b * NN_ + d], 1);
    srcs[b * NE + pos] = ei[e];
    eav[b * NE + pos] = ea[e];
}

// ---------------- GAT per-dst aggregation, both branches in one grid ----------------
__global__ __launch_bounds__(64) void k_gat(
    const int* __restrict__ srcs, const float* __restrict__ eav,
    const int* __restrict__ rows, const float* __restrict__ x,
    const float* __restrict__ asd, const float* __restrict__ dote,
    const float* __restrict__ meansum,
    __hip_bfloat16* __restrict__ gH, __hip_bfloat16* __restrict__ gL)
{
    int b = blockIdx.x >> 12;           // branch
    int n = blockIdx.x & 4095;
    srcs += (size_t)b * NE; eav += (size_t)b * NE; rows += b * (NN_ + 16);
    const float* a_s = asd + (size_t)(2 * b) * NN_ * NH;
    const float* a_d = asd + (size_t)(2 * b + 1) * NN_ * NH;
    dote += b * NH;
    gH += (size_t)b * NN_ * KK; gL += (size_t)b * NN_ * KK;

    int lane = threadIdx.x;
    __shared__ float xb[64][32];
    __shared__ float eb[64][8];
    __shared__ float denb[8];

    float adn[NH], dt[NH];
#pragma unroll
    for (int h = 0; h < NH; ++h) { adn[h] = a_d[n * NH + h]; dt[h] = dote[h]; }
    float mean_attr = meansum[b] * (1.0f / NE);

    const int hOwn = lane >> 3;
    const int kOwn = (lane & 7) * 4;

    float acc0, acc1, acc2, acc3;
    {
        float al = a_s[n * NH + hOwn] + adn[hOwn] + mean_attr * dt[hOwn];
        al = al > 0.f ? al : 0.2f * al;
        float es = __expf(al);
        float xv0 = (kOwn + 0 < INF) ? x[n * INF + kOwn + 0] : 0.f;
        float xv1 = (kOwn + 1 < INF) ? x[n * INF + kOwn + 1] : 0.f;
        float xv2 = (kOwn + 2 < INF) ? x[n * INF + kOwn + 2] : 0.f;
        float xv3 = (kOwn + 3 < INF) ? x[n * INF + kOwn + 3] : ((kOwn + 3 == 31) ? 1.f : 0.f);
        acc0 = es * xv0; acc1 = es * xv1; acc2 = es * xv2; acc3 = es * xv3;
    }

    int e0 = rows[n], e1 = rows[n + 1];
    for (int base = e0; base < e1; base += 64) {
        int m = e1 - base; if (m > 64) m = 64;
        if (lane < m) {
            int sidx = srcs[base + lane];
            float ea = eav[base + lane];
            const float4* xr = (const float4*)(x + sidx * INF);
#pragma unroll
            for (int q = 0; q < 7; ++q) ((float4*)&xb[lane][0])[q] = xr[q];
            xb[lane][28] = 0.f; xb[lane][29] = 0.f; xb[lane][30] = 0.f; xb[lane][31] = 1.f;
            const float* asr = a_s + sidx * NH;
#pragma unroll
            for (int h = 0; h < NH; ++h) {
                float al = asr[h] + adn[h] + ea * dt[h];
                al = al > 0.f ? al : 0.2f * al;
                eb[lane][h] = __expf(al);
            }
        }
        __syncthreads();
        for (int j = 0; j < m; ++j) {
            float e = eb[j][hOwn];
            float4 xv = *(const float4*)&xb[j][kOwn];
            acc0 += e * xv.x; acc1 += e * xv.y; acc2 += e * xv.z; acc3 += e * xv.w;
        }
        __syncthreads();
    }

    if ((lane & 7) == 7) denb[hOwn] = acc3;
    __syncthreads();
    float inv = 1.0f / denb[hOwn];
    size_t gr = (size_t)n * KK + hOwn * INF + kOwn;
    if (kOwn + 0 < INF) split_store(acc0 * inv, gH, gL, gr + 0);
    if (kOwn + 1 < INF) split_store(acc1 * inv, gH, gL, gr + 1);
    if (kOwn + 2 < INF) split_store(acc2 * inv, gH, gL, gr + 2);
    if (kOwn + 3 < INF) split_store(acc3 * inv, gH, gL, gr + 3);
}

// ---------------- bf16x3-split MFMA GEMM ----------------
// MS: rows per wave /16. EPI==1: write qkv directly as bf16
// Qb[h][n][64]*0.125 / Kb[h][n][64] / Vt[h][kt][64][32-key'] (replaces k_cvt).
// V key' within a 32-key tile is the PV B-fragment order: key'=lgrp*8+hi*4+r
// so the attention kernel loads one bf16x8 per d-chunk (4 loads, 16B each).
template<bool RELU, int MS, int EPI>
__global__ __launch_bounds__(256) void k_mgemm(
    const __hip_bfloat16* __restrict__ Ahi_, const __hip_bfloat16* __restrict__ Alo_, int lda, int aOffZ,
    const __hip_bfloat16* __restrict__ Bhi_, const __hip_bfloat16* __restrict__ Blo_, int ldb, int bOffZ,
    const float* __restrict__ bias,
    float* __restrict__ Cf, int ldcf,
    __hip_bfloat16* __restrict__ Chi, __hip_bfloat16* __restrict__ Clo, int ldch, int cOffZ,
    __hip_bfloat16* __restrict__ Qbp, __hip_bfloat16* __restrict__ Kbp, __hip_bfloat16* __restrict__ Vtp,
    int M, int N, int K)
{
    int z = blockIdx.z;
    const short* Ah = (const short*)Ahi_ + (size_t)z * aOffZ;
    const short* Al = (const short*)Alo_ + (size_t)z * aOffZ;
    const short* Bh = (const short*)Bhi_ + (size_t)z * bOffZ;
    const short* Bl = (const short*)Blo_ + (size_t)z * bOffZ;
    int wave = threadIdx.x >> 6, lane = threadIdx.x & 63;
    int l16 = lane & 15, lgrp = lane >> 4;
    int m0 = blockIdx.x * (64 * MS) + wave * (16 * MS);
    int n0 = blockIdx.y * 64;

    f32x4 acc[MS][4];
#pragma unroll
    for (int i = 0; i < MS; ++i)
#pragma unroll
        for (int j = 0; j < 4; ++j) acc[i][j] = (f32x4){0.f, 0.f, 0.f, 0.f};

    int nrow[4]; bool nval[4];
#pragma unroll
    for (int ns = 0; ns < 4; ++ns) { nrow[ns] = n0 + ns * 16 + l16; nval[ns] = nrow[ns] < N; }

#pragma unroll 2
    for (int k0 = 0; k0 < K; k0 += 32) {
        size_t ka = (size_t)k0 + lgrp * 8;
        bf16x8 ah[MS], al[MS];
#pragma unroll
        for (int ms = 0; ms < MS; ++ms) {
            ah[ms] = *(const bf16x8*)(Ah + (size_t)(m0 + ms * 16 + l16) * lda + ka);
            al[ms] = *(const bf16x8*)(Al + (size_t)(m0 + ms * 16 + l16) * lda + ka);
        }
        bf16x8 bh[4], bl[4];
#pragma unroll
        for (int ns = 0; ns < 4; ++ns) {
            bh[ns] = (bf16x8){0, 0, 0, 0, 0, 0, 0, 0};
            bl[ns] = (bf16x8){0, 0, 0, 0, 0, 0, 0, 0};
            if (nval[ns]) {
                bh[ns] = *(const bf16x8*)(Bh + (size_t)nrow[ns] * ldb + ka);
                bl[ns] = *(const bf16x8*)(Bl + (size_t)nrow[ns] * ldb + ka);
            }
        }
#pragma unroll
        for (int ns = 0; ns < 4; ++ns)
#pragma unroll
            for (int ms = 0; ms < MS; ++ms) {
                acc[ms][ns] = __builtin_amdgcn_mfma_f32_16x16x32_bf16(ah[ms], bh[ns], acc[ms][ns], 0, 0, 0);
                acc[ms][ns] = __builtin_amdgcn_mfma_f32_16x16x32_bf16(ah[ms], bl[ns], acc[ms][ns], 0, 0, 0);
                acc[ms][ns] = __builtin_amdgcn_mfma_f32_16x16x32_bf16(al[ms], bh[ns], acc[ms][ns], 0, 0, 0);
            }
    }

#pragma unroll
    for (int ms = 0; ms < MS; ++ms)
#pragma unroll
        for (int ns = 0; ns < 4; ++ns)
#pragma unroll
            for (int r = 0; r < 4; ++r) {
                int m = m0 + ms * 16 + lgrp * 4 + r;
                int n = n0 + ns * 16 + l16;
                if (n >= N) continue;
                float v = acc[ms][ns][r];
                if (bias) v += bias[n];
                if (RELU) v = v > 0.f ? v : 0.f;
                if (EPI == 1) {
                    int sec = n >> 8, hh = (n >> 6) & 3, d = n & 63;
                    if (sec == 0)      Qbp[((size_t)hh * NN_ + m) * 64 + d] = __float2bfloat16(v * 0.125f);
                    else if (sec == 1) Kbp[((size_t)hh * NN_ + m) * 64 + d] = __float2bfloat16(v);
                    else {
                        int p = m & 31;
                        int kp = (((p & 15) >> 2) << 3) + ((p >> 4) << 2) + (p & 3);
                        Vtp[(((size_t)hh * (NN_ / 32) + (m >> 5)) * 64 + d) * 32 + kp]
                            = __float2bfloat16(v);
                    }
                } else {
                    if (Cf) Cf[(size_t)m * ldcf + n] = v;
                    if (Chi) split_store(v, Chi, Clo, (size_t)m * ldch + (size_t)z * cOffZ + n);
                }
            }
}

// ---------------- fused gates GEMM + LSTM ----------------
__global__ __launch_bounds__(256) void k_gates_lstm(
    const __hip_bfloat16* __restrict__ gHi, const __hip_bfloat16* __restrict__ gLo,
    const __hip_bfloat16* __restrict__ MtH, const __hip_bfloat16* __restrict__ MtL,
    const float* __restrict__ bg,
    float* __restrict__ hout, __hip_bfloat16* __restrict__ ccH, __hip_bfloat16* __restrict__ ccL)
{
    int wave = threadIdx.x >> 6, lane = threadIdx.x & 63;
    int l16 = lane & 15, lgrp = lane >> 4;
    int m0 = blockIdx.x * 64 + wave * 16;
    int n0 = blockIdx.y * 64;
    const short* Ah = (const short*)gHi;
    const short* Al = (const short*)gLo;
    const short* Bh = (const short*)MtH;
    const short* Bl = (const short*)MtL;

    bf16x8 ah[7], al[7];
#pragma unroll
    for (int k = 0; k < 7; ++k) {
        size_t ka = (size_t)k * 32 + lgrp * 8;
        ah[k] = *(const bf16x8*)(Ah + (size_t)(m0 + l16) * KK + ka);
        al[k] = *(const bf16x8*)(Al + (size_t)(m0 + l16) * KK + ka);
    }

    const int secBase[3] = {0, 512, 768};   // i, g, o rows of Mt
    f32x4 acc[3][4];
#pragma unroll
    for (int s = 0; s < 3; ++s) {
#pragma unroll
        for (int ns = 0; ns < 4; ++ns) acc[s][ns] = (f32x4){0.f, 0.f, 0.f, 0.f};
        const short* Bhs = Bh + (size_t)(secBase[s] + n0) * KK;
        const short* Bls = Bl + (size_t)(secBase[s] + n0) * KK;
#pragma unroll
        for (int k = 0; k < 7; ++k) {
            size_t ka = (size_t)k * 32 + lgrp * 8;
            bf16x8 bh[4], bl[4];
#pragma unroll
            for (int ns = 0; ns < 4; ++ns) {
                bh[ns] = *(const bf16x8*)(Bhs + (size_t)(ns * 16 + l16) * KK + ka);
                bl[ns] = *(const bf16x8*)(Bls + (size_t)(ns * 16 + l16) * KK + ka);
            }
#pragma unroll
            for (int ns = 0; ns < 4; ++ns) {
                acc[s][ns] = __builtin_amdgcn_mfma_f32_16x16x32_bf16(ah[k], bh[ns], acc[s][ns], 0, 0, 0);
                acc[s][ns] = __builtin_amdgcn_mfma_f32_16x16x32_bf16(ah[k], bl[ns], acc[s][ns], 0, 0, 0);
                acc[s][ns] = __builtin_amdgcn_mfma_f32_16x16x32_bf16(al[k], bh[ns], acc[s][ns], 0, 0, 0);
            }
        }
    }

#pragma unroll
    for (int ns = 0; ns < 4; ++ns)
#pragma unroll
        for (int r = 0; r < 4; ++r) {
            int m = m0 + lgrp * 4 + r;
            int n = n0 + ns * 16 + l16;
            float gi = acc[0][ns][r] + bg[n];
            float gg = acc[1][ns][r] + bg[512 + n];
            float go = acc[2][ns][r] + bg[768 + n];
            float c = (1.f / (1.f + __expf(-gi))) * tanhf(gg);
            float h = (1.f / (1.f + __expf(-go))) * tanhf(c);
            hout[(size_t)m * 256 + n] = h;
            split_store(h, ccH, ccL, (size_t)m * 512 + n);
        }
}

// ---------------- MHA: bf16 MFMA flash attention ----------------
// grid 512 (flattened), 512 thr = 8 waves. Head→XCD swizzle (per-XCD L2 holds one
// head). Block owns 32 q-rows; wave w covers keys [w*512, w*512+512).
// __launch_bounds__(512, 2): min 2 waves/EU -> VGPR cap 256 so the K/V stream and
// register double-buffer actually stay resident (R8's VGPR=80 serialized the 16
// loads/tile at ~280cyc each = the 72us wall). V is stored in PV-fragment key
// order so LOADV is 4x16B.
__global__ __launch_bounds__(512, 2) void k_attn_mfma(
    const __hip_bfloat16* __restrict__ Qb, const __hip_bfloat16* __restrict__ Kb,
    const __hip_bfloat16* __restrict__ Vt,
    __hip_bfloat16* __restrict__ aoH, __hip_bfloat16* __restrict__ aoL)
{
    __shared__ float redN[4][2][16][65];
    __shared__ float redD[4][2][16];
    int tid = threadIdx.x;
    int wave = tid >> 6, lane = tid & 63;
    int l16 = lane & 15, lgrp = lane >> 4;
    int wg = blockIdx.x;
    int xcd = wg & 7;
    int h = xcd >> 1;
    int q0 = (((wg >> 3) << 1) | (xcd & 1)) * 32;
    int kbase = wave * 512;

    const short* Qs = (const short*)Qb;
    const short* Kbase_ = (const short*)Kb + (size_t)h * NN_ * 64;
    const short* Vbase_ = (const short*)Vt + (size_t)h * NN_ * 64;

    bf16x8 qf[2][2];
#pragma unroll
    for (int qt = 0; qt < 2; ++qt)
#pragma unroll
        for (int dh = 0; dh < 2; ++dh)
            qf[qt][dh] = *(const bf16x8*)(Qs + ((size_t)h * NN_ + q0 + qt * 16 + l16) * 64 + dh * 32 + lgrp * 8);

    f32x4 oacc[2][4];
#pragma unroll
    for (int qt = 0; qt < 2; ++qt)
#pragma unroll
        for (int dc = 0; dc < 4; ++dc) oacc[qt][dc] = (f32x4){0.f, 0.f, 0.f, 0.f};
    float dn[2] = {0.f, 0.f};

    bf16x8 kA[2][2], kB[2][2];
    bf16x8 vA[4], vB[4];

#define LOADK(K0, kf)                                                                 \
    { int k0_ = (K0);                                                                 \
      _Pragma("unroll") for (int kh = 0; kh < 2; ++kh)                                \
      _Pragma("unroll") for (int dh = 0; dh < 2; ++dh)                                \
          kf[kh][dh] = *(const bf16x8*)(Kbase_ + (size_t)(k0_ + kh * 16 + l16) * 64   \
                                        + dh * 32 + lgrp * 8); }
#define LOADV(K0, vf)                                                                 \
    { const short* tb_ = Vbase_ + ((size_t)((K0) >> 5)) * 2048;                       \
      _Pragma("unroll") for (int dc = 0; dc < 4; ++dc)                                \
          vf[dc] = *(const bf16x8*)(tb_ + (dc * 16 + l16) * 32 + lgrp * 8); }
#define COMPUTE(kf, vf)                                                               \
    { f32x4 st_[2][2];                                                                \
      _Pragma("unroll") for (int kh = 0; kh < 2; ++kh)                                \
      _Pragma("unroll") for (int qt = 0; qt < 2; ++qt) {                              \
          f32x4 s_ = (f32x4){0.f, 0.f, 0.f, 0.f};                                     \
          s_ = __builtin_amdgcn_mfma_f32_16x16x32_bf16(kf[kh][0], qf[qt][0], s_, 0, 0, 0); \
          s_ = __builtin_amdgcn_mfma_f32_16x16x32_bf16(kf[kh][1], qf[qt][1], s_, 0, 0, 0); \
          st_[kh][qt] = s_; }                                                         \
      _Pragma("unroll") for (int qt = 0; qt < 2; ++qt) {                              \
          bf16x8 pa_;                                                                 \
          float dsum_ = 0.f;                                                          \
          _Pragma("unroll") for (int r = 0; r < 4; ++r) {                             \
              float e0_ = __expf(st_[0][qt][r]);                                      \
              float e1_ = __expf(st_[1][qt][r]);                                      \
              dsum_ += e0_ + e1_;                                                     \
              pa_[r]     = f2bs(e0_);                                                 \
              pa_[4 + r] = f2bs(e1_); }                                               \
          dn[qt] += dsum_;                                                            \
          _Pragma("unroll") for (int dc = 0; dc < 4; ++dc)                            \
              oacc[qt][dc] = __builtin_amdgcn_mfma_f32_16x16x32_bf16(pa_, vf[dc], oacc[qt][dc], 0, 0, 0); } }

    LOADK(kbase, kA); LOADV(kbase, vA);
    for (int kt = 0; kt < 16; kt += 2) {
        int k1 = kbase + (kt + 1) * 32;
        LOADK(k1, kB); LOADV(k1, vB);
        COMPUTE(kA, vA);
        if (kt + 2 < 16) {
            int k2 = kbase + (kt + 2) * 32;
            LOADK(k2, kA); LOADV(k2, vA);
        }
        COMPUTE(kB, vB);
    }
#undef LOADK
#undef LOADV
#undef COMPUTE

    // full per-q denominator: reduce over the 4 lane groups
#pragma unroll
    for (int qt = 0; qt < 2; ++qt) {
        dn[qt] += __shfl_xor(dn[qt], 16);
        dn[qt] += __shfl_xor(dn[qt], 32);
    }

    // LDS merge tree: 8 -> 4 -> 2 -> 1
#define STORE_(s)                                                                   \
    {                                                                               \
        _Pragma("unroll") for (int qt = 0; qt < 2; ++qt) {                          \
            _Pragma("unroll") for (int dc = 0; dc < 4; ++dc)                        \
                _Pragma("unroll") for (int r = 0; r < 4; ++r)                       \
                    redN[s][qt][lgrp * 4 + r][dc * 16 + l16] = oacc[qt][dc][r];     \
            if (lane < 16) redD[s][qt][lane] = dn[qt];                              \
        }                                                                           \
    }
#define ACCUM_(s)                                                                   \
    {                                                                               \
        _Pragma("unroll") for (int qt = 0; qt < 2; ++qt) {                          \
            _Pragma("unroll") for (int dc = 0; dc < 4; ++dc)                        \
                _Pragma("unroll") for (int r = 0; r < 4; ++r)                       \
                    oacc[qt][dc][r] += redN[s][qt][lgrp * 4 + r][dc * 16 + l16];    \
            dn[qt] += redD[s][qt][l16];                                             \
        }                                                                           \
    }
    if (wave >= 4) STORE_(wave - 4);
    __syncthreads();
    if (wave < 4) ACCUM_(wave);
    __syncthreads();
    if (wave == 2 || wave == 3) STORE_(wave - 2);
    __syncthreads();
    if (wave < 2) ACCUM_(wave);
    __syncthreads();
    if (wave == 1) STORE_(0);
    __syncthreads();
    if (wave == 0) {
        ACCUM_(0);
#pragma unroll
        for (int qt = 0; qt < 2; ++qt) {
            float inv = 1.f / dn[qt];
#pragma unroll
            for (int r = 0; r < 4; ++r) {
                float invr = __shfl(inv, lgrp * 4 + r);
#pragma unroll
                for (int dc = 0; dc < 4; ++dc)
                    split_store(oacc[qt][dc][r] * invr, aoH, aoL,
                                (size_t)(q0 + qt * 16 + lgrp * 4 + r) * 256 + h * 64 + dc * 16 + l16);
            }
        }
    }
#undef STORE_
#undef ACCUM_
}

// ---------------- launch ----------------
extern "C" void kernel_launch(void* const* d_in, const int* in_sizes, int n_in,
                              void* d_out, int out_size, void* d_ws, size_t ws_size,
                              hipStream_t stream)
{
    const float* x      = (const float*)d_in[0];
    const int*   ei_t   = (const int*)d_in[1];
    const int*   ei_c   = (const int*)d_in[2];
    const float* ea_t   = (const float*)d_in[3];
    const float* ea_c   = (const float*)d_in[4];
    const float* W_t    = (const float*)d_in[5];
    const float* asrc_t = (const float*)d_in[6];
    const float* adst_t = (const float*)d_in[7];
    const float* We_t   = (const float*)d_in[8];
    const float* aedg_t = (const float*)d_in[9];
    const float* b_t    = (const float*)d_in[10];
    const float* W_c    = (const float*)d_in[11];
    const float* asrc_c = (const float*)d_in[12];
    const float* adst_c = (const float*)d_in[13];
    const float* We_c   = (const float*)d_in[14];
    const float* aedg_c = (const float*)d_in[15];
    const float* b_c    = (const float*)d_in[16];
    const float* Wih    = (const float*)d_in[17];
    const float* bih    = (const float*)d_in[19];
    const float* bhh    = (const float*)d_in[20];
    const float* min_w  = (const float*)d_in[21];
    const float* min_b  = (const float*)d_in[22];
    const float* mout_w = (const float*)d_in[23];
    const float* mout_b = (const float*)d_in[24];
    const float* fus_w  = (const float*)d_in[25];
    const float* fus_b  = (const float*)d_in[26];
    const float* out_w  = (const float*)d_in[27];
    const float* out_b  = (const float*)d_in[28];
    float* outp = (float*)d_out;

    char* W = (char*)d_ws;
    size_t off = 0;
    auto alloc = [&](size_t bytes) { size_t r = off; off += (bytes + 255) & ~(size_t)255; return r; };
    size_t oMean  = alloc(2 * 4);
    size_t oCnt   = alloc(2 * NN_ * 4);
    size_t oCur   = alloc(2 * NN_ * 4);
    size_t zeroBytes = off;
    size_t oRows  = alloc(2 * (NN_ + 16) * 4);
    size_t oSrcs  = alloc(2 * NE * 4);
    size_t oEav   = alloc(2 * NE * 4);
    size_t oWa    = alloc(4 * INF * NH * 4);
    size_t oDote  = alloc(2 * NH * 4);
    size_t oAsd   = alloc(4 * NN_ * NH * 4);
    size_t oBg    = alloc(1024 * 4);
    size_t oGH    = alloc((size_t)2 * NN_ * KK * 2);
    size_t oGL    = alloc((size_t)2 * NN_ * KK * 2);
    size_t oMtH   = alloc((size_t)1024 * KK * 2);
    size_t oMtL   = alloc((size_t)1024 * KK * 2);
    size_t oBctH  = alloc((size_t)CC * KK * 2);
    size_t oBctL  = alloc((size_t)CC * KK * 2);
    size_t oWihH  = alloc((size_t)1024 * HC * 2);      // reused as concatHi
    size_t oWihL  = alloc((size_t)1024 * HC * 2);      // reused as concatLo
    size_t oWtH   = alloc((size_t)INF * HC * 2);
    size_t oWtL   = alloc((size_t)INF * HC * 2);
    size_t oMinH  = alloc((size_t)768 * HID * 2);
    size_t oMinL  = alloc((size_t)768 * HID * 2);
    size_t oMoutH = alloc((size_t)HID * HID * 2);
    size_t oMoutL = alloc((size_t)HID * HID * 2);
    size_t oFusH  = alloc((size_t)HID * 512 * 2);
    size_t oFusL  = alloc((size_t)HID * 512 * 2);
    size_t oOutwH = alloc((size_t)128 * HID * 2);
    size_t oOutwL = alloc((size_t)128 * HID * 2);
    size_t oHcH   = alloc((size_t)NN_ * HID * 2);      // reused as hfusHi
    size_t oHcL   = alloc((size_t)NN_ * HID * 2);      // reused as hfusLo
    size_t oQb    = alloc((size_t)4 * NN_ * 64 * 2);
    size_t oKb    = alloc((size_t)4 * NN_ * 64 * 2);
    size_t oVt    = alloc((size_t)4 * NN_ * 64 * 2);
    size_t oCcH   = oWihH;    // WihSplit dead after Mt GEMM
    size_t oCcL   = oWihL;
    size_t oAoH   = oGH;      // g dead after gates & hc GEMMs
    size_t oAoL   = oGL;
    size_t oHfH   = oHcH;     // hc dead after qkv GEMM
    size_t oHfL   = oHcL;
    (void)ws_size; (void)in_sizes; (void)n_in; (void)out_size;

    hipMemsetAsync(W, 0, zeroBytes, stream);

    // stage 1: weight splits + GAT scalar precomputes + bias_g + mean/hist
    k_stage1<<<11812, 256, 0, stream>>>(
        Wih,    (__hip_bfloat16*)(W + oWihH),  (__hip_bfloat16*)(W + oWihL),
        W_t,    (__hip_bfloat16*)(W + oWtH),   (__hip_bfloat16*)(W + oWtL),
        min_w,  (__hip_bfloat16*)(W + oMinH),  (__hip_bfloat16*)(W + oMinL),
        mout_w, (__hip_bfloat16*)(W + oMoutH), (__hip_bfloat16*)(W + oMoutL),
        fus_w,  (__hip_bfloat16*)(W + oFusH),  (__hip_bfloat16*)(W + oFusL),
        out_w,  (__hip_bfloat16*)(W + oOutwH), (__hip_bfloat16*)(W + oOutwL),
        W_c,    (__hip_bfloat16*)(W + oBctH),  (__hip_bfloat16*)(W + oBctL),
        asrc_t, adst_t, We_t, aedg_t, asrc_c, adst_c, We_c, aedg_c,
        (float*)(W + oWa), (float*)(W + oDote),
        b_t, bih, bhh, (float*)(W + oBg),
        ea_t, ea_c, ei_t, ei_c, (float*)(W + oMean), (int*)(W + oCnt));
    // stage 2: a_s/a_d + CSR scan
    k_stage2<<<514, 256, 0, stream>>>(x, (float*)(W + oWa), (float*)(W + oAsd),
                                      (int*)(W + oCnt), (int*)(W + oRows));
    // Mt[j][h*28+k] = sum_c Wih[j][h*256+c] * Wt[k][h*256+c] — batched over heads
    {
        dim3 grid(8, 1, 8);
        k_mgemm<false, 2, 0><<<grid, 256, 0, stream>>>(
            (__hip_bfloat16*)(W + oWihH), (__hip_bfloat16*)(W + oWihL), HC, CC,
            (__hip_bfloat16*)(W + oWtH),  (__hip_bfloat16*)(W + oWtL),  HC, CC,
            nullptr, nullptr, 0,
            (__hip_bfloat16*)(W + oMtH), (__hip_bfloat16*)(W + oMtL), KK, INF,
            nullptr, nullptr, nullptr,
            1024, INF, CC);
    }
    k_scatter<<<2 * NE / 256, 256, 0, stream>>>(ei_t, ei_c, ea_t, ea_c,
                                                (int*)(W + oRows), (int*)(W + oCur),
                                                (int*)(W + oSrcs), (float*)(W + oEav));
    // GAT aggregation, both branches
    k_gat<<<2 * NN_, 64, 0, stream>>>((int*)(W + oSrcs), (float*)(W + oEav), (int*)(W + oRows), x,
                                      (float*)(W + oAsd), (float*)(W + oDote), (float*)(W + oMean),
                                      (__hip_bfloat16*)(W + oGH), (__hip_bfloat16*)(W + oGL));
    // fused gates GEMM (i/g/o) + LSTM -> h_temporal (d_out) + concat hi/lo
    {
        dim3 grid(NN_ / 64, HID / 64);
        k_gates_lstm<<<grid, 256, 0, stream>>>(
            (__hip_bfloat16*)(W + oGH), (__hip_bfloat16*)(W + oGL),
            (__hip_bfloat16*)(W + oMtH), (__hip_bfloat16*)(W + oMtL),
            (float*)(W + oBg),
            outp + 524288, (__hip_bfloat16*)(W + oCcH), (__hip_bfloat16*)(W + oCcL));
    }
    // h_c = g_c @ Bct^T + b_c -> hi/lo
    {
        dim3 grid(64, 4, 1);
        k_mgemm<false, 1, 0><<<grid, 256, 0, stream>>>(
            (__hip_bfloat16*)(W + oGH) + (size_t)NN_ * KK, (__hip_bfloat16*)(W + oGL) + (size_t)NN_ * KK, KK, 0,
            (__hip_bfloat16*)(W + oBctH), (__hip_bfloat16*)(W + oBctL), KK, 0,
            b_c, nullptr, 0,
            (__hip_bfloat16*)(W + oHcH), (__hip_bfloat16*)(W + oHcL), HID, 0,
            nullptr, nullptr, nullptr,
            NN_, HID, KK);
    }
    // qkv = h_c @ min_w^T + min_b, written directly as bf16 Qb/Kb/Vt-tiled (fused k_cvt)
    {
        dim3 grid(32, 12, 1);
        k_mgemm<false, 2, 1><<<grid, 256, 0, stream>>>(
            (__hip_bfloat16*)(W + oHcH), (__hip_bfloat16*)(W + oHcL), HID, 0,
            (__hip_bfloat16*)(W + oMinH), (__hip_bfloat16*)(W + oMinL), HID, 0,
            min_b, nullptr, 0,
            nullptr, nullptr, 0, 0,
            (__hip_bfloat16*)(W + oQb), (__hip_bfloat16*)(W + oKb), (__hip_bfloat16*)(W + oVt),
            NN_, 768, HID);
    }
    // attention: head->XCD swizzled, tiled+packed V, high-VGPR pipelined stream
    {
        k_attn_mfma<<<512, 512, 0, stream>>>(
            (__hip_bfloat16*)(W + oQb), (__hip_bfloat16*)(W + oKb), (__hip_bfloat16*)(W + oVt),
            (__hip_bfloat16*)(W + oAoH), (__hip_bfloat16*)(W + oAoL));
    }
    // out-proj: concat[:,256:512] (hi/lo) + h_causal (fp32 d_out)
    {
        dim3 grid(64, 4, 1);
        k_mgemm<false, 1, 0><<<grid, 256, 0, stream>>>(
            (__hip_bfloat16*)(W + oAoH), (__hip_bfloat16*)(W + oAoL), HID, 0,
            (__hip_bfloat16*)(W + oMoutH), (__hip_bfloat16*)(W + oMoutL), HID, 0,
            mout_b, outp + 524288 + 1048576, 256,
            (__hip_bfloat16*)(W + oCcH) + 256, (__hip_bfloat16*)(W + oCcL) + 256, 512, 0,
            nullptr, nullptr, nullptr,
            NN_, HID, HID);
    }
    // fusion: relu(concat @ fus_w^T + fus_b) -> hi/lo
    {
        dim3 grid(64, 4, 1);
        k_mgemm<true, 1, 0><<<grid, 256, 0, stream>>>(
            (__hip_bfloat16*)(W + oCcH), (__hip_bfloat16*)(W + oCcL), 512, 0,
            (__hip_bfloat16*)(W + oFusH), (__hip_bfloat16*)(W + oFusL), 512, 0,
            fus_b, nullptr, 0,
            (__hip_bfloat16*)(W + oHfH), (__hip_bfloat16*)(W + oHfL), HID, 0,
            nullptr, nullptr, nullptr,
            NN_, HID, 512);
    }
    // out = hfus @ out_w^T + out_b (fp32 d_out)
    {
        dim3 grid(64, 2, 1);
        k_mgemm<false, 1, 0><<<grid, 256, 0, stream>>>(
            (__hip_bfloat16*)(W + oHfH), (__hip_bfloat16*)(W + oHfL), HID, 0,
            (__hip_bfloat16*)(W + oOutwH), (__hip_bfloat16*)(W + oOutwL), HID, 0,
            out_b, outp, 128,
            nullptr, nullptr, 0, 0,
            nullptr, nullptr, nullptr,
            NN_, 128, HID);
    }
}

// Round 10
// 359.197 us; speedup vs baseline: 4.9070x; 1.1175x over previous
//
#include <hip/hip_runtime.h>
#include <hip/hip_bf16.h>

// ---------------- problem constants ----------------
constexpr int NN_ = 4096;     // nodes
constexpr int INF = 28;       // input features
constexpr int NH  = 8;        // GAT heads
constexpr int CC  = 256;      // channels per head
constexpr int HC  = 2048;     // NH*CC
constexpr int HID = 256;
constexpr int NE  = 131072;   // edges per branch
constexpr int KK  = NH * INF; // 224

typedef short bf16x8 __attribute__((ext_vector_type(8)));
typedef short bf16x4 __attribute__((ext_vector_type(4)));
typedef float f32x4 __attribute__((ext_vector_type(4)));

__device__ inline void split_store(float v, __hip_bfloat16* H, __hip_bfloat16* L, size_t idx)
{
    __hip_bfloat16 h = __float2bfloat16(v);
    H[idx] = h;
    L[idx] = __float2bfloat16(v - __bfloat162float(h));
}

__device__ inline short f2bs(float v)
{
    __hip_bfloat16 h = __float2bfloat16(v);
    return *reinterpret_cast<short*>(&h);
}

__device__ inline float wave_sum(float v)
{
    v += __shfl_xor(v, 1);  v += __shfl_xor(v, 2);  v += __shfl_xor(v, 4);
    v += __shfl_xor(v, 8);  v += __shfl_xor(v, 16); v += __shfl_xor(v, 32);
    return v;
}

// ---------------- stage 1: split_all(x4 vec) + small_pre + biasg + mean_hist ----------------
// blocks: [0,2576) split (4 elems/thread) | [2576,2804) small_pre | [2804,3060) biasg
//         | [3060,4084) mean_hist (atomics into 256-slot partials, NOT meansum directly)
__global__ void k_stage1(
    const float* __restrict__ Wih,  __hip_bfloat16* WihH,  __hip_bfloat16* WihL,
    const float* __restrict__ Wt,   __hip_bfloat16* WtH,   __hip_bfloat16* WtL,
    const float* __restrict__ minw, __hip_bfloat16* minH,  __hip_bfloat16* minL,
    const float* __restrict__ moutw,__hip_bfloat16* moutH, __hip_bfloat16* moutL,
    const float* __restrict__ fusw, __hip_bfloat16* fusH,  __hip_bfloat16* fusL,
    const float* __restrict__ outw, __hip_bfloat16* outH,  __hip_bfloat16* outL,
    const float* __restrict__ Wc,   __hip_bfloat16* BH,    __hip_bfloat16* BL,
    const float* __restrict__ ast, const float* __restrict__ adt,
    const float* __restrict__ Wet, const float* __restrict__ aet,
    const float* __restrict__ asc, const float* __restrict__ adc,
    const float* __restrict__ Wec, const float* __restrict__ aec,
    float* __restrict__ wa, float* __restrict__ dote,
    const float* __restrict__ bt, const float* __restrict__ bih, const float* __restrict__ bhh,
    float* __restrict__ bg,
    const float* __restrict__ ea_t, const float* __restrict__ ea_c,
    const int* __restrict__ ei_t, const int* __restrict__ ei_c,
    float* __restrict__ meanpart, int* __restrict__ cnt)
{
    int bx = blockIdx.x;
    if (bx < 2576) {
        int i = (bx * 256 + threadIdx.x) * 4;
        if (i < 2580480) {
            const float* src; __hip_bfloat16 *H, *L; int o;
            if (i < 2097152)      { src = Wih;  H = WihH;  L = WihL;  o = i; }
            else if (i < 2154496) { src = Wt;   H = WtH;   L = WtL;   o = i - 2097152; }
            else if (i < 2351104) { src = minw; H = minH;  L = minL;  o = i - 2154496; }
            else if (i < 2416640) { src = moutw;H = moutH; L = moutL; o = i - 2351104; }
            else if (i < 2547712) { src = fusw; H = fusH;  L = fusL;  o = i - 2416640; }
            else                  { src = outw; H = outH;  L = outL;  o = i - 2547712; }
            float4 v = *(const float4*)(src + o);
            short4 hs, ls;
            hs.x = f2bs(v.x); hs.y = f2bs(v.y); hs.z = f2bs(v.z); hs.w = f2bs(v.w);
            __hip_bfloat16* hp = (__hip_bfloat16*)&hs;
            ls.x = f2bs(v.x - __bfloat162float(hp[0]));
            ls.y = f2bs(v.y - __bfloat162float(hp[1]));
            ls.z = f2bs(v.z - __bfloat162float(hp[2]));
            ls.w = f2bs(v.w - __bfloat162float(hp[3]));
            *(short4*)((short*)H + o) = hs;
            *(short4*)((short*)L + o) = ls;
        } else {                               // Bct[c][kk] = Wc[k, h*CC+c]/8 (gather)
            int i2 = i - 2580480;
#pragma unroll
            for (int q = 0; q < 4; ++q) {
                int j = i2 + q;
                int c = j / KK, kk = j % KK;
                int h = kk / INF, k = kk % INF;
                split_store(Wc[k * HC + h * CC + c] * 0.125f, BH, BL, j);
            }
        }
    } else if (bx < 2804) {
        int w = ((bx - 2576) * 256 + threadIdx.x) >> 6;
        int lane = threadIdx.x & 63;
        if (w < 2 * 2 * INF * NH) {
            int b = w / (2 * INF * NH);
            int r = w % (2 * INF * NH);
            int kind = r / (INF * NH);
            int r2 = r % (INF * NH);
            int k = r2 / NH, h = r2 % NH;
            const float* Wm = b ? Wc : Wt;
            const float* a  = b ? (kind ? adc : asc) : (kind ? adt : ast);
            float s = 0.f;
            for (int c = lane; c < CC; c += 64) s += Wm[k * HC + h * CC + c] * a[h * CC + c];
            s = wave_sum(s);
            if (lane == 0) wa[((b * 2 + kind) * INF + k) * NH + h] = s;
        } else if (w < 2 * 2 * INF * NH + 16) {
            int j = w - 2 * 2 * INF * NH;
            int b = j / NH, h = j % NH;
            const float* We = b ? Wec : Wet;
            const float* a  = b ? aec : aet;
            float s = 0.f;
            for (int c = lane; c < CC; c += 64) s += We[h * CC + c] * a[h * CC + c];
            s = wave_sum(s);
            if (lane == 0) dote[b * NH + h] = s;
        }
    } else if (bx < 3060) {
        int j = ((bx - 2804) * 256 + threadIdx.x) >> 6;
        int lane = threadIdx.x & 63;
        if (j < 1024) {
            const float* w = Wih + (size_t)j * HC;
            float s = 0.f;
            for (int c = lane; c < HC; c += 64) s += bt[c] * w[c];
            s = wave_sum(s);
            if (lane == 0) bg[j] = s + bih[j] + bhh[j];
        }
    } else {
        int rel = bx - 3060;                   // 0..1023
        int i = rel * 256 + threadIdx.x;
        int b = i >> 17, e = i & (NE - 1);
        float v = (b ? ea_c : ea_t)[e];
        for (int off = 32; off; off >>= 1) v += __shfl_down(v, off);
        if ((threadIdx.x & 63) == 0)
            atomicAdd(&meanpart[b * 256 + (rel & 255)], v);   // <=8 collisions/slot
        const int* ei = b ? ei_c : ei_t;
        atomicAdd(&cnt[b * NN_ + ei[NE + e]], 1);
    }
}

// ---------------- stage 2: as_ad + CSR scan + meansum final reduce ----------------
// blocks [0,512) as_ad | [512,514) scan | 514: reduce meanpart -> meansum
__global__ __launch_bounds__(256) void k_stage2(
    const float* __restrict__ x, const float* __restrict__ wa, float* __restrict__ asd,
    const int* __restrict__ cnt, int* __restrict__ rows,
    const float* __restrict__ meanpart, float* __restrict__ meansum)
{
    int bx = blockIdx.x;
    if (bx < 512) {
        int i = bx * 256 + threadIdx.x;
        int bk = i / (NN_ * NH);
        int r = i % (NN_ * NH);
        int n = r / NH, h = r % NH;
        const float* W = wa + bk * INF * NH;
        const float* xr = x + n * INF;
        float s = 0.f;
#pragma unroll
        for (int k = 0; k < INF; ++k) s += xr[k] * W[k * NH + h];
        asd[(bk * NN_ + n) * NH + h] = s;
    } else if (bx < 514) {
        int b = bx - 512;
        const int* c = cnt + b * NN_;
        int* r = rows + b * (NN_ + 16);
        __shared__ int ts[256];
        int t = threadIdx.x;
        int v[16]; int s = 0;
#pragma unroll
        for (int i = 0; i < 16; ++i) { v[i] = c[t * 16 + i]; s += v[i]; }
        ts[t] = s;
        __syncthreads();
        for (int off = 1; off < 256; off <<= 1) {
            int add = (t >= off) ? ts[t - off] : 0;
            __syncthreads();
            ts[t] += add;
            __syncthreads();
        }
        int excl = t ? ts[t - 1] : 0;
#pragma unroll
        for (int i = 0; i < 16; ++i) { r[t * 16 + i] = excl; excl += v[i]; }
        if (t == 255) r[NN_] = excl;
    } else {
        int t = threadIdx.x;
        float v0 = meanpart[t];
        float v1 = meanpart[256 + t];
        v0 = wave_sum(v0);
        v1 = wave_sum(v1);
        __shared__ float s0[4], s1[4];
        if ((t & 63) == 0) { s0[t >> 6] = v0; s1[t >> 6] = v1; }
        __syncthreads();
        if (t == 0) meansum[0] = s0[0] + s0[1] + s0[2] + s0[3];
        if (t == 1) meansum[1] = s1[0] + s1[1] + s1[2] + s1[3];
    }
}

__global__ void k_scatter(const int* __restrict__ ei_t, const int* __restrict__ ei_c,
                          const float* __restrict__ ea_t, const float* __restrict__ ea_c,
                          const int* __restrict__ rows, int* __restrict__ cur,
                          int* __restrict__ srcs, float* __restrict__ eav)
{
    int i = blockIdx.x * blockDim.x + threadIdx.x;
    if (i >= 2 * NE) return;
    int b = i / NE, e = i - b * NE;
    const int* ei = b ? ei_c : ei_t;
    const float* ea = b ? ea_c : ea_t;
    int d = ei[NE + e];
    int pos = rows[b * (NN_ + 16) + d] + atomicAdd(&cur[b * NN_ + d], 1);
    srcs[b * NE + pos] = ei[e];
    eav[b * NE + pos] = ea[e];
}

// ---------------- GAT per-dst aggregation, both branches in one grid ----------------
__global__ __launch_bounds__(64) void k_gat(
    const int* __restrict__ srcs, const float* __restrict__ eav,
    const int* __restrict__ rows, const float* __restrict__ x,
    const float* __restrict__ asd, const float* __restrict__ dote,
    const float* __restrict__ meansum,
    __hip_bfloat16* __restrict__ gH, __hip_bfloat16* __restrict__ gL)
{
    int b = blockIdx.x >> 12;           // branch
    int n = blockIdx.x & 4095;
    srcs += (size_t)b * NE; eav += (size_t)b * NE; rows += b * (NN_ + 16);
    const float* a_s = asd + (size_t)(2 * b) * NN_ * NH;
    const float* a_d = asd + (size_t)(2 * b + 1) * NN_ * NH;
    dote += b * NH;
    gH += (size_t)b * NN_ * KK; gL += (size_t)b * NN_ * KK;

    int lane = threadIdx.x;
    __shared__ float xb[64][32];
    __shared__ float eb[64][8];
    __shared__ float denb[8];

    float adn[NH], dt[NH];
#pragma unroll
    for (int h = 0; h < NH; ++h) { adn[h] = a_d[n * NH + h]; dt[h] = dote[h]; }
    float mean_attr = meansum[b] * (1.0f / NE);

    const int hOwn = lane >> 3;
    const int kOwn = (lane & 7) * 4;

    float acc0, acc1, acc2, acc3;
    {
        float al = a_s[n * NH + hOwn] + adn[hOwn] + mean_attr * dt[hOwn];
        al = al > 0.f ? al : 0.2f * al;
        float es = __expf(al);
        float xv0 = (kOwn + 0 < INF) ? x[n * INF + kOwn + 0] : 0.f;
        float xv1 = (kOwn + 1 < INF) ? x[n * INF + kOwn + 1] : 0.f;
        float xv2 = (kOwn + 2 < INF) ? x[n * INF + kOwn + 2] : 0.f;
        float xv3 = (kOwn + 3 < INF) ? x[n * INF + kOwn + 3] : ((kOwn + 3 == 31) ? 1.f : 0.f);
        acc0 = es * xv0; acc1 = es * xv1; acc2 = es * xv2; acc3 = es * xv3;
    }

    int e0 = rows[n], e1 = rows[n + 1];
    for (int base = e0; base < e1; base += 64) {
        int m = e1 - base; if (m > 64) m = 64;
        if (lane < m) {
            int sidx = srcs[base + lane];
            float ea = eav[base + lane];
            const float4* xr = (const float4*)(x + sidx * INF);
#pragma unroll
            for (int q = 0; q < 7; ++q) ((float4*)&xb[lane][0])[q] = xr[q];
            xb[lane][28] = 0.f; xb[lane][29] = 0.f; xb[lane][30] = 0.f; xb[lane][31] = 1.f;
            const float* asr = a_s + sidx * NH;
#pragma unroll
            for (int h = 0; h < NH; ++h) {
                float al = asr[h] + adn[h] + ea * dt[h];
                al = al > 0.f ? al : 0.2f * al;
                eb[lane][h] = __expf(al);
            }
        }
        __syncthreads();
        for (int j = 0; j < m; ++j) {
            float e = eb[j][hOwn];
            float4 xv = *(const float4*)&xb[j][kOwn];
            acc0 += e * xv.x; acc1 += e * xv.y; acc2 += e * xv.z; acc3 += e * xv.w;
        }
        __syncthreads();
    }

    if ((lane & 7) == 7) denb[hOwn] = acc3;
    __syncthreads();
    float inv = 1.0f / denb[hOwn];
    size_t gr = (size_t)n * KK + hOwn * INF + kOwn;
    if (kOwn + 0 < INF) split_store(acc0 * inv, gH, gL, gr + 0);
    if (kOwn + 1 < INF) split_store(acc1 * inv, gH, gL, gr + 1);
    if (kOwn + 2 < INF) split_store(acc2 * inv, gH, gL, gr + 2);
    if (kOwn + 3 < INF) split_store(acc3 * inv, gH, gL, gr + 3);
}

// ---------------- bf16x3-split MFMA GEMM ----------------
// MS: rows per wave /16. EPI==1: write qkv directly as bf16
// Qb[h][n][64]*0.125 / Kb[h][n][64] / Vt[h][kt][64][32-key'] (replaces k_cvt).
template<bool RELU, int MS, int EPI>
__global__ __launch_bounds__(256) void k_mgemm(
    const __hip_bfloat16* __restrict__ Ahi_, const __hip_bfloat16* __restrict__ Alo_, int lda, int aOffZ,
    const __hip_bfloat16* __restrict__ Bhi_, const __hip_bfloat16* __restrict__ Blo_, int ldb, int bOffZ,
    const float* __restrict__ bias,
    float* __restrict__ Cf, int ldcf,
    __hip_bfloat16* __restrict__ Chi, __hip_bfloat16* __restrict__ Clo, int ldch, int cOffZ,
    __hip_bfloat16* __restrict__ Qbp, __hip_bfloat16* __restrict__ Kbp, __hip_bfloat16* __restrict__ Vtp,
    int M, int N, int K)
{
    int z = blockIdx.z;
    const short* Ah = (const short*)Ahi_ + (size_t)z * aOffZ;
    const short* Al = (const short*)Alo_ + (size_t)z * aOffZ;
    const short* Bh = (const short*)Bhi_ + (size_t)z * bOffZ;
    const short* Bl = (const short*)Blo_ + (size_t)z * bOffZ;
    int wave = threadIdx.x >> 6, lane = threadIdx.x & 63;
    int l16 = lane & 15, lgrp = lane >> 4;
    int m0 = blockIdx.x * (64 * MS) + wave * (16 * MS);
    int n0 = blockIdx.y * 64;

    f32x4 acc[MS][4];
#pragma unroll
    for (int i = 0; i < MS; ++i)
#pragma unroll
        for (int j = 0; j < 4; ++j) acc[i][j] = (f32x4){0.f, 0.f, 0.f, 0.f};

    int nrow[4]; bool nval[4];
#pragma unroll
    for (int ns = 0; ns < 4; ++ns) { nrow[ns] = n0 + ns * 16 + l16; nval[ns] = nrow[ns] < N; }

#pragma unroll 2
    for (int k0 = 0; k0 < K; k0 += 32) {
        size_t ka = (size_t)k0 + lgrp * 8;
        bf16x8 ah[MS], al[MS];
#pragma unroll
        for (int ms = 0; ms < MS; ++ms) {
            ah[ms] = *(const bf16x8*)(Ah + (size_t)(m0 + ms * 16 + l16) * lda + ka);
            al[ms] = *(const bf16x8*)(Al + (size_t)(m0 + ms * 16 + l16) * lda + ka);
        }
        bf16x8 bh[4], bl[4];
#pragma unroll
        for (int ns = 0; ns < 4; ++ns) {
            bh[ns] = (bf16x8){0, 0, 0, 0, 0, 0, 0, 0};
            bl[ns] = (bf16x8){0, 0, 0, 0, 0, 0, 0, 0};
            if (nval[ns]) {
                bh[ns] = *(const bf16x8*)(Bh + (size_t)nrow[ns] * ldb + ka);
                bl[ns] = *(const bf16x8*)(Bl + (size_t)nrow[ns] * ldb + ka);
            }
        }
#pragma unroll
        for (int ns = 0; ns < 4; ++ns)
#pragma unroll
            for (int ms = 0; ms < MS; ++ms) {
                acc[ms][ns] = __builtin_amdgcn_mfma_f32_16x16x32_bf16(ah[ms], bh[ns], acc[ms][ns], 0, 0, 0);
                acc[ms][ns] = __builtin_amdgcn_mfma_f32_16x16x32_bf16(ah[ms], bl[ns], acc[ms][ns], 0, 0, 0);
                acc[ms][ns] = __builtin_amdgcn_mfma_f32_16x16x32_bf16(al[ms], bh[ns], acc[ms][ns], 0, 0, 0);
            }
    }

#pragma unroll
    for (int ms = 0; ms < MS; ++ms)
#pragma unroll
        for (int ns = 0; ns < 4; ++ns)
#pragma unroll
            for (int r = 0; r < 4; ++r) {
                int m = m0 + ms * 16 + lgrp * 4 + r;
                int n = n0 + ns * 16 + l16;
                if (n >= N) continue;
                float v = acc[ms][ns][r];
                if (bias) v += bias[n];
                if (RELU) v = v > 0.f ? v : 0.f;
                if (EPI == 1) {
                    int sec = n >> 8, hh = (n >> 6) & 3, d = n & 63;
                    if (sec == 0)      Qbp[((size_t)hh * NN_ + m) * 64 + d] = __float2bfloat16(v * 0.125f);
                    else if (sec == 1) Kbp[((size_t)hh * NN_ + m) * 64 + d] = __float2bfloat16(v);
                    else {
                        int p = m & 31;
                        int kp = (((p & 15) >> 2) << 3) + ((p >> 4) << 2) + (p & 3);
                        Vtp[(((size_t)hh * (NN_ / 32) + (m >> 5)) * 64 + d) * 32 + kp]
                            = __float2bfloat16(v);
                    }
                } else {
                    if (Cf) Cf[(size_t)m * ldcf + n] = v;
                    if (Chi) split_store(v, Chi, Clo, (size_t)m * ldch + (size_t)z * cOffZ + n);
                }
            }
}

// ---------------- fused gates GEMM + LSTM ----------------
__global__ __launch_bounds__(256) void k_gates_lstm(
    const __hip_bfloat16* __restrict__ gHi, const __hip_bfloat16* __restrict__ gLo,
    const __hip_bfloat16* __restrict__ MtH, const __hip_bfloat16* __restrict__ MtL,
    const float* __restrict__ bg,
    float* __restrict__ hout, __hip_bfloat16* __restrict__ ccH, __hip_bfloat16* __restrict__ ccL)
{
    int wave = threadIdx.x >> 6, lane = threadIdx.x & 63;
    int l16 = lane & 15, lgrp = lane >> 4;
    int m0 = blockIdx.x * 64 + wave * 16;
    int n0 = blockIdx.y * 64;
    const short* Ah = (const short*)gHi;
    const short* Al = (const short*)gLo;
    const short* Bh = (const short*)MtH;
    const short* Bl = (const short*)MtL;

    bf16x8 ah[7], al[7];
#pragma unroll
    for (int k = 0; k < 7; ++k) {
        size_t ka = (size_t)k * 32 + lgrp * 8;
        ah[k] = *(const bf16x8*)(Ah + (size_t)(m0 + l16) * KK + ka);
        al[k] = *(const bf16x8*)(Al + (size_t)(m0 + l16) * KK + ka);
    }

    const int secBase[3] = {0, 512, 768};   // i, g, o rows of Mt
    f32x4 acc[3][4];
#pragma unroll
    for (int s = 0; s < 3; ++s) {
#pragma unroll
        for (int ns = 0; ns < 4; ++ns) acc[s][ns] = (f32x4){0.f, 0.f, 0.f, 0.f};
        const short* Bhs = Bh + (size_t)(secBase[s] + n0) * KK;
        const short* Bls = Bl + (size_t)(secBase[s] + n0) * KK;
#pragma unroll
        for (int k = 0; k < 7; ++k) {
            size_t ka = (size_t)k * 32 + lgrp * 8;
            bf16x8 bh[4], bl[4];
#pragma unroll
            for (int ns = 0; ns < 4; ++ns) {
                bh[ns] = *(const bf16x8*)(Bhs + (size_t)(ns * 16 + l16) * KK + ka);
                bl[ns] = *(const bf16x8*)(Bls + (size_t)(ns * 16 + l16) * KK + ka);
            }
#pragma unroll
            for (int ns = 0; ns < 4; ++ns) {
                acc[s][ns] = __builtin_amdgcn_mfma_f32_16x16x32_bf16(ah[k], bh[ns], acc[s][ns], 0, 0, 0);
                acc[s][ns] = __builtin_amdgcn_mfma_f32_16x16x32_bf16(ah[k], bl[ns], acc[s][ns], 0, 0, 0);
                acc[s][ns] = __builtin_amdgcn_mfma_f32_16x16x32_bf16(al[k], bh[ns], acc[s][ns], 0, 0, 0);
            }
        }
    }

#pragma unroll
    for (int ns = 0; ns < 4; ++ns)
#pragma unroll
        for (int r = 0; r < 4; ++r) {
            int m = m0 + lgrp * 4 + r;
            int n = n0 + ns * 16 + l16;
            float gi = acc[0][ns][r] + bg[n];
            float gg = acc[1][ns][r] + bg[512 + n];
            float go = acc[2][ns][r] + bg[768 + n];
            float c = (1.f / (1.f + __expf(-gi))) * tanhf(gg);
            float h = (1.f / (1.f + __expf(-go))) * tanhf(c);
            hout[(size_t)m * 256 + n] = h;
            split_store(h, ccH, ccL, (size_t)m * 512 + n);
        }
}

// ---------------- MHA: bf16 MFMA flash attention ----------------
// grid 512 (flattened), 512 thr = 8 waves. Head→XCD swizzle; tiled+packed V;
// __launch_bounds__(512,2) keeps the K/V double-buffer in registers (R9 fix).
__global__ __launch_bounds__(512, 2) void k_attn_mfma(
    const __hip_bfloat16* __restrict__ Qb, const __hip_bfloat16* __restrict__ Kb,
    const __hip_bfloat16* __restrict__ Vt,
    __hip_bfloat16* __restrict__ aoH, __hip_bfloat16* __restrict__ aoL)
{
    __shared__ float redN[4][2][16][65];
    __shared__ float redD[4][2][16];
    int tid = threadIdx.x;
    int wave = tid >> 6, lane = tid & 63;
    int l16 = lane & 15, lgrp = lane >> 4;
    int wg = blockIdx.x;
    int xcd = wg & 7;
    int h = xcd >> 1;
    int q0 = (((wg >> 3) << 1) | (xcd & 1)) * 32;
    int kbase = wave * 512;

    const short* Qs = (const short*)Qb;
    const short* Kbase_ = (const short*)Kb + (size_t)h * NN_ * 64;
    const short* Vbase_ = (const short*)Vt + (size_t)h * NN_ * 64;

    bf16x8 qf[2][2];
#pragma unroll
    for (int qt = 0; qt < 2; ++qt)
#pragma unroll
        for (int dh = 0; dh < 2; ++dh)
            qf[qt][dh] = *(const bf16x8*)(Qs + ((size_t)h * NN_ + q0 + qt * 16 + l16) * 64 + dh * 32 + lgrp * 8);

    f32x4 oacc[2][4];
#pragma unroll
    for (int qt = 0; qt < 2; ++qt)
#pragma unroll
        for (int dc = 0; dc < 4; ++dc) oacc[qt][dc] = (f32x4){0.f, 0.f, 0.f, 0.f};
    float dn[2] = {0.f, 0.f};

    bf16x8 kA[2][2], kB[2][2];
    bf16x8 vA[4], vB[4];

#define LOADK(K0, kf)                                                                 \
    { int k0_ = (K0);                                                                 \
      _Pragma("unroll") for (int kh = 0; kh < 2; ++kh)                                \
      _Pragma("unroll") for (int dh = 0; dh < 2; ++dh)                                \
          kf[kh][dh] = *(const bf16x8*)(Kbase_ + (size_t)(k0_ + kh * 16 + l16) * 64   \
                                        + dh * 32 + lgrp * 8); }
#define LOADV(K0, vf)                                                                 \
    { const short* tb_ = Vbase_ + ((size_t)((K0) >> 5)) * 2048;                       \
      _Pragma("unroll") for (int dc = 0; dc < 4; ++dc)                                \
          vf[dc] = *(const bf16x8*)(tb_ + (dc * 16 + l16) * 32 + lgrp * 8); }
#define COMPUTE(kf, vf)                                                               \
    { f32x4 st_[2][2];                                                                \
      _Pragma("unroll") for (int kh = 0; kh < 2; ++kh)                                \
      _Pragma("unroll") for (int qt = 0; qt < 2; ++qt) {                              \
          f32x4 s_ = (f32x4){0.f, 0.f, 0.f, 0.f};                                     \
          s_ = __builtin_amdgcn_mfma_f32_16x16x32_bf16(kf[kh][0], qf[qt][0], s_, 0, 0, 0); \
          s_ = __builtin_amdgcn_mfma_f32_16x16x32_bf16(kf[kh][1], qf[qt][1], s_, 0, 0, 0); \
          st_[kh][qt] = s_; }                                                         \
      _Pragma("unroll") for (int qt = 0; qt < 2; ++qt) {                              \
          bf16x8 pa_;                                                                 \
          float dsum_ = 0.f;                                                          \
          _Pragma("unroll") for (int r = 0; r < 4; ++r) {                             \
              float e0_ = __expf(st_[0][qt][r]);                                      \
              float e1_ = __expf(st_[1][qt][r]);                                      \
              dsum_ += e0_ + e1_;                                                     \
              pa_[r]     = f2bs(e0_);                                                 \
              pa_[4 + r] = f2bs(e1_); }                                               \
          dn[qt] += dsum_;                                                            \
          _Pragma("unroll") for (int dc = 0; dc < 4; ++dc)                            \
              oacc[qt][dc] = __builtin_amdgcn_mfma_f32_16x16x32_bf16(pa_, vf[dc], oacc[qt][dc], 0, 0, 0); } }

    LOADK(kbase, kA); LOADV(kbase, vA);
    for (int kt = 0; kt < 16; kt += 2) {
        int k1 = kbase + (kt + 1) * 32;
        LOADK(k1, kB); LOADV(k1, vB);
        COMPUTE(kA, vA);
        if (kt + 2 < 16) {
            int k2 = kbase + (kt + 2) * 32;
            LOADK(k2, kA); LOADV(k2, vA);
        }
        COMPUTE(kB, vB);
    }
#undef LOADK
#undef LOADV
#undef COMPUTE

    // full per-q denominator: reduce over the 4 lane groups
#pragma unroll
    for (int qt = 0; qt < 2; ++qt) {
        dn[qt] += __shfl_xor(dn[qt], 16);
        dn[qt] += __shfl_xor(dn[qt], 32);
    }

    // LDS merge tree: 8 -> 4 -> 2 -> 1
#define STORE_(s)                                                                   \
    {                                                                               \
        _Pragma("unroll") for (int qt = 0; qt < 2; ++qt) {                          \
            _Pragma("unroll") for (int dc = 0; dc < 4; ++dc)                        \
                _Pragma("unroll") for (int r = 0; r < 4; ++r)                       \
                    redN[s][qt][lgrp * 4 + r][dc * 16 + l16] = oacc[qt][dc][r];     \
            if (lane < 16) redD[s][qt][lane] = dn[qt];                              \
        }                                                                           \
    }
#define ACCUM_(s)                                                                   \
    {                                                                               \
        _Pragma("unroll") for (int qt = 0; qt < 2; ++qt) {                          \
            _Pragma("unroll") for (int dc = 0; dc < 4; ++dc)                        \
                _Pragma("unroll") for (int r = 0; r < 4; ++r)                       \
                    oacc[qt][dc][r] += redN[s][qt][lgrp * 4 + r][dc * 16 + l16];    \
            dn[qt] += redD[s][qt][l16];                                             \
        }                                                                           \
    }
    if (wave >= 4) STORE_(wave - 4);
    __syncthreads();
    if (wave < 4) ACCUM_(wave);
    __syncthreads();
    if (wave == 2 || wave == 3) STORE_(wave - 2);
    __syncthreads();
    if (wave < 2) ACCUM_(wave);
    __syncthreads();
    if (wave == 1) STORE_(0);
    __syncthreads();
    if (wave == 0) {
        ACCUM_(0);
#pragma unroll
        for (int qt = 0; qt < 2; ++qt) {
            float inv = 1.f / dn[qt];
#pragma unroll
            for (int r = 0; r < 4; ++r) {
                float invr = __shfl(inv, lgrp * 4 + r);
#pragma unroll
                for (int dc = 0; dc < 4; ++dc)
                    split_store(oacc[qt][dc][r] * invr, aoH, aoL,
                                (size_t)(q0 + qt * 16 + lgrp * 4 + r) * 256 + h * 64 + dc * 16 + l16);
            }
        }
    }
#undef STORE_
#undef ACCUM_
}

// ---------------- launch ----------------
extern "C" void kernel_launch(void* const* d_in, const int* in_sizes, int n_in,
                              void* d_out, int out_size, void* d_ws, size_t ws_size,
                              hipStream_t stream)
{
    const float* x      = (const float*)d_in[0];
    const int*   ei_t   = (const int*)d_in[1];
    const int*   ei_c   = (const int*)d_in[2];
    const float* ea_t   = (const float*)d_in[3];
    const float* ea_c   = (const float*)d_in[4];
    const float* W_t    = (const float*)d_in[5];
    const float* asrc_t = (const float*)d_in[6];
    const float* adst_t = (const float*)d_in[7];
    const float* We_t   = (const float*)d_in[8];
    const float* aedg_t = (const float*)d_in[9];
    const float* b_t    = (const float*)d_in[10];
    const float* W_c    = (const float*)d_in[11];
    const float* asrc_c = (const float*)d_in[12];
    const float* adst_c = (const float*)d_in[13];
    const float* We_c   = (const float*)d_in[14];
    const float* aedg_c = (const float*)d_in[15];
    const float* b_c    = (const float*)d_in[16];
    const float* Wih    = (const float*)d_in[17];
    const float* bih    = (const float*)d_in[19];
    const float* bhh    = (const float*)d_in[20];
    const float* min_w  = (const float*)d_in[21];
    const float* min_b  = (const float*)d_in[22];
    const float* mout_w = (const float*)d_in[23];
    const float* mout_b = (const float*)d_in[24];
    const float* fus_w  = (const float*)d_in[25];
    const float* fus_b  = (const float*)d_in[26];
    const float* out_w  = (const float*)d_in[27];
    const float* out_b  = (const float*)d_in[28];
    float* outp = (float*)d_out;

    char* W = (char*)d_ws;
    size_t off = 0;
    auto alloc = [&](size_t bytes) { size_t r = off; off += (bytes + 255) & ~(size_t)255; return r; };
    size_t oMeanPart = alloc(512 * 4);
    size_t oCnt   = alloc(2 * NN_ * 4);
    size_t oCur   = alloc(2 * NN_ * 4);
    size_t zeroBytes = off;
    size_t oMean  = alloc(2 * 4);
    size_t oRows  = alloc(2 * (NN_ + 16) * 4);
    size_t oSrcs  = alloc(2 * NE * 4);
    size_t oEav   = alloc(2 * NE * 4);
    size_t oWa    = alloc(4 * INF * NH * 4);
    size_t oDote  = alloc(2 * NH * 4);
    size_t oAsd   = alloc(4 * NN_ * NH * 4);
    size_t oBg    = alloc(1024 * 4);
    size_t oGH    = alloc((size_t)2 * NN_ * KK * 2);
    size_t oGL    = alloc((size_t)2 * NN_ * KK * 2);
    size_t oMtH   = alloc((size_t)1024 * KK * 2);
    size_t oMtL   = alloc((size_t)1024 * KK * 2);
    size_t oBctH  = alloc((size_t)CC * KK * 2);
    size_t oBctL  = alloc((size_t)CC * KK * 2);
    size_t oWihH  = alloc((size_t)1024 * HC * 2);      // reused as concatHi
    size_t oWihL  = alloc((size_t)1024 * HC * 2);      // reused as concatLo
    size_t oWtH   = alloc((size_t)INF * HC * 2);
    size_t oWtL   = alloc((size_t)INF * HC * 2);
    size_t oMinH  = alloc((size_t)768 * HID * 2);
    size_t oMinL  = alloc((size_t)768 * HID * 2);
    size_t oMoutH = alloc((size_t)HID * HID * 2);
    size_t oMoutL = alloc((size_t)HID * HID * 2);
    size_t oFusH  = alloc((size_t)HID * 512 * 2);
    size_t oFusL  = alloc((size_t)HID * 512 * 2);
    size_t oOutwH = alloc((size_t)128 * HID * 2);
    size_t oOutwL = alloc((size_t)128 * HID * 2);
    size_t oHcH   = alloc((size_t)NN_ * HID * 2);      // reused as hfusHi
    size_t oHcL   = alloc((size_t)NN_ * HID * 2);      // reused as hfusLo
    size_t oQb    = alloc((size_t)4 * NN_ * 64 * 2);
    size_t oKb    = alloc((size_t)4 * NN_ * 64 * 2);
    size_t oVt    = alloc((size_t)4 * NN_ * 64 * 2);
    size_t oCcH   = oWihH;    // WihSplit dead after Mt GEMM
    size_t oCcL   = oWihL;
    size_t oAoH   = oGH;      // g dead after gates & hc GEMMs
    size_t oAoL   = oGL;
    size_t oHfH   = oHcH;     // hc dead after qkv GEMM
    size_t oHfL   = oHcL;
    (void)ws_size; (void)in_sizes; (void)n_in; (void)out_size;

    hipMemsetAsync(W, 0, zeroBytes, stream);

    // stage 1: weight splits(x4 vec) + GAT scalar precomputes + bias_g + mean/hist
    k_stage1<<<4084, 256, 0, stream>>>(
        Wih,    (__hip_bfloat16*)(W + oWihH),  (__hip_bfloat16*)(W + oWihL),
        W_t,    (__hip_bfloat16*)(W + oWtH),   (__hip_bfloat16*)(W + oWtL),
        min_w,  (__hip_bfloat16*)(W + oMinH),  (__hip_bfloat16*)(W + oMinL),
        mout_w, (__hip_bfloat16*)(W + oMoutH), (__hip_bfloat16*)(W + oMoutL),
        fus_w,  (__hip_bfloat16*)(W + oFusH),  (__hip_bfloat16*)(W + oFusL),
        out_w,  (__hip_bfloat16*)(W + oOutwH), (__hip_bfloat16*)(W + oOutwL),
        W_c,    (__hip_bfloat16*)(W + oBctH),  (__hip_bfloat16*)(W + oBctL),
        asrc_t, adst_t, We_t, aedg_t, asrc_c, adst_c, We_c, aedg_c,
        (float*)(W + oWa), (float*)(W + oDote),
        b_t, bih, bhh, (float*)(W + oBg),
        ea_t, ea_c, ei_t, ei_c, (float*)(W + oMeanPart), (int*)(W + oCnt));
    // stage 2: a_s/a_d + CSR scan + meansum final reduce
    k_stage2<<<515, 256, 0, stream>>>(x, (float*)(W + oWa), (float*)(W + oAsd),
                                      (int*)(W + oCnt), (int*)(W + oRows),
                                      (float*)(W + oMeanPart), (float*)(W + oMean));
    // Mt[j][h*28+k] = sum_c Wih[j][h*256+c] * Wt[k][h*256+c] — batched over heads
    {
        dim3 grid(8, 1, 8);
        k_mgemm<false, 2, 0><<<grid, 256, 0, stream>>>(
            (__hip_bfloat16*)(W + oWihH), (__hip_bfloat16*)(W + oWihL), HC, CC,
            (__hip_bfloat16*)(W + oWtH),  (__hip_bfloat16*)(W + oWtL),  HC, CC,
            nullptr, nullptr, 0,
            (__hip_bfloat16*)(W + oMtH), (__hip_bfloat16*)(W + oMtL), KK, INF,
            nullptr, nullptr, nullptr,
            1024, INF, CC);
    }
    k_scatter<<<2 * NE / 256, 256, 0, stream>>>(ei_t, ei_c, ea_t, ea_c,
                                                (int*)(W + oRows), (int*)(W + oCur),
                                                (int*)(W + oSrcs), (float*)(W + oEav));
    // GAT aggregation, both branches
    k_gat<<<2 * NN_, 64, 0, stream>>>((int*)(W + oSrcs), (float*)(W + oEav), (int*)(W + oRows), x,
                                      (float*)(W + oAsd), (float*)(W + oDote), (float*)(W + oMean),
                                      (__hip_bfloat16*)(W + oGH), (__hip_bfloat16*)(W + oGL));
    // fused gates GEMM (i/g/o) + LSTM -> h_temporal (d_out) + concat hi/lo
    {
        dim3 grid(NN_ / 64, HID / 64);
        k_gates_lstm<<<grid, 256, 0, stream>>>(
            (__hip_bfloat16*)(W + oGH), (__hip_bfloat16*)(W + oGL),
            (__hip_bfloat16*)(W + oMtH), (__hip_bfloat16*)(W + oMtL),
            (float*)(W + oBg),
            outp + 524288, (__hip_bfloat16*)(W + oCcH), (__hip_bfloat16*)(W + oCcL));
    }
    // h_c = g_c @ Bct^T + b_c -> hi/lo
    {
        dim3 grid(64, 4, 1);
        k_mgemm<false, 1, 0><<<grid, 256, 0, stream>>>(
            (__hip_bfloat16*)(W + oGH) + (size_t)NN_ * KK, (__hip_bfloat16*)(W + oGL) + (size_t)NN_ * KK, KK, 0,
            (__hip_bfloat16*)(W + oBctH), (__hip_bfloat16*)(W + oBctL), KK, 0,
            b_c, nullptr, 0,
            (__hip_bfloat16*)(W + oHcH), (__hip_bfloat16*)(W + oHcL), HID, 0,
            nullptr, nullptr, nullptr,
            NN_, HID, KK);
    }
    // qkv = h_c @ min_w^T + min_b, written directly as bf16 Qb/Kb/Vt-tiled
    {
        dim3 grid(32, 12, 1);
        k_mgemm<false, 2, 1><<<grid, 256, 0, stream>>>(
            (__hip_bfloat16*)(W + oHcH), (__hip_bfloat16*)(W + oHcL), HID, 0,
            (__hip_bfloat16*)(W + oMinH), (__hip_bfloat16*)(W + oMinL), HID, 0,
            min_b, nullptr, 0,
            nullptr, nullptr, 0, 0,
            (__hip_bfloat16*)(W + oQb), (__hip_bfloat16*)(W + oKb), (__hip_bfloat16*)(W + oVt),
            NN_, 768, HID);
    }
    // attention: head->XCD swizzled, tiled+packed V, high-VGPR pipelined stream
    {
        k_attn_mfma<<<512, 512, 0, stream>>>(
            (__hip_bfloat16*)(W + oQb), (__hip_bfloat16*)(W + oKb), (__hip_bfloat16*)(W + oVt),
            (__hip_bfloat16*)(W + oAoH), (__hip_bfloat16*)(W + oAoL));
    }
    // out-proj: concat[:,256:512] (hi/lo) + h_causal (fp32 d_out)
    {
        dim3 grid(64, 4, 1);
        k_mgemm<false, 1, 0><<<grid, 256, 0, stream>>>(
            (__hip_bfloat16*)(W + oAoH), (__hip_bfloat16*)(W + oAoL), HID, 0,
            (__hip_bfloat16*)(W + oMoutH), (__hip_bfloat16*)(W + oMoutL), HID, 0,
            mout_b, outp + 524288 + 1048576, 256,
            (__hip_bfloat16*)(W + oCcH) + 256, (__hip_bfloat16*)(W + oCcL) + 256, 512, 0,
            nullptr, nullptr, nullptr,
            NN_, HID, HID);
    }
    // fusion: relu(concat @ fus_w^T + fus_b) -> hi/lo
    {
        dim3 grid(64, 4, 1);
        k_mgemm<true, 1, 0><<<grid, 256, 0, stream>>>(
            (__hip_bfloat16*)(W + oCcH), (__hip_bfloat16*)(W + oCcL), 512, 0,
            (__hip_bfloat16*)(W + oFusH), (__hip_bfloat16*)(W + oFusL), 512, 0,
            fus_b, nullptr, 0,
            (__hip_bfloat16*)(W + oHfH), (__hip_bfloat16*)(W + oHfL), HID, 0,
            nullptr, nullptr, nullptr,
            NN_, HID, 512);
    }
    // out = hfus @ out_w^T + out_b (fp32 d_out)
    {
        dim3 grid(64, 2, 1);
        k_mgemm<false, 1, 0><<<grid, 256, 0, stream>>>(
            (__hip_bfloat16*)(W + oHfH), (__hip_bfloat16*)(W + oHfL), HID, 0,
            (__hip_bfloat16*)(W + oOutwH), (__hip_bfloat16*)(W + oOutwL), HID, 0,
            out_b, outp, 128,
            nullptr, nullptr, 0, 0,
            nullptr, nullptr, nullptr,
            NN_, 128, HID);
    }
}

// Round 11
// 318.003 us; speedup vs baseline: 5.5426x; 1.1295x over previous
//
#include <hip/hip_runtime.h>
#include <hip/hip_bf16.h>

// ---------------- problem constants ----------------
constexpr int NN_ = 4096;     // nodes
constexpr int INF = 28;       // input features
constexpr int NH  = 8;        // GAT heads
constexpr int CC  = 256;      // channels per head
constexpr int HC  = 2048;     // NH*CC
constexpr int HID = 256;
constexpr int NE  = 131072;   // edges per branch
constexpr int KK  = NH * INF; // 224

typedef short bf16x8 __attribute__((ext_vector_type(8)));
typedef float f32x4 __attribute__((ext_vector_type(4)));

__device__ inline void split_store(float v, __hip_bfloat16* H, __hip_bfloat16* L, size_t idx)
{
    __hip_bfloat16 h = __float2bfloat16(v);
    H[idx] = h;
    L[idx] = __float2bfloat16(v - __bfloat162float(h));
}

__device__ inline short f2bs(float v)
{
    __hip_bfloat16 h = __float2bfloat16(v);
    return *reinterpret_cast<short*>(&h);
}

__device__ inline float wave_sum(float v)
{
    v += __shfl_xor(v, 1);  v += __shfl_xor(v, 2);  v += __shfl_xor(v, 4);
    v += __shfl_xor(v, 8);  v += __shfl_xor(v, 16); v += __shfl_xor(v, 32);
    return v;
}

// async global->LDS DMA, 16B/lane; dest = uniform base + lane*16
__device__ inline void load_lds16(const void* g, void* l)
{
    __builtin_amdgcn_global_load_lds(
        (const __attribute__((address_space(1))) void*)g,
        (__attribute__((address_space(3))) void*)l, 16, 0, 0);
}

// ---------------- stage 1: split_all(x4 vec) + small_pre + biasg + mean_hist ----------------
__global__ void k_stage1(
    const float* __restrict__ Wih,  __hip_bfloat16* WihH,  __hip_bfloat16* WihL,
    const float* __restrict__ Wt,   __hip_bfloat16* WtH,   __hip_bfloat16* WtL,
    const float* __restrict__ minw, __hip_bfloat16* minH,  __hip_bfloat16* minL,
    const float* __restrict__ moutw,__hip_bfloat16* moutH, __hip_bfloat16* moutL,
    const float* __restrict__ fusw, __hip_bfloat16* fusH,  __hip_bfloat16* fusL,
    const float* __restrict__ outw, __hip_bfloat16* outH,  __hip_bfloat16* outL,
    const float* __restrict__ Wc,   __hip_bfloat16* BH,    __hip_bfloat16* BL,
    const float* __restrict__ ast, const float* __restrict__ adt,
    const float* __restrict__ Wet, const float* __restrict__ aet,
    const float* __restrict__ asc, const float* __restrict__ adc,
    const float* __restrict__ Wec, const float* __restrict__ aec,
    float* __restrict__ wa, float* __restrict__ dote,
    const float* __restrict__ bt, const float* __restrict__ bih, const float* __restrict__ bhh,
    float* __restrict__ bg,
    const float* __restrict__ ea_t, const float* __restrict__ ea_c,
    const int* __restrict__ ei_t, const int* __restrict__ ei_c,
    float* __restrict__ meanpart, int* __restrict__ cnt)
{
    int bx = blockIdx.x;
    if (bx < 2576) {
        int i = (bx * 256 + threadIdx.x) * 4;
        if (i < 2580480) {
            const float* src; __hip_bfloat16 *H, *L; int o;
            if (i < 2097152)      { src = Wih;  H = WihH;  L = WihL;  o = i; }
            else if (i < 2154496) { src = Wt;   H = WtH;   L = WtL;   o = i - 2097152; }
            else if (i < 2351104) { src = minw; H = minH;  L = minL;  o = i - 2154496; }
            else if (i < 2416640) { src = moutw;H = moutH; L = moutL; o = i - 2351104; }
            else if (i < 2547712) { src = fusw; H = fusH;  L = fusL;  o = i - 2416640; }
            else                  { src = outw; H = outH;  L = outL;  o = i - 2547712; }
            float4 v = *(const float4*)(src + o);
            short4 hs, ls;
            hs.x = f2bs(v.x); hs.y = f2bs(v.y); hs.z = f2bs(v.z); hs.w = f2bs(v.w);
            __hip_bfloat16* hp = (__hip_bfloat16*)&hs;
            ls.x = f2bs(v.x - __bfloat162float(hp[0]));
            ls.y = f2bs(v.y - __bfloat162float(hp[1]));
            ls.z = f2bs(v.z - __bfloat162float(hp[2]));
            ls.w = f2bs(v.w - __bfloat162float(hp[3]));
            *(short4*)((short*)H + o) = hs;
            *(short4*)((short*)L + o) = ls;
        } else {
            int i2 = i - 2580480;
#pragma unroll
            for (int q = 0; q < 4; ++q) {
                int j = i2 + q;
                int c = j / KK, kk = j % KK;
                int h = kk / INF, k = kk % INF;
                split_store(Wc[k * HC + h * CC + c] * 0.125f, BH, BL, j);
            }
        }
    } else if (bx < 2804) {
        int w = ((bx - 2576) * 256 + threadIdx.x) >> 6;
        int lane = threadIdx.x & 63;
        if (w < 2 * 2 * INF * NH) {
            int b = w / (2 * INF * NH);
            int r = w % (2 * INF * NH);
            int kind = r / (INF * NH);
            int r2 = r % (INF * NH);
            int k = r2 / NH, h = r2 % NH;
            const float* Wm = b ? Wc : Wt;
            const float* a  = b ? (kind ? adc : asc) : (kind ? adt : ast);
            float s = 0.f;
            for (int c = lane; c < CC; c += 64) s += Wm[k * HC + h * CC + c] * a[h * CC + c];
            s = wave_sum(s);
            if (lane == 0) wa[((b * 2 + kind) * INF + k) * NH + h] = s;
        } else if (w < 2 * 2 * INF * NH + 16) {
            int j = w - 2 * 2 * INF * NH;
            int b = j / NH, h = j % NH;
            const float* We = b ? Wec : Wet;
            const float* a  = b ? aec : aet;
            float s = 0.f;
            for (int c = lane; c < CC; c += 64) s += We[h * CC + c] * a[h * CC + c];
            s = wave_sum(s);
            if (lane == 0) dote[b * NH + h] = s;
        }
    } else if (bx < 3060) {
        int j = ((bx - 2804) * 256 + threadIdx.x) >> 6;
        int lane = threadIdx.x & 63;
        if (j < 1024) {
            const float* w = Wih + (size_t)j * HC;
            float s = 0.f;
            for (int c = lane; c < HC; c += 64) s += bt[c] * w[c];
            s = wave_sum(s);
            if (lane == 0) bg[j] = s + bih[j] + bhh[j];
        }
    } else {
        int rel = bx - 3060;
        int i = rel * 256 + threadIdx.x;
        int b = i >> 17, e = i & (NE - 1);
        float v = (b ? ea_c : ea_t)[e];
        for (int off = 32; off; off >>= 1) v += __shfl_down(v, off);
        if ((threadIdx.x & 63) == 0)
            atomicAdd(&meanpart[b * 256 + (rel & 255)], v);
        const int* ei = b ? ei_c : ei_t;
        atomicAdd(&cnt[b * NN_ + ei[NE + e]], 1);
    }
}

// ---------------- stage 2: as_ad + CSR scan + meansum final reduce ----------------
__global__ __launch_bounds__(256) void k_stage2(
    const float* __restrict__ x, const float* __restrict__ wa, float* __restrict__ asd,
    const int* __restrict__ cnt, int* __restrict__ rows,
    const float* __restrict__ meanpart, float* __restrict__ meansum)
{
    int bx = blockIdx.x;
    if (bx < 512) {
        int i = bx * 256 + threadIdx.x;
        int bk = i / (NN_ * NH);
        int r = i % (NN_ * NH);
        int n = r / NH, h = r % NH;
        const float* W = wa + bk * INF * NH;
        const float* xr = x + n * INF;
        float s = 0.f;
#pragma unroll
        for (int k = 0; k < INF; ++k) s += xr[k] * W[k * NH + h];
        asd[(bk * NN_ + n) * NH + h] = s;
    } else if (bx < 514) {
        int b = bx - 512;
        const int* c = cnt + b * NN_;
        int* r = rows + b * (NN_ + 16);
        __shared__ int ts[256];
        int t = threadIdx.x;
        int v[16]; int s = 0;
#pragma unroll
        for (int i = 0; i < 16; ++i) { v[i] = c[t * 16 + i]; s += v[i]; }
        ts[t] = s;
        __syncthreads();
        for (int off = 1; off < 256; off <<= 1) {
            int add = (t >= off) ? ts[t - off] : 0;
            __syncthreads();
            ts[t] += add;
            __syncthreads();
        }
        int excl = t ? ts[t - 1] : 0;
#pragma unroll
        for (int i = 0; i < 16; ++i) { r[t * 16 + i] = excl; excl += v[i]; }
        if (t == 255) r[NN_] = excl;
    } else {
        int t = threadIdx.x;
        float v0 = meanpart[t];
        float v1 = meanpart[256 + t];
        v0 = wave_sum(v0);
        v1 = wave_sum(v1);
        __shared__ float s0[4], s1[4];
        if ((t & 63) == 0) { s0[t >> 6] = v0; s1[t >> 6] = v1; }
        __syncthreads();
        if (t == 0) meansum[0] = s0[0] + s0[1] + s0[2] + s0[3];
        if (t == 1) meansum[1] = s1[0] + s1[1] + s1[2] + s1[3];
    }
}

__global__ void k_scatter(const int* __restrict__ ei_t, const int* __restrict__ ei_c,
                          const float* __restrict__ ea_t, const float* __restrict__ ea_c,
                          const int* __restrict__ rows, int* __restrict__ cur,
                          int* __restrict__ srcs, float* __restrict__ eav)
{
    int i = blockIdx.x * blockDim.x + threadIdx.x;
    if (i >= 2 * NE) return;
    int b = i / NE, e = i - b * NE;
    const int* ei = b ? ei_c : ei_t;
    const float* ea = b ? ea_c : ea_t;
    int d = ei[NE + e];
    int pos = rows[b * (NN_ + 16) + d] + atomicAdd(&cur[b * NN_ + d], 1);
    srcs[b * NE + pos] = ei[e];
    eav[b * NE + pos] = ea[e];
}

// ---------------- GAT per-dst aggregation, both branches in one grid ----------------
__global__ __launch_bounds__(64) void k_gat(
    const int* __restrict__ srcs, const float* __restrict__ eav,
    const int* __restrict__ rows, const float* __restrict__ x,
    const float* __restrict__ asd, const float* __restrict__ dote,
    const float* __restrict__ meansum,
    __hip_bfloat16* __restrict__ gH, __hip_bfloat16* __restrict__ gL)
{
    int b = blockIdx.x >> 12;
    int n = blockIdx.x & 4095;
    srcs += (size_t)b * NE; eav += (size_t)b * NE; rows += b * (NN_ + 16);
    const float* a_s = asd + (size_t)(2 * b) * NN_ * NH;
    const float* a_d = asd + (size_t)(2 * b + 1) * NN_ * NH;
    dote += b * NH;
    gH += (size_t)b * NN_ * KK; gL += (size_t)b * NN_ * KK;

    int lane = threadIdx.x;
    __shared__ float xb[64][32];
    __shared__ float eb[64][8];
    __shared__ float denb[8];

    float adn[NH], dt[NH];
#pragma unroll
    for (int h = 0; h < NH; ++h) { adn[h] = a_d[n * NH + h]; dt[h] = dote[h]; }
    float mean_attr = meansum[b] * (1.0f / NE);

    const int hOwn = lane >> 3;
    const int kOwn = (lane & 7) * 4;

    float acc0, acc1, acc2, acc3;
    {
        float al = a_s[n * NH + hOwn] + adn[hOwn] + mean_attr * dt[hOwn];
        al = al > 0.f ? al : 0.2f * al;
        float es = __expf(al);
        float xv0 = (kOwn + 0 < INF) ? x[n * INF + kOwn + 0] : 0.f;
        float xv1 = (kOwn + 1 < INF) ? x[n * INF + kOwn + 1] : 0.f;
        float xv2 = (kOwn + 2 < INF) ? x[n * INF + kOwn + 2] : 0.f;
        float xv3 = (kOwn + 3 < INF) ? x[n * INF + kOwn + 3] : ((kOwn + 3 == 31) ? 1.f : 0.f);
        acc0 = es * xv0; acc1 = es * xv1; acc2 = es * xv2; acc3 = es * xv3;
    }

    int e0 = rows[n], e1 = rows[n + 1];
    for (int base = e0; base < e1; base += 64) {
        int m = e1 - base; if (m > 64) m = 64;
        if (lane < m) {
            int sidx = srcs[base + lane];
            float ea = eav[base + lane];
            const float4* xr = (const float4*)(x + sidx * INF);
#pragma unroll
            for (int q = 0; q < 7; ++q) ((float4*)&xb[lane][0])[q] = xr[q];
            xb[lane][28] = 0.f; xb[lane][29] = 0.f; xb[lane][30] = 0.f; xb[lane][31] = 1.f;
            const float* asr = a_s + sidx * NH;
#pragma unroll
            for (int h = 0; h < NH; ++h) {
                float al = asr[h] + adn[h] + ea * dt[h];
                al = al > 0.f ? al : 0.2f * al;
                eb[lane][h] = __expf(al);
            }
        }
        __syncthreads();
        for (int j = 0; j < m; ++j) {
            float e = eb[j][hOwn];
            float4 xv = *(const float4*)&xb[j][kOwn];
            acc0 += e * xv.x; acc1 += e * xv.y; acc2 += e * xv.z; acc3 += e * xv.w;
        }
        __syncthreads();
    }

    if ((lane & 7) == 7) denb[hOwn] = acc3;
    __syncthreads();
    float inv = 1.0f / denb[hOwn];
    size_t gr = (size_t)n * KK + hOwn * INF + kOwn;
    if (kOwn + 0 < INF) split_store(acc0 * inv, gH, gL, gr + 0);
    if (kOwn + 1 < INF) split_store(acc1 * inv, gH, gL, gr + 1);
    if (kOwn + 2 < INF) split_store(acc2 * inv, gH, gL, gr + 2);
    if (kOwn + 3 < INF) split_store(acc3 * inv, gH, gL, gr + 3);
}

// ---------------- bf16x3-split MFMA GEMM, B staged via global_load_lds ----------------
// B panel (64 n-rows x 32 k, hi+lo) cooperatively DMA'd into LDS each K-step:
// batched issue + single barrier drain replaces 8-16 serialized VMEM loads/iter
// (the R10 VGPR=80 load-serialization wall). LDS layout swizzled (u^=(row&3))
// via pre-swizzled SOURCE address + swizzled ds_read (both-sides rule).
template<bool RELU, int MS, int EPI>
__global__ __launch_bounds__(256) void k_mgemm(
    const __hip_bfloat16* __restrict__ Ahi_, const __hip_bfloat16* __restrict__ Alo_, int lda, int aOffZ,
    const __hip_bfloat16* __restrict__ Bhi_, const __hip_bfloat16* __restrict__ Blo_, int ldb, int bOffZ,
    const float* __restrict__ bias,
    float* __restrict__ Cf, int ldcf,
    __hip_bfloat16* __restrict__ Chi, __hip_bfloat16* __restrict__ Clo, int ldch, int cOffZ,
    __hip_bfloat16* __restrict__ Qbp, __hip_bfloat16* __restrict__ Kbp, __hip_bfloat16* __restrict__ Vtp,
    int M, int N, int K)
{
    __shared__ short bstage[4096];   // hi tile: shorts [0,2048), lo tile: [2048,4096)
    int z = blockIdx.z;
    const short* Ah = (const short*)Ahi_ + (size_t)z * aOffZ;
    const short* Al = (const short*)Alo_ + (size_t)z * aOffZ;
    const short* Bh = (const short*)Bhi_ + (size_t)z * bOffZ;
    const short* Bl = (const short*)Blo_ + (size_t)z * bOffZ;
    int wave = threadIdx.x >> 6, lane = threadIdx.x & 63;
    int l16 = lane & 15, lgrp = lane >> 4;
    int m0 = blockIdx.x * (64 * MS) + wave * (16 * MS);
    int n0 = blockIdx.y * 64;

    f32x4 acc[MS][4];
#pragma unroll
    for (int i = 0; i < MS; ++i)
#pragma unroll
        for (int j = 0; j < 4; ++j) acc[i][j] = (f32x4){0.f, 0.f, 0.f, 0.f};

    // this wave's 2 DMA chunks: c = wave*2 + j ; c<4 -> hi chunk c, else lo chunk c-4
    int gsrc[2], cc_[2]; bool hi_[2];
#pragma unroll
    for (int j = 0; j < 2; ++j) {
        int c = wave * 2 + j;
        hi_[j] = c < 4; cc_[j] = c & 3;
        int w = cc_[j] * 64 + lane;
        gsrc[j] = w ^ ((w >> 2) & 3);        // pre-swizzled source unit
    }

    for (int k0 = 0; k0 < K; k0 += 32) {
#pragma unroll
        for (int j = 0; j < 2; ++j) {
            const short* src = hi_[j] ? Bh : Bl;
            int g = gsrc[j];
            load_lds16(src + (size_t)(n0 + (g >> 2)) * ldb + k0 + (g & 3) * 8,
                       &bstage[(hi_[j] ? 0 : 2048) + cc_[j] * 512]);
        }
        __syncthreads();   // drains vmcnt -> B tile resident for all waves

        bf16x8 ah[MS], al[MS];
#pragma unroll
        for (int ms = 0; ms < MS; ++ms) {
            size_t ka = (size_t)k0 + lgrp * 8;
            ah[ms] = *(const bf16x8*)(Ah + (size_t)(m0 + ms * 16 + l16) * lda + ka);
            al[ms] = *(const bf16x8*)(Al + (size_t)(m0 + ms * 16 + l16) * lda + ka);
        }
        bf16x8 bh[4], bl[4];
#pragma unroll
        for (int ns = 0; ns < 4; ++ns) {
            int u = (ns * 16 + l16) * 4 + lgrp;
            int us = u ^ (l16 & 3);
            bh[ns] = *(const bf16x8*)&bstage[us * 8];
            bl[ns] = *(const bf16x8*)&bstage[2048 + us * 8];
        }
#pragma unroll
        for (int ns = 0; ns < 4; ++ns)
#pragma unroll
            for (int ms = 0; ms < MS; ++ms) {
                acc[ms][ns] = __builtin_amdgcn_mfma_f32_16x16x32_bf16(ah[ms], bh[ns], acc[ms][ns], 0, 0, 0);
                acc[ms][ns] = __builtin_amdgcn_mfma_f32_16x16x32_bf16(ah[ms], bl[ns], acc[ms][ns], 0, 0, 0);
                acc[ms][ns] = __builtin_amdgcn_mfma_f32_16x16x32_bf16(al[ms], bh[ns], acc[ms][ns], 0, 0, 0);
            }
        __syncthreads();   // all reads done before next tile overwrites
    }

#pragma unroll
    for (int ms = 0; ms < MS; ++ms)
#pragma unroll
        for (int ns = 0; ns < 4; ++ns)
#pragma unroll
            for (int r = 0; r < 4; ++r) {
                int m = m0 + ms * 16 + lgrp * 4 + r;
                int n = n0 + ns * 16 + l16;
                if (n >= N) continue;
                float v = acc[ms][ns][r];
                if (bias) v += bias[n];
                if (RELU) v = v > 0.f ? v : 0.f;
                if (EPI == 1) {
                    int sec = n >> 8, hh = (n >> 6) & 3, d = n & 63;
                    if (sec == 0)      Qbp[((size_t)hh * NN_ + m) * 64 + d] = __float2bfloat16(v * 0.125f);
                    else if (sec == 1) Kbp[((size_t)hh * NN_ + m) * 64 + d] = __float2bfloat16(v);
                    else {
                        int p = m & 31;
                        int kp = (((p & 15) >> 2) << 3) + ((p >> 4) << 2) + (p & 3);
                        Vtp[(((size_t)hh * (NN_ / 32) + (m >> 5)) * 64 + d) * 32 + kp]
                            = __float2bfloat16(v);
                    }
                } else {
                    if (Cf) Cf[(size_t)m * ldcf + n] = v;
                    if (Chi) split_store(v, Chi, Clo, (size_t)m * ldch + (size_t)z * cOffZ + n);
                }
            }
}

// ---------------- fused gates GEMM + LSTM (B staged via global_load_lds) ----------------
__global__ __launch_bounds__(256) void k_gates_lstm(
    const __hip_bfloat16* __restrict__ gHi, const __hip_bfloat16* __restrict__ gLo,
    const __hip_bfloat16* __restrict__ MtH, const __hip_bfloat16* __restrict__ MtL,
    const float* __restrict__ bg,
    float* __restrict__ hout, __hip_bfloat16* __restrict__ ccH, __hip_bfloat16* __restrict__ ccL)
{
    __shared__ short bstage[4096];
    int wave = threadIdx.x >> 6, lane = threadIdx.x & 63;
    int l16 = lane & 15, lgrp = lane >> 4;
    int m0 = blockIdx.x * 64 + wave * 16;
    int n0 = blockIdx.y * 64;
    const short* Ah = (const short*)gHi;
    const short* Al = (const short*)gLo;
    const short* Bh = (const short*)MtH;
    const short* Bl = (const short*)MtL;

    bf16x8 ah[7], al[7];
#pragma unroll
    for (int k = 0; k < 7; ++k) {
        size_t ka = (size_t)k * 32 + lgrp * 8;
        ah[k] = *(const bf16x8*)(Ah + (size_t)(m0 + l16) * KK + ka);
        al[k] = *(const bf16x8*)(Al + (size_t)(m0 + l16) * KK + ka);
    }

    int gsrc[2], cc_[2]; bool hi_[2];
#pragma unroll
    for (int j = 0; j < 2; ++j) {
        int c = wave * 2 + j;
        hi_[j] = c < 4; cc_[j] = c & 3;
        int w = cc_[j] * 64 + lane;
        gsrc[j] = w ^ ((w >> 2) & 3);
    }

    const int secBase[3] = {0, 512, 768};   // i, g, o rows of Mt
    f32x4 acc[3][4];
#pragma unroll
    for (int s = 0; s < 3; ++s)
#pragma unroll
        for (int ns = 0; ns < 4; ++ns) acc[s][ns] = (f32x4){0.f, 0.f, 0.f, 0.f};

    for (int s = 0; s < 3; ++s) {
        int rbase = secBase[s] + n0;
        for (int k = 0; k < 7; ++k) {
            int k0 = k * 32;
#pragma unroll
            for (int j = 0; j < 2; ++j) {
                const short* src = hi_[j] ? Bh : Bl;
                int g = gsrc[j];
                load_lds16(src + (size_t)(rbase + (g >> 2)) * KK + k0 + (g & 3) * 8,
                           &bstage[(hi_[j] ? 0 : 2048) + cc_[j] * 512]);
            }
            __syncthreads();
            bf16x8 bh[4], bl[4];
#pragma unroll
            for (int ns = 0; ns < 4; ++ns) {
                int u = (ns * 16 + l16) * 4 + lgrp;
                int us = u ^ (l16 & 3);
                bh[ns] = *(const bf16x8*)&bstage[us * 8];
                bl[ns] = *(const bf16x8*)&bstage[2048 + us * 8];
            }
#pragma unroll
            for (int ns = 0; ns < 4; ++ns) {
                acc[s][ns] = __builtin_amdgcn_mfma_f32_16x16x32_bf16(ah[k], bh[ns], acc[s][ns], 0, 0, 0);
                acc[s][ns] = __builtin_amdgcn_mfma_f32_16x16x32_bf16(ah[k], bl[ns], acc[s][ns], 0, 0, 0);
                acc[s][ns] = __builtin_amdgcn_mfma_f32_16x16x32_bf16(al[k], bh[ns], acc[s][ns], 0, 0, 0);
            }
            __syncthreads();
        }
    }

#pragma unroll
    for (int ns = 0; ns < 4; ++ns)
#pragma unroll
        for (int r = 0; r < 4; ++r) {
            int m = m0 + lgrp * 4 + r;
            int n = n0 + ns * 16 + l16;
            float gi = acc[0][ns][r] + bg[n];
            float gg = acc[1][ns][r] + bg[512 + n];
            float go = acc[2][ns][r] + bg[768 + n];
            float c = (1.f / (1.f + __expf(-gi))) * tanhf(gg);
            float h = (1.f / (1.f + __expf(-go))) * tanhf(c);
            hout[(size_t)m * 256 + n] = h;
            split_store(h, ccH, ccL, (size_t)m * 512 + n);
        }
}

// ---------------- MHA: bf16 MFMA flash attention, LDS-staged K/V ----------------
// grid 512 flattened, 256 thr = 4 waves. Head->XCD swizzle. Block owns 32 q-rows;
// wave w covers keys [w*1024, +1024) in 32-key tiles. Per tile: 8 batched
// global_load_lds ops into the wave-PRIVATE LDS slice (no barrier in loop, only
// per-wave vmcnt(0)) -> replaces the 12 serialized VMEM loads that pinned R8-R10
// at ~60-72us. K reads swizzled u^=(l16&7) (was 16-way conflict), V u^=(l16&3).
__global__ __launch_bounds__(256) void k_attn_mfma(
    const __hip_bfloat16* __restrict__ Qb, const __hip_bfloat16* __restrict__ Kb,
    const __hip_bfloat16* __restrict__ Vt,
    __hip_bfloat16* __restrict__ aoH, __hip_bfloat16* __restrict__ aoL)
{
    __shared__ short kst[4][2048];            // 4KB K tile per wave (swizzled)
    __shared__ short vst[4][2048];            // 4KB V tile per wave (swizzled)
    __shared__ float redN[2][2][16][65];
    __shared__ float redD[2][2][16];
    int tid = threadIdx.x;
    int wave = tid >> 6, lane = tid & 63;
    int l16 = lane & 15, lgrp = lane >> 4;
    int wg = blockIdx.x;
    int xcd = wg & 7;
    int h = xcd >> 1;
    int q0 = (((wg >> 3) << 1) | (xcd & 1)) * 32;
    int kbase = wave * 1024;

    const short* Qs = (const short*)Qb;
    const short* Kg = (const short*)Kb + (size_t)h * NN_ * 64;
    const short* Vg = (const short*)Vt + (size_t)h * NN_ * 64;

    bf16x8 qf[2][2];
#pragma unroll
    for (int qt = 0; qt < 2; ++qt)
#pragma unroll
        for (int dh = 0; dh < 2; ++dh)
            qf[qt][dh] = *(const bf16x8*)(Qs + ((size_t)h * NN_ + q0 + qt * 16 + l16) * 64 + dh * 32 + lgrp * 8);

    f32x4 oacc[2][4];
#pragma unroll
    for (int qt = 0; qt < 2; ++qt)
#pragma unroll
        for (int dc = 0; dc < 4; ++dc) oacc[qt][dc] = (f32x4){0.f, 0.f, 0.f, 0.f};
    float dn[2] = {0.f, 0.f};

    // pre-swizzled per-lane DMA source units
    int gk[4], gv[4];
#pragma unroll
    for (int c = 0; c < 4; ++c) {
        int w = c * 64 + lane;
        gk[c] = w ^ ((w >> 3) & 7);
        gv[c] = w ^ ((w >> 2) & 3);
    }

    for (int kt = 0; kt < 32; ++kt) {
        int k0 = kbase + kt * 32;
        const short* ktile = Kg + (size_t)k0 * 64;
        const short* vtile = Vg + (size_t)(k0 >> 5) * 2048;
#pragma unroll
        for (int c = 0; c < 4; ++c)
            load_lds16(ktile + (size_t)(gk[c] >> 3) * 64 + (gk[c] & 7) * 8, &kst[wave][c * 512]);
#pragma unroll
        for (int c = 0; c < 4; ++c)
            load_lds16(vtile + (gv[c] >> 2) * 32 + (gv[c] & 3) * 8, &vst[wave][c * 512]);
        asm volatile("s_waitcnt vmcnt(0)" ::: "memory");

        bf16x8 kf[2][2], vf[4];
#pragma unroll
        for (int kh = 0; kh < 2; ++kh)
#pragma unroll
            for (int dh = 0; dh < 2; ++dh) {
                int u = (kh * 16 + l16) * 8 + dh * 4 + lgrp;
                kf[kh][dh] = *(const bf16x8*)&kst[wave][(u ^ (l16 & 7)) * 8];
            }
#pragma unroll
        for (int dc = 0; dc < 4; ++dc) {
            int u = (dc * 16 + l16) * 4 + lgrp;
            vf[dc] = *(const bf16x8*)&vst[wave][(u ^ (l16 & 3)) * 8];
        }

        f32x4 st[2][2];
#pragma unroll
        for (int kh = 0; kh < 2; ++kh)
#pragma unroll
            for (int qt = 0; qt < 2; ++qt) {
                f32x4 s = (f32x4){0.f, 0.f, 0.f, 0.f};
                s = __builtin_amdgcn_mfma_f32_16x16x32_bf16(kf[kh][0], qf[qt][0], s, 0, 0, 0);
                s = __builtin_amdgcn_mfma_f32_16x16x32_bf16(kf[kh][1], qf[qt][1], s, 0, 0, 0);
                st[kh][qt] = s;
            }
#pragma unroll
        for (int qt = 0; qt < 2; ++qt) {
            bf16x8 pa;
            float dsum = 0.f;
#pragma unroll
            for (int r = 0; r < 4; ++r) {
                float e0 = __expf(st[0][qt][r]);
                float e1 = __expf(st[1][qt][r]);
                dsum += e0 + e1;
                pa[r]     = f2bs(e0);
                pa[4 + r] = f2bs(e1);
            }
            dn[qt] += dsum;
#pragma unroll
            for (int dc = 0; dc < 4; ++dc)
                oacc[qt][dc] = __builtin_amdgcn_mfma_f32_16x16x32_bf16(pa, vf[dc], oacc[qt][dc], 0, 0, 0);
        }
        asm volatile("s_waitcnt lgkmcnt(0)" ::: "memory");  // reads done before overwrite
    }

#pragma unroll
    for (int qt = 0; qt < 2; ++qt) {
        dn[qt] += __shfl_xor(dn[qt], 16);
        dn[qt] += __shfl_xor(dn[qt], 32);
    }

    // merge tree: 4 -> 2 -> 1
#define STORE_(s)                                                                   \
    {                                                                               \
        _Pragma("unroll") for (int qt = 0; qt < 2; ++qt) {                          \
            _Pragma("unroll") for (int dc = 0; dc < 4; ++dc)                        \
                _Pragma("unroll") for (int r = 0; r < 4; ++r)                       \
                    redN[s][qt][lgrp * 4 + r][dc * 16 + l16] = oacc[qt][dc][r];     \
            if (lane < 16) redD[s][qt][lane] = dn[qt];                              \
        }                                                                           \
    }
#define ACCUM_(s)                                                                   \
    {                                                                               \
        _Pragma("unroll") for (int qt = 0; qt < 2; ++qt) {                          \
            _Pragma("unroll") for (int dc = 0; dc < 4; ++dc)                        \
                _Pragma("unroll") for (int r = 0; r < 4; ++r)                       \
                    oacc[qt][dc][r] += redN[s][qt][lgrp * 4 + r][dc * 16 + l16];    \
            dn[qt] += redD[s][qt][l16];                                             \
        }                                                                           \
    }
    if (wave >= 2) STORE_(wave - 2);
    __syncthreads();
    if (wave < 2) ACCUM_(wave);
    __syncthreads();
    if (wave == 1) STORE_(0);
    __syncthreads();
    if (wave == 0) {
        ACCUM_(0);
#pragma unroll
        for (int qt = 0; qt < 2; ++qt) {
            float inv = 1.f / dn[qt];
#pragma unroll
            for (int r = 0; r < 4; ++r) {
                float invr = __shfl(inv, lgrp * 4 + r);
#pragma unroll
                for (int dc = 0; dc < 4; ++dc)
                    split_store(oacc[qt][dc][r] * invr, aoH, aoL,
                                (size_t)(q0 + qt * 16 + lgrp * 4 + r) * 256 + h * 64 + dc * 16 + l16);
            }
        }
    }
#undef STORE_
#undef ACCUM_
}

// ---------------- launch ----------------
extern "C" void kernel_launch(void* const* d_in, const int* in_sizes, int n_in,
                              void* d_out, int out_size, void* d_ws, size_t ws_size,
                              hipStream_t stream)
{
    const float* x      = (const float*)d_in[0];
    const int*   ei_t   = (const int*)d_in[1];
    const int*   ei_c   = (const int*)d_in[2];
    const float* ea_t   = (const float*)d_in[3];
    const float* ea_c   = (const float*)d_in[4];
    const float* W_t    = (const float*)d_in[5];
    const float* asrc_t = (const float*)d_in[6];
    const float* adst_t = (const float*)d_in[7];
    const float* We_t   = (const float*)d_in[8];
    const float* aedg_t = (const float*)d_in[9];
    const float* b_t    = (const float*)d_in[10];
    const float* W_c    = (const float*)d_in[11];
    const float* asrc_c = (const float*)d_in[12];
    const float* adst_c = (const float*)d_in[13];
    const float* We_c   = (const float*)d_in[14];
    const float* aedg_c = (const float*)d_in[15];
    const float* b_c    = (const float*)d_in[16];
    const float* Wih    = (const float*)d_in[17];
    const float* bih    = (const float*)d_in[19];
    const float* bhh    = (const float*)d_in[20];
    const float* min_w  = (const float*)d_in[21];
    const float* min_b  = (const float*)d_in[22];
    const float* mout_w = (const float*)d_in[23];
    const float* mout_b = (const float*)d_in[24];
    const float* fus_w  = (const float*)d_in[25];
    const float* fus_b  = (const float*)d_in[26];
    const float* out_w  = (const float*)d_in[27];
    const float* out_b  = (const float*)d_in[28];
    float* outp = (float*)d_out;

    char* W = (char*)d_ws;
    size_t off = 0;
    auto alloc = [&](size_t bytes) { size_t r = off; off += (bytes + 255) & ~(size_t)255; return r; };
    size_t oMeanPart = alloc(512 * 4);
    size_t oCnt   = alloc(2 * NN_ * 4);
    size_t oCur   = alloc(2 * NN_ * 4);
    size_t zeroBytes = off;
    size_t oMean  = alloc(2 * 4);
    size_t oRows  = alloc(2 * (NN_ + 16) * 4);
    size_t oSrcs  = alloc(2 * NE * 4);
    size_t oEav   = alloc(2 * NE * 4);
    size_t oWa    = alloc(4 * INF * NH * 4);
    size_t oDote  = alloc(2 * NH * 4);
    size_t oAsd   = alloc(4 * NN_ * NH * 4);
    size_t oBg    = alloc(1024 * 4);
    size_t oGH    = alloc((size_t)2 * NN_ * KK * 2);
    size_t oGL    = alloc((size_t)2 * NN_ * KK * 2);
    size_t oMtH   = alloc((size_t)1024 * KK * 2);
    size_t oMtL   = alloc((size_t)1024 * KK * 2);
    size_t oBctH  = alloc((size_t)CC * KK * 2);
    size_t oBctL  = alloc((size_t)CC * KK * 2);
    size_t oWihH  = alloc((size_t)1024 * HC * 2);      // reused as concatHi
    size_t oWihL  = alloc((size_t)1024 * HC * 2);      // reused as concatLo
    size_t oWtH   = alloc((size_t)INF * HC * 2);
    size_t oWtL   = alloc((size_t)INF * HC * 2);
    size_t oMinH  = alloc((size_t)768 * HID * 2);
    size_t oMinL  = alloc((size_t)768 * HID * 2);
    size_t oMoutH = alloc((size_t)HID * HID * 2);
    size_t oMoutL = alloc((size_t)HID * HID * 2);
    size_t oFusH  = alloc((size_t)HID * 512 * 2);
    size_t oFusL  = alloc((size_t)HID * 512 * 2);
    size_t oOutwH = alloc((size_t)128 * HID * 2);
    size_t oOutwL = alloc((size_t)128 * HID * 2);
    size_t oHcH   = alloc((size_t)NN_ * HID * 2);      // reused as hfusHi
    size_t oHcL   = alloc((size_t)NN_ * HID * 2);      // reused as hfusLo
    size_t oQb    = alloc((size_t)4 * NN_ * 64 * 2);
    size_t oKb    = alloc((size_t)4 * NN_ * 64 * 2);
    size_t oVt    = alloc((size_t)4 * NN_ * 64 * 2);
    size_t oCcH   = oWihH;    // WihSplit dead after Mt GEMM
    size_t oCcL   = oWihL;
    size_t oAoH   = oGH;      // g dead after gates & hc GEMMs
    size_t oAoL   = oGL;
    size_t oHfH   = oHcH;     // hc dead after qkv GEMM
    size_t oHfL   = oHcL;
    (void)ws_size; (void)in_sizes; (void)n_in; (void)out_size;

    hipMemsetAsync(W, 0, zeroBytes, stream);

    k_stage1<<<4084, 256, 0, stream>>>(
        Wih,    (__hip_bfloat16*)(W + oWihH),  (__hip_bfloat16*)(W + oWihL),
        W_t,    (__hip_bfloat16*)(W + oWtH),   (__hip_bfloat16*)(W + oWtL),
        min_w,  (__hip_bfloat16*)(W + oMinH),  (__hip_bfloat16*)(W + oMinL),
        mout_w, (__hip_bfloat16*)(W + oMoutH), (__hip_bfloat16*)(W + oMoutL),
        fus_w,  (__hip_bfloat16*)(W + oFusH),  (__hip_bfloat16*)(W + oFusL),
        out_w,  (__hip_bfloat16*)(W + oOutwH), (__hip_bfloat16*)(W + oOutwL),
        W_c,    (__hip_bfloat16*)(W + oBctH),  (__hip_bfloat16*)(W + oBctL),
        asrc_t, adst_t, We_t, aedg_t, asrc_c, adst_c, We_c, aedg_c,
        (float*)(W + oWa), (float*)(W + oDote),
        b_t, bih, bhh, (float*)(W + oBg),
        ea_t, ea_c, ei_t, ei_c, (float*)(W + oMeanPart), (int*)(W + oCnt));
    k_stage2<<<515, 256, 0, stream>>>(x, (float*)(W + oWa), (float*)(W + oAsd),
                                      (int*)(W + oCnt), (int*)(W + oRows),
                                      (float*)(W + oMeanPart), (float*)(W + oMean));
    // Mt — batched over heads
    {
        dim3 grid(8, 1, 8);
        k_mgemm<false, 2, 0><<<grid, 256, 0, stream>>>(
            (__hip_bfloat16*)(W + oWihH), (__hip_bfloat16*)(W + oWihL), HC, CC,
            (__hip_bfloat16*)(W + oWtH),  (__hip_bfloat16*)(W + oWtL),  HC, CC,
            nullptr, nullptr, 0,
            (__hip_bfloat16*)(W + oMtH), (__hip_bfloat16*)(W + oMtL), KK, INF,
            nullptr, nullptr, nullptr,
            1024, INF, CC);
    }
    k_scatter<<<2 * NE / 256, 256, 0, stream>>>(ei_t, ei_c, ea_t, ea_c,
                                                (int*)(W + oRows), (int*)(W + oCur),
                                                (int*)(W + oSrcs), (float*)(W + oEav));
    k_gat<<<2 * NN_, 64, 0, stream>>>((int*)(W + oSrcs), (float*)(W + oEav), (int*)(W + oRows), x,
                                      (float*)(W + oAsd), (float*)(W + oDote), (float*)(W + oMean),
                                      (__hip_bfloat16*)(W + oGH), (__hip_bfloat16*)(W + oGL));
    // fused gates GEMM (i/g/o) + LSTM
    {
        dim3 grid(NN_ / 64, HID / 64);
        k_gates_lstm<<<grid, 256, 0, stream>>>(
            (__hip_bfloat16*)(W + oGH), (__hip_bfloat16*)(W + oGL),
            (__hip_bfloat16*)(W + oMtH), (__hip_bfloat16*)(W + oMtL),
            (float*)(W + oBg),
            outp + 524288, (__hip_bfloat16*)(W + oCcH), (__hip_bfloat16*)(W + oCcL));
    }
    // h_c = g_c @ Bct^T + b_c -> hi/lo
    {
        dim3 grid(64, 4, 1);
        k_mgemm<false, 1, 0><<<grid, 256, 0, stream>>>(
            (__hip_bfloat16*)(W + oGH) + (size_t)NN_ * KK, (__hip_bfloat16*)(W + oGL) + (size_t)NN_ * KK, KK, 0,
            (__hip_bfloat16*)(W + oBctH), (__hip_bfloat16*)(W + oBctL), KK, 0,
            b_c, nullptr, 0,
            (__hip_bfloat16*)(W + oHcH), (__hip_bfloat16*)(W + oHcL), HID, 0,
            nullptr, nullptr, nullptr,
            NN_, HID, KK);
    }
    // qkv -> bf16 Qb/Kb/Vt-tiled
    {
        dim3 grid(32, 12, 1);
        k_mgemm<false, 2, 1><<<grid, 256, 0, stream>>>(
            (__hip_bfloat16*)(W + oHcH), (__hip_bfloat16*)(W + oHcL), HID, 0,
            (__hip_bfloat16*)(W + oMinH), (__hip_bfloat16*)(W + oMinL), HID, 0,
            min_b, nullptr, 0,
            nullptr, nullptr, 0, 0,
            (__hip_bfloat16*)(W + oQb), (__hip_bfloat16*)(W + oKb), (__hip_bfloat16*)(W + oVt),
            NN_, 768, HID);
    }
    // attention: LDS-staged K/V, head->XCD swizzle
    {
        k_attn_mfma<<<512, 256, 0, stream>>>(
            (__hip_bfloat16*)(W + oQb), (__hip_bfloat16*)(W + oKb), (__hip_bfloat16*)(W + oVt),
            (__hip_bfloat16*)(W + oAoH), (__hip_bfloat16*)(W + oAoL));
    }
    // out-proj
    {
        dim3 grid(64, 4, 1);
        k_mgemm<false, 1, 0><<<grid, 256, 0, stream>>>(
            (__hip_bfloat16*)(W + oAoH), (__hip_bfloat16*)(W + oAoL), HID, 0,
            (__hip_bfloat16*)(W + oMoutH), (__hip_bfloat16*)(W + oMoutL), HID, 0,
            mout_b, outp + 524288 + 1048576, 256,
            (__hip_bfloat16*)(W + oCcH) + 256, (__hip_bfloat16*)(W + oCcL) + 256, 512, 0,
            nullptr, nullptr, nullptr,
            NN_, HID, HID);
    }
    // fusion
    {
        dim3 grid(64, 4, 1);
        k_mgemm<true, 1, 0><<<grid, 256, 0, stream>>>(
            (__hip_bfloat16*)(W + oCcH), (__hip_bfloat16*)(W + oCcL), 512, 0,
            (__hip_bfloat16*)(W + oFusH), (__hip_bfloat16*)(W + oFusL), 512, 0,
            fus_b, nullptr, 0,
            (__hip_bfloat16*)(W + oHfH), (__hip_bfloat16*)(W + oHfL), HID, 0,
            nullptr, nullptr, nullptr,
            NN_, HID, 512);
    }
    // out
    {
        dim3 grid(64, 2, 1);
        k_mgemm<false, 1, 0><<<grid, 256, 0, stream>>>(
            (__hip_bfloat16*)(W + oHfH), (__hip_bfloat16*)(W + oHfL), HID, 0,
            (__hip_bfloat16*)(W + oOutwH), (__hip_bfloat16*)(W + oOutwL), HID, 0,
            out_b, outp, 128,
            nullptr, nullptr, 0, 0,
            nullptr, nullptr, nullptr,
            NN_, 128, HID);
    }
}